// Round 2
// baseline (1441.878 us; speedup 1.0000x reference)
//
#include <hip/hip_runtime.h>
#include <math.h>

#define N_NODES 50000
#define N_EDGES 800000
#define B_ 512
#define S_ 200
#define D_ 128
#define BS_ (B_*S_)
#define NCHUNK 2
#define BCH (B_/NCHUNK)        // 256 batch rows per chunk
#define MCH (BCH*S_)           // 51200 rows per chunk

// ---------------------------------------------------------------- utilities
__global__ void zero_i32_kernel(int* __restrict__ p, int n) {
  int i = blockIdx.x * 256 + threadIdx.x;
  if (i < n) p[i] = 0;
}

// ---------------------------------------------------------------- graph prep
__global__ void hist_kernel(const int* __restrict__ dst, int* __restrict__ cnt, int E) {
  int e = blockIdx.x * 256 + threadIdx.x;
  if (e < E) atomicAdd(&cnt[dst[e]], 1);
}

__global__ void dis_kernel(const int* __restrict__ cnt, float* __restrict__ dis, int N) {
  int n = blockIdx.x * 256 + threadIdx.x;
  if (n < N) dis[n] = rsqrtf(1.0f + (float)cnt[n]);
}

__global__ __launch_bounds__(1024) void scan_kernel(const int* __restrict__ cnt,
                                                    int* __restrict__ row_ptr,
                                                    int* __restrict__ fill, int N) {
  __shared__ int wsums[16];
  __shared__ int s_carry;
  int t = threadIdx.x, lane = t & 63, wid = t >> 6;
  if (t == 0) s_carry = 0;
  __syncthreads();
  for (int base = 0; base < N; base += 1024) {
    int i = base + t;
    int v = (i < N) ? cnt[i] : 0;
    int x = v;
    #pragma unroll
    for (int off = 1; off < 64; off <<= 1) {
      int y = __shfl_up(x, off);
      if (lane >= off) x += y;
    }
    if (lane == 63) wsums[wid] = x;
    __syncthreads();
    int woff = 0;
    for (int w = 0; w < wid; ++w) woff += wsums[w];
    int excl = s_carry + woff + x - v;
    if (i < N) { row_ptr[i] = excl; fill[i] = excl; }
    __syncthreads();
    if (t == 1023) s_carry = excl + v;
    __syncthreads();
  }
  if (t == 0) row_ptr[N] = s_carry;
}

__global__ void scatter_kernel(const int* __restrict__ src, const int* __restrict__ dst,
                               int* __restrict__ fill, int* __restrict__ csr_src, int E) {
  int e = blockIdx.x * 256 + threadIdx.x;
  if (e >= E) return;
  int d = dst[e];
  int pos = atomicAdd(&fill[d], 1);
  csr_src[pos] = src[e];
}

// ------------------------------------------------------------- small matmuls
// Z[i][j] = sum_t X[i*128+t] * Y[t*128+j]   (both row-major, Y is [128][128])
__global__ void smallmm_kernel(const float* __restrict__ X, const float* __restrict__ Y,
                               float* __restrict__ Z, int rows) {
  int idx = blockIdx.x * 256 + threadIdx.x;
  if (idx >= rows * 128) return;
  int i = idx >> 7, j = idx & 127;
  float acc = 0.f;
  for (int t = 0; t < 128; ++t) acc += X[i * 128 + t] * Y[t * 128 + j];
  Z[idx] = acc;
}

// ------------------------------------------------------------------ GEMM 128
// C[M,128] = A'[M,128] @ W[128,128]  (+bias +posEmb[r%S] +selVec[sel[r]] +resid[r]) (relu opt)
// A' row r = A[gidx[r]] if gidx else A[r]
__global__ __launch_bounds__(256) void gemm128_kernel(
    const float* __restrict__ A, const int* __restrict__ gidx,
    const float* __restrict__ W, const float* __restrict__ bias,
    const float* __restrict__ posEmb, const int* __restrict__ sel,
    const float* __restrict__ selVec, const float* __restrict__ resid,
    float* __restrict__ C, int M, int doRelu) {
  __shared__ float ldsA[64][132];
  __shared__ float ldsW[32][128];
  __shared__ int ldsIdx[64];

  int t = threadIdx.x;
  int r0 = blockIdx.x * 64;

  if (t < 64) {
    int r = r0 + t;
    ldsIdx[t] = (r < M) ? (gidx ? gidx[r] : r) : 0;
  }
  __syncthreads();

  #pragma unroll
  for (int it = 0; it < 8; ++it) {
    int i = t + 256 * it;       // 0..2047
    int row = i >> 5;           // 0..63
    int k4 = i & 31;
    int r = r0 + row;
    float4 v = make_float4(0.f, 0.f, 0.f, 0.f);
    if (r < M) v = *(const float4*)(A + (size_t)ldsIdx[row] * 128 + k4 * 4);
    *(float4*)&ldsA[row][k4 * 4] = v;
  }

  int tx = t & 15, ty = t >> 4;   // cols tx*8..+7, rows ty*4..+3
  float acc[4][8];
  #pragma unroll
  for (int i = 0; i < 4; ++i)
    #pragma unroll
    for (int j = 0; j < 8; ++j) acc[i][j] = 0.f;

  for (int kc = 0; kc < 4; ++kc) {
    __syncthreads();
    #pragma unroll
    for (int it = 0; it < 4; ++it) {
      int i = t + 256 * it;     // 0..1023
      int kk = i >> 5, c4 = i & 31;
      *(float4*)&ldsW[kk][c4 * 4] = *(const float4*)(W + (size_t)(kc * 32 + kk) * 128 + c4 * 4);
    }
    __syncthreads();
    #pragma unroll
    for (int kk = 0; kk < 32; ++kk) {
      int k = kc * 32 + kk;
      float av[4];
      av[0] = ldsA[ty * 4 + 0][k];
      av[1] = ldsA[ty * 4 + 1][k];
      av[2] = ldsA[ty * 4 + 2][k];
      av[3] = ldsA[ty * 4 + 3][k];
      float4 w0 = *(const float4*)&ldsW[kk][tx * 8];
      float4 w1 = *(const float4*)&ldsW[kk][tx * 8 + 4];
      float wv[8] = {w0.x, w0.y, w0.z, w0.w, w1.x, w1.y, w1.z, w1.w};
      #pragma unroll
      for (int i = 0; i < 4; ++i)
        #pragma unroll
        for (int j = 0; j < 8; ++j)
          acc[i][j] += av[i] * wv[j];
    }
  }

  int c0 = tx * 8;
  #pragma unroll
  for (int i = 0; i < 4; ++i) {
    int r = r0 + ty * 4 + i;
    if (r >= M) continue;
    float vals[8];
    #pragma unroll
    for (int j = 0; j < 8; ++j) vals[j] = acc[i][j];
    if (bias) {
      #pragma unroll
      for (int j = 0; j < 8; ++j) vals[j] += bias[c0 + j];
    }
    if (posEmb) {
      const float* p = posEmb + (size_t)(r % S_) * 128 + c0;
      #pragma unroll
      for (int j = 0; j < 8; ++j) vals[j] += p[j];
    }
    if (selVec) {
      const float* p = selVec + (size_t)sel[r] * 128 + c0;
      #pragma unroll
      for (int j = 0; j < 8; ++j) vals[j] += p[j];
    }
    if (resid) {
      const float* p = resid + (size_t)r * 128 + c0;
      #pragma unroll
      for (int j = 0; j < 8; ++j) vals[j] += p[j];
    }
    if (doRelu) {
      #pragma unroll
      for (int j = 0; j < 8; ++j) vals[j] = fmaxf(vals[j], 0.f);
    }
    float4 o0 = make_float4(vals[0], vals[1], vals[2], vals[3]);
    float4 o1 = make_float4(vals[4], vals[5], vals[6], vals[7]);
    *(float4*)(C + (size_t)r * 128 + c0) = o0;
    *(float4*)(C + (size_t)r * 128 + c0 + 4) = o1;
  }
}

// ------------------------------------------------------------- GCN aggregate
// out[n] = LN?(relu( dis[n]^2*xw[n] + sum_e dis[src]*dis[n]*xw[src] + bias ))
__global__ __launch_bounds__(256) void agg_kernel(
    const float* __restrict__ xw, const float* __restrict__ dis,
    const int* __restrict__ row_ptr, const int* __restrict__ csr_src,
    const float* __restrict__ bias, const float* __restrict__ lng,
    const float* __restrict__ lnb, float* __restrict__ out, int N, int doLN) {
  int lane = threadIdx.x & 63;
  int n = blockIdx.x * 4 + (threadIdx.x >> 6);
  if (n >= N) return;
  float dn = dis[n];
  const float2* xw2 = (const float2*)xw;
  float2 self = xw2[(size_t)n * 64 + lane];
  float ax = dn * dn * self.x, ay = dn * dn * self.y;
  int e0 = row_ptr[n], e1 = row_ptr[n + 1];
  for (int e = e0; e < e1; ++e) {
    int s = csr_src[e];
    float w = dis[s] * dn;
    float2 v = xw2[(size_t)s * 64 + lane];
    ax += w * v.x; ay += w * v.y;
  }
  int c0 = lane * 2;
  ax += bias[c0]; ay += bias[c0 + 1];
  ax = fmaxf(ax, 0.f); ay = fmaxf(ay, 0.f);
  if (doLN) {
    float s1 = ax + ay, s2 = ax * ax + ay * ay;
    #pragma unroll
    for (int off = 32; off > 0; off >>= 1) {
      s1 += __shfl_xor(s1, off);
      s2 += __shfl_xor(s2, off);
    }
    float mean = s1 * (1.f / 128.f);
    float var = s2 * (1.f / 128.f) - mean * mean;
    float inv = rsqrtf(var + 1e-5f);
    ax = (ax - mean) * inv * lng[c0] + lnb[c0];
    ay = (ay - mean) * inv * lng[c0 + 1] + lnb[c0 + 1];
  }
  float2 o; o.x = ax; o.y = ay;
  ((float2*)out)[(size_t)n * 64 + lane] = o;
}

// ----------------------------------------------------------------- attention
// block = (b,h); thread t = query row; online softmax; ao written over qh.
__global__ __launch_bounds__(256) void attn_kernel(float* qh_ao,
                                                   const float* __restrict__ kh,
                                                   const float* __restrict__ vh) {
  __shared__ float ks[S_][16];
  __shared__ float vs[S_][16];
  int b = blockIdx.x >> 3;
  int h = blockIdx.x & 7;
  int t = threadIdx.x;
  size_t base = ((size_t)b * S_) * 128 + h * 16;
  for (int i = t; i < S_ * 4; i += 256) {
    int s = i >> 2, c4 = (i & 3) * 4;
    *(float4*)&ks[s][c4] = *(const float4*)(kh + base + (size_t)s * 128 + c4);
    *(float4*)&vs[s][c4] = *(const float4*)(vh + base + (size_t)s * 128 + c4);
  }
  float qreg[16], accv[16];
  float m = -1e30f, l = 0.f;
  if (t < S_) {
    #pragma unroll
    for (int i = 0; i < 16; i += 4) {
      float4 v = *(const float4*)(qh_ao + base + (size_t)t * 128 + i);
      qreg[i] = v.x; qreg[i + 1] = v.y; qreg[i + 2] = v.z; qreg[i + 3] = v.w;
    }
    #pragma unroll
    for (int i = 0; i < 16; ++i) accv[i] = 0.f;
  }
  __syncthreads();
  if (t < S_) {
    for (int k = 0; k <= t; ++k) {
      float s = 0.f;
      #pragma unroll
      for (int i = 0; i < 16; ++i) s += qreg[i] * ks[k][i];
      s *= 0.25f;   // 1/sqrt(16)
      float mn = fmaxf(m, s);
      float scale = __expf(m - mn);
      float p = __expf(s - mn);
      l = l * scale + p;
      #pragma unroll
      for (int i = 0; i < 16; ++i) accv[i] = accv[i] * scale + p * vs[k][i];
      m = mn;
    }
    float inv = 1.f / l;
    #pragma unroll
    for (int i = 0; i < 16; i += 4) {
      float4 o = make_float4(accv[i] * inv, accv[i + 1] * inv, accv[i + 2] * inv, accv[i + 3] * inv);
      *(float4*)(qh_ao + base + (size_t)t * 128 + i) = o;
    }
  }
}

// -------------------------------------------------------------- layer norms
__global__ __launch_bounds__(256) void ln_kernel(const float* __restrict__ in,
                                                 const float* __restrict__ g,
                                                 const float* __restrict__ b,
                                                 float* __restrict__ out, int M) {
  int lane = threadIdx.x & 63;
  int r = blockIdx.x * 4 + (threadIdx.x >> 6);
  if (r >= M) return;
  float2 v = ((const float2*)in)[(size_t)r * 64 + lane];
  float s1 = v.x + v.y, s2 = v.x * v.x + v.y * v.y;
  #pragma unroll
  for (int off = 32; off > 0; off >>= 1) {
    s1 += __shfl_xor(s1, off);
    s2 += __shfl_xor(s2, off);
  }
  float mean = s1 * (1.f / 128.f);
  float var = s2 * (1.f / 128.f) - mean * mean;
  float inv = rsqrtf(var + 1e-5f);
  float2 gg = ((const float2*)g)[lane];
  float2 bb = ((const float2*)b)[lane];
  float2 o;
  o.x = (v.x - mean) * inv * gg.x + bb.x;
  o.y = (v.y - mean) * inv * gg.y + bb.y;
  ((float2*)out)[(size_t)r * 64 + lane] = o;
}

__global__ __launch_bounds__(256) void ln_pred_kernel(const float* __restrict__ in,
                                                      const float* __restrict__ g,
                                                      const float* __restrict__ b,
                                                      const float* __restrict__ w4,
                                                      const float* __restrict__ b4,
                                                      float* __restrict__ pred, int M) {
  int lane = threadIdx.x & 63;
  int r = blockIdx.x * 4 + (threadIdx.x >> 6);
  if (r >= M) return;
  float2 v = ((const float2*)in)[(size_t)r * 64 + lane];
  float s1 = v.x + v.y, s2 = v.x * v.x + v.y * v.y;
  #pragma unroll
  for (int off = 32; off > 0; off >>= 1) {
    s1 += __shfl_xor(s1, off);
    s2 += __shfl_xor(s2, off);
  }
  float mean = s1 * (1.f / 128.f);
  float var = s2 * (1.f / 128.f) - mean * mean;
  float inv = rsqrtf(var + 1e-5f);
  float2 gg = ((const float2*)g)[lane];
  float2 bb = ((const float2*)b)[lane];
  float ox = (v.x - mean) * inv * gg.x + bb.x;
  float oy = (v.y - mean) * inv * gg.y + bb.y;
  float2 ww = ((const float2*)w4)[lane];
  float p = ox * ww.x + oy * ww.y;
  #pragma unroll
  for (int off = 32; off > 0; off >>= 1) p += __shfl_xor(p, off);
  if (lane == 0) pred[r] = p + b4[0];
}

// ---------------------------------------------------------------------------
extern "C" void kernel_launch(void* const* d_in, const int* in_sizes, int n_in,
                              void* d_out, int out_size, void* d_ws, size_t ws_size,
                              hipStream_t stream) {
  const int* hist_seq = (const int*)d_in[0];
  const int* hist_ans = (const int*)d_in[1];
  const int* new_seq = (const int*)d_in[2];
  const int* edge_index = (const int*)d_in[3];
  const float* node_x = (const float*)d_in[4];
  const float* gcn_w0 = (const float*)d_in[5];
  const float* gcn_b0 = (const float*)d_in[6];
  const float* gcn_w1 = (const float*)d_in[7];
  const float* gcn_b1 = (const float*)d_in[8];
  const float* gcn_w2 = (const float*)d_in[9];
  const float* gcn_b2 = (const float*)d_in[10];
  const float* ln0_g = (const float*)d_in[11];
  const float* ln0_b = (const float*)d_in[12];
  const float* ln1_g = (const float*)d_in[13];
  const float* ln1_b = (const float*)d_in[14];
  const float* ln2_g = (const float*)d_in[15];
  const float* ln2_b = (const float*)d_in[16];
  const float* ln3_g = (const float*)d_in[17];
  const float* ln3_b = (const float*)d_in[18];
  const float* corr_emb = (const float*)d_in[19];
  const float* lin0_w = (const float*)d_in[20];
  const float* lin0_b = (const float*)d_in[21];
  const float* lin1_w = (const float*)d_in[22];
  const float* lin2_w = (const float*)d_in[23];
  const float* lin3_w = (const float*)d_in[24];
  const float* lin4_w = (const float*)d_in[25];
  const float* lin4_b = (const float*)d_in[26];
  const float* pos_emb = (const float*)d_in[27];
  const float* mha_wq = (const float*)d_in[28];
  const float* mha_bq = (const float*)d_in[29];
  const float* mha_wk = (const float*)d_in[30];
  const float* mha_bk = (const float*)d_in[31];
  const float* mha_wv = (const float*)d_in[32];
  const float* mha_bv = (const float*)d_in[33];
  const float* mha_wo = (const float*)d_in[34];
  const float* mha_bo = (const float*)d_in[35];
  const float* ffn0_w = (const float*)d_in[36];
  const float* ffn0_b = (const float*)d_in[37];
  const float* ffn1_w = (const float*)d_in[38];
  const float* ffn1_b = (const float*)d_in[39];
  (void)in_sizes; (void)n_in; (void)out_size;

  // ---- explicit workspace layout (bytes), peak ~134.7 MB ----
  char* ws = (char*)d_ws;
  size_t off = 0;
  auto alloc = [&](size_t bytes) -> void* {
    void* p = ws + off;
    off += (bytes + 255) & ~(size_t)255;
    return p;
  };
  int* cnt = (int*)alloc((size_t)N_NODES * 4);
  int* row_ptr = (int*)alloc((size_t)(N_NODES + 1) * 4);
  int* fill = (int*)alloc((size_t)N_NODES * 4);
  float* dis = (float*)alloc((size_t)N_NODES * 4);
  float* wkp = (float*)alloc(128 * 128 * 4);
  float* wvp = (float*)alloc(128 * 128 * 4);
  float* wqp = (float*)alloc(128 * 128 * 4);
  float* c01 = (float*)alloc(2 * 128 * 4);
  int* csr_src = (int*)alloc((size_t)N_EDGES * 4);
  float* xa = (float*)alloc((size_t)N_NODES * 128 * 4);   // x after each GCN layer
  size_t Rbase = off;
  const size_t CB = (size_t)MCH * 128 * 4;                // 26.2 MB per chunk buffer
  float* xw   = (float*)(ws + Rbase);                     // GCN scratch, overlaid on bufI/bufQ
  float* bufI = (float*)(ws + Rbase);                     // inter / ao2
  float* bufQ = (float*)(ws + Rbase + CB);                // qh(ao) / f1
  float* bufK = (float*)(ws + Rbase + 2 * CB);            // kh / atn
  float* bufV = (float*)(ws + Rbase + 3 * CB);            // vh / f2
  size_t need = Rbase + 4 * CB;
  if (ws_size < need) return;   // diagnostic guard: clean absmax failure instead of fault

  // ---- graph prep ----
  zero_i32_kernel<<<(N_NODES + 255) / 256, 256, 0, stream>>>(cnt, N_NODES);
  hist_kernel<<<(N_EDGES + 255) / 256, 256, 0, stream>>>(edge_index + N_EDGES, cnt, N_EDGES);
  dis_kernel<<<(N_NODES + 255) / 256, 256, 0, stream>>>(cnt, dis, N_NODES);
  scan_kernel<<<1, 1024, 0, stream>>>(cnt, row_ptr, fill, N_NODES);
  scatter_kernel<<<(N_EDGES + 255) / 256, 256, 0, stream>>>(edge_index, edge_index + N_EDGES,
                                                            fill, csr_src, N_EDGES);
  // ---- fused weights ----
  smallmm_kernel<<<64, 256, 0, stream>>>(lin2_w, mha_wk, wkp, 128);   // kh path
  smallmm_kernel<<<64, 256, 0, stream>>>(lin1_w, mha_wv, wvp, 128);   // vh path
  smallmm_kernel<<<64, 256, 0, stream>>>(lin3_w, mha_wq, wqp, 128);   // qh path
  smallmm_kernel<<<1, 256, 0, stream>>>(corr_emb, lin0_w + 128 * 128, c01, 2);

  int gN = (N_NODES + 63) / 64;
  int aN = (N_NODES + 3) / 4;

  // ---- GCN (xw overlays chunk-buffer region; dead before chunks start) ----
  gemm128_kernel<<<gN, 256, 0, stream>>>(node_x, nullptr, gcn_w0, nullptr, nullptr, nullptr,
                                         nullptr, nullptr, xw, N_NODES, 0);
  agg_kernel<<<aN, 256, 0, stream>>>(xw, dis, row_ptr, csr_src, gcn_b0, ln0_g, ln0_b, xa, N_NODES, 1);
  gemm128_kernel<<<gN, 256, 0, stream>>>(xa, nullptr, gcn_w1, nullptr, nullptr, nullptr,
                                         nullptr, nullptr, xw, N_NODES, 0);
  agg_kernel<<<aN, 256, 0, stream>>>(xw, dis, row_ptr, csr_src, gcn_b1, ln1_g, ln1_b, xa, N_NODES, 1);
  gemm128_kernel<<<gN, 256, 0, stream>>>(xa, nullptr, gcn_w2, nullptr, nullptr, nullptr,
                                         nullptr, nullptr, xw, N_NODES, 0);
  agg_kernel<<<aN, 256, 0, stream>>>(xw, dis, row_ptr, csr_src, gcn_b2, nullptr, nullptr, xa, N_NODES, 0);

  // ---- transformer in batch chunks (row-independent) ----
  int gC = (MCH + 63) / 64;      // 800 blocks
  int lC = (MCH + 3) / 4;
  for (int c = 0; c < NCHUNK; ++c) {
    int r0 = c * MCH;
    // inter = x3[hist]@lin0_w[:128] + b + pos + corr[ans]  -> bufI
    gemm128_kernel<<<gC, 256, 0, stream>>>(xa, hist_seq + r0, lin0_w, lin0_b, pos_emb,
                                           hist_ans + r0, c01, nullptr, bufI, MCH, 0);
    // qh = x3[new]@(lin3@wq) + bq -> bufQ
    gemm128_kernel<<<gC, 256, 0, stream>>>(xa, new_seq + r0, wqp, mha_bq, nullptr, nullptr,
                                           nullptr, nullptr, bufQ, MCH, 0);
    // kh = inter@(lin2@wk) + bk -> bufK ; vh = inter@(lin1@wv) + bv -> bufV
    gemm128_kernel<<<gC, 256, 0, stream>>>(bufI, nullptr, wkp, mha_bk, nullptr, nullptr,
                                           nullptr, nullptr, bufK, MCH, 0);
    gemm128_kernel<<<gC, 256, 0, stream>>>(bufI, nullptr, wvp, mha_bv, nullptr, nullptr,
                                           nullptr, nullptr, bufV, MCH, 0);
    // attention in place on bufQ
    attn_kernel<<<BCH * 8, 256, 0, stream>>>(bufQ, bufK, bufV);
    // ao2 = ao@wo + bo -> bufI; then ao2 += x3[new]@lin3_w (residual q), in place
    gemm128_kernel<<<gC, 256, 0, stream>>>(bufQ, nullptr, mha_wo, mha_bo, nullptr, nullptr,
                                           nullptr, nullptr, bufI, MCH, 0);
    gemm128_kernel<<<gC, 256, 0, stream>>>(xa, new_seq + r0, lin3_w, nullptr, nullptr, nullptr,
                                           nullptr, bufI, bufI, MCH, 0);
    // atn = LN(ao2) -> bufK
    ln_kernel<<<lC, 256, 0, stream>>>(bufI, ln2_g, ln2_b, bufK, MCH);
    // f1 = relu(atn@ffn0 + b0) -> bufQ
    gemm128_kernel<<<gC, 256, 0, stream>>>(bufK, nullptr, ffn0_w, ffn0_b, nullptr, nullptr,
                                           nullptr, nullptr, bufQ, MCH, 1);
    // f2 = f1@ffn1 + b1 + atn -> bufV
    gemm128_kernel<<<gC, 256, 0, stream>>>(bufQ, nullptr, ffn1_w, ffn1_b, nullptr, nullptr,
                                           nullptr, bufK, bufV, MCH, 0);
    // pred = LN(f2)@lin4 + b4 -> d_out[r0..]
    ln_pred_kernel<<<lC, 256, 0, stream>>>(bufV, ln3_g, ln3_b, lin4_w, lin4_b,
                                           (float*)d_out + r0, MCH);
  }
}

// Round 3
// 1198.384 us; speedup vs baseline: 1.2032x; 1.2032x over previous
//
#include <hip/hip_runtime.h>
#include <math.h>

#define N_NODES 50000
#define N_EDGES 800000
#define B_ 512
#define S_ 200
#define D_ 128
#define BS_ (B_*S_)
#define NCHUNK 2
#define BCH (B_/NCHUNK)        // 256 batch rows per chunk
#define MCH (BCH*S_)           // 51200 rows per chunk

typedef unsigned short u16;
typedef unsigned int u32;
using bfrag = __attribute__((ext_vector_type(8))) short;
using f32x4 = __attribute__((ext_vector_type(4))) float;

__device__ __forceinline__ u16 f2bf(float f) {        // RNE f32 -> bf16 bits
  u32 u = __float_as_uint(f);
  u32 r = (u + 0x7fffu + ((u >> 16) & 1u)) >> 16;
  return (u16)r;
}
__device__ __forceinline__ float bflo(u32 v) { return __uint_as_float(v << 16); }
__device__ __forceinline__ float bfhi(u32 v) { return __uint_as_float(v & 0xffff0000u); }
__device__ __forceinline__ u32 pack2(float a, float b) {
  return (u32)f2bf(a) | ((u32)f2bf(b) << 16);
}

// ---------------------------------------------------------------- utilities
__global__ void zero_i32_kernel(int* __restrict__ p, int n) {
  int i = blockIdx.x * 256 + threadIdx.x;
  if (i < n) p[i] = 0;
}

__global__ void f2bf_kernel(const float* __restrict__ in, u16* __restrict__ out, int n) {
  int i = blockIdx.x * 256 + threadIdx.x;
  if (i < n) out[i] = f2bf(in[i]);
}

// transpose f32 [128][128] -> bf16 wT[c][k]
__global__ void wT_kernel(const float* __restrict__ W, u16* __restrict__ wT) {
  int i = blockIdx.x * 256 + threadIdx.x;   // 16384
  int k = i >> 7, c = i & 127;
  wT[c * 128 + k] = f2bf(W[k * 128 + c]);
}

// ZT (bf16, transposed) = (X @ Y)^T for [128][128] inputs
__global__ void smallmmT_kernel(const float* __restrict__ X, const float* __restrict__ Y,
                                u16* __restrict__ ZT) {
  int i = blockIdx.x * 256 + threadIdx.x;
  int k = i >> 7, c = i & 127;
  float acc = 0.f;
  for (int t = 0; t < 128; ++t) acc += X[k * 128 + t] * Y[t * 128 + c];
  ZT[c * 128 + k] = f2bf(acc);
}

// f32 small matmul (for c01: rows=2)
__global__ void smallmm_kernel(const float* __restrict__ X, const float* __restrict__ Y,
                               float* __restrict__ Z, int rows) {
  int idx = blockIdx.x * 256 + threadIdx.x;
  if (idx >= rows * 128) return;
  int i = idx >> 7, j = idx & 127;
  float acc = 0.f;
  for (int t = 0; t < 128; ++t) acc += X[i * 128 + t] * Y[t * 128 + j];
  Z[idx] = acc;
}

// ---------------------------------------------------------------- graph prep
__global__ void hist_kernel(const int* __restrict__ dst, int* __restrict__ cnt, int E) {
  int e = blockIdx.x * 256 + threadIdx.x;
  if (e < E) atomicAdd(&cnt[dst[e]], 1);
}

__global__ void dis_kernel(const int* __restrict__ cnt, float* __restrict__ dis, int N) {
  int n = blockIdx.x * 256 + threadIdx.x;
  if (n < N) dis[n] = rsqrtf(1.0f + (float)cnt[n]);
}

__global__ __launch_bounds__(1024) void scan_kernel(const int* __restrict__ cnt,
                                                    int* __restrict__ row_ptr,
                                                    int* __restrict__ fill, int N) {
  __shared__ int wsums[16];
  __shared__ int s_carry;
  int t = threadIdx.x, lane = t & 63, wid = t >> 6;
  if (t == 0) s_carry = 0;
  __syncthreads();
  for (int base = 0; base < N; base += 1024) {
    int i = base + t;
    int v = (i < N) ? cnt[i] : 0;
    int x = v;
    #pragma unroll
    for (int off = 1; off < 64; off <<= 1) {
      int y = __shfl_up(x, off);
      if (lane >= off) x += y;
    }
    if (lane == 63) wsums[wid] = x;
    __syncthreads();
    int woff = 0;
    for (int w = 0; w < wid; ++w) woff += wsums[w];
    int excl = s_carry + woff + x - v;
    if (i < N) { row_ptr[i] = excl; fill[i] = excl; }
    __syncthreads();
    if (t == 1023) s_carry = excl + v;
    __syncthreads();
  }
  if (t == 0) row_ptr[N] = s_carry;
}

__global__ void scatter_kernel(const int* __restrict__ src, const int* __restrict__ dst,
                               int* __restrict__ fill, int* __restrict__ csr_src, int E) {
  int e = blockIdx.x * 256 + threadIdx.x;
  if (e >= E) return;
  int d = dst[e];
  int pos = atomicAdd(&fill[d], 1);
  csr_src[pos] = src[e];
}

// ------------------------------------------------------------ MFMA bf16 GEMM
// C[M,128](bf16) = A'[M,128](bf16) @ W[128,128] with wT[c][k] bf16 layout.
// epilogue (f32): +bias +posEmb[r%S] +selVec[sel[r]] +resid[r](bf16) , relu opt.
// A' row r = A[gidx[r]] if gidx else A[r]
__global__ __launch_bounds__(256) void gemm_bf16_kernel(
    const u16* __restrict__ A, const int* __restrict__ gidx,
    const u16* __restrict__ wT, const float* __restrict__ bias,
    const float* __restrict__ posEmb, const int* __restrict__ sel,
    const float* __restrict__ selVec, const u16* __restrict__ resid,
    u16* __restrict__ C, int M, int doRelu) {
  __shared__ float lds[64 * 136];
  int t = threadIdx.x;
  int wv = t >> 6, l = t & 63, lr = l & 15, lg = l >> 4;
  int r0 = blockIdx.x * 64;

  int row = r0 + wv * 16 + lr;
  int arow = 0;
  if (row < M) arow = gidx ? gidx[row] : row;
  const u16* Arow = A + (size_t)arow * 128;

  f32x4 acc[8];
  #pragma unroll
  for (int ct = 0; ct < 8; ++ct) acc[ct] = (f32x4){0.f, 0.f, 0.f, 0.f};

  #pragma unroll
  for (int ks = 0; ks < 4; ++ks) {
    bfrag a = *(const bfrag*)(Arow + ks * 32 + lg * 8);
    #pragma unroll
    for (int ct = 0; ct < 8; ++ct) {
      bfrag b = *(const bfrag*)(wT + (size_t)((ct * 16 + lr) * 128 + ks * 32 + lg * 8));
      acc[ct] = __builtin_amdgcn_mfma_f32_16x16x32_bf16(a, b, acc[ct], 0, 0, 0);
    }
  }

  // C fragment: col = ct*16 + (l&15), row = wv*16 + (l>>4)*4 + i
  #pragma unroll
  for (int ct = 0; ct < 8; ++ct)
    #pragma unroll
    for (int i = 0; i < 4; ++i)
      lds[(wv * 16 + lg * 4 + i) * 136 + ct * 16 + lr] = acc[ct][i];
  __syncthreads();

  int er = t >> 2, c0 = (t & 3) * 32;
  int gr = r0 + er;
  if (gr >= M) return;
  float v[32];
  #pragma unroll
  for (int j = 0; j < 32; ++j) v[j] = lds[er * 136 + c0 + j];
  if (bias) {
    #pragma unroll
    for (int j = 0; j < 32; ++j) v[j] += bias[c0 + j];
  }
  if (posEmb) {
    const float* p = posEmb + (size_t)(gr % S_) * 128 + c0;
    #pragma unroll
    for (int j = 0; j < 32; ++j) v[j] += p[j];
  }
  if (selVec) {
    const float* p = selVec + (size_t)sel[gr] * 128 + c0;
    #pragma unroll
    for (int j = 0; j < 32; ++j) v[j] += p[j];
  }
  if (resid) {
    const u16* p = resid + (size_t)gr * 128 + c0;
    #pragma unroll
    for (int j0 = 0; j0 < 32; j0 += 8) {
      uint4 q = *(const uint4*)(p + j0);
      v[j0 + 0] += bflo(q.x); v[j0 + 1] += bfhi(q.x);
      v[j0 + 2] += bflo(q.y); v[j0 + 3] += bfhi(q.y);
      v[j0 + 4] += bflo(q.z); v[j0 + 5] += bfhi(q.z);
      v[j0 + 6] += bflo(q.w); v[j0 + 7] += bfhi(q.w);
    }
  }
  if (doRelu) {
    #pragma unroll
    for (int j = 0; j < 32; ++j) v[j] = fmaxf(v[j], 0.f);
  }
  #pragma unroll
  for (int j0 = 0; j0 < 32; j0 += 8) {
    uint4 o;
    o.x = pack2(v[j0 + 0], v[j0 + 1]);
    o.y = pack2(v[j0 + 2], v[j0 + 3]);
    o.z = pack2(v[j0 + 4], v[j0 + 5]);
    o.w = pack2(v[j0 + 6], v[j0 + 7]);
    *(uint4*)(C + (size_t)gr * 128 + c0 + j0) = o;
  }
}

// ------------------------------------------------------------- GCN aggregate
// out[n] = LN?(relu( dis[n]^2*xw[n] + sum_e dis[src]*dis[n]*xw[src] + bias ))
__global__ __launch_bounds__(256) void agg_kernel(
    const u16* __restrict__ xw, const float* __restrict__ dis,
    const int* __restrict__ row_ptr, const int* __restrict__ csr_src,
    const float* __restrict__ bias, const float* __restrict__ lng,
    const float* __restrict__ lnb, u16* __restrict__ out, int N, int doLN) {
  int lane = threadIdx.x & 63;
  int n = blockIdx.x * 4 + (threadIdx.x >> 6);
  if (n >= N) return;
  float dn = dis[n];
  u32 sv = *(const u32*)(xw + (size_t)n * 128 + lane * 2);
  float ax = dn * dn * bflo(sv), ay = dn * dn * bfhi(sv);
  int e0 = row_ptr[n], e1 = row_ptr[n + 1];
  for (int e = e0; e < e1; ++e) {
    int s = csr_src[e];
    float w = dis[s] * dn;
    u32 v = *(const u32*)(xw + (size_t)s * 128 + lane * 2);
    ax += w * bflo(v); ay += w * bfhi(v);
  }
  int c0 = lane * 2;
  ax += bias[c0]; ay += bias[c0 + 1];
  ax = fmaxf(ax, 0.f); ay = fmaxf(ay, 0.f);
  if (doLN) {
    float s1 = ax + ay, s2 = ax * ax + ay * ay;
    #pragma unroll
    for (int off = 32; off > 0; off >>= 1) {
      s1 += __shfl_xor(s1, off);
      s2 += __shfl_xor(s2, off);
    }
    float mean = s1 * (1.f / 128.f);
    float var = s2 * (1.f / 128.f) - mean * mean;
    float inv = rsqrtf(var + 1e-5f);
    ax = (ax - mean) * inv * lng[c0] + lnb[c0];
    ay = (ay - mean) * inv * lng[c0 + 1] + lnb[c0 + 1];
  }
  ((u32*)out)[(size_t)n * 64 + lane] = pack2(ax, ay);
}

// ----------------------------------------------------------------- attention
// block = (b,h); thread t = query row; no-max softmax (scores provably tiny);
// ao written over qh in place. bf16 I/O, f32 LDS tiles + f32 math.
__global__ __launch_bounds__(256) void attn_kernel(u16* __restrict__ qh_ao,
                                                   const u16* __restrict__ kh,
                                                   const u16* __restrict__ vh) {
  __shared__ float ks[S_][16];
  __shared__ float vs[S_][16];
  int b = blockIdx.x >> 3;
  int h = blockIdx.x & 7;
  int t = threadIdx.x;
  size_t base = ((size_t)b * S_) * 128 + h * 16;
  for (int i = t; i < S_ * 8; i += 256) {
    int s = i >> 3, c2 = (i & 7) * 2;
    u32 kv = *(const u32*)(kh + base + (size_t)s * 128 + c2);
    u32 vv = *(const u32*)(vh + base + (size_t)s * 128 + c2);
    ks[s][c2] = bflo(kv); ks[s][c2 + 1] = bfhi(kv);
    vs[s][c2] = bflo(vv); vs[s][c2 + 1] = bfhi(vv);
  }
  float qreg[16], accv[16], l = 0.f;
  if (t < S_) {
    #pragma unroll
    for (int i0 = 0; i0 < 16; i0 += 8) {
      uint4 q = *(const uint4*)(qh_ao + base + (size_t)t * 128 + i0);
      qreg[i0 + 0] = bflo(q.x); qreg[i0 + 1] = bfhi(q.x);
      qreg[i0 + 2] = bflo(q.y); qreg[i0 + 3] = bfhi(q.y);
      qreg[i0 + 4] = bflo(q.z); qreg[i0 + 5] = bfhi(q.z);
      qreg[i0 + 6] = bflo(q.w); qreg[i0 + 7] = bfhi(q.w);
    }
    #pragma unroll
    for (int i = 0; i < 16; ++i) accv[i] = 0.f;
  }
  __syncthreads();
  if (t < S_) {
    for (int k = 0; k <= t; ++k) {
      float s = 0.f;
      #pragma unroll
      for (int i = 0; i < 16; ++i) s += qreg[i] * ks[k][i];
      float p = __expf(s * 0.25f);   // 1/sqrt(16); |s| << 1, no max needed
      l += p;
      #pragma unroll
      for (int i = 0; i < 16; ++i) accv[i] += p * vs[k][i];
    }
    float inv = 1.f / l;
    #pragma unroll
    for (int i0 = 0; i0 < 16; i0 += 8) {
      uint4 o;
      o.x = pack2(accv[i0 + 0] * inv, accv[i0 + 1] * inv);
      o.y = pack2(accv[i0 + 2] * inv, accv[i0 + 3] * inv);
      o.z = pack2(accv[i0 + 4] * inv, accv[i0 + 5] * inv);
      o.w = pack2(accv[i0 + 6] * inv, accv[i0 + 7] * inv);
      *(uint4*)(qh_ao + base + (size_t)t * 128 + i0) = o;
    }
  }
}

// -------------------------------------------------------------- layer norms
__global__ __launch_bounds__(256) void ln_kernel(const u16* __restrict__ in,
                                                 const float* __restrict__ g,
                                                 const float* __restrict__ b,
                                                 u16* __restrict__ out, int M) {
  int lane = threadIdx.x & 63;
  int r = blockIdx.x * 4 + (threadIdx.x >> 6);
  if (r >= M) return;
  u32 v = ((const u32*)in)[(size_t)r * 64 + lane];
  float x = bflo(v), y = bfhi(v);
  float s1 = x + y, s2 = x * x + y * y;
  #pragma unroll
  for (int off = 32; off > 0; off >>= 1) {
    s1 += __shfl_xor(s1, off);
    s2 += __shfl_xor(s2, off);
  }
  float mean = s1 * (1.f / 128.f);
  float var = s2 * (1.f / 128.f) - mean * mean;
  float inv = rsqrtf(var + 1e-5f);
  int c0 = lane * 2;
  float ox = (x - mean) * inv * g[c0] + b[c0];
  float oy = (y - mean) * inv * g[c0 + 1] + b[c0 + 1];
  ((u32*)out)[(size_t)r * 64 + lane] = pack2(ox, oy);
}

__global__ __launch_bounds__(256) void ln_pred_kernel(const u16* __restrict__ in,
                                                      const float* __restrict__ g,
                                                      const float* __restrict__ b,
                                                      const float* __restrict__ w4,
                                                      const float* __restrict__ b4,
                                                      float* __restrict__ pred, int M) {
  int lane = threadIdx.x & 63;
  int r = blockIdx.x * 4 + (threadIdx.x >> 6);
  if (r >= M) return;
  u32 v = ((const u32*)in)[(size_t)r * 64 + lane];
  float x = bflo(v), y = bfhi(v);
  float s1 = x + y, s2 = x * x + y * y;
  #pragma unroll
  for (int off = 32; off > 0; off >>= 1) {
    s1 += __shfl_xor(s1, off);
    s2 += __shfl_xor(s2, off);
  }
  float mean = s1 * (1.f / 128.f);
  float var = s2 * (1.f / 128.f) - mean * mean;
  float inv = rsqrtf(var + 1e-5f);
  int c0 = lane * 2;
  float ox = (x - mean) * inv * g[c0] + b[c0];
  float oy = (y - mean) * inv * g[c0 + 1] + b[c0 + 1];
  float p = ox * w4[c0] + oy * w4[c0 + 1];
  #pragma unroll
  for (int off = 32; off > 0; off >>= 1) p += __shfl_xor(p, off);
  if (lane == 0) pred[r] = p + b4[0];
}

// ---------------------------------------------------------------------------
extern "C" void kernel_launch(void* const* d_in, const int* in_sizes, int n_in,
                              void* d_out, int out_size, void* d_ws, size_t ws_size,
                              hipStream_t stream) {
  const int* hist_seq = (const int*)d_in[0];
  const int* hist_ans = (const int*)d_in[1];
  const int* new_seq = (const int*)d_in[2];
  const int* edge_index = (const int*)d_in[3];
  const float* node_x = (const float*)d_in[4];
  const float* gcn_w0 = (const float*)d_in[5];
  const float* gcn_b0 = (const float*)d_in[6];
  const float* gcn_w1 = (const float*)d_in[7];
  const float* gcn_b1 = (const float*)d_in[8];
  const float* gcn_w2 = (const float*)d_in[9];
  const float* gcn_b2 = (const float*)d_in[10];
  const float* ln0_g = (const float*)d_in[11];
  const float* ln0_b = (const float*)d_in[12];
  const float* ln1_g = (const float*)d_in[13];
  const float* ln1_b = (const float*)d_in[14];
  const float* ln2_g = (const float*)d_in[15];
  const float* ln2_b = (const float*)d_in[16];
  const float* ln3_g = (const float*)d_in[17];
  const float* ln3_b = (const float*)d_in[18];
  const float* corr_emb = (const float*)d_in[19];
  const float* lin0_w = (const float*)d_in[20];
  const float* lin0_b = (const float*)d_in[21];
  const float* lin1_w = (const float*)d_in[22];
  const float* lin2_w = (const float*)d_in[23];
  const float* lin3_w = (const float*)d_in[24];
  const float* lin4_w = (const float*)d_in[25];
  const float* lin4_b = (const float*)d_in[26];
  const float* pos_emb = (const float*)d_in[27];
  const float* mha_wq = (const float*)d_in[28];
  const float* mha_bq = (const float*)d_in[29];
  const float* mha_wk = (const float*)d_in[30];
  const float* mha_bk = (const float*)d_in[31];
  const float* mha_wv = (const float*)d_in[32];
  const float* mha_bv = (const float*)d_in[33];
  const float* mha_wo = (const float*)d_in[34];
  const float* mha_bo = (const float*)d_in[35];
  const float* ffn0_w = (const float*)d_in[36];
  const float* ffn0_b = (const float*)d_in[37];
  const float* ffn1_w = (const float*)d_in[38];
  const float* ffn1_b = (const float*)d_in[39];
  (void)in_sizes; (void)n_in; (void)out_size;

  char* ws = (char*)d_ws;
  size_t off = 0;
  auto alloc = [&](size_t bytes) -> void* {
    void* p = ws + off;
    off += (bytes + 255) & ~(size_t)255;
    return p;
  };
  int* cnt = (int*)alloc((size_t)N_NODES * 4);
  int* row_ptr = (int*)alloc((size_t)(N_NODES + 1) * 4);
  int* fill = (int*)alloc((size_t)N_NODES * 4);
  float* dis = (float*)alloc((size_t)N_NODES * 4);
  int* csr_src = (int*)alloc((size_t)N_EDGES * 4);
  const size_t WB = 128 * 128 * 2;
  u16* g0T = (u16*)alloc(WB);
  u16* g1T = (u16*)alloc(WB);
  u16* g2T = (u16*)alloc(WB);
  u16* l0T = (u16*)alloc(WB);
  u16* l3T = (u16*)alloc(WB);
  u16* woT = (u16*)alloc(WB);
  u16* f0T = (u16*)alloc(WB);
  u16* f1T = (u16*)alloc(WB);
  u16* wqT = (u16*)alloc(WB);
  u16* wkT = (u16*)alloc(WB);
  u16* wvT = (u16*)alloc(WB);
  float* c01 = (float*)alloc(2 * 128 * 4);
  u16* xb = (u16*)alloc((size_t)N_NODES * 128 * 2);
  u16* xa = (u16*)alloc((size_t)N_NODES * 128 * 2);
  u16* xw = (u16*)alloc((size_t)N_NODES * 128 * 2);
  const size_t CB = (size_t)MCH * 128 * 2;
  u16* bufI = (u16*)alloc(CB);
  u16* bufQ = (u16*)alloc(CB);
  u16* bufK = (u16*)alloc(CB);
  u16* bufV = (u16*)alloc(CB);
  if (ws_size < off) return;   // diagnostic guard

  // ---- graph prep ----
  zero_i32_kernel<<<(N_NODES + 255) / 256, 256, 0, stream>>>(cnt, N_NODES);
  hist_kernel<<<(N_EDGES + 255) / 256, 256, 0, stream>>>(edge_index + N_EDGES, cnt, N_EDGES);
  dis_kernel<<<(N_NODES + 255) / 256, 256, 0, stream>>>(cnt, dis, N_NODES);
  scan_kernel<<<1, 1024, 0, stream>>>(cnt, row_ptr, fill, N_NODES);
  scatter_kernel<<<(N_EDGES + 255) / 256, 256, 0, stream>>>(edge_index, edge_index + N_EDGES,
                                                            fill, csr_src, N_EDGES);
  // ---- weight prep (bf16, transposed) ----
  wT_kernel<<<64, 256, 0, stream>>>(gcn_w0, g0T);
  wT_kernel<<<64, 256, 0, stream>>>(gcn_w1, g1T);
  wT_kernel<<<64, 256, 0, stream>>>(gcn_w2, g2T);
  wT_kernel<<<64, 256, 0, stream>>>(lin0_w, l0T);       // rows 0..127 of lin0_w
  wT_kernel<<<64, 256, 0, stream>>>(lin3_w, l3T);
  wT_kernel<<<64, 256, 0, stream>>>(mha_wo, woT);
  wT_kernel<<<64, 256, 0, stream>>>(ffn0_w, f0T);
  wT_kernel<<<64, 256, 0, stream>>>(ffn1_w, f1T);
  smallmmT_kernel<<<64, 256, 0, stream>>>(lin3_w, mha_wq, wqT);   // qh path
  smallmmT_kernel<<<64, 256, 0, stream>>>(lin2_w, mha_wk, wkT);   // kh path
  smallmmT_kernel<<<64, 256, 0, stream>>>(lin1_w, mha_wv, wvT);   // vh path
  smallmm_kernel<<<1, 256, 0, stream>>>(corr_emb, lin0_w + 128 * 128, c01, 2);
  f2bf_kernel<<<(N_NODES * 128 + 255) / 256, 256, 0, stream>>>(node_x, xb, N_NODES * 128);

  int gN = (N_NODES + 63) / 64;
  int aN = (N_NODES + 3) / 4;

  // ---- GCN ----
  gemm_bf16_kernel<<<gN, 256, 0, stream>>>(xb, nullptr, g0T, nullptr, nullptr, nullptr,
                                           nullptr, nullptr, xw, N_NODES, 0);
  agg_kernel<<<aN, 256, 0, stream>>>(xw, dis, row_ptr, csr_src, gcn_b0, ln0_g, ln0_b, xa, N_NODES, 1);
  gemm_bf16_kernel<<<gN, 256, 0, stream>>>(xa, nullptr, g1T, nullptr, nullptr, nullptr,
                                           nullptr, nullptr, xw, N_NODES, 0);
  agg_kernel<<<aN, 256, 0, stream>>>(xw, dis, row_ptr, csr_src, gcn_b1, ln1_g, ln1_b, xa, N_NODES, 1);
  gemm_bf16_kernel<<<gN, 256, 0, stream>>>(xa, nullptr, g2T, nullptr, nullptr, nullptr,
                                           nullptr, nullptr, xw, N_NODES, 0);
  agg_kernel<<<aN, 256, 0, stream>>>(xw, dis, row_ptr, csr_src, gcn_b2, nullptr, nullptr, xa, N_NODES, 0);

  // ---- transformer in batch chunks ----
  int gC = (MCH + 63) / 64;
  int lC = (MCH + 3) / 4;
  for (int c = 0; c < NCHUNK; ++c) {
    int r0 = c * MCH;
    // inter = x3[hist]@lin0[:128] + b + pos + corr[ans] -> bufI
    gemm_bf16_kernel<<<gC, 256, 0, stream>>>(xa, hist_seq + r0, l0T, lin0_b, pos_emb,
                                             hist_ans + r0, c01, nullptr, bufI, MCH, 0);
    // qh = x3[new]@(lin3@wq) + bq -> bufQ
    gemm_bf16_kernel<<<gC, 256, 0, stream>>>(xa, new_seq + r0, wqT, mha_bq, nullptr, nullptr,
                                             nullptr, nullptr, bufQ, MCH, 0);
    // kh/vh
    gemm_bf16_kernel<<<gC, 256, 0, stream>>>(bufI, nullptr, wkT, mha_bk, nullptr, nullptr,
                                             nullptr, nullptr, bufK, MCH, 0);
    gemm_bf16_kernel<<<gC, 256, 0, stream>>>(bufI, nullptr, wvT, mha_bv, nullptr, nullptr,
                                             nullptr, nullptr, bufV, MCH, 0);
    // attention in place on bufQ
    attn_kernel<<<BCH * 8, 256, 0, stream>>>(bufQ, bufK, bufV);
    // ao2 = ao@wo + bo -> bufI ; then += x3[new]@lin3 (residual q), in place
    gemm_bf16_kernel<<<gC, 256, 0, stream>>>(bufQ, nullptr, woT, mha_bo, nullptr, nullptr,
                                             nullptr, nullptr, bufI, MCH, 0);
    gemm_bf16_kernel<<<gC, 256, 0, stream>>>(xa, new_seq + r0, l3T, nullptr, nullptr, nullptr,
                                             nullptr, bufI, bufI, MCH, 0);
    // atn = LN(ao2) -> bufK
    ln_kernel<<<lC, 256, 0, stream>>>(bufI, ln2_g, ln2_b, bufK, MCH);
    // f1 = relu(atn@ffn0 + b0) -> bufQ
    gemm_bf16_kernel<<<gC, 256, 0, stream>>>(bufK, nullptr, f0T, ffn0_b, nullptr, nullptr,
                                             nullptr, nullptr, bufQ, MCH, 1);
    // f2 = f1@ffn1 + b1 + atn -> bufV
    gemm_bf16_kernel<<<gC, 256, 0, stream>>>(bufQ, nullptr, f1T, ffn1_b, nullptr, nullptr,
                                             nullptr, bufK, bufV, MCH, 0);
    // pred = LN(f2)@lin4 + b4 -> d_out[r0..]
    ln_pred_kernel<<<lC, 256, 0, stream>>>(bufV, ln3_g, ln3_b, lin4_w, lin4_b,
                                           (float*)d_out + r0, MCH);
  }
}

// Round 5
// 939.351 us; speedup vs baseline: 1.5350x; 1.2758x over previous
//
#include <hip/hip_runtime.h>
#include <math.h>

#define N_NODES 50000
#define N_EDGES 800000
#define B_ 512
#define S_ 200
#define D_ 128
#define BS_ (B_*S_)
#define NCHUNK 2
#define BCH (B_/NCHUNK)        // 256 batch rows per chunk
#define MCH (BCH*S_)           // 51200 rows per chunk

typedef unsigned short u16;
typedef unsigned int u32;
using bfrag = __attribute__((ext_vector_type(8))) short;
using f32x4 = __attribute__((ext_vector_type(4))) float;

__device__ __forceinline__ u16 f2bf(float f) {        // RNE f32 -> bf16 bits
  u32 u = __float_as_uint(f);
  u32 r = (u + 0x7fffu + ((u >> 16) & 1u)) >> 16;
  return (u16)r;
}
__device__ __forceinline__ float bf2f(u16 v) { return __uint_as_float(((u32)v) << 16); }
__device__ __forceinline__ float bflo(u32 v) { return __uint_as_float(v << 16); }
__device__ __forceinline__ float bfhi(u32 v) { return __uint_as_float(v & 0xffff0000u); }
__device__ __forceinline__ u32 pack2(float a, float b) {
  return (u32)f2bf(a) | ((u32)f2bf(b) << 16);
}
#define MFMA16(a, b, c) __builtin_amdgcn_mfma_f32_16x16x32_bf16((a), (b), (c), 0, 0, 0)

// ---------------------------------------------------------------- utilities
__global__ void zero_i32_kernel(int* __restrict__ p, int n) {
  int i = blockIdx.x * 256 + threadIdx.x;
  if (i < n) p[i] = 0;
}

__global__ void f2bf_kernel(const float* __restrict__ in, u16* __restrict__ out, int n) {
  int i = blockIdx.x * 256 + threadIdx.x;
  if (i < n) out[i] = f2bf(in[i]);
}

// transpose f32 [128][128] -> bf16 wT[c][k]
__global__ void wT_kernel(const float* __restrict__ W, u16* __restrict__ wT) {
  int i = blockIdx.x * 256 + threadIdx.x;   // 16384
  int k = i >> 7, c = i & 127;
  wT[c * 128 + k] = f2bf(W[k * 128 + c]);
}

// ZT (bf16, transposed) = (X @ Y)^T for [128][128] inputs
__global__ void smallmmT_kernel(const float* __restrict__ X, const float* __restrict__ Y,
                                u16* __restrict__ ZT) {
  int i = blockIdx.x * 256 + threadIdx.x;
  int k = i >> 7, c = i & 127;
  float acc = 0.f;
  for (int t = 0; t < 128; ++t) acc += X[k * 128 + t] * Y[t * 128 + c];
  ZT[c * 128 + k] = f2bf(acc);
}

// f32 small matmul (for c01: rows=2)
__global__ void smallmm_kernel(const float* __restrict__ X, const float* __restrict__ Y,
                               float* __restrict__ Z, int rows) {
  int idx = blockIdx.x * 256 + threadIdx.x;
  if (idx >= rows * 128) return;
  int i = idx >> 7, j = idx & 127;
  float acc = 0.f;
  for (int t = 0; t < 128; ++t) acc += X[i * 128 + t] * Y[t * 128 + j];
  Z[idx] = acc;
}

// ---------------------------------------------------------------- graph prep
__global__ void hist_kernel(const int* __restrict__ dst, int* __restrict__ cnt, int E) {
  int e = blockIdx.x * 256 + threadIdx.x;
  if (e < E) atomicAdd(&cnt[dst[e]], 1);
}

__global__ void dis_kernel(const int* __restrict__ cnt, float* __restrict__ dis, int N) {
  int n = blockIdx.x * 256 + threadIdx.x;
  if (n < N) dis[n] = rsqrtf(1.0f + (float)cnt[n]);
}

__global__ __launch_bounds__(1024) void scan_kernel(const int* __restrict__ cnt,
                                                    int* __restrict__ row_ptr,
                                                    int* __restrict__ fill, int N) {
  __shared__ int wsums[16];
  __shared__ int s_carry;
  int t = threadIdx.x, lane = t & 63, wid = t >> 6;
  if (t == 0) s_carry = 0;
  __syncthreads();
  for (int base = 0; base < N; base += 1024) {
    int i = base + t;
    int v = (i < N) ? cnt[i] : 0;
    int x = v;
    #pragma unroll
    for (int off = 1; off < 64; off <<= 1) {
      int y = __shfl_up(x, off);
      if (lane >= off) x += y;
    }
    if (lane == 63) wsums[wid] = x;
    __syncthreads();
    int woff = 0;
    for (int w = 0; w < wid; ++w) woff += wsums[w];
    int excl = s_carry + woff + x - v;
    if (i < N) { row_ptr[i] = excl; fill[i] = excl; }
    __syncthreads();
    if (t == 1023) s_carry = excl + v;
    __syncthreads();
  }
  if (t == 0) row_ptr[N] = s_carry;
}

__global__ void scatter_kernel(const int* __restrict__ src, const int* __restrict__ dst,
                               int* __restrict__ fill, int* __restrict__ csr_src, int E) {
  int e = blockIdx.x * 256 + threadIdx.x;
  if (e >= E) return;
  int d = dst[e];
  int pos = atomicAdd(&fill[d], 1);
  csr_src[pos] = src[e];
}

// ------------------------------------------------------------ MFMA bf16 GEMM
// (GCN layers) C[M,128](bf16) = A[M,128](bf16) @ W ; wT[c][k] layout.
__global__ __launch_bounds__(256) void gemm_bf16_kernel(
    const u16* __restrict__ A, const u16* __restrict__ wT,
    u16* __restrict__ C, int M) {
  int t = threadIdx.x;
  int w = t >> 6, l = t & 63, lr = l & 15, lg = l >> 4;
  int r0 = blockIdx.x * 64 + w * 16;

  int row = r0 + lr;
  const u16* Arow = A + (size_t)(row < M ? row : 0) * 128;

  bfrag a[4];
  #pragma unroll
  for (int ks = 0; ks < 4; ++ks) a[ks] = *(const bfrag*)(Arow + ks * 32 + lg * 8);

  f32x4 acc[8];
  #pragma unroll
  for (int ct = 0; ct < 8; ++ct) acc[ct] = (f32x4){0.f, 0.f, 0.f, 0.f};
  #pragma unroll
  for (int ks = 0; ks < 4; ++ks)
    #pragma unroll
    for (int ct = 0; ct < 8; ++ct) {
      bfrag b = *(const bfrag*)(wT + (size_t)(ct * 16 + lr) * 128 + ks * 32 + lg * 8);
      acc[ct] = MFMA16(a[ks], b, acc[ct]);
    }
  #pragma unroll
  for (int ct = 0; ct < 8; ++ct)
    #pragma unroll
    for (int i = 0; i < 4; ++i) {
      int r = r0 + lg * 4 + i;
      if (r < M) C[(size_t)r * 128 + ct * 16 + lr] = f2bf(acc[ct][i]);
    }
}

// ------------------------------------------------------------- GCN aggregate
__global__ __launch_bounds__(256) void agg_kernel(
    const u16* __restrict__ xw, const float* __restrict__ dis,
    const int* __restrict__ row_ptr, const int* __restrict__ csr_src,
    const float* __restrict__ bias, const float* __restrict__ lng,
    const float* __restrict__ lnb, u16* __restrict__ out, int N, int doLN) {
  int lane = threadIdx.x & 63;
  int n = blockIdx.x * 4 + (threadIdx.x >> 6);
  if (n >= N) return;
  float dn = dis[n];
  u32 sv = *(const u32*)(xw + (size_t)n * 128 + lane * 2);
  float ax = dn * dn * bflo(sv), ay = dn * dn * bfhi(sv);
  int e0 = row_ptr[n], e1 = row_ptr[n + 1];
  for (int e = e0; e < e1; ++e) {
    int s = csr_src[e];
    float w = dis[s] * dn;
    u32 v = *(const u32*)(xw + (size_t)s * 128 + lane * 2);
    ax += w * bflo(v); ay += w * bfhi(v);
  }
  int c0 = lane * 2;
  ax += bias[c0]; ay += bias[c0 + 1];
  ax = fmaxf(ax, 0.f); ay = fmaxf(ay, 0.f);
  if (doLN) {
    float s1 = ax + ay, s2 = ax * ax + ay * ay;
    #pragma unroll
    for (int off = 32; off > 0; off >>= 1) {
      s1 += __shfl_xor(s1, off);
      s2 += __shfl_xor(s2, off);
    }
    float mean = s1 * (1.f / 128.f);
    float var = s2 * (1.f / 128.f) - mean * mean;
    float inv = rsqrtf(var + 1e-5f);
    ax = (ax - mean) * inv * lng[c0] + lnb[c0];
    ay = (ay - mean) * inv * lng[c0 + 1] + lnb[c0 + 1];
  }
  ((u32*)out)[(size_t)n * 64 + lane] = pack2(ax, ay);
}

// ------------------------------------------------- fused gather -> q and qh
__global__ __launch_bounds__(256) void q_qh_kernel(
    const u16* __restrict__ xa, const int* __restrict__ gidx,
    const u16* __restrict__ l3T, const u16* __restrict__ wqT,
    const float* __restrict__ bq,
    u16* __restrict__ qout, u16* __restrict__ qhout) {
  int t = threadIdx.x, w = t >> 6, l = t & 63, lr = l & 15, lg = l >> 4;
  int r0 = blockIdx.x * 64 + w * 16;
  int arow = gidx[r0 + lr];
  const u16* Arow = xa + (size_t)arow * 128;
  bfrag a[4];
  #pragma unroll
  for (int ks = 0; ks < 4; ++ks) a[ks] = *(const bfrag*)(Arow + ks * 32 + lg * 8);

  f32x4 acc[8];
  #pragma unroll
  for (int ct = 0; ct < 8; ++ct) acc[ct] = (f32x4){0.f, 0.f, 0.f, 0.f};
  #pragma unroll
  for (int ks = 0; ks < 4; ++ks)
    #pragma unroll
    for (int ct = 0; ct < 8; ++ct) {
      bfrag b = *(const bfrag*)(l3T + (size_t)(ct * 16 + lr) * 128 + ks * 32 + lg * 8);
      acc[ct] = MFMA16(a[ks], b, acc[ct]);
    }
  #pragma unroll
  for (int ct = 0; ct < 8; ++ct)
    #pragma unroll
    for (int i = 0; i < 4; ++i)
      qout[(size_t)(r0 + lg * 4 + i) * 128 + ct * 16 + lr] = f2bf(acc[ct][i]);

  #pragma unroll
  for (int ct = 0; ct < 8; ++ct) acc[ct] = (f32x4){0.f, 0.f, 0.f, 0.f};
  #pragma unroll
  for (int ks = 0; ks < 4; ++ks)
    #pragma unroll
    for (int ct = 0; ct < 8; ++ct) {
      bfrag b = *(const bfrag*)(wqT + (size_t)(ct * 16 + lr) * 128 + ks * 32 + lg * 8);
      acc[ct] = MFMA16(a[ks], b, acc[ct]);
    }
  #pragma unroll
  for (int ct = 0; ct < 8; ++ct)
    #pragma unroll
    for (int i = 0; i < 4; ++i)
      qhout[(size_t)(r0 + lg * 4 + i) * 128 + ct * 16 + lr] =
          f2bf(acc[ct][i] + bq[ct * 16 + lr]);
}

// ---------------------------- fused gather -> inter(LDS) -> kh, vh
__global__ __launch_bounds__(256) void inter_kv_kernel(
    const u16* __restrict__ xa, const int* __restrict__ hist, const int* __restrict__ ans,
    const u16* __restrict__ l0T, const float* __restrict__ lin0_b,
    const float* __restrict__ pos_emb, const float* __restrict__ c01,
    const u16* __restrict__ wkT, const float* __restrict__ bk,
    const u16* __restrict__ wvT, const float* __restrict__ bv,
    u16* __restrict__ khout, u16* __restrict__ vhout) {
  __shared__ u16 interl[4][16 * 136];
  int t = threadIdx.x, w = t >> 6, l = t & 63, lr = l & 15, lg = l >> 4;
  int r0 = blockIdx.x * 64 + w * 16;
  int arow = hist[r0 + lr];
  const u16* Arow = xa + (size_t)arow * 128;
  bfrag a[4];
  #pragma unroll
  for (int ks = 0; ks < 4; ++ks) a[ks] = *(const bfrag*)(Arow + ks * 32 + lg * 8);

  f32x4 acc[8];
  #pragma unroll
  for (int ct = 0; ct < 8; ++ct) acc[ct] = (f32x4){0.f, 0.f, 0.f, 0.f};
  #pragma unroll
  for (int ks = 0; ks < 4; ++ks)
    #pragma unroll
    for (int ct = 0; ct < 8; ++ct) {
      bfrag b = *(const bfrag*)(l0T + (size_t)(ct * 16 + lr) * 128 + ks * 32 + lg * 8);
      acc[ct] = MFMA16(a[ks], b, acc[ct]);
    }
  // epilogue: + lin0_b + pos_emb[r%S] + c01[ans[r]]  -> interl (bf16)
  int posr[4], ansr[4];
  #pragma unroll
  for (int i = 0; i < 4; ++i) {
    int r = r0 + lg * 4 + i;
    posr[i] = r % S_;
    ansr[i] = ans[r];
  }
  #pragma unroll
  for (int ct = 0; ct < 8; ++ct) {
    int col = ct * 16 + lr;
    float bcol = lin0_b[col];
    #pragma unroll
    for (int i = 0; i < 4; ++i) {
      float v = acc[ct][i] + bcol + pos_emb[(size_t)posr[i] * 128 + col]
                + c01[ansr[i] * 128 + col];
      interl[w][(lg * 4 + i) * 136 + col] = f2bf(v);
    }
  }
  // second stage: kh, vh from interl (per-wave private; compiler inserts lgkmcnt)
  bfrag a2[4];
  #pragma unroll
  for (int ks = 0; ks < 4; ++ks)
    a2[ks] = *(const bfrag*)(&interl[w][lr * 136 + ks * 32 + lg * 8]);

  #pragma unroll
  for (int ct = 0; ct < 8; ++ct) acc[ct] = (f32x4){0.f, 0.f, 0.f, 0.f};
  #pragma unroll
  for (int ks = 0; ks < 4; ++ks)
    #pragma unroll
    for (int ct = 0; ct < 8; ++ct) {
      bfrag b = *(const bfrag*)(wkT + (size_t)(ct * 16 + lr) * 128 + ks * 32 + lg * 8);
      acc[ct] = MFMA16(a2[ks], b, acc[ct]);
    }
  #pragma unroll
  for (int ct = 0; ct < 8; ++ct)
    #pragma unroll
    for (int i = 0; i < 4; ++i)
      khout[(size_t)(r0 + lg * 4 + i) * 128 + ct * 16 + lr] =
          f2bf(acc[ct][i] + bk[ct * 16 + lr]);

  #pragma unroll
  for (int ct = 0; ct < 8; ++ct) acc[ct] = (f32x4){0.f, 0.f, 0.f, 0.f};
  #pragma unroll
  for (int ks = 0; ks < 4; ++ks)
    #pragma unroll
    for (int ct = 0; ct < 8; ++ct) {
      bfrag b = *(const bfrag*)(wvT + (size_t)(ct * 16 + lr) * 128 + ks * 32 + lg * 8);
      acc[ct] = MFMA16(a2[ks], b, acc[ct]);
    }
  #pragma unroll
  for (int ct = 0; ct < 8; ++ct)
    #pragma unroll
    for (int i = 0; i < 4; ++i)
      vhout[(size_t)(r0 + lg * 4 + i) * 128 + ct * 16 + lr] =
          f2bf(acc[ct][i] + bv[ct * 16 + lr]);
}

// ----------------------------------------------------------- MFMA attention
// block = (b,h); 4 waves, wave w owns q-tiles w, w+4, w+8, w+12. In-place on qh.
__global__ __launch_bounds__(256) void attn_mfma_kernel(
    u16* qh_ao, const u16* __restrict__ kh, const u16* __restrict__ vh) {
  __shared__ u16 Kl[208 * 24];        // [key][d0..15], pad stride 24
  __shared__ u16 Vt[16 * 232];        // [d][key], keys>=200 zero
  __shared__ u16 Pl[4 * 16 * 232];    // per-wave P (bf16), zero-init
  int b = blockIdx.x >> 3, h = blockIdx.x & 7;
  int t = threadIdx.x;
  size_t base = ((size_t)b * S_) * 128 + h * 16;

  for (int i = t; i < 208 * 16; i += 256) {
    int key = i >> 4, d = i & 15;
    Kl[key * 24 + d] = (key < S_) ? kh[base + (size_t)key * 128 + d] : (u16)0;
  }
  for (int i = t; i < 16 * 232; i += 256) {
    int d = i / 232, key = i - d * 232;
    Vt[d * 232 + key] = (key < S_) ? vh[base + (size_t)key * 128 + d] : (u16)0;
  }
  for (int i = t; i < 4 * 16 * 232 / 2; i += 256) ((u32*)Pl)[i] = 0;
  __syncthreads();

  int w = t >> 6, l = t & 63, lr = l & 15, lg = l >> 4;
  u16* Pw = Pl + w * 16 * 232;
  const f32x4 zero4 = {0.f, 0.f, 0.f, 0.f};

  for (int qi = w; qi < 13; qi += 4) {
    bfrag aq = (bfrag){0, 0, 0, 0, 0, 0, 0, 0};
    int qrow = qi * 16 + lr;
    if (lg < 2 && qrow < S_)
      aq = *(const bfrag*)(qh_ao + base + (size_t)qrow * 128 + lg * 8);
    float rsum[4] = {0.f, 0.f, 0.f, 0.f};
    for (int kj = 0; kj <= qi; ++kj) {
      bfrag bk = (bfrag){0, 0, 0, 0, 0, 0, 0, 0};
      if (lg < 2) bk = *(const bfrag*)(Kl + (kj * 16 + lr) * 24 + lg * 8);
      f32x4 sc = MFMA16(aq, bk, zero4);
      #pragma unroll
      for (int i = 0; i < 4; ++i) {
        int q = qi * 16 + lg * 4 + i, key = kj * 16 + lr;
        float p = 0.f;
        if (key <= q && q < S_) p = __expf(sc[i] * 0.25f);
        rsum[i] += p;
        Pw[(lg * 4 + i) * 232 + key] = f2bf(p);
      }
    }
    #pragma unroll
    for (int i = 0; i < 4; ++i) {
      rsum[i] += __shfl_xor(rsum[i], 1);
      rsum[i] += __shfl_xor(rsum[i], 2);
      rsum[i] += __shfl_xor(rsum[i], 4);
      rsum[i] += __shfl_xor(rsum[i], 8);
    }
    f32x4 o = zero4;
    #pragma unroll
    for (int kt = 0; kt < 7; ++kt) {
      bfrag ap = *(const bfrag*)(Pw + lr * 232 + kt * 32 + lg * 8);
      bfrag bv = *(const bfrag*)(Vt + lr * 232 + kt * 32 + lg * 8);
      o = MFMA16(ap, bv, o);
    }
    #pragma unroll
    for (int i = 0; i < 4; ++i) {
      int q = qi * 16 + lg * 4 + i;
      if (q < S_) qh_ao[base + (size_t)q * 128 + lr] = f2bf(o[i] / rsum[i]);
    }
  }
}

// ------------------------------------- fused ao@wo + bo + resid(q) -> LN2
__global__ __launch_bounds__(256) void wo_ln_kernel(
    const u16* __restrict__ ao, const u16* __restrict__ qres,
    const u16* __restrict__ woT, const float* __restrict__ bo,
    const float* __restrict__ g, const float* __restrict__ bb,
    u16* __restrict__ atn) {
  int t = threadIdx.x, w = t >> 6, l = t & 63, lr = l & 15, lg = l >> 4;
  int r0 = blockIdx.x * 64 + w * 16;
  const u16* Arow = ao + (size_t)(r0 + lr) * 128;
  bfrag a[4];
  #pragma unroll
  for (int ks = 0; ks < 4; ++ks) a[ks] = *(const bfrag*)(Arow + ks * 32 + lg * 8);

  f32x4 acc[8];
  #pragma unroll
  for (int ct = 0; ct < 8; ++ct) acc[ct] = (f32x4){0.f, 0.f, 0.f, 0.f};
  #pragma unroll
  for (int ks = 0; ks < 4; ++ks)
    #pragma unroll
    for (int ct = 0; ct < 8; ++ct) {
      bfrag b = *(const bfrag*)(woT + (size_t)(ct * 16 + lr) * 128 + ks * 32 + lg * 8);
      acc[ct] = MFMA16(a[ks], b, acc[ct]);
    }
  // + bo + resid
  #pragma unroll
  for (int ct = 0; ct < 8; ++ct) {
    int col = ct * 16 + lr;
    float bcol = bo[col];
    #pragma unroll
    for (int i = 0; i < 4; ++i)
      acc[ct][i] += bcol + bf2f(qres[(size_t)(r0 + lg * 4 + i) * 128 + col]);
  }
  // LN per row
  float s1[4] = {0, 0, 0, 0}, s2[4] = {0, 0, 0, 0};
  #pragma unroll
  for (int ct = 0; ct < 8; ++ct)
    #pragma unroll
    for (int i = 0; i < 4; ++i) {
      s1[i] += acc[ct][i];
      s2[i] += acc[ct][i] * acc[ct][i];
    }
  #pragma unroll
  for (int i = 0; i < 4; ++i) {
    s1[i] += __shfl_xor(s1[i], 1); s2[i] += __shfl_xor(s2[i], 1);
    s1[i] += __shfl_xor(s1[i], 2); s2[i] += __shfl_xor(s2[i], 2);
    s1[i] += __shfl_xor(s1[i], 4); s2[i] += __shfl_xor(s2[i], 4);
    s1[i] += __shfl_xor(s1[i], 8); s2[i] += __shfl_xor(s2[i], 8);
  }
  float mean[4], inv[4];
  #pragma unroll
  for (int i = 0; i < 4; ++i) {
    mean[i] = s1[i] * (1.f / 128.f);
    float var = s2[i] * (1.f / 128.f) - mean[i] * mean[i];
    inv[i] = rsqrtf(var + 1e-5f);
  }
  #pragma unroll
  for (int ct = 0; ct < 8; ++ct) {
    int col = ct * 16 + lr;
    float gc = g[col], bc = bb[col];
    #pragma unroll
    for (int i = 0; i < 4; ++i)
      atn[(size_t)(r0 + lg * 4 + i) * 128 + col] =
          f2bf((acc[ct][i] - mean[i]) * inv[i] * gc + bc);
  }
}

// --------------------- fused FFN: relu(atn@f0+b0)@f1 + b1 + atn -> LN3 -> pred
__global__ __launch_bounds__(256) void ffn_kernel(
    const u16* __restrict__ atn, const u16* __restrict__ f0T,
    const float* __restrict__ b0, const u16* __restrict__ f1T,
    const float* __restrict__ b1, const float* __restrict__ g,
    const float* __restrict__ bb, const float* __restrict__ w4,
    const float* __restrict__ b4, float* __restrict__ pred) {
  __shared__ u16 f1l[4][16 * 136];
  int t = threadIdx.x, w = t >> 6, l = t & 63, lr = l & 15, lg = l >> 4;
  int r0 = blockIdx.x * 64 + w * 16;
  const u16* Arow = atn + (size_t)(r0 + lr) * 128;
  bfrag a[4];
  #pragma unroll
  for (int ks = 0; ks < 4; ++ks) a[ks] = *(const bfrag*)(Arow + ks * 32 + lg * 8);

  f32x4 acc[8];
  #pragma unroll
  for (int ct = 0; ct < 8; ++ct) acc[ct] = (f32x4){0.f, 0.f, 0.f, 0.f};
  #pragma unroll
  for (int ks = 0; ks < 4; ++ks)
    #pragma unroll
    for (int ct = 0; ct < 8; ++ct) {
      bfrag b = *(const bfrag*)(f0T + (size_t)(ct * 16 + lr) * 128 + ks * 32 + lg * 8);
      acc[ct] = MFMA16(a[ks], b, acc[ct]);
    }
  #pragma unroll
  for (int ct = 0; ct < 8; ++ct) {
    int col = ct * 16 + lr;
    float bcol = b0[col];
    #pragma unroll
    for (int i = 0; i < 4; ++i)
      f1l[w][(lg * 4 + i) * 136 + col] = f2bf(fmaxf(acc[ct][i] + bcol, 0.f));
  }
  bfrag a2[4];
  #pragma unroll
  for (int ks = 0; ks < 4; ++ks)
    a2[ks] = *(const bfrag*)(&f1l[w][lr * 136 + ks * 32 + lg * 8]);

  #pragma unroll
  for (int ct = 0; ct < 8; ++ct) acc[ct] = (f32x4){0.f, 0.f, 0.f, 0.f};
  #pragma unroll
  for (int ks = 0; ks < 4; ++ks)
    #pragma unroll
    for (int ct = 0; ct < 8; ++ct) {
      bfrag b = *(const bfrag*)(f1T + (size_t)(ct * 16 + lr) * 128 + ks * 32 + lg * 8);
      acc[ct] = MFMA16(a2[ks], b, acc[ct]);
    }
  // + b1 + resid(atn)
  #pragma unroll
  for (int ct = 0; ct < 8; ++ct) {
    int col = ct * 16 + lr;
    float bcol = b1[col];
    #pragma unroll
    for (int i = 0; i < 4; ++i)
      acc[ct][i] += bcol + bf2f(atn[(size_t)(r0 + lg * 4 + i) * 128 + col]);
  }
  // LN3
  float s1[4] = {0, 0, 0, 0}, s2[4] = {0, 0, 0, 0};
  #pragma unroll
  for (int ct = 0; ct < 8; ++ct)
    #pragma unroll
    for (int i = 0; i < 4; ++i) {
      s1[i] += acc[ct][i];
      s2[i] += acc[ct][i] * acc[ct][i];
    }
  #pragma unroll
  for (int i = 0; i < 4; ++i) {
    s1[i] += __shfl_xor(s1[i], 1); s2[i] += __shfl_xor(s2[i], 1);
    s1[i] += __shfl_xor(s1[i], 2); s2[i] += __shfl_xor(s2[i], 2);
    s1[i] += __shfl_xor(s1[i], 4); s2[i] += __shfl_xor(s2[i], 4);
    s1[i] += __shfl_xor(s1[i], 8); s2[i] += __shfl_xor(s2[i], 8);
  }
  float p[4] = {0, 0, 0, 0};
  #pragma unroll
  for (int i = 0; i < 4; ++i) {
    float mean = s1[i] * (1.f / 128.f);
    float var = s2[i] * (1.f / 128.f) - mean * mean;
    float inv = rsqrtf(var + 1e-5f);
    #pragma unroll
    for (int ct = 0; ct < 8; ++ct) {
      int col = ct * 16 + lr;
      p[i] += ((acc[ct][i] - mean) * inv * g[col] + bb[col]) * w4[col];
    }
  }
  #pragma unroll
  for (int i = 0; i < 4; ++i) {
    p[i] += __shfl_xor(p[i], 1);
    p[i] += __shfl_xor(p[i], 2);
    p[i] += __shfl_xor(p[i], 4);
    p[i] += __shfl_xor(p[i], 8);
  }
  if (lr == 0) {
    float bias4 = b4[0];
    #pragma unroll
    for (int i = 0; i < 4; ++i) pred[r0 + lg * 4 + i] = p[i] + bias4;
  }
}

// ---------------------------------------------------------------------------
extern "C" void kernel_launch(void* const* d_in, const int* in_sizes, int n_in,
                              void* d_out, int out_size, void* d_ws, size_t ws_size,
                              hipStream_t stream) {
  const int* hist_seq = (const int*)d_in[0];
  const int* hist_ans = (const int*)d_in[1];
  const int* new_seq = (const int*)d_in[2];
  const int* edge_index = (const int*)d_in[3];
  const float* node_x = (const float*)d_in[4];
  const float* gcn_w0 = (const float*)d_in[5];
  const float* gcn_b0 = (const float*)d_in[6];
  const float* gcn_w1 = (const float*)d_in[7];
  const float* gcn_b1 = (const float*)d_in[8];
  const float* gcn_w2 = (const float*)d_in[9];
  const float* gcn_b2 = (const float*)d_in[10];
  const float* ln0_g = (const float*)d_in[11];
  const float* ln0_b = (const float*)d_in[12];
  const float* ln1_g = (const float*)d_in[13];
  const float* ln1_b = (const float*)d_in[14];
  const float* ln2_g = (const float*)d_in[15];
  const float* ln2_b = (const float*)d_in[16];
  const float* ln3_g = (const float*)d_in[17];
  const float* ln3_b = (const float*)d_in[18];
  const float* corr_emb = (const float*)d_in[19];
  const float* lin0_w = (const float*)d_in[20];
  const float* lin0_b = (const float*)d_in[21];
  const float* lin1_w = (const float*)d_in[22];
  const float* lin2_w = (const float*)d_in[23];
  const float* lin3_w = (const float*)d_in[24];
  const float* lin4_w = (const float*)d_in[25];
  const float* lin4_b = (const float*)d_in[26];
  const float* pos_emb = (const float*)d_in[27];
  const float* mha_wq = (const float*)d_in[28];
  const float* mha_bq = (const float*)d_in[29];
  const float* mha_wk = (const float*)d_in[30];
  const float* mha_bk = (const float*)d_in[31];
  const float* mha_wv = (const float*)d_in[32];
  const float* mha_bv = (const float*)d_in[33];
  const float* mha_wo = (const float*)d_in[34];
  const float* mha_bo = (const float*)d_in[35];
  const float* ffn0_w = (const float*)d_in[36];
  const float* ffn0_b = (const float*)d_in[37];
  const float* ffn1_w = (const float*)d_in[38];
  const float* ffn1_b = (const float*)d_in[39];
  (void)in_sizes; (void)n_in; (void)out_size;

  char* ws = (char*)d_ws;
  size_t off = 0;
  auto alloc = [&](size_t bytes) -> void* {
    void* p = ws + off;
    off += (bytes + 255) & ~(size_t)255;
    return p;
  };
  int* cnt = (int*)alloc((size_t)N_NODES * 4);
  int* row_ptr = (int*)alloc((size_t)(N_NODES + 1) * 4);
  int* fill = (int*)alloc((size_t)N_NODES * 4);
  float* dis = (float*)alloc((size_t)N_NODES * 4);
  int* csr_src = (int*)alloc((size_t)N_EDGES * 4);
  const size_t WB = 128 * 128 * 2;
  u16* g0T = (u16*)alloc(WB);
  u16* g1T = (u16*)alloc(WB);
  u16* g2T = (u16*)alloc(WB);
  u16* l0T = (u16*)alloc(WB);
  u16* l3T = (u16*)alloc(WB);
  u16* woT = (u16*)alloc(WB);
  u16* f0T = (u16*)alloc(WB);
  u16* f1T = (u16*)alloc(WB);
  u16* wqT = (u16*)alloc(WB);
  u16* wkT = (u16*)alloc(WB);
  u16* wvT = (u16*)alloc(WB);
  float* c01 = (float*)alloc(2 * 128 * 4);
  u16* xb = (u16*)alloc((size_t)N_NODES * 128 * 2);
  u16* xa = (u16*)alloc((size_t)N_NODES * 128 * 2);
  u16* xw = (u16*)alloc((size_t)N_NODES * 128 * 2);
  const size_t CB = (size_t)MCH * 128 * 2;
  u16* bufQ0 = (u16*)alloc(CB);   // q (resid)
  u16* bufQ = (u16*)alloc(CB);    // qh -> ao (in place)
  u16* bufK = (u16*)alloc(CB);    // kh
  u16* bufV = (u16*)alloc(CB);    // vh
  u16* bufI = (u16*)alloc(CB);    // atn
  if (ws_size < off) return;      // diagnostic guard

  // ---- graph prep ----
  zero_i32_kernel<<<(N_NODES + 255) / 256, 256, 0, stream>>>(cnt, N_NODES);
  hist_kernel<<<(N_EDGES + 255) / 256, 256, 0, stream>>>(edge_index + N_EDGES, cnt, N_EDGES);
  dis_kernel<<<(N_NODES + 255) / 256, 256, 0, stream>>>(cnt, dis, N_NODES);
  scan_kernel<<<1, 1024, 0, stream>>>(cnt, row_ptr, fill, N_NODES);
  scatter_kernel<<<(N_EDGES + 255) / 256, 256, 0, stream>>>(edge_index, edge_index + N_EDGES,
                                                            fill, csr_src, N_EDGES);
  // ---- weight prep ----
  wT_kernel<<<64, 256, 0, stream>>>(gcn_w0, g0T);
  wT_kernel<<<64, 256, 0, stream>>>(gcn_w1, g1T);
  wT_kernel<<<64, 256, 0, stream>>>(gcn_w2, g2T);
  wT_kernel<<<64, 256, 0, stream>>>(lin0_w, l0T);
  wT_kernel<<<64, 256, 0, stream>>>(lin3_w, l3T);
  wT_kernel<<<64, 256, 0, stream>>>(mha_wo, woT);
  wT_kernel<<<64, 256, 0, stream>>>(ffn0_w, f0T);
  wT_kernel<<<64, 256, 0, stream>>>(ffn1_w, f1T);
  smallmmT_kernel<<<64, 256, 0, stream>>>(lin3_w, mha_wq, wqT);
  smallmmT_kernel<<<64, 256, 0, stream>>>(lin2_w, mha_wk, wkT);
  smallmmT_kernel<<<64, 256, 0, stream>>>(lin1_w, mha_wv, wvT);
  smallmm_kernel<<<1, 256, 0, stream>>>(corr_emb, lin0_w + 128 * 128, c01, 2);
  f2bf_kernel<<<(N_NODES * 128 + 255) / 256, 256, 0, stream>>>(node_x, xb, N_NODES * 128);

  int gN = (N_NODES + 63) / 64;
  int aN = (N_NODES + 3) / 4;

  // ---- GCN ----
  gemm_bf16_kernel<<<gN, 256, 0, stream>>>(xb, g0T, xw, N_NODES);
  agg_kernel<<<aN, 256, 0, stream>>>(xw, dis, row_ptr, csr_src, gcn_b0, ln0_g, ln0_b, xa, N_NODES, 1);
  gemm_bf16_kernel<<<gN, 256, 0, stream>>>(xa, g1T, xw, N_NODES);
  agg_kernel<<<aN, 256, 0, stream>>>(xw, dis, row_ptr, csr_src, gcn_b1, ln1_g, ln1_b, xa, N_NODES, 1);
  gemm_bf16_kernel<<<gN, 256, 0, stream>>>(xa, g2T, xw, N_NODES);
  agg_kernel<<<aN, 256, 0, stream>>>(xw, dis, row_ptr, csr_src, gcn_b2, nullptr, nullptr, xa, N_NODES, 0);

  // ---- transformer, 2 chunks, 5 fused dispatches each ----
  int gC = MCH / 64;   // 800
  for (int c = 0; c < NCHUNK; ++c) {
    int r0 = c * MCH;
    inter_kv_kernel<<<gC, 256, 0, stream>>>(xa, hist_seq + r0, hist_ans + r0,
                                            l0T, lin0_b, pos_emb, c01,
                                            wkT, mha_bk, wvT, mha_bv, bufK, bufV);
    q_qh_kernel<<<gC, 256, 0, stream>>>(xa, new_seq + r0, l3T, wqT, mha_bq, bufQ0, bufQ);
    attn_mfma_kernel<<<BCH * 8, 256, 0, stream>>>(bufQ, bufK, bufV);
    wo_ln_kernel<<<gC, 256, 0, stream>>>(bufQ, bufQ0, woT, mha_bo, ln2_g, ln2_b, bufI);
    ffn_kernel<<<gC, 256, 0, stream>>>(bufI, f0T, ffn0_b, f1T, ffn1_b, ln3_g, ln3_b,
                                       lin4_w, lin4_b, (float*)d_out + r0);
  }
}

// Round 6
// 718.328 us; speedup vs baseline: 2.0073x; 1.3077x over previous
//
#include <hip/hip_runtime.h>
#include <math.h>

#define N_NODES 50000
#define N_EDGES 800000
#define B_ 512
#define S_ 200
#define D_ 128
#define BS_ (B_*S_)
#define NCHUNK 2
#define BCH (B_/NCHUNK)        // 256 batch rows per chunk
#define MCH (BCH*S_)           // 51200 rows per chunk

typedef unsigned short u16;
typedef unsigned int u32;
using bfrag = __attribute__((ext_vector_type(8))) short;
using f32x4 = __attribute__((ext_vector_type(4))) float;

__device__ __forceinline__ u16 f2bf(float f) {        // RNE f32 -> bf16 bits
  u32 u = __float_as_uint(f);
  u32 r = (u + 0x7fffu + ((u >> 16) & 1u)) >> 16;
  return (u16)r;
}
__device__ __forceinline__ float bf2f(u16 v) { return __uint_as_float(((u32)v) << 16); }
__device__ __forceinline__ float bflo(u32 v) { return __uint_as_float(v << 16); }
__device__ __forceinline__ float bfhi(u32 v) { return __uint_as_float(v & 0xffff0000u); }
__device__ __forceinline__ u32 pack2(float a, float b) {
  return (u32)f2bf(a) | ((u32)f2bf(b) << 16);
}
#define MFMA16(a, b, c) __builtin_amdgcn_mfma_f32_16x16x32_bf16((a), (b), (c), 0, 0, 0)

// ---------------------------------------------------------------- utilities
__global__ void zero_i32_kernel(int* __restrict__ p, int n) {
  int i = blockIdx.x * 256 + threadIdx.x;
  if (i < n) p[i] = 0;
}

// vectorized f32 -> bf16 (8 elems/thread)
__global__ void f2bf8_kernel(const float* __restrict__ in, u16* __restrict__ out, int n8) {
  int i = blockIdx.x * 256 + threadIdx.x;
  if (i >= n8) return;
  float4 a = ((const float4*)in)[i * 2];
  float4 b = ((const float4*)in)[i * 2 + 1];
  uint4 o;
  o.x = pack2(a.x, a.y); o.y = pack2(a.z, a.w);
  o.z = pack2(b.x, b.y); o.w = pack2(b.z, b.w);
  ((uint4*)out)[i] = o;
}

// ---------------- fused weight prep: 8 transposes + 3 products + c01
__global__ __launch_bounds__(256) void wprep_kernel(
    const float* __restrict__ gcn_w0, const float* __restrict__ gcn_w1,
    const float* __restrict__ gcn_w2, const float* __restrict__ lin0_w,
    const float* __restrict__ lin3_w, const float* __restrict__ mha_wo,
    const float* __restrict__ ffn0_w, const float* __restrict__ ffn1_w,
    const float* __restrict__ lin1_w, const float* __restrict__ lin2_w,
    const float* __restrict__ mha_wq, const float* __restrict__ mha_wk,
    const float* __restrict__ mha_wv, const float* __restrict__ corr_emb,
    u16* __restrict__ g0T, u16* __restrict__ g1T, u16* __restrict__ g2T,
    u16* __restrict__ l0T, u16* __restrict__ l3T, u16* __restrict__ woT,
    u16* __restrict__ f0T, u16* __restrict__ f1T,
    u16* __restrict__ wqT, u16* __restrict__ wkT, u16* __restrict__ wvT,
    float* __restrict__ c01) {
  int bb = blockIdx.x;
  if (bb < 512) {                        // plain transpose W[k][c] -> D[c][k]
    const float* W; u16* D;
    switch (bb >> 6) {
      case 0: W = gcn_w0; D = g0T; break;
      case 1: W = gcn_w1; D = g1T; break;
      case 2: W = gcn_w2; D = g2T; break;
      case 3: W = lin0_w; D = l0T; break;
      case 4: W = lin3_w; D = l3T; break;
      case 5: W = mha_wo; D = woT; break;
      case 6: W = ffn0_w; D = f0T; break;
      default: W = ffn1_w; D = f1T; break;
    }
    int i = (bb & 63) * 256 + threadIdx.x;
    int k = i >> 7, c = i & 127;
    D[c * 128 + k] = f2bf(W[k * 128 + c]);
  } else if (bb < 704) {                 // (X@Y)^T -> D
    const float* X; const float* Y; u16* D;
    switch ((bb - 512) >> 6) {
      case 0: X = lin3_w; Y = mha_wq; D = wqT; break;
      case 1: X = lin2_w; Y = mha_wk; D = wkT; break;
      default: X = lin1_w; Y = mha_wv; D = wvT; break;
    }
    int i = ((bb - 512) & 63) * 256 + threadIdx.x;
    int k = i >> 7, c = i & 127;
    float acc = 0.f;
    for (int t = 0; t < 128; ++t) acc += X[k * 128 + t] * Y[t * 128 + c];
    D[c * 128 + k] = f2bf(acc);
  } else {                               // c01 = corr_emb @ lin0_w[128:]
    int idx = threadIdx.x;               // 0..255 = 2*128
    int i = idx >> 7, j = idx & 127;
    float acc = 0.f;
    for (int t = 0; t < 128; ++t)
      acc += corr_emb[i * 128 + t] * lin0_w[128 * 128 + t * 128 + j];
    c01[idx] = acc;
  }
}

// ---------------------------------------------------------------- graph prep
__global__ void hist_kernel(const int* __restrict__ dst, int* __restrict__ cnt, int E) {
  int e = blockIdx.x * 256 + threadIdx.x;
  if (e < E) atomicAdd(&cnt[dst[e]], 1);
}

// per-block(1024) local exclusive scan; block totals; dis fused
__global__ __launch_bounds__(1024) void scanA_kernel(
    const int* __restrict__ cnt, int* __restrict__ locpref,
    int* __restrict__ btot, float* __restrict__ dis, int N) {
  __shared__ int wsum[16];
  int t = threadIdx.x, lane = t & 63, wid = t >> 6;
  int i = blockIdx.x * 1024 + t;
  int v = (i < N) ? cnt[i] : 0;
  if (i < N) dis[i] = rsqrtf(1.f + (float)v);
  int x = v;
  #pragma unroll
  for (int off = 1; off < 64; off <<= 1) {
    int y = __shfl_up(x, off);
    if (lane >= off) x += y;
  }
  if (lane == 63) wsum[wid] = x;
  __syncthreads();
  if (wid == 0 && lane < 16) {
    int s = wsum[lane];
    #pragma unroll
    for (int off = 1; off < 16; off <<= 1) {
      int y = __shfl_up(s, off);
      if (lane >= off) s += y;
    }
    wsum[lane] = s;
  }
  __syncthreads();
  int woff = (wid > 0) ? wsum[wid - 1] : 0;
  if (i < N) locpref[i] = woff + x - v;
  if (t == 1023) btot[blockIdx.x] = woff + x;
}

// scan of block totals (nb <= 64), single wave
__global__ void scanB_kernel(const int* __restrict__ btot, int* __restrict__ boff, int nb) {
  int lane = threadIdx.x;
  int v = (lane < nb) ? btot[lane] : 0;
  int x = v;
  #pragma unroll
  for (int off = 1; off < 64; off <<= 1) {
    int y = __shfl_up(x, off);
    if (lane >= off) x += y;
  }
  if (lane < nb) boff[lane] = x - v;
}

__global__ void scanC_kernel(const int* __restrict__ locpref, const int* __restrict__ boff,
                             int* __restrict__ row_ptr, int* __restrict__ fill, int N) {
  int i = blockIdx.x * 256 + threadIdx.x;
  if (i < N) {
    int r = locpref[i] + boff[i >> 10];
    row_ptr[i] = r; fill[i] = r;
  }
  if (i == 0) row_ptr[N] = N_EDGES;
}

__global__ void scatter_kernel(const int* __restrict__ src, const int* __restrict__ dst,
                               int* __restrict__ fill, int* __restrict__ csr_src, int E) {
  int e = blockIdx.x * 256 + threadIdx.x;
  if (e >= E) return;
  int d = dst[e];
  int pos = atomicAdd(&fill[d], 1);
  csr_src[pos] = src[e];
}

// ------------------------------------------------------------ MFMA bf16 GEMM
// (GCN layers) C[M,128](bf16) = A[M,128](bf16) @ W ; wT[c][k] layout.
__global__ __launch_bounds__(256) void gemm_bf16_kernel(
    const u16* __restrict__ A, const u16* __restrict__ wT,
    u16* __restrict__ C, int M) {
  int t = threadIdx.x;
  int w = t >> 6, l = t & 63, lr = l & 15, lg = l >> 4;
  int r0 = blockIdx.x * 64 + w * 16;

  int row = r0 + lr;
  const u16* Arow = A + (size_t)(row < M ? row : 0) * 128;

  bfrag a[4];
  #pragma unroll
  for (int ks = 0; ks < 4; ++ks) a[ks] = *(const bfrag*)(Arow + ks * 32 + lg * 8);

  f32x4 acc[8];
  #pragma unroll
  for (int ct = 0; ct < 8; ++ct) acc[ct] = (f32x4){0.f, 0.f, 0.f, 0.f};
  #pragma unroll
  for (int ks = 0; ks < 4; ++ks)
    #pragma unroll
    for (int ct = 0; ct < 8; ++ct) {
      bfrag b = *(const bfrag*)(wT + (size_t)(ct * 16 + lr) * 128 + ks * 32 + lg * 8);
      acc[ct] = MFMA16(a[ks], b, acc[ct]);
    }
  #pragma unroll
  for (int ct = 0; ct < 8; ++ct)
    #pragma unroll
    for (int i = 0; i < 4; ++i) {
      int r = r0 + lg * 4 + i;
      if (r < M) C[(size_t)r * 128 + ct * 16 + lr] = f2bf(acc[ct][i]);
    }
}

// ------------------------------------------------------------- GCN aggregate
// wave per node; lane: colgrp=l&15 (8 cols, dwordx4), edgegrp=l>>4 (4 edges in flight)
__global__ __launch_bounds__(256) void agg_kernel(
    const u16* __restrict__ xw, const float* __restrict__ dis,
    const int* __restrict__ row_ptr, const int* __restrict__ csr_src,
    const float* __restrict__ bias, const float* __restrict__ lng,
    const float* __restrict__ lnb, u16* __restrict__ out, int N, int doLN) {
  int t = threadIdx.x;
  int n = blockIdx.x * 4 + (t >> 6);
  if (n >= N) return;
  int l = t & 63, cg = l & 15, eg = l >> 4;
  float dn = dis[n];
  float acc[8] = {0.f, 0.f, 0.f, 0.f, 0.f, 0.f, 0.f, 0.f};
  if (eg == 0) {
    uint4 r = *(const uint4*)(xw + (size_t)n * 128 + cg * 8);
    float w = dn * dn;
    acc[0] += w * bflo(r.x); acc[1] += w * bfhi(r.x);
    acc[2] += w * bflo(r.y); acc[3] += w * bfhi(r.y);
    acc[4] += w * bflo(r.z); acc[5] += w * bfhi(r.z);
    acc[6] += w * bflo(r.w); acc[7] += w * bfhi(r.w);
  }
  int e1 = row_ptr[n + 1];
  int e = row_ptr[n] + eg;
  int sn = (e < e1) ? csr_src[e] : -1;       // software-pipelined index prefetch
  while (sn >= 0) {
    int s = sn;
    e += 4;
    sn = (e < e1) ? csr_src[e] : -1;
    float w = dis[s] * dn;
    uint4 r = *(const uint4*)(xw + (size_t)s * 128 + cg * 8);
    acc[0] += w * bflo(r.x); acc[1] += w * bfhi(r.x);
    acc[2] += w * bflo(r.y); acc[3] += w * bfhi(r.y);
    acc[4] += w * bflo(r.z); acc[5] += w * bfhi(r.z);
    acc[6] += w * bflo(r.w); acc[7] += w * bfhi(r.w);
  }
  #pragma unroll
  for (int j = 0; j < 8; ++j) {
    acc[j] += __shfl_xor(acc[j], 16);
    acc[j] += __shfl_xor(acc[j], 32);
  }
  int c0 = cg * 8;
  #pragma unroll
  for (int j = 0; j < 8; ++j) acc[j] = fmaxf(acc[j] + bias[c0 + j], 0.f);
  if (doLN) {
    float s1 = 0.f, s2 = 0.f;
    #pragma unroll
    for (int j = 0; j < 8; ++j) { s1 += acc[j]; s2 += acc[j] * acc[j]; }
    #pragma unroll
    for (int off = 1; off < 16; off <<= 1) {
      s1 += __shfl_xor(s1, off);
      s2 += __shfl_xor(s2, off);
    }
    float mean = s1 * (1.f / 128.f);
    float var = s2 * (1.f / 128.f) - mean * mean;
    float inv = rsqrtf(var + 1e-5f);
    #pragma unroll
    for (int j = 0; j < 8; ++j)
      acc[j] = (acc[j] - mean) * inv * lng[c0 + j] + lnb[c0 + j];
  }
  if (eg == 0) {
    uint4 o;
    o.x = pack2(acc[0], acc[1]); o.y = pack2(acc[2], acc[3]);
    o.z = pack2(acc[4], acc[5]); o.w = pack2(acc[6], acc[7]);
    *(uint4*)(out + (size_t)n * 128 + cg * 8) = o;
  }
}

// ------------------------------------------------- fused gather -> q and qh
__global__ __launch_bounds__(256) void q_qh_kernel(
    const u16* __restrict__ xa, const int* __restrict__ gidx,
    const u16* __restrict__ l3T, const u16* __restrict__ wqT,
    const float* __restrict__ bq,
    u16* __restrict__ qout, u16* __restrict__ qhout) {
  int t = threadIdx.x, w = t >> 6, l = t & 63, lr = l & 15, lg = l >> 4;
  int r0 = blockIdx.x * 64 + w * 16;
  int arow = gidx[r0 + lr];
  const u16* Arow = xa + (size_t)arow * 128;
  bfrag a[4];
  #pragma unroll
  for (int ks = 0; ks < 4; ++ks) a[ks] = *(const bfrag*)(Arow + ks * 32 + lg * 8);

  f32x4 acc[8];
  #pragma unroll
  for (int ct = 0; ct < 8; ++ct) acc[ct] = (f32x4){0.f, 0.f, 0.f, 0.f};
  #pragma unroll
  for (int ks = 0; ks < 4; ++ks)
    #pragma unroll
    for (int ct = 0; ct < 8; ++ct) {
      bfrag b = *(const bfrag*)(l3T + (size_t)(ct * 16 + lr) * 128 + ks * 32 + lg * 8);
      acc[ct] = MFMA16(a[ks], b, acc[ct]);
    }
  #pragma unroll
  for (int ct = 0; ct < 8; ++ct)
    #pragma unroll
    for (int i = 0; i < 4; ++i)
      qout[(size_t)(r0 + lg * 4 + i) * 128 + ct * 16 + lr] = f2bf(acc[ct][i]);

  #pragma unroll
  for (int ct = 0; ct < 8; ++ct) acc[ct] = (f32x4){0.f, 0.f, 0.f, 0.f};
  #pragma unroll
  for (int ks = 0; ks < 4; ++ks)
    #pragma unroll
    for (int ct = 0; ct < 8; ++ct) {
      bfrag b = *(const bfrag*)(wqT + (size_t)(ct * 16 + lr) * 128 + ks * 32 + lg * 8);
      acc[ct] = MFMA16(a[ks], b, acc[ct]);
    }
  #pragma unroll
  for (int ct = 0; ct < 8; ++ct)
    #pragma unroll
    for (int i = 0; i < 4; ++i)
      qhout[(size_t)(r0 + lg * 4 + i) * 128 + ct * 16 + lr] =
          f2bf(acc[ct][i] + bq[ct * 16 + lr]);
}

// ---------------------------- fused gather -> inter(LDS) -> kh, vh
__global__ __launch_bounds__(256) void inter_kv_kernel(
    const u16* __restrict__ xa, const int* __restrict__ hist, const int* __restrict__ ans,
    const u16* __restrict__ l0T, const float* __restrict__ lin0_b,
    const float* __restrict__ pos_emb, const float* __restrict__ c01,
    const u16* __restrict__ wkT, const float* __restrict__ bk,
    const u16* __restrict__ wvT, const float* __restrict__ bv,
    u16* __restrict__ khout, u16* __restrict__ vhout) {
  __shared__ u16 interl[4][16 * 136];
  int t = threadIdx.x, w = t >> 6, l = t & 63, lr = l & 15, lg = l >> 4;
  int r0 = blockIdx.x * 64 + w * 16;
  int arow = hist[r0 + lr];
  const u16* Arow = xa + (size_t)arow * 128;
  bfrag a[4];
  #pragma unroll
  for (int ks = 0; ks < 4; ++ks) a[ks] = *(const bfrag*)(Arow + ks * 32 + lg * 8);

  f32x4 acc[8];
  #pragma unroll
  for (int ct = 0; ct < 8; ++ct) acc[ct] = (f32x4){0.f, 0.f, 0.f, 0.f};
  #pragma unroll
  for (int ks = 0; ks < 4; ++ks)
    #pragma unroll
    for (int ct = 0; ct < 8; ++ct) {
      bfrag b = *(const bfrag*)(l0T + (size_t)(ct * 16 + lr) * 128 + ks * 32 + lg * 8);
      acc[ct] = MFMA16(a[ks], b, acc[ct]);
    }
  // epilogue: + lin0_b + pos_emb[r%S] + c01[ans[r]]  -> interl (bf16)
  int posr[4], ansr[4];
  #pragma unroll
  for (int i = 0; i < 4; ++i) {
    int r = r0 + lg * 4 + i;
    posr[i] = r % S_;
    ansr[i] = ans[r];
  }
  #pragma unroll
  for (int ct = 0; ct < 8; ++ct) {
    int col = ct * 16 + lr;
    float bcol = lin0_b[col];
    #pragma unroll
    for (int i = 0; i < 4; ++i) {
      float v = acc[ct][i] + bcol + pos_emb[(size_t)posr[i] * 128 + col]
                + c01[ansr[i] * 128 + col];
      interl[w][(lg * 4 + i) * 136 + col] = f2bf(v);
    }
  }
  // second stage: kh, vh from interl (per-wave private)
  bfrag a2[4];
  #pragma unroll
  for (int ks = 0; ks < 4; ++ks)
    a2[ks] = *(const bfrag*)(&interl[w][lr * 136 + ks * 32 + lg * 8]);

  #pragma unroll
  for (int ct = 0; ct < 8; ++ct) acc[ct] = (f32x4){0.f, 0.f, 0.f, 0.f};
  #pragma unroll
  for (int ks = 0; ks < 4; ++ks)
    #pragma unroll
    for (int ct = 0; ct < 8; ++ct) {
      bfrag b = *(const bfrag*)(wkT + (size_t)(ct * 16 + lr) * 128 + ks * 32 + lg * 8);
      acc[ct] = MFMA16(a2[ks], b, acc[ct]);
    }
  #pragma unroll
  for (int ct = 0; ct < 8; ++ct)
    #pragma unroll
    for (int i = 0; i < 4; ++i)
      khout[(size_t)(r0 + lg * 4 + i) * 128 + ct * 16 + lr] =
          f2bf(acc[ct][i] + bk[ct * 16 + lr]);

  #pragma unroll
  for (int ct = 0; ct < 8; ++ct) acc[ct] = (f32x4){0.f, 0.f, 0.f, 0.f};
  #pragma unroll
  for (int ks = 0; ks < 4; ++ks)
    #pragma unroll
    for (int ct = 0; ct < 8; ++ct) {
      bfrag b = *(const bfrag*)(wvT + (size_t)(ct * 16 + lr) * 128 + ks * 32 + lg * 8);
      acc[ct] = MFMA16(a2[ks], b, acc[ct]);
    }
  #pragma unroll
  for (int ct = 0; ct < 8; ++ct)
    #pragma unroll
    for (int i = 0; i < 4; ++i)
      vhout[(size_t)(r0 + lg * 4 + i) * 128 + ct * 16 + lr] =
          f2bf(acc[ct][i] + bv[ct * 16 + lr]);
}

// ----------------------------------------------------------- MFMA attention
// block = (b,h); 4 waves, wave w owns q-tiles w, w+4, w+8, w+12. In-place on qh.
__global__ __launch_bounds__(256) void attn_mfma_kernel(
    u16* qh_ao, const u16* __restrict__ kh, const u16* __restrict__ vh) {
  __shared__ u16 Kl[208 * 24];        // [key][d0..15], pad stride 24
  __shared__ u16 Vt[16 * 232];        // [d][key], keys>=200 zero
  __shared__ u16 Pl[4 * 16 * 232];    // per-wave P (bf16), zero-init
  int b = blockIdx.x >> 3, h = blockIdx.x & 7;
  int t = threadIdx.x;
  size_t base = ((size_t)b * S_) * 128 + h * 16;

  for (int i = t; i < 208 * 16; i += 256) {
    int key = i >> 4, d = i & 15;
    Kl[key * 24 + d] = (key < S_) ? kh[base + (size_t)key * 128 + d] : (u16)0;
  }
  for (int i = t; i < 16 * 232; i += 256) {
    int d = i / 232, key = i - d * 232;
    Vt[d * 232 + key] = (key < S_) ? vh[base + (size_t)key * 128 + d] : (u16)0;
  }
  for (int i = t; i < 4 * 16 * 232 / 2; i += 256) ((u32*)Pl)[i] = 0;
  __syncthreads();

  int w = t >> 6, l = t & 63, lr = l & 15, lg = l >> 4;
  u16* Pw = Pl + w * 16 * 232;
  const f32x4 zero4 = {0.f, 0.f, 0.f, 0.f};

  for (int qi = w; qi < 13; qi += 4) {
    bfrag aq = (bfrag){0, 0, 0, 0, 0, 0, 0, 0};
    int qrow = qi * 16 + lr;
    if (lg < 2 && qrow < S_)
      aq = *(const bfrag*)(qh_ao + base + (size_t)qrow * 128 + lg * 8);
    float rsum[4] = {0.f, 0.f, 0.f, 0.f};
    for (int kj = 0; kj <= qi; ++kj) {
      bfrag bk = (bfrag){0, 0, 0, 0, 0, 0, 0, 0};
      if (lg < 2) bk = *(const bfrag*)(Kl + (kj * 16 + lr) * 24 + lg * 8);
      f32x4 sc = MFMA16(aq, bk, zero4);
      #pragma unroll
      for (int i = 0; i < 4; ++i) {
        int q = qi * 16 + lg * 4 + i, key = kj * 16 + lr;
        float p = 0.f;
        if (key <= q && q < S_) p = __expf(sc[i] * 0.25f);
        rsum[i] += p;
        Pw[(lg * 4 + i) * 232 + key] = f2bf(p);
      }
    }
    #pragma unroll
    for (int i = 0; i < 4; ++i) {
      rsum[i] += __shfl_xor(rsum[i], 1);
      rsum[i] += __shfl_xor(rsum[i], 2);
      rsum[i] += __shfl_xor(rsum[i], 4);
      rsum[i] += __shfl_xor(rsum[i], 8);
    }
    f32x4 o = zero4;
    #pragma unroll
    for (int kt = 0; kt < 7; ++kt) {
      bfrag ap = *(const bfrag*)(Pw + lr * 232 + kt * 32 + lg * 8);
      bfrag bv = *(const bfrag*)(Vt + lr * 232 + kt * 32 + lg * 8);
      o = MFMA16(ap, bv, o);
    }
    #pragma unroll
    for (int i = 0; i < 4; ++i) {
      int q = qi * 16 + lg * 4 + i;
      if (q < S_) qh_ao[base + (size_t)q * 128 + lr] = f2bf(o[i] / rsum[i]);
    }
  }
}

// ------------------------------------- fused ao@wo + bo + resid(q) -> LN2
__global__ __launch_bounds__(256) void wo_ln_kernel(
    const u16* __restrict__ ao, const u16* __restrict__ qres,
    const u16* __restrict__ woT, const float* __restrict__ bo,
    const float* __restrict__ g, const float* __restrict__ bb,
    u16* __restrict__ atn) {
  int t = threadIdx.x, w = t >> 6, l = t & 63, lr = l & 15, lg = l >> 4;
  int r0 = blockIdx.x * 64 + w * 16;
  const u16* Arow = ao + (size_t)(r0 + lr) * 128;
  bfrag a[4];
  #pragma unroll
  for (int ks = 0; ks < 4; ++ks) a[ks] = *(const bfrag*)(Arow + ks * 32 + lg * 8);

  f32x4 acc[8];
  #pragma unroll
  for (int ct = 0; ct < 8; ++ct) acc[ct] = (f32x4){0.f, 0.f, 0.f, 0.f};
  #pragma unroll
  for (int ks = 0; ks < 4; ++ks)
    #pragma unroll
    for (int ct = 0; ct < 8; ++ct) {
      bfrag b = *(const bfrag*)(woT + (size_t)(ct * 16 + lr) * 128 + ks * 32 + lg * 8);
      acc[ct] = MFMA16(a[ks], b, acc[ct]);
    }
  // + bo + resid
  #pragma unroll
  for (int ct = 0; ct < 8; ++ct) {
    int col = ct * 16 + lr;
    float bcol = bo[col];
    #pragma unroll
    for (int i = 0; i < 4; ++i)
      acc[ct][i] += bcol + bf2f(qres[(size_t)(r0 + lg * 4 + i) * 128 + col]);
  }
  // LN per row
  float s1[4] = {0, 0, 0, 0}, s2[4] = {0, 0, 0, 0};
  #pragma unroll
  for (int ct = 0; ct < 8; ++ct)
    #pragma unroll
    for (int i = 0; i < 4; ++i) {
      s1[i] += acc[ct][i];
      s2[i] += acc[ct][i] * acc[ct][i];
    }
  #pragma unroll
  for (int i = 0; i < 4; ++i) {
    s1[i] += __shfl_xor(s1[i], 1); s2[i] += __shfl_xor(s2[i], 1);
    s1[i] += __shfl_xor(s1[i], 2); s2[i] += __shfl_xor(s2[i], 2);
    s1[i] += __shfl_xor(s1[i], 4); s2[i] += __shfl_xor(s2[i], 4);
    s1[i] += __shfl_xor(s1[i], 8); s2[i] += __shfl_xor(s2[i], 8);
  }
  float mean[4], inv[4];
  #pragma unroll
  for (int i = 0; i < 4; ++i) {
    mean[i] = s1[i] * (1.f / 128.f);
    float var = s2[i] * (1.f / 128.f) - mean[i] * mean[i];
    inv[i] = rsqrtf(var + 1e-5f);
  }
  #pragma unroll
  for (int ct = 0; ct < 8; ++ct) {
    int col = ct * 16 + lr;
    float gc = g[col], bc = bb[col];
    #pragma unroll
    for (int i = 0; i < 4; ++i)
      atn[(size_t)(r0 + lg * 4 + i) * 128 + col] =
          f2bf((acc[ct][i] - mean[i]) * inv[i] * gc + bc);
  }
}

// --------------------- fused FFN: relu(atn@f0+b0)@f1 + b1 + atn -> LN3 -> pred
__global__ __launch_bounds__(256) void ffn_kernel(
    const u16* __restrict__ atn, const u16* __restrict__ f0T,
    const float* __restrict__ b0, const u16* __restrict__ f1T,
    const float* __restrict__ b1, const float* __restrict__ g,
    const float* __restrict__ bb, const float* __restrict__ w4,
    const float* __restrict__ b4, float* __restrict__ pred) {
  __shared__ u16 f1l[4][16 * 136];
  int t = threadIdx.x, w = t >> 6, l = t & 63, lr = l & 15, lg = l >> 4;
  int r0 = blockIdx.x * 64 + w * 16;
  const u16* Arow = atn + (size_t)(r0 + lr) * 128;
  bfrag a[4];
  #pragma unroll
  for (int ks = 0; ks < 4; ++ks) a[ks] = *(const bfrag*)(Arow + ks * 32 + lg * 8);

  f32x4 acc[8];
  #pragma unroll
  for (int ct = 0; ct < 8; ++ct) acc[ct] = (f32x4){0.f, 0.f, 0.f, 0.f};
  #pragma unroll
  for (int ks = 0; ks < 4; ++ks)
    #pragma unroll
    for (int ct = 0; ct < 8; ++ct) {
      bfrag b = *(const bfrag*)(f0T + (size_t)(ct * 16 + lr) * 128 + ks * 32 + lg * 8);
      acc[ct] = MFMA16(a[ks], b, acc[ct]);
    }
  #pragma unroll
  for (int ct = 0; ct < 8; ++ct) {
    int col = ct * 16 + lr;
    float bcol = b0[col];
    #pragma unroll
    for (int i = 0; i < 4; ++i)
      f1l[w][(lg * 4 + i) * 136 + col] = f2bf(fmaxf(acc[ct][i] + bcol, 0.f));
  }
  bfrag a2[4];
  #pragma unroll
  for (int ks = 0; ks < 4; ++ks)
    a2[ks] = *(const bfrag*)(&f1l[w][lr * 136 + ks * 32 + lg * 8]);

  #pragma unroll
  for (int ct = 0; ct < 8; ++ct) acc[ct] = (f32x4){0.f, 0.f, 0.f, 0.f};
  #pragma unroll
  for (int ks = 0; ks < 4; ++ks)
    #pragma unroll
    for (int ct = 0; ct < 8; ++ct) {
      bfrag b = *(const bfrag*)(f1T + (size_t)(ct * 16 + lr) * 128 + ks * 32 + lg * 8);
      acc[ct] = MFMA16(a2[ks], b, acc[ct]);
    }
  // + b1 + resid(atn)
  #pragma unroll
  for (int ct = 0; ct < 8; ++ct) {
    int col = ct * 16 + lr;
    float bcol = b1[col];
    #pragma unroll
    for (int i = 0; i < 4; ++i)
      acc[ct][i] += bcol + bf2f(atn[(size_t)(r0 + lg * 4 + i) * 128 + col]);
  }
  // LN3
  float s1[4] = {0, 0, 0, 0}, s2[4] = {0, 0, 0, 0};
  #pragma unroll
  for (int ct = 0; ct < 8; ++ct)
    #pragma unroll
    for (int i = 0; i < 4; ++i) {
      s1[i] += acc[ct][i];
      s2[i] += acc[ct][i] * acc[ct][i];
    }
  #pragma unroll
  for (int i = 0; i < 4; ++i) {
    s1[i] += __shfl_xor(s1[i], 1); s2[i] += __shfl_xor(s2[i], 1);
    s1[i] += __shfl_xor(s1[i], 2); s2[i] += __shfl_xor(s2[i], 2);
    s1[i] += __shfl_xor(s1[i], 4); s2[i] += __shfl_xor(s2[i], 4);
    s1[i] += __shfl_xor(s1[i], 8); s2[i] += __shfl_xor(s2[i], 8);
  }
  float p[4] = {0, 0, 0, 0};
  #pragma unroll
  for (int i = 0; i < 4; ++i) {
    float mean = s1[i] * (1.f / 128.f);
    float var = s2[i] * (1.f / 128.f) - mean * mean;
    float inv = rsqrtf(var + 1e-5f);
    #pragma unroll
    for (int ct = 0; ct < 8; ++ct) {
      int col = ct * 16 + lr;
      p[i] += ((acc[ct][i] - mean) * inv * g[col] + bb[col]) * w4[col];
    }
  }
  #pragma unroll
  for (int i = 0; i < 4; ++i) {
    p[i] += __shfl_xor(p[i], 1);
    p[i] += __shfl_xor(p[i], 2);
    p[i] += __shfl_xor(p[i], 4);
    p[i] += __shfl_xor(p[i], 8);
  }
  if (lr == 0) {
    float bias4 = b4[0];
    #pragma unroll
    for (int i = 0; i < 4; ++i) pred[r0 + lg * 4 + i] = p[i] + bias4;
  }
}

// ---------------------------------------------------------------------------
extern "C" void kernel_launch(void* const* d_in, const int* in_sizes, int n_in,
                              void* d_out, int out_size, void* d_ws, size_t ws_size,
                              hipStream_t stream) {
  const int* hist_seq = (const int*)d_in[0];
  const int* hist_ans = (const int*)d_in[1];
  const int* new_seq = (const int*)d_in[2];
  const int* edge_index = (const int*)d_in[3];
  const float* node_x = (const float*)d_in[4];
  const float* gcn_w0 = (const float*)d_in[5];
  const float* gcn_b0 = (const float*)d_in[6];
  const float* gcn_w1 = (const float*)d_in[7];
  const float* gcn_b1 = (const float*)d_in[8];
  const float* gcn_w2 = (const float*)d_in[9];
  const float* gcn_b2 = (const float*)d_in[10];
  const float* ln0_g = (const float*)d_in[11];
  const float* ln0_b = (const float*)d_in[12];
  const float* ln1_g = (const float*)d_in[13];
  const float* ln1_b = (const float*)d_in[14];
  const float* ln2_g = (const float*)d_in[15];
  const float* ln2_b = (const float*)d_in[16];
  const float* ln3_g = (const float*)d_in[17];
  const float* ln3_b = (const float*)d_in[18];
  const float* corr_emb = (const float*)d_in[19];
  const float* lin0_w = (const float*)d_in[20];
  const float* lin0_b = (const float*)d_in[21];
  const float* lin1_w = (const float*)d_in[22];
  const float* lin2_w = (const float*)d_in[23];
  const float* lin3_w = (const float*)d_in[24];
  const float* lin4_w = (const float*)d_in[25];
  const float* lin4_b = (const float*)d_in[26];
  const float* pos_emb = (const float*)d_in[27];
  const float* mha_wq = (const float*)d_in[28];
  const float* mha_bq = (const float*)d_in[29];
  const float* mha_wk = (const float*)d_in[30];
  const float* mha_bk = (const float*)d_in[31];
  const float* mha_wv = (const float*)d_in[32];
  const float* mha_bv = (const float*)d_in[33];
  const float* mha_wo = (const float*)d_in[34];
  const float* mha_bo = (const float*)d_in[35];
  const float* ffn0_w = (const float*)d_in[36];
  const float* ffn0_b = (const float*)d_in[37];
  const float* ffn1_w = (const float*)d_in[38];
  const float* ffn1_b = (const float*)d_in[39];
  (void)in_sizes; (void)n_in; (void)out_size;

  char* ws = (char*)d_ws;
  size_t off = 0;
  auto alloc = [&](size_t bytes) -> void* {
    void* p = ws + off;
    off += (bytes + 255) & ~(size_t)255;
    return p;
  };
  int* cnt = (int*)alloc((size_t)N_NODES * 4);
  int* row_ptr = (int*)alloc((size_t)(N_NODES + 1) * 4);
  int* fill = (int*)alloc((size_t)N_NODES * 4);
  int* locpref = (int*)alloc((size_t)N_NODES * 4);
  int* btot = (int*)alloc(64 * 4);
  int* boff = (int*)alloc(64 * 4);
  float* dis = (float*)alloc((size_t)N_NODES * 4);
  int* csr_src = (int*)alloc((size_t)N_EDGES * 4);
  const size_t WB = 128 * 128 * 2;
  u16* g0T = (u16*)alloc(WB);
  u16* g1T = (u16*)alloc(WB);
  u16* g2T = (u16*)alloc(WB);
  u16* l0T = (u16*)alloc(WB);
  u16* l3T = (u16*)alloc(WB);
  u16* woT = (u16*)alloc(WB);
  u16* f0T = (u16*)alloc(WB);
  u16* f1T = (u16*)alloc(WB);
  u16* wqT = (u16*)alloc(WB);
  u16* wkT = (u16*)alloc(WB);
  u16* wvT = (u16*)alloc(WB);
  float* c01 = (float*)alloc(2 * 128 * 4);
  u16* xb = (u16*)alloc((size_t)N_NODES * 128 * 2);
  u16* xa = (u16*)alloc((size_t)N_NODES * 128 * 2);
  u16* xw = (u16*)alloc((size_t)N_NODES * 128 * 2);
  const size_t CB = (size_t)MCH * 128 * 2;
  u16* bufQ0 = (u16*)alloc(CB);   // q (resid)
  u16* bufQ = (u16*)alloc(CB);    // qh -> ao (in place)
  u16* bufK = (u16*)alloc(CB);    // kh
  u16* bufV = (u16*)alloc(CB);    // vh
  u16* bufI = (u16*)alloc(CB);    // atn
  if (ws_size < off) return;      // diagnostic guard

  // ---- graph prep ----
  int nb = (N_NODES + 1023) / 1024;   // 49
  zero_i32_kernel<<<(N_NODES + 255) / 256, 256, 0, stream>>>(cnt, N_NODES);
  hist_kernel<<<(N_EDGES + 255) / 256, 256, 0, stream>>>(edge_index + N_EDGES, cnt, N_EDGES);
  scanA_kernel<<<nb, 1024, 0, stream>>>(cnt, locpref, btot, dis, N_NODES);
  scanB_kernel<<<1, 64, 0, stream>>>(btot, boff, nb);
  scanC_kernel<<<(N_NODES + 255) / 256, 256, 0, stream>>>(locpref, boff, row_ptr, fill, N_NODES);
  scatter_kernel<<<(N_EDGES + 255) / 256, 256, 0, stream>>>(edge_index, edge_index + N_EDGES,
                                                            fill, csr_src, N_EDGES);
  // ---- weight prep (one fused kernel) + node_x cast ----
  wprep_kernel<<<705, 256, 0, stream>>>(gcn_w0, gcn_w1, gcn_w2, lin0_w, lin3_w, mha_wo,
                                        ffn0_w, ffn1_w, lin1_w, lin2_w, mha_wq, mha_wk,
                                        mha_wv, corr_emb, g0T, g1T, g2T, l0T, l3T, woT,
                                        f0T, f1T, wqT, wkT, wvT, c01);
  f2bf8_kernel<<<(N_NODES * 128 / 8 + 255) / 256, 256, 0, stream>>>(node_x, xb, N_NODES * 16);

  int gN = (N_NODES + 63) / 64;
  int aN = (N_NODES + 3) / 4;

  // ---- GCN ----
  gemm_bf16_kernel<<<gN, 256, 0, stream>>>(xb, g0T, xw, N_NODES);
  agg_kernel<<<aN, 256, 0, stream>>>(xw, dis, row_ptr, csr_src, gcn_b0, ln0_g, ln0_b, xa, N_NODES, 1);
  gemm_bf16_kernel<<<gN, 256, 0, stream>>>(xa, g1T, xw, N_NODES);
  agg_kernel<<<aN, 256, 0, stream>>>(xw, dis, row_ptr, csr_src, gcn_b1, ln1_g, ln1_b, xa, N_NODES, 1);
  gemm_bf16_kernel<<<gN, 256, 0, stream>>>(xa, g2T, xw, N_NODES);
  agg_kernel<<<aN, 256, 0, stream>>>(xw, dis, row_ptr, csr_src, gcn_b2, nullptr, nullptr, xa, N_NODES, 0);

  // ---- transformer, 2 chunks, 5 fused dispatches each ----
  int gC = MCH / 64;   // 800
  for (int c = 0; c < NCHUNK; ++c) {
    int r0 = c * MCH;
    inter_kv_kernel<<<gC, 256, 0, stream>>>(xa, hist_seq + r0, hist_ans + r0,
                                            l0T, lin0_b, pos_emb, c01,
                                            wkT, mha_bk, wvT, mha_bv, bufK, bufV);
    q_qh_kernel<<<gC, 256, 0, stream>>>(xa, new_seq + r0, l3T, wqT, mha_bq, bufQ0, bufQ);
    attn_mfma_kernel<<<BCH * 8, 256, 0, stream>>>(bufQ, bufK, bufV);
    wo_ln_kernel<<<gC, 256, 0, stream>>>(bufQ, bufQ0, woT, mha_bo, ln2_g, ln2_b, bufI);
    ffn_kernel<<<gC, 256, 0, stream>>>(bufI, f0T, ffn0_b, f1T, ffn1_b, ln3_g, ln3_b,
                                       lin4_w, lin4_b, (float*)d_out + r0);
  }
}

// Round 7
// 668.375 us; speedup vs baseline: 2.1573x; 1.0747x over previous
//
#include <hip/hip_runtime.h>
#include <math.h>

#define N_NODES 50000
#define N_EDGES 800000
#define B_ 512
#define S_ 200
#define D_ 128
#define BS_ (B_*S_)
#define NCHUNK 2
#define BCH (B_/NCHUNK)        // 256 batch rows per chunk
#define MCH (BCH*S_)           // 51200 rows per chunk

typedef unsigned short u16;
typedef unsigned int u32;
using bfrag = __attribute__((ext_vector_type(8))) short;
using f32x4 = __attribute__((ext_vector_type(4))) float;

__device__ __forceinline__ u16 f2bf(float f) {        // RNE f32 -> bf16 bits
  u32 u = __float_as_uint(f);
  u32 r = (u + 0x7fffu + ((u >> 16) & 1u)) >> 16;
  return (u16)r;
}
__device__ __forceinline__ float bf2f(u16 v) { return __uint_as_float(((u32)v) << 16); }
__device__ __forceinline__ float bflo(u32 v) { return __uint_as_float(v << 16); }
__device__ __forceinline__ float bfhi(u32 v) { return __uint_as_float(v & 0xffff0000u); }
__device__ __forceinline__ u32 pack2(float a, float b) {
  return (u32)f2bf(a) | ((u32)f2bf(b) << 16);
}
#define MFMA16(a, b, c) __builtin_amdgcn_mfma_f32_16x16x32_bf16((a), (b), (c), 0, 0, 0)

// ---------------------------------------------------------------- utilities
__global__ void zero_i32_kernel(int* __restrict__ p, int n) {
  int i = blockIdx.x * 256 + threadIdx.x;
  if (i < n) p[i] = 0;
}

// vectorized f32 -> bf16 (8 elems/thread)
__global__ void f2bf8_kernel(const float* __restrict__ in, u16* __restrict__ out, int n8) {
  int i = blockIdx.x * 256 + threadIdx.x;
  if (i >= n8) return;
  float4 a = ((const float4*)in)[i * 2];
  float4 b = ((const float4*)in)[i * 2 + 1];
  uint4 o;
  o.x = pack2(a.x, a.y); o.y = pack2(a.z, a.w);
  o.z = pack2(b.x, b.y); o.w = pack2(b.z, b.w);
  ((uint4*)out)[i] = o;
}

// ---------------- fused weight prep: 8 transposes + 3 products + c01
__global__ __launch_bounds__(256) void wprep_kernel(
    const float* __restrict__ gcn_w0, const float* __restrict__ gcn_w1,
    const float* __restrict__ gcn_w2, const float* __restrict__ lin0_w,
    const float* __restrict__ lin3_w, const float* __restrict__ mha_wo,
    const float* __restrict__ ffn0_w, const float* __restrict__ ffn1_w,
    const float* __restrict__ lin1_w, const float* __restrict__ lin2_w,
    const float* __restrict__ mha_wq, const float* __restrict__ mha_wk,
    const float* __restrict__ mha_wv, const float* __restrict__ corr_emb,
    u16* __restrict__ g0T, u16* __restrict__ g1T, u16* __restrict__ g2T,
    u16* __restrict__ l0T, u16* __restrict__ l3T, u16* __restrict__ woT,
    u16* __restrict__ f0T, u16* __restrict__ f1T,
    u16* __restrict__ wqT, u16* __restrict__ wkT, u16* __restrict__ wvT,
    float* __restrict__ c01) {
  int bb = blockIdx.x;
  if (bb < 512) {                        // plain transpose W[k][c] -> D[c][k]
    const float* W; u16* D;
    switch (bb >> 6) {
      case 0: W = gcn_w0; D = g0T; break;
      case 1: W = gcn_w1; D = g1T; break;
      case 2: W = gcn_w2; D = g2T; break;
      case 3: W = lin0_w; D = l0T; break;
      case 4: W = lin3_w; D = l3T; break;
      case 5: W = mha_wo; D = woT; break;
      case 6: W = ffn0_w; D = f0T; break;
      default: W = ffn1_w; D = f1T; break;
    }
    int i = (bb & 63) * 256 + threadIdx.x;
    int k = i >> 7, c = i & 127;
    D[c * 128 + k] = f2bf(W[k * 128 + c]);
  } else if (bb < 704) {                 // (X@Y)^T -> D
    const float* X; const float* Y; u16* D;
    switch ((bb - 512) >> 6) {
      case 0: X = lin3_w; Y = mha_wq; D = wqT; break;
      case 1: X = lin2_w; Y = mha_wk; D = wkT; break;
      default: X = lin1_w; Y = mha_wv; D = wvT; break;
    }
    int i = ((bb - 512) & 63) * 256 + threadIdx.x;
    int k = i >> 7, c = i & 127;
    float acc = 0.f;
    for (int t = 0; t < 128; ++t) acc += X[k * 128 + t] * Y[t * 128 + c];
    D[c * 128 + k] = f2bf(acc);
  } else {                               // c01 = corr_emb @ lin0_w[128:]
    int idx = threadIdx.x;               // 0..255 = 2*128
    int i = idx >> 7, j = idx & 127;
    float acc = 0.f;
    for (int t = 0; t < 128; ++t)
      acc += corr_emb[i * 128 + t] * lin0_w[128 * 128 + t * 128 + j];
    c01[idx] = acc;
  }
}

// ---------------------------------------------------------------- graph prep
__global__ void hist_kernel(const int* __restrict__ dst, int* __restrict__ cnt, int E) {
  int e = blockIdx.x * 256 + threadIdx.x;
  if (e < E) atomicAdd(&cnt[dst[e]], 1);
}

// per-block(1024) local exclusive scan; block totals; dis fused
__global__ __launch_bounds__(1024) void scanA_kernel(
    const int* __restrict__ cnt, int* __restrict__ locpref,
    int* __restrict__ btot, float* __restrict__ dis, int N) {
  __shared__ int wsum[16];
  int t = threadIdx.x, lane = t & 63, wid = t >> 6;
  int i = blockIdx.x * 1024 + t;
  int v = (i < N) ? cnt[i] : 0;
  if (i < N) dis[i] = rsqrtf(1.f + (float)v);
  int x = v;
  #pragma unroll
  for (int off = 1; off < 64; off <<= 1) {
    int y = __shfl_up(x, off);
    if (lane >= off) x += y;
  }
  if (lane == 63) wsum[wid] = x;
  __syncthreads();
  if (wid == 0 && lane < 16) {
    int s = wsum[lane];
    #pragma unroll
    for (int off = 1; off < 16; off <<= 1) {
      int y = __shfl_up(s, off);
      if (lane >= off) s += y;
    }
    wsum[lane] = s;
  }
  __syncthreads();
  int woff = (wid > 0) ? wsum[wid - 1] : 0;
  if (i < N) locpref[i] = woff + x - v;
  if (t == 1023) btot[blockIdx.x] = woff + x;
}

// scan of block totals (nb <= 64), single wave
__global__ void scanB_kernel(const int* __restrict__ btot, int* __restrict__ boff, int nb) {
  int lane = threadIdx.x;
  int v = (lane < nb) ? btot[lane] : 0;
  int x = v;
  #pragma unroll
  for (int off = 1; off < 64; off <<= 1) {
    int y = __shfl_up(x, off);
    if (lane >= off) x += y;
  }
  if (lane < nb) boff[lane] = x - v;
}

__global__ void scanC_kernel(const int* __restrict__ locpref, const int* __restrict__ boff,
                             int* __restrict__ row_ptr, int* __restrict__ fill, int N) {
  int i = blockIdx.x * 256 + threadIdx.x;
  if (i < N) {
    int r = locpref[i] + boff[i >> 10];
    row_ptr[i] = r; fill[i] = r;
  }
  if (i == 0) row_ptr[N] = N_EDGES;
}

__global__ void scatter_kernel(const int* __restrict__ src, const int* __restrict__ dst,
                               int* __restrict__ fill, int* __restrict__ csr_src, int E) {
  int e = blockIdx.x * 256 + threadIdx.x;
  if (e >= E) return;
  int d = dst[e];
  int pos = atomicAdd(&fill[d], 1);
  csr_src[pos] = src[e];
}

// ------------------------------------------------------------ MFMA bf16 GEMM
// (GCN layers) C[M,128](bf16) = A[M,128](bf16) @ W ; wT[c][k] layout.
__global__ __launch_bounds__(256) void gemm_bf16_kernel(
    const u16* __restrict__ A, const u16* __restrict__ wT,
    u16* __restrict__ C, int M) {
  int t = threadIdx.x;
  int w = t >> 6, l = t & 63, lr = l & 15, lg = l >> 4;
  int r0 = blockIdx.x * 64 + w * 16;

  int row = r0 + lr;
  const u16* Arow = A + (size_t)(row < M ? row : 0) * 128;

  bfrag a[4];
  #pragma unroll
  for (int ks = 0; ks < 4; ++ks) a[ks] = *(const bfrag*)(Arow + ks * 32 + lg * 8);

  f32x4 acc[8];
  #pragma unroll
  for (int ct = 0; ct < 8; ++ct) acc[ct] = (f32x4){0.f, 0.f, 0.f, 0.f};
  #pragma unroll
  for (int ks = 0; ks < 4; ++ks)
    #pragma unroll
    for (int ct = 0; ct < 8; ++ct) {
      bfrag b = *(const bfrag*)(wT + (size_t)(ct * 16 + lr) * 128 + ks * 32 + lg * 8);
      acc[ct] = MFMA16(a[ks], b, acc[ct]);
    }
  #pragma unroll
  for (int ct = 0; ct < 8; ++ct)
    #pragma unroll
    for (int i = 0; i < 4; ++i) {
      int r = r0 + lg * 4 + i;
      if (r < M) C[(size_t)r * 128 + ct * 16 + lr] = f2bf(acc[ct][i]);
    }
}

// ------------------------------------------------------------- GCN aggregate
// wave per node; lane: colgrp=l&15 (8 cols, dwordx4), edgegrp=l>>4 (4 edges in flight)
__global__ __launch_bounds__(256) void agg_kernel(
    const u16* __restrict__ xw, const float* __restrict__ dis,
    const int* __restrict__ row_ptr, const int* __restrict__ csr_src,
    const float* __restrict__ bias, const float* __restrict__ lng,
    const float* __restrict__ lnb, u16* __restrict__ out, int N, int doLN) {
  int t = threadIdx.x;
  int n = blockIdx.x * 4 + (t >> 6);
  if (n >= N) return;
  int l = t & 63, cg = l & 15, eg = l >> 4;
  float dn = dis[n];
  float acc[8] = {0.f, 0.f, 0.f, 0.f, 0.f, 0.f, 0.f, 0.f};
  if (eg == 0) {
    uint4 r = *(const uint4*)(xw + (size_t)n * 128 + cg * 8);
    float w = dn * dn;
    acc[0] += w * bflo(r.x); acc[1] += w * bfhi(r.x);
    acc[2] += w * bflo(r.y); acc[3] += w * bfhi(r.y);
    acc[4] += w * bflo(r.z); acc[5] += w * bfhi(r.z);
    acc[6] += w * bflo(r.w); acc[7] += w * bfhi(r.w);
  }
  int e1 = row_ptr[n + 1];
  int e = row_ptr[n] + eg;
  int sn = (e < e1) ? csr_src[e] : -1;       // software-pipelined index prefetch
  while (sn >= 0) {
    int s = sn;
    e += 4;
    sn = (e < e1) ? csr_src[e] : -1;
    float w = dis[s] * dn;
    uint4 r = *(const uint4*)(xw + (size_t)s * 128 + cg * 8);
    acc[0] += w * bflo(r.x); acc[1] += w * bfhi(r.x);
    acc[2] += w * bflo(r.y); acc[3] += w * bfhi(r.y);
    acc[4] += w * bflo(r.z); acc[5] += w * bfhi(r.z);
    acc[6] += w * bflo(r.w); acc[7] += w * bfhi(r.w);
  }
  #pragma unroll
  for (int j = 0; j < 8; ++j) {
    acc[j] += __shfl_xor(acc[j], 16);
    acc[j] += __shfl_xor(acc[j], 32);
  }
  int c0 = cg * 8;
  #pragma unroll
  for (int j = 0; j < 8; ++j) acc[j] = fmaxf(acc[j] + bias[c0 + j], 0.f);
  if (doLN) {
    float s1 = 0.f, s2 = 0.f;
    #pragma unroll
    for (int j = 0; j < 8; ++j) { s1 += acc[j]; s2 += acc[j] * acc[j]; }
    #pragma unroll
    for (int off = 1; off < 16; off <<= 1) {
      s1 += __shfl_xor(s1, off);
      s2 += __shfl_xor(s2, off);
    }
    float mean = s1 * (1.f / 128.f);
    float var = s2 * (1.f / 128.f) - mean * mean;
    float inv = rsqrtf(var + 1e-5f);
    #pragma unroll
    for (int j = 0; j < 8; ++j)
      acc[j] = (acc[j] - mean) * inv * lng[c0 + j] + lnb[c0 + j];
  }
  if (eg == 0) {
    uint4 o;
    o.x = pack2(acc[0], acc[1]); o.y = pack2(acc[2], acc[3]);
    o.z = pack2(acc[4], acc[5]); o.w = pack2(acc[6], acc[7]);
    *(uint4*)(out + (size_t)n * 128 + cg * 8) = o;
  }
}

// ------------------------------------------------- fused gather -> q and qh
// qout: row-major [r][128]; qhout: head-major [h][MCH][16]
__global__ __launch_bounds__(256) void q_qh_kernel(
    const u16* __restrict__ xa, const int* __restrict__ gidx,
    const u16* __restrict__ l3T, const u16* __restrict__ wqT,
    const float* __restrict__ bq,
    u16* __restrict__ qout, u16* __restrict__ qhout) {
  int t = threadIdx.x, w = t >> 6, l = t & 63, lr = l & 15, lg = l >> 4;
  int r0 = blockIdx.x * 64 + w * 16;
  int arow = gidx[r0 + lr];
  const u16* Arow = xa + (size_t)arow * 128;
  bfrag a[4];
  #pragma unroll
  for (int ks = 0; ks < 4; ++ks) a[ks] = *(const bfrag*)(Arow + ks * 32 + lg * 8);

  f32x4 acc[8];
  #pragma unroll
  for (int ct = 0; ct < 8; ++ct) acc[ct] = (f32x4){0.f, 0.f, 0.f, 0.f};
  #pragma unroll
  for (int ks = 0; ks < 4; ++ks)
    #pragma unroll
    for (int ct = 0; ct < 8; ++ct) {
      bfrag b = *(const bfrag*)(l3T + (size_t)(ct * 16 + lr) * 128 + ks * 32 + lg * 8);
      acc[ct] = MFMA16(a[ks], b, acc[ct]);
    }
  #pragma unroll
  for (int ct = 0; ct < 8; ++ct)
    #pragma unroll
    for (int i = 0; i < 4; ++i)
      qout[(size_t)(r0 + lg * 4 + i) * 128 + ct * 16 + lr] = f2bf(acc[ct][i]);

  #pragma unroll
  for (int ct = 0; ct < 8; ++ct) acc[ct] = (f32x4){0.f, 0.f, 0.f, 0.f};
  #pragma unroll
  for (int ks = 0; ks < 4; ++ks)
    #pragma unroll
    for (int ct = 0; ct < 8; ++ct) {
      bfrag b = *(const bfrag*)(wqT + (size_t)(ct * 16 + lr) * 128 + ks * 32 + lg * 8);
      acc[ct] = MFMA16(a[ks], b, acc[ct]);
    }
  #pragma unroll
  for (int ct = 0; ct < 8; ++ct)
    #pragma unroll
    for (int i = 0; i < 4; ++i)
      qhout[((size_t)ct * MCH + r0 + lg * 4 + i) * 16 + lr] =
          f2bf(acc[ct][i] + bq[ct * 16 + lr]);
}

// ---------------------------- fused gather -> inter(LDS) -> kh, vh (head-major)
__global__ __launch_bounds__(256) void inter_kv_kernel(
    const u16* __restrict__ xa, const int* __restrict__ hist, const int* __restrict__ ans,
    const u16* __restrict__ l0T, const float* __restrict__ lin0_b,
    const float* __restrict__ pos_emb, const float* __restrict__ c01,
    const u16* __restrict__ wkT, const float* __restrict__ bk,
    const u16* __restrict__ wvT, const float* __restrict__ bv,
    u16* __restrict__ khout, u16* __restrict__ vhout) {
  __shared__ u16 interl[4][16 * 136];
  int t = threadIdx.x, w = t >> 6, l = t & 63, lr = l & 15, lg = l >> 4;
  int r0 = blockIdx.x * 64 + w * 16;
  int arow = hist[r0 + lr];
  const u16* Arow = xa + (size_t)arow * 128;
  bfrag a[4];
  #pragma unroll
  for (int ks = 0; ks < 4; ++ks) a[ks] = *(const bfrag*)(Arow + ks * 32 + lg * 8);

  f32x4 acc[8];
  #pragma unroll
  for (int ct = 0; ct < 8; ++ct) acc[ct] = (f32x4){0.f, 0.f, 0.f, 0.f};
  #pragma unroll
  for (int ks = 0; ks < 4; ++ks)
    #pragma unroll
    for (int ct = 0; ct < 8; ++ct) {
      bfrag b = *(const bfrag*)(l0T + (size_t)(ct * 16 + lr) * 128 + ks * 32 + lg * 8);
      acc[ct] = MFMA16(a[ks], b, acc[ct]);
    }
  // epilogue: + lin0_b + pos_emb[r%S] + c01[ans[r]]  -> interl (bf16)
  int posr[4], ansr[4];
  #pragma unroll
  for (int i = 0; i < 4; ++i) {
    int r = r0 + lg * 4 + i;
    posr[i] = r % S_;
    ansr[i] = ans[r];
  }
  #pragma unroll
  for (int ct = 0; ct < 8; ++ct) {
    int col = ct * 16 + lr;
    float bcol = lin0_b[col];
    #pragma unroll
    for (int i = 0; i < 4; ++i) {
      float v = acc[ct][i] + bcol + pos_emb[(size_t)posr[i] * 128 + col]
                + c01[ansr[i] * 128 + col];
      interl[w][(lg * 4 + i) * 136 + col] = f2bf(v);
    }
  }
  // second stage: kh, vh from interl (per-wave private)
  bfrag a2[4];
  #pragma unroll
  for (int ks = 0; ks < 4; ++ks)
    a2[ks] = *(const bfrag*)(&interl[w][lr * 136 + ks * 32 + lg * 8]);

  #pragma unroll
  for (int ct = 0; ct < 8; ++ct) acc[ct] = (f32x4){0.f, 0.f, 0.f, 0.f};
  #pragma unroll
  for (int ks = 0; ks < 4; ++ks)
    #pragma unroll
    for (int ct = 0; ct < 8; ++ct) {
      bfrag b = *(const bfrag*)(wkT + (size_t)(ct * 16 + lr) * 128 + ks * 32 + lg * 8);
      acc[ct] = MFMA16(a2[ks], b, acc[ct]);
    }
  #pragma unroll
  for (int ct = 0; ct < 8; ++ct)
    #pragma unroll
    for (int i = 0; i < 4; ++i)
      khout[((size_t)ct * MCH + r0 + lg * 4 + i) * 16 + lr] =
          f2bf(acc[ct][i] + bk[ct * 16 + lr]);

  #pragma unroll
  for (int ct = 0; ct < 8; ++ct) acc[ct] = (f32x4){0.f, 0.f, 0.f, 0.f};
  #pragma unroll
  for (int ks = 0; ks < 4; ++ks)
    #pragma unroll
    for (int ct = 0; ct < 8; ++ct) {
      bfrag b = *(const bfrag*)(wvT + (size_t)(ct * 16 + lr) * 128 + ks * 32 + lg * 8);
      acc[ct] = MFMA16(a2[ks], b, acc[ct]);
    }
  #pragma unroll
  for (int ct = 0; ct < 8; ++ct)
    #pragma unroll
    for (int i = 0; i < 4; ++i)
      vhout[((size_t)ct * MCH + r0 + lg * 4 + i) * 16 + lr] =
          f2bf(acc[ct][i] + bv[ct * 16 + lr]);
}

// ----------------------------------------------------------- MFMA attention
// block = (b,h); head-major inputs [h][MCH][16]; ao output head-major too.
__global__ __launch_bounds__(256) void attn_mfma_kernel(
    const u16* __restrict__ qh, const u16* __restrict__ kh,
    const u16* __restrict__ vh, u16* __restrict__ ao) {
  __shared__ u16 Kl[208 * 24];        // [key][d0..15], pad stride 24
  __shared__ u16 Vt[16 * 232];        // [d][key], keys>=200 zero
  __shared__ u16 Pl[4 * 16 * 232];    // per-wave P (bf16), zero-init
  int b = blockIdx.x >> 3, h = blockIdx.x & 7;
  int t = threadIdx.x;
  size_t base = ((size_t)h * MCH + (size_t)b * S_) * 16;

  // stage K: contiguous 200*16 u16 -> Kl[key*24+d]; rows 200..207 zeroed
  for (int i = t; i < 208 * 2; i += 256) {
    int key = i >> 1, d = (i & 1) * 8;
    uint4 v = make_uint4(0, 0, 0, 0);
    if (key < S_) v = *(const uint4*)(kh + base + (size_t)key * 16 + d);
    *(uint4*)(Kl + key * 24 + d) = v;
  }
  // stage V transposed: Vt[d][key], keys >= 200 zero
  for (int i = t; i < 16 * 232; i += 256) {
    int d = i / 232, key = i - d * 232;
    Vt[d * 232 + key] = (key < S_) ? vh[base + (size_t)key * 16 + d] : (u16)0;
  }
  for (int i = t; i < 4 * 16 * 232 / 2; i += 256) ((u32*)Pl)[i] = 0;
  __syncthreads();

  int w = t >> 6, l = t & 63, lr = l & 15, lg = l >> 4;
  u16* Pw = Pl + w * 16 * 232;
  const f32x4 zero4 = {0.f, 0.f, 0.f, 0.f};

  for (int qi = w; qi < 13; qi += 4) {
    bfrag aq = (bfrag){0, 0, 0, 0, 0, 0, 0, 0};
    int qrow = qi * 16 + lr;
    if (lg < 2 && qrow < S_)
      aq = *(const bfrag*)(qh + base + (size_t)qrow * 16 + lg * 8);
    float rsum[4] = {0.f, 0.f, 0.f, 0.f};
    for (int kj = 0; kj <= qi; ++kj) {
      bfrag bk = (bfrag){0, 0, 0, 0, 0, 0, 0, 0};
      if (lg < 2) bk = *(const bfrag*)(Kl + (kj * 16 + lr) * 24 + lg * 8);
      f32x4 sc = MFMA16(aq, bk, zero4);
      #pragma unroll
      for (int i = 0; i < 4; ++i) {
        int q = qi * 16 + lg * 4 + i, key = kj * 16 + lr;
        float p = 0.f;
        if (key <= q && q < S_) p = __expf(sc[i] * 0.25f);
        rsum[i] += p;
        Pw[(lg * 4 + i) * 232 + key] = f2bf(p);
      }
    }
    #pragma unroll
    for (int i = 0; i < 4; ++i) {
      rsum[i] += __shfl_xor(rsum[i], 1);
      rsum[i] += __shfl_xor(rsum[i], 2);
      rsum[i] += __shfl_xor(rsum[i], 4);
      rsum[i] += __shfl_xor(rsum[i], 8);
    }
    f32x4 o = zero4;
    #pragma unroll
    for (int kt = 0; kt < 7; ++kt) {
      bfrag ap = *(const bfrag*)(Pw + lr * 232 + kt * 32 + lg * 8);
      bfrag bv = *(const bfrag*)(Vt + lr * 232 + kt * 32 + lg * 8);
      o = MFMA16(ap, bv, o);
    }
    #pragma unroll
    for (int i = 0; i < 4; ++i) {
      int q = qi * 16 + lg * 4 + i;
      if (q < S_) ao[base + (size_t)q * 16 + lr] = f2bf(o[i] / rsum[i]);
    }
  }
}

// ------------------------------------- fused ao@wo + bo + resid(q) -> LN2
// ao is head-major [h][MCH][16]; qres row-major [r][128].
__global__ __launch_bounds__(256) void wo_ln_kernel(
    const u16* __restrict__ ao, const u16* __restrict__ qres,
    const u16* __restrict__ woT, const float* __restrict__ bo,
    const float* __restrict__ g, const float* __restrict__ bb,
    u16* __restrict__ atn) {
  int t = threadIdx.x, w = t >> 6, l = t & 63, lr = l & 15, lg = l >> 4;
  int r0 = blockIdx.x * 64 + w * 16;
  bfrag a[4];
  #pragma unroll
  for (int ks = 0; ks < 4; ++ks) {
    int head = ks * 2 + (lg >> 1);
    int d0 = (lg & 1) * 8;
    a[ks] = *(const bfrag*)(ao + ((size_t)head * MCH + r0 + lr) * 16 + d0);
  }

  f32x4 acc[8];
  #pragma unroll
  for (int ct = 0; ct < 8; ++ct) acc[ct] = (f32x4){0.f, 0.f, 0.f, 0.f};
  #pragma unroll
  for (int ks = 0; ks < 4; ++ks)
    #pragma unroll
    for (int ct = 0; ct < 8; ++ct) {
      bfrag b = *(const bfrag*)(woT + (size_t)(ct * 16 + lr) * 128 + ks * 32 + lg * 8);
      acc[ct] = MFMA16(a[ks], b, acc[ct]);
    }
  // + bo + resid
  #pragma unroll
  for (int ct = 0; ct < 8; ++ct) {
    int col = ct * 16 + lr;
    float bcol = bo[col];
    #pragma unroll
    for (int i = 0; i < 4; ++i)
      acc[ct][i] += bcol + bf2f(qres[(size_t)(r0 + lg * 4 + i) * 128 + col]);
  }
  // LN per row
  float s1[4] = {0, 0, 0, 0}, s2[4] = {0, 0, 0, 0};
  #pragma unroll
  for (int ct = 0; ct < 8; ++ct)
    #pragma unroll
    for (int i = 0; i < 4; ++i) {
      s1[i] += acc[ct][i];
      s2[i] += acc[ct][i] * acc[ct][i];
    }
  #pragma unroll
  for (int i = 0; i < 4; ++i) {
    s1[i] += __shfl_xor(s1[i], 1); s2[i] += __shfl_xor(s2[i], 1);
    s1[i] += __shfl_xor(s1[i], 2); s2[i] += __shfl_xor(s2[i], 2);
    s1[i] += __shfl_xor(s1[i], 4); s2[i] += __shfl_xor(s2[i], 4);
    s1[i] += __shfl_xor(s1[i], 8); s2[i] += __shfl_xor(s2[i], 8);
  }
  float mean[4], inv[4];
  #pragma unroll
  for (int i = 0; i < 4; ++i) {
    mean[i] = s1[i] * (1.f / 128.f);
    float var = s2[i] * (1.f / 128.f) - mean[i] * mean[i];
    inv[i] = rsqrtf(var + 1e-5f);
  }
  #pragma unroll
  for (int ct = 0; ct < 8; ++ct) {
    int col = ct * 16 + lr;
    float gc = g[col], bc = bb[col];
    #pragma unroll
    for (int i = 0; i < 4; ++i)
      atn[(size_t)(r0 + lg * 4 + i) * 128 + col] =
          f2bf((acc[ct][i] - mean[i]) * inv[i] * gc + bc);
  }
}

// --------------------- fused FFN: relu(atn@f0+b0)@f1 + b1 + atn -> LN3 -> pred
__global__ __launch_bounds__(256) void ffn_kernel(
    const u16* __restrict__ atn, const u16* __restrict__ f0T,
    const float* __restrict__ b0, const u16* __restrict__ f1T,
    const float* __restrict__ b1, const float* __restrict__ g,
    const float* __restrict__ bb, const float* __restrict__ w4,
    const float* __restrict__ b4, float* __restrict__ pred) {
  __shared__ u16 f1l[4][16 * 136];
  int t = threadIdx.x, w = t >> 6, l = t & 63, lr = l & 15, lg = l >> 4;
  int r0 = blockIdx.x * 64 + w * 16;
  const u16* Arow = atn + (size_t)(r0 + lr) * 128;
  bfrag a[4];
  #pragma unroll
  for (int ks = 0; ks < 4; ++ks) a[ks] = *(const bfrag*)(Arow + ks * 32 + lg * 8);

  f32x4 acc[8];
  #pragma unroll
  for (int ct = 0; ct < 8; ++ct) acc[ct] = (f32x4){0.f, 0.f, 0.f, 0.f};
  #pragma unroll
  for (int ks = 0; ks < 4; ++ks)
    #pragma unroll
    for (int ct = 0; ct < 8; ++ct) {
      bfrag b = *(const bfrag*)(f0T + (size_t)(ct * 16 + lr) * 128 + ks * 32 + lg * 8);
      acc[ct] = MFMA16(a[ks], b, acc[ct]);
    }
  #pragma unroll
  for (int ct = 0; ct < 8; ++ct) {
    int col = ct * 16 + lr;
    float bcol = b0[col];
    #pragma unroll
    for (int i = 0; i < 4; ++i)
      f1l[w][(lg * 4 + i) * 136 + col] = f2bf(fmaxf(acc[ct][i] + bcol, 0.f));
  }
  bfrag a2[4];
  #pragma unroll
  for (int ks = 0; ks < 4; ++ks)
    a2[ks] = *(const bfrag*)(&f1l[w][lr * 136 + ks * 32 + lg * 8]);

  #pragma unroll
  for (int ct = 0; ct < 8; ++ct) acc[ct] = (f32x4){0.f, 0.f, 0.f, 0.f};
  #pragma unroll
  for (int ks = 0; ks < 4; ++ks)
    #pragma unroll
    for (int ct = 0; ct < 8; ++ct) {
      bfrag b = *(const bfrag*)(f1T + (size_t)(ct * 16 + lr) * 128 + ks * 32 + lg * 8);
      acc[ct] = MFMA16(a2[ks], b, acc[ct]);
    }
  // + b1 + resid(atn)
  #pragma unroll
  for (int ct = 0; ct < 8; ++ct) {
    int col = ct * 16 + lr;
    float bcol = b1[col];
    #pragma unroll
    for (int i = 0; i < 4; ++i)
      acc[ct][i] += bcol + bf2f(atn[(size_t)(r0 + lg * 4 + i) * 128 + col]);
  }
  // LN3
  float s1[4] = {0, 0, 0, 0}, s2[4] = {0, 0, 0, 0};
  #pragma unroll
  for (int ct = 0; ct < 8; ++ct)
    #pragma unroll
    for (int i = 0; i < 4; ++i) {
      s1[i] += acc[ct][i];
      s2[i] += acc[ct][i] * acc[ct][i];
    }
  #pragma unroll
  for (int i = 0; i < 4; ++i) {
    s1[i] += __shfl_xor(s1[i], 1); s2[i] += __shfl_xor(s2[i], 1);
    s1[i] += __shfl_xor(s1[i], 2); s2[i] += __shfl_xor(s2[i], 2);
    s1[i] += __shfl_xor(s1[i], 4); s2[i] += __shfl_xor(s2[i], 4);
    s1[i] += __shfl_xor(s1[i], 8); s2[i] += __shfl_xor(s2[i], 8);
  }
  float p[4] = {0, 0, 0, 0};
  #pragma unroll
  for (int i = 0; i < 4; ++i) {
    float mean = s1[i] * (1.f / 128.f);
    float var = s2[i] * (1.f / 128.f) - mean * mean;
    float inv = rsqrtf(var + 1e-5f);
    #pragma unroll
    for (int ct = 0; ct < 8; ++ct) {
      int col = ct * 16 + lr;
      p[i] += ((acc[ct][i] - mean) * inv * g[col] + bb[col]) * w4[col];
    }
  }
  #pragma unroll
  for (int i = 0; i < 4; ++i) {
    p[i] += __shfl_xor(p[i], 1);
    p[i] += __shfl_xor(p[i], 2);
    p[i] += __shfl_xor(p[i], 4);
    p[i] += __shfl_xor(p[i], 8);
  }
  if (lr == 0) {
    float bias4 = b4[0];
    #pragma unroll
    for (int i = 0; i < 4; ++i) pred[r0 + lg * 4 + i] = p[i] + bias4;
  }
}

// ---------------------------------------------------------------------------
extern "C" void kernel_launch(void* const* d_in, const int* in_sizes, int n_in,
                              void* d_out, int out_size, void* d_ws, size_t ws_size,
                              hipStream_t stream) {
  const int* hist_seq = (const int*)d_in[0];
  const int* hist_ans = (const int*)d_in[1];
  const int* new_seq = (const int*)d_in[2];
  const int* edge_index = (const int*)d_in[3];
  const float* node_x = (const float*)d_in[4];
  const float* gcn_w0 = (const float*)d_in[5];
  const float* gcn_b0 = (const float*)d_in[6];
  const float* gcn_w1 = (const float*)d_in[7];
  const float* gcn_b1 = (const float*)d_in[8];
  const float* gcn_w2 = (const float*)d_in[9];
  const float* gcn_b2 = (const float*)d_in[10];
  const float* ln0_g = (const float*)d_in[11];
  const float* ln0_b = (const float*)d_in[12];
  const float* ln1_g = (const float*)d_in[13];
  const float* ln1_b = (const float*)d_in[14];
  const float* ln2_g = (const float*)d_in[15];
  const float* ln2_b = (const float*)d_in[16];
  const float* ln3_g = (const float*)d_in[17];
  const float* ln3_b = (const float*)d_in[18];
  const float* corr_emb = (const float*)d_in[19];
  const float* lin0_w = (const float*)d_in[20];
  const float* lin0_b = (const float*)d_in[21];
  const float* lin1_w = (const float*)d_in[22];
  const float* lin2_w = (const float*)d_in[23];
  const float* lin3_w = (const float*)d_in[24];
  const float* lin4_w = (const float*)d_in[25];
  const float* lin4_b = (const float*)d_in[26];
  const float* pos_emb = (const float*)d_in[27];
  const float* mha_wq = (const float*)d_in[28];
  const float* mha_bq = (const float*)d_in[29];
  const float* mha_wk = (const float*)d_in[30];
  const float* mha_bk = (const float*)d_in[31];
  const float* mha_wv = (const float*)d_in[32];
  const float* mha_bv = (const float*)d_in[33];
  const float* mha_wo = (const float*)d_in[34];
  const float* mha_bo = (const float*)d_in[35];
  const float* ffn0_w = (const float*)d_in[36];
  const float* ffn0_b = (const float*)d_in[37];
  const float* ffn1_w = (const float*)d_in[38];
  const float* ffn1_b = (const float*)d_in[39];
  (void)in_sizes; (void)n_in; (void)out_size;

  char* ws = (char*)d_ws;
  size_t off = 0;
  auto alloc = [&](size_t bytes) -> void* {
    void* p = ws + off;
    off += (bytes + 255) & ~(size_t)255;
    return p;
  };
  int* cnt = (int*)alloc((size_t)N_NODES * 4);
  int* row_ptr = (int*)alloc((size_t)(N_NODES + 1) * 4);
  int* fill = (int*)alloc((size_t)N_NODES * 4);
  int* locpref = (int*)alloc((size_t)N_NODES * 4);
  int* btot = (int*)alloc(64 * 4);
  int* boff = (int*)alloc(64 * 4);
  float* dis = (float*)alloc((size_t)N_NODES * 4);
  int* csr_src = (int*)alloc((size_t)N_EDGES * 4);
  const size_t WB = 128 * 128 * 2;
  u16* g0T = (u16*)alloc(WB);
  u16* g1T = (u16*)alloc(WB);
  u16* g2T = (u16*)alloc(WB);
  u16* l0T = (u16*)alloc(WB);
  u16* l3T = (u16*)alloc(WB);
  u16* woT = (u16*)alloc(WB);
  u16* f0T = (u16*)alloc(WB);
  u16* f1T = (u16*)alloc(WB);
  u16* wqT = (u16*)alloc(WB);
  u16* wkT = (u16*)alloc(WB);
  u16* wvT = (u16*)alloc(WB);
  float* c01 = (float*)alloc(2 * 128 * 4);
  u16* xb = (u16*)alloc((size_t)N_NODES * 128 * 2);
  u16* xa = (u16*)alloc((size_t)N_NODES * 128 * 2);
  u16* xw = (u16*)alloc((size_t)N_NODES * 128 * 2);
  const size_t CB = (size_t)MCH * 128 * 2;
  u16* bufQ0 = (u16*)alloc(CB);   // q (resid), row-major
  u16* bufQ = (u16*)alloc(CB);    // qh, head-major
  u16* bufK = (u16*)alloc(CB);    // kh, head-major
  u16* bufV = (u16*)alloc(CB);    // vh, head-major
  u16* bufA = (u16*)alloc(CB);    // ao, head-major
  u16* bufI = (u16*)alloc(CB);    // atn, row-major
  if (ws_size < off) return;      // diagnostic guard

  // ---- graph prep ----
  int nb = (N_NODES + 1023) / 1024;   // 49
  zero_i32_kernel<<<(N_NODES + 255) / 256, 256, 0, stream>>>(cnt, N_NODES);
  hist_kernel<<<(N_EDGES + 255) / 256, 256, 0, stream>>>(edge_index + N_EDGES, cnt, N_EDGES);
  scanA_kernel<<<nb, 1024, 0, stream>>>(cnt, locpref, btot, dis, N_NODES);
  scanB_kernel<<<1, 64, 0, stream>>>(btot, boff, nb);
  scanC_kernel<<<(N_NODES + 255) / 256, 256, 0, stream>>>(locpref, boff, row_ptr, fill, N_NODES);
  scatter_kernel<<<(N_EDGES + 255) / 256, 256, 0, stream>>>(edge_index, edge_index + N_EDGES,
                                                            fill, csr_src, N_EDGES);
  // ---- weight prep (one fused kernel) + node_x cast ----
  wprep_kernel<<<705, 256, 0, stream>>>(gcn_w0, gcn_w1, gcn_w2, lin0_w, lin3_w, mha_wo,
                                        ffn0_w, ffn1_w, lin1_w, lin2_w, mha_wq, mha_wk,
                                        mha_wv, corr_emb, g0T, g1T, g2T, l0T, l3T, woT,
                                        f0T, f1T, wqT, wkT, wvT, c01);
  f2bf8_kernel<<<(N_NODES * 128 / 8 + 255) / 256, 256, 0, stream>>>(node_x, xb, N_NODES * 16);

  int gN = (N_NODES + 63) / 64;
  int aN = (N_NODES + 3) / 4;

  // ---- GCN ----
  gemm_bf16_kernel<<<gN, 256, 0, stream>>>(xb, g0T, xw, N_NODES);
  agg_kernel<<<aN, 256, 0, stream>>>(xw, dis, row_ptr, csr_src, gcn_b0, ln0_g, ln0_b, xa, N_NODES, 1);
  gemm_bf16_kernel<<<gN, 256, 0, stream>>>(xa, g1T, xw, N_NODES);
  agg_kernel<<<aN, 256, 0, stream>>>(xw, dis, row_ptr, csr_src, gcn_b1, ln1_g, ln1_b, xa, N_NODES, 1);
  gemm_bf16_kernel<<<gN, 256, 0, stream>>>(xa, g2T, xw, N_NODES);
  agg_kernel<<<aN, 256, 0, stream>>>(xw, dis, row_ptr, csr_src, gcn_b2, nullptr, nullptr, xa, N_NODES, 0);

  // ---- transformer, 2 chunks, 5 fused dispatches each ----
  int gC = MCH / 64;   // 800
  for (int c = 0; c < NCHUNK; ++c) {
    int r0 = c * MCH;
    inter_kv_kernel<<<gC, 256, 0, stream>>>(xa, hist_seq + r0, hist_ans + r0,
                                            l0T, lin0_b, pos_emb, c01,
                                            wkT, mha_bk, wvT, mha_bv, bufK, bufV);
    q_qh_kernel<<<gC, 256, 0, stream>>>(xa, new_seq + r0, l3T, wqT, mha_bq, bufQ0, bufQ);
    attn_mfma_kernel<<<BCH * 8, 256, 0, stream>>>(bufQ, bufK, bufV, bufA);
    wo_ln_kernel<<<gC, 256, 0, stream>>>(bufA, bufQ0, woT, mha_bo, ln2_g, ln2_b, bufI);
    ffn_kernel<<<gC, 256, 0, stream>>>(bufI, f0T, ffn0_b, f1T, ffn1_b, ln3_g, ln3_b,
                                       lin4_w, lin4_b, (float*)d_out + r0);
  }
}

// Round 8
// 613.419 us; speedup vs baseline: 2.3506x; 1.0896x over previous
//
#include <hip/hip_runtime.h>
#include <math.h>

#define N_NODES 50000
#define N_EDGES 800000
#define B_ 512
#define S_ 200
#define D_ 128
#define BS_ (B_*S_)            // 102400 rows, full batch

typedef unsigned short u16;
typedef unsigned int u32;
using bfrag = __attribute__((ext_vector_type(8))) short;
using f32x4 = __attribute__((ext_vector_type(4))) float;

__device__ __forceinline__ u16 f2bf(float f) {        // RNE f32 -> bf16 bits
  u32 u = __float_as_uint(f);
  u32 r = (u + 0x7fffu + ((u >> 16) & 1u)) >> 16;
  return (u16)r;
}
__device__ __forceinline__ float bf2f(u16 v) { return __uint_as_float(((u32)v) << 16); }
__device__ __forceinline__ float bflo(u32 v) { return __uint_as_float(v << 16); }
__device__ __forceinline__ float bfhi(u32 v) { return __uint_as_float(v & 0xffff0000u); }
__device__ __forceinline__ u32 pack2(float a, float b) {
  return (u32)f2bf(a) | ((u32)f2bf(b) << 16);
}
#define MFMA16(a, b, c) __builtin_amdgcn_mfma_f32_16x16x32_bf16((a), (b), (c), 0, 0, 0)

// ---------------------------------------------------------------- utilities
__global__ void zero_i32_kernel(int* __restrict__ p, int n) {
  int i = blockIdx.x * 256 + threadIdx.x;
  if (i < n) p[i] = 0;
}

__global__ void f2bf8_kernel(const float* __restrict__ in, u16* __restrict__ out, int n8) {
  int i = blockIdx.x * 256 + threadIdx.x;
  if (i >= n8) return;
  float4 a = ((const float4*)in)[i * 2];
  float4 b = ((const float4*)in)[i * 2 + 1];
  uint4 o;
  o.x = pack2(a.x, a.y); o.y = pack2(a.z, a.w);
  o.z = pack2(b.x, b.y); o.w = pack2(b.z, b.w);
  ((uint4*)out)[i] = o;
}

// ---------------- fused weight prep: 8 transposes + 3 products + c01
__global__ __launch_bounds__(256) void wprep_kernel(
    const float* __restrict__ gcn_w0, const float* __restrict__ gcn_w1,
    const float* __restrict__ gcn_w2, const float* __restrict__ lin0_w,
    const float* __restrict__ lin3_w, const float* __restrict__ mha_wo,
    const float* __restrict__ ffn0_w, const float* __restrict__ ffn1_w,
    const float* __restrict__ lin1_w, const float* __restrict__ lin2_w,
    const float* __restrict__ mha_wq, const float* __restrict__ mha_wk,
    const float* __restrict__ mha_wv, const float* __restrict__ corr_emb,
    u16* __restrict__ g0T, u16* __restrict__ g1T, u16* __restrict__ g2T,
    u16* __restrict__ l0T, u16* __restrict__ l3T, u16* __restrict__ woT,
    u16* __restrict__ f0T, u16* __restrict__ f1T,
    u16* __restrict__ wqT, u16* __restrict__ wkT, u16* __restrict__ wvT,
    float* __restrict__ c01) {
  int bb = blockIdx.x;
  if (bb < 512) {                        // plain transpose W[k][c] -> D[c][k]
    const float* W; u16* D;
    switch (bb >> 6) {
      case 0: W = gcn_w0; D = g0T; break;
      case 1: W = gcn_w1; D = g1T; break;
      case 2: W = gcn_w2; D = g2T; break;
      case 3: W = lin0_w; D = l0T; break;
      case 4: W = lin3_w; D = l3T; break;
      case 5: W = mha_wo; D = woT; break;
      case 6: W = ffn0_w; D = f0T; break;
      default: W = ffn1_w; D = f1T; break;
    }
    int i = (bb & 63) * 256 + threadIdx.x;
    int k = i >> 7, c = i & 127;
    D[c * 128 + k] = f2bf(W[k * 128 + c]);
  } else if (bb < 704) {                 // (X@Y)^T -> D
    const float* X; const float* Y; u16* D;
    switch ((bb - 512) >> 6) {
      case 0: X = lin3_w; Y = mha_wq; D = wqT; break;
      case 1: X = lin2_w; Y = mha_wk; D = wkT; break;
      default: X = lin1_w; Y = mha_wv; D = wvT; break;
    }
    int i = ((bb - 512) & 63) * 256 + threadIdx.x;
    int k = i >> 7, c = i & 127;
    float acc = 0.f;
    for (int t = 0; t < 128; ++t) acc += X[k * 128 + t] * Y[t * 128 + c];
    D[c * 128 + k] = f2bf(acc);
  } else {                               // c01 = corr_emb @ lin0_w[128:]
    int idx = threadIdx.x;               // 0..255 = 2*128
    int i = idx >> 7, j = idx & 127;
    float acc = 0.f;
    for (int t = 0; t < 128; ++t)
      acc += corr_emb[i * 128 + t] * lin0_w[128 * 128 + t * 128 + j];
    c01[idx] = acc;
  }
}

// pc[a][s][c] = lin0_b[c] + pos_emb[s][c] + c01[a][c]   (2*200*128 f32)
__global__ void pc_kernel(const float* __restrict__ lin0_b, const float* __restrict__ pos_emb,
                          const float* __restrict__ c01, float* __restrict__ pc) {
  int i = blockIdx.x * 256 + threadIdx.x;   // 51200
  int c = i & 127, s = (i >> 7) % S_, a = i / (128 * S_);
  pc[i] = lin0_b[c] + pos_emb[s * 128 + c] + c01[a * 128 + c];
}

// ---------------------------------------------------------------- graph prep
__global__ void hist_kernel(const int* __restrict__ dst, int* __restrict__ cnt, int E) {
  int e = blockIdx.x * 256 + threadIdx.x;
  if (e < E) atomicAdd(&cnt[dst[e]], 1);
}

__global__ __launch_bounds__(1024) void scanA_kernel(
    const int* __restrict__ cnt, int* __restrict__ locpref,
    int* __restrict__ btot, float* __restrict__ dis, int N) {
  __shared__ int wsum[16];
  int t = threadIdx.x, lane = t & 63, wid = t >> 6;
  int i = blockIdx.x * 1024 + t;
  int v = (i < N) ? cnt[i] : 0;
  if (i < N) dis[i] = rsqrtf(1.f + (float)v);
  int x = v;
  #pragma unroll
  for (int off = 1; off < 64; off <<= 1) {
    int y = __shfl_up(x, off);
    if (lane >= off) x += y;
  }
  if (lane == 63) wsum[wid] = x;
  __syncthreads();
  if (wid == 0 && lane < 16) {
    int s = wsum[lane];
    #pragma unroll
    for (int off = 1; off < 16; off <<= 1) {
      int y = __shfl_up(s, off);
      if (lane >= off) s += y;
    }
    wsum[lane] = s;
  }
  __syncthreads();
  int woff = (wid > 0) ? wsum[wid - 1] : 0;
  if (i < N) locpref[i] = woff + x - v;
  if (t == 1023) btot[blockIdx.x] = woff + x;
}

__global__ void scanB_kernel(const int* __restrict__ btot, int* __restrict__ boff, int nb) {
  int lane = threadIdx.x;
  int v = (lane < nb) ? btot[lane] : 0;
  int x = v;
  #pragma unroll
  for (int off = 1; off < 64; off <<= 1) {
    int y = __shfl_up(x, off);
    if (lane >= off) x += y;
  }
  if (lane < nb) boff[lane] = x - v;
}

__global__ void scanC_kernel(const int* __restrict__ locpref, const int* __restrict__ boff,
                             int* __restrict__ row_ptr, int* __restrict__ fill, int N) {
  int i = blockIdx.x * 256 + threadIdx.x;
  if (i < N) {
    int r = locpref[i] + boff[i >> 10];
    row_ptr[i] = r; fill[i] = r;
  }
  if (i == 0) row_ptr[N] = N_EDGES;
}

__global__ void scatter_kernel(const int* __restrict__ src, const int* __restrict__ dst,
                               int* __restrict__ fill, int* __restrict__ csr_src, int E) {
  int e = blockIdx.x * 256 + threadIdx.x;
  if (e >= E) return;
  int d = dst[e];
  int pos = atomicAdd(&fill[d], 1);
  csr_src[pos] = src[e];
}

// ------------------------------------------------------------ MFMA bf16 GEMM
__global__ __launch_bounds__(256) void gemm_bf16_kernel(
    const u16* __restrict__ A, const u16* __restrict__ wT,
    u16* __restrict__ C, int M) {
  int t = threadIdx.x;
  int w = t >> 6, l = t & 63, lr = l & 15, lg = l >> 4;
  int r0 = blockIdx.x * 64 + w * 16;

  int row = r0 + lr;
  const u16* Arow = A + (size_t)(row < M ? row : 0) * 128;

  bfrag a[4];
  #pragma unroll
  for (int ks = 0; ks < 4; ++ks) a[ks] = *(const bfrag*)(Arow + ks * 32 + lg * 8);

  f32x4 acc[8];
  #pragma unroll
  for (int ct = 0; ct < 8; ++ct) acc[ct] = (f32x4){0.f, 0.f, 0.f, 0.f};
  #pragma unroll
  for (int ks = 0; ks < 4; ++ks)
    #pragma unroll
    for (int ct = 0; ct < 8; ++ct) {
      bfrag b = *(const bfrag*)(wT + (size_t)(ct * 16 + lr) * 128 + ks * 32 + lg * 8);
      acc[ct] = MFMA16(a[ks], b, acc[ct]);
    }
  #pragma unroll
  for (int ct = 0; ct < 8; ++ct)
    #pragma unroll
    for (int i = 0; i < 4; ++i) {
      int r = r0 + lg * 4 + i;
      if (r < M) C[(size_t)r * 128 + ct * 16 + lr] = f2bf(acc[ct][i]);
    }
}

// ------------------------------------------------------------- GCN aggregate
__global__ __launch_bounds__(256) void agg_kernel(
    const u16* __restrict__ xw, const float* __restrict__ dis,
    const int* __restrict__ row_ptr, const int* __restrict__ csr_src,
    const float* __restrict__ bias, const float* __restrict__ lng,
    const float* __restrict__ lnb, u16* __restrict__ out, int N, int doLN) {
  int t = threadIdx.x;
  int n = blockIdx.x * 4 + (t >> 6);
  if (n >= N) return;
  int l = t & 63, cg = l & 15, eg = l >> 4;
  float dn = dis[n];
  float acc[8] = {0.f, 0.f, 0.f, 0.f, 0.f, 0.f, 0.f, 0.f};
  if (eg == 0) {
    uint4 r = *(const uint4*)(xw + (size_t)n * 128 + cg * 8);
    float w = dn * dn;
    acc[0] += w * bflo(r.x); acc[1] += w * bfhi(r.x);
    acc[2] += w * bflo(r.y); acc[3] += w * bfhi(r.y);
    acc[4] += w * bflo(r.z); acc[5] += w * bfhi(r.z);
    acc[6] += w * bflo(r.w); acc[7] += w * bfhi(r.w);
  }
  int e1 = row_ptr[n + 1];
  int e = row_ptr[n] + eg;
  int sn = (e < e1) ? csr_src[e] : -1;
  while (sn >= 0) {
    int s = sn;
    e += 4;
    sn = (e < e1) ? csr_src[e] : -1;
    float w = dis[s] * dn;
    uint4 r = *(const uint4*)(xw + (size_t)s * 128 + cg * 8);
    acc[0] += w * bflo(r.x); acc[1] += w * bfhi(r.x);
    acc[2] += w * bflo(r.y); acc[3] += w * bfhi(r.y);
    acc[4] += w * bflo(r.z); acc[5] += w * bfhi(r.z);
    acc[6] += w * bflo(r.w); acc[7] += w * bfhi(r.w);
  }
  #pragma unroll
  for (int j = 0; j < 8; ++j) {
    acc[j] += __shfl_xor(acc[j], 16);
    acc[j] += __shfl_xor(acc[j], 32);
  }
  int c0 = cg * 8;
  #pragma unroll
  for (int j = 0; j < 8; ++j) acc[j] = fmaxf(acc[j] + bias[c0 + j], 0.f);
  if (doLN) {
    float s1 = 0.f, s2 = 0.f;
    #pragma unroll
    for (int j = 0; j < 8; ++j) { s1 += acc[j]; s2 += acc[j] * acc[j]; }
    #pragma unroll
    for (int off = 1; off < 16; off <<= 1) {
      s1 += __shfl_xor(s1, off);
      s2 += __shfl_xor(s2, off);
    }
    float mean = s1 * (1.f / 128.f);
    float var = s2 * (1.f / 128.f) - mean * mean;
    float inv = rsqrtf(var + 1e-5f);
    #pragma unroll
    for (int j = 0; j < 8; ++j)
      acc[j] = (acc[j] - mean) * inv * lng[c0 + j] + lnb[c0 + j];
  }
  if (eg == 0) {
    uint4 o;
    o.x = pack2(acc[0], acc[1]); o.y = pack2(acc[2], acc[3]);
    o.z = pack2(acc[4], acc[5]); o.w = pack2(acc[6], acc[7]);
    *(uint4*)(out + (size_t)n * 128 + cg * 8) = o;
  }
}

// ----------------------- merged QKV: role A (inter->kh,vh) / role B (q,qh)
// head-major outputs [h][BS_][16]; qout row-major [r][128].
__global__ __launch_bounds__(256) void qkv_kernel(
    const u16* __restrict__ xa, const int* __restrict__ hist,
    const int* __restrict__ ans, const int* __restrict__ nseq,
    const u16* __restrict__ l0T, const float* __restrict__ pc,
    const u16* __restrict__ wkT, const float* __restrict__ bk,
    const u16* __restrict__ wvT, const float* __restrict__ bv,
    const u16* __restrict__ l3T, const u16* __restrict__ wqT,
    const float* __restrict__ bq,
    u16* __restrict__ khout, u16* __restrict__ vhout,
    u16* __restrict__ qout, u16* __restrict__ qhout, int nblk) {
  __shared__ u16 interl[4][16 * 136];
  int bb = blockIdx.x;
  int t = threadIdx.x, w = t >> 6, l = t & 63, lr = l & 15, lg = l >> 4;

  if (bb < nblk) {
    // ---- role A: gather(hist) -> inter(LDS) -> kh, vh ----
    int r0 = bb * 64 + w * 16;
    int arow = hist[r0 + lr];
    const u16* Arow = xa + (size_t)arow * 128;
    bfrag a[4];
    #pragma unroll
    for (int ks = 0; ks < 4; ++ks) a[ks] = *(const bfrag*)(Arow + ks * 32 + lg * 8);

    f32x4 acc[8];
    #pragma unroll
    for (int ct = 0; ct < 8; ++ct) acc[ct] = (f32x4){0.f, 0.f, 0.f, 0.f};
    #pragma unroll
    for (int ks = 0; ks < 4; ++ks)
      #pragma unroll
      for (int ct = 0; ct < 8; ++ct) {
        bfrag b = *(const bfrag*)(l0T + (size_t)(ct * 16 + lr) * 128 + ks * 32 + lg * 8);
        acc[ct] = MFMA16(a[ks], b, acc[ct]);
      }
    int pcoff[4];
    #pragma unroll
    for (int i = 0; i < 4; ++i) {
      int r = r0 + lg * 4 + i;
      pcoff[i] = (ans[r] * S_ + (r % S_)) * 128;
    }
    #pragma unroll
    for (int ct = 0; ct < 8; ++ct) {
      int col = ct * 16 + lr;
      #pragma unroll
      for (int i = 0; i < 4; ++i)
        interl[w][(lg * 4 + i) * 136 + col] = f2bf(acc[ct][i] + pc[pcoff[i] + col]);
    }
    bfrag a2[4];
    #pragma unroll
    for (int ks = 0; ks < 4; ++ks)
      a2[ks] = *(const bfrag*)(&interl[w][lr * 136 + ks * 32 + lg * 8]);

    #pragma unroll
    for (int ct = 0; ct < 8; ++ct) acc[ct] = (f32x4){0.f, 0.f, 0.f, 0.f};
    #pragma unroll
    for (int ks = 0; ks < 4; ++ks)
      #pragma unroll
      for (int ct = 0; ct < 8; ++ct) {
        bfrag b = *(const bfrag*)(wkT + (size_t)(ct * 16 + lr) * 128 + ks * 32 + lg * 8);
        acc[ct] = MFMA16(a2[ks], b, acc[ct]);
      }
    #pragma unroll
    for (int ct = 0; ct < 8; ++ct)
      #pragma unroll
      for (int i = 0; i < 4; ++i)
        khout[((size_t)ct * BS_ + r0 + lg * 4 + i) * 16 + lr] =
            f2bf(acc[ct][i] + bk[ct * 16 + lr]);

    #pragma unroll
    for (int ct = 0; ct < 8; ++ct) acc[ct] = (f32x4){0.f, 0.f, 0.f, 0.f};
    #pragma unroll
    for (int ks = 0; ks < 4; ++ks)
      #pragma unroll
      for (int ct = 0; ct < 8; ++ct) {
        bfrag b = *(const bfrag*)(wvT + (size_t)(ct * 16 + lr) * 128 + ks * 32 + lg * 8);
        acc[ct] = MFMA16(a2[ks], b, acc[ct]);
      }
    #pragma unroll
    for (int ct = 0; ct < 8; ++ct)
      #pragma unroll
      for (int i = 0; i < 4; ++i)
        vhout[((size_t)ct * BS_ + r0 + lg * 4 + i) * 16 + lr] =
            f2bf(acc[ct][i] + bv[ct * 16 + lr]);
  } else {
    // ---- role B: gather(new) -> q (row-major), qh (head-major) ----
    int r0 = (bb - nblk) * 64 + w * 16;
    int arow = nseq[r0 + lr];
    const u16* Arow = xa + (size_t)arow * 128;
    bfrag a[4];
    #pragma unroll
    for (int ks = 0; ks < 4; ++ks) a[ks] = *(const bfrag*)(Arow + ks * 32 + lg * 8);

    f32x4 acc[8];
    #pragma unroll
    for (int ct = 0; ct < 8; ++ct) acc[ct] = (f32x4){0.f, 0.f, 0.f, 0.f};
    #pragma unroll
    for (int ks = 0; ks < 4; ++ks)
      #pragma unroll
      for (int ct = 0; ct < 8; ++ct) {
        bfrag b = *(const bfrag*)(l3T + (size_t)(ct * 16 + lr) * 128 + ks * 32 + lg * 8);
        acc[ct] = MFMA16(a[ks], b, acc[ct]);
      }
    #pragma unroll
    for (int ct = 0; ct < 8; ++ct)
      #pragma unroll
      for (int i = 0; i < 4; ++i)
        qout[(size_t)(r0 + lg * 4 + i) * 128 + ct * 16 + lr] = f2bf(acc[ct][i]);

    #pragma unroll
    for (int ct = 0; ct < 8; ++ct) acc[ct] = (f32x4){0.f, 0.f, 0.f, 0.f};
    #pragma unroll
    for (int ks = 0; ks < 4; ++ks)
      #pragma unroll
      for (int ct = 0; ct < 8; ++ct) {
        bfrag b = *(const bfrag*)(wqT + (size_t)(ct * 16 + lr) * 128 + ks * 32 + lg * 8);
        acc[ct] = MFMA16(a[ks], b, acc[ct]);
      }
    #pragma unroll
    for (int ct = 0; ct < 8; ++ct)
      #pragma unroll
      for (int i = 0; i < 4; ++i)
        qhout[((size_t)ct * BS_ + r0 + lg * 4 + i) * 16 + lr] =
            f2bf(acc[ct][i] + bq[ct * 16 + lr]);
  }
}

// ----------------------------------------------------------- MFMA attention
// block = (b,h); head-major [h][BS_][16]; in-place ao over qh.
__global__ __launch_bounds__(256) void attn_mfma_kernel(
    u16* qh_ao, const u16* __restrict__ kh, const u16* __restrict__ vh) {
  __shared__ u16 Kl[208 * 24];
  __shared__ u16 Vt[16 * 232];
  __shared__ u16 Pl[4 * 16 * 232];
  int b = blockIdx.x >> 3, h = blockIdx.x & 7;
  int t = threadIdx.x;
  size_t base = ((size_t)h * BS_ + (size_t)b * S_) * 16;

  for (int i = t; i < 208 * 2; i += 256) {
    int key = i >> 1, d = (i & 1) * 8;
    uint4 v = make_uint4(0, 0, 0, 0);
    if (key < S_) v = *(const uint4*)(kh + base + (size_t)key * 16 + d);
    *(uint4*)(Kl + key * 24 + d) = v;
  }
  for (int i = t; i < 16 * 232; i += 256) {
    int d = i / 232, key = i - d * 232;
    Vt[d * 232 + key] = (key < S_) ? vh[base + (size_t)key * 16 + d] : (u16)0;
  }
  for (int i = t; i < 4 * 16 * 232 / 2; i += 256) ((u32*)Pl)[i] = 0;
  __syncthreads();

  int w = t >> 6, l = t & 63, lr = l & 15, lg = l >> 4;
  u16* Pw = Pl + w * 16 * 232;
  const f32x4 zero4 = {0.f, 0.f, 0.f, 0.f};

  for (int qi = w; qi < 13; qi += 4) {
    bfrag aq = (bfrag){0, 0, 0, 0, 0, 0, 0, 0};
    int qrow = qi * 16 + lr;
    if (lg < 2 && qrow < S_)
      aq = *(const bfrag*)(qh_ao + base + (size_t)qrow * 16 + lg * 8);
    float rsum[4] = {0.f, 0.f, 0.f, 0.f};
    for (int kj = 0; kj <= qi; ++kj) {
      bfrag bk = (bfrag){0, 0, 0, 0, 0, 0, 0, 0};
      if (lg < 2) bk = *(const bfrag*)(Kl + (kj * 16 + lr) * 24 + lg * 8);
      f32x4 sc = MFMA16(aq, bk, zero4);
      #pragma unroll
      for (int i = 0; i < 4; ++i) {
        int q = qi * 16 + lg * 4 + i, key = kj * 16 + lr;
        float p = 0.f;
        if (key <= q && q < S_) p = __expf(sc[i] * 0.25f);
        rsum[i] += p;
        Pw[(lg * 4 + i) * 232 + key] = f2bf(p);
      }
    }
    #pragma unroll
    for (int i = 0; i < 4; ++i) {
      rsum[i] += __shfl_xor(rsum[i], 1);
      rsum[i] += __shfl_xor(rsum[i], 2);
      rsum[i] += __shfl_xor(rsum[i], 4);
      rsum[i] += __shfl_xor(rsum[i], 8);
    }
    f32x4 o = zero4;
    #pragma unroll
    for (int kt = 0; kt < 7; ++kt) {
      bfrag ap = *(const bfrag*)(Pw + lr * 232 + kt * 32 + lg * 8);
      bfrag bv = *(const bfrag*)(Vt + lr * 232 + kt * 32 + lg * 8);
      o = MFMA16(ap, bv, o);
    }
    #pragma unroll
    for (int i = 0; i < 4; ++i) {
      int q = qi * 16 + lg * 4 + i;
      if (q < S_) qh_ao[base + (size_t)q * 16 + lr] = f2bf(o[i] / rsum[i]);
    }
  }
}

// ------------------------------------- fused ao@wo + bo + resid(q) -> LN2
__global__ __launch_bounds__(256) void wo_ln_kernel(
    const u16* __restrict__ ao, const u16* __restrict__ qres,
    const u16* __restrict__ woT, const float* __restrict__ bo,
    const float* __restrict__ g, const float* __restrict__ bb,
    u16* __restrict__ atn) {
  int t = threadIdx.x, w = t >> 6, l = t & 63, lr = l & 15, lg = l >> 4;
  int r0 = blockIdx.x * 64 + w * 16;
  bfrag a[4];
  #pragma unroll
  for (int ks = 0; ks < 4; ++ks) {
    int head = ks * 2 + (lg >> 1);
    int d0 = (lg & 1) * 8;
    a[ks] = *(const bfrag*)(ao + ((size_t)head * BS_ + r0 + lr) * 16 + d0);
  }

  f32x4 acc[8];
  #pragma unroll
  for (int ct = 0; ct < 8; ++ct) acc[ct] = (f32x4){0.f, 0.f, 0.f, 0.f};
  #pragma unroll
  for (int ks = 0; ks < 4; ++ks)
    #pragma unroll
    for (int ct = 0; ct < 8; ++ct) {
      bfrag b = *(const bfrag*)(woT + (size_t)(ct * 16 + lr) * 128 + ks * 32 + lg * 8);
      acc[ct] = MFMA16(a[ks], b, acc[ct]);
    }
  #pragma unroll
  for (int ct = 0; ct < 8; ++ct) {
    int col = ct * 16 + lr;
    float bcol = bo[col];
    #pragma unroll
    for (int i = 0; i < 4; ++i)
      acc[ct][i] += bcol + bf2f(qres[(size_t)(r0 + lg * 4 + i) * 128 + col]);
  }
  float s1[4] = {0, 0, 0, 0}, s2[4] = {0, 0, 0, 0};
  #pragma unroll
  for (int ct = 0; ct < 8; ++ct)
    #pragma unroll
    for (int i = 0; i < 4; ++i) {
      s1[i] += acc[ct][i];
      s2[i] += acc[ct][i] * acc[ct][i];
    }
  #pragma unroll
  for (int i = 0; i < 4; ++i) {
    s1[i] += __shfl_xor(s1[i], 1); s2[i] += __shfl_xor(s2[i], 1);
    s1[i] += __shfl_xor(s1[i], 2); s2[i] += __shfl_xor(s2[i], 2);
    s1[i] += __shfl_xor(s1[i], 4); s2[i] += __shfl_xor(s2[i], 4);
    s1[i] += __shfl_xor(s1[i], 8); s2[i] += __shfl_xor(s2[i], 8);
  }
  float mean[4], inv[4];
  #pragma unroll
  for (int i = 0; i < 4; ++i) {
    mean[i] = s1[i] * (1.f / 128.f);
    float var = s2[i] * (1.f / 128.f) - mean[i] * mean[i];
    inv[i] = rsqrtf(var + 1e-5f);
  }
  #pragma unroll
  for (int ct = 0; ct < 8; ++ct) {
    int col = ct * 16 + lr;
    float gc = g[col], bc = bb[col];
    #pragma unroll
    for (int i = 0; i < 4; ++i)
      atn[(size_t)(r0 + lg * 4 + i) * 128 + col] =
          f2bf((acc[ct][i] - mean[i]) * inv[i] * gc + bc);
  }
}

// --------------------- fused FFN: relu(atn@f0+b0)@f1 + b1 + atn -> LN3 -> pred
__global__ __launch_bounds__(256) void ffn_kernel(
    const u16* __restrict__ atn, const u16* __restrict__ f0T,
    const float* __restrict__ b0, const u16* __restrict__ f1T,
    const float* __restrict__ b1, const float* __restrict__ g,
    const float* __restrict__ bb, const float* __restrict__ w4,
    const float* __restrict__ b4, float* __restrict__ pred) {
  __shared__ u16 f1l[4][16 * 136];
  int t = threadIdx.x, w = t >> 6, l = t & 63, lr = l & 15, lg = l >> 4;
  int r0 = blockIdx.x * 64 + w * 16;
  const u16* Arow = atn + (size_t)(r0 + lr) * 128;
  bfrag a[4];
  #pragma unroll
  for (int ks = 0; ks < 4; ++ks) a[ks] = *(const bfrag*)(Arow + ks * 32 + lg * 8);

  f32x4 acc[8];
  #pragma unroll
  for (int ct = 0; ct < 8; ++ct) acc[ct] = (f32x4){0.f, 0.f, 0.f, 0.f};
  #pragma unroll
  for (int ks = 0; ks < 4; ++ks)
    #pragma unroll
    for (int ct = 0; ct < 8; ++ct) {
      bfrag b = *(const bfrag*)(f0T + (size_t)(ct * 16 + lr) * 128 + ks * 32 + lg * 8);
      acc[ct] = MFMA16(a[ks], b, acc[ct]);
    }
  #pragma unroll
  for (int ct = 0; ct < 8; ++ct) {
    int col = ct * 16 + lr;
    float bcol = b0[col];
    #pragma unroll
    for (int i = 0; i < 4; ++i)
      f1l[w][(lg * 4 + i) * 136 + col] = f2bf(fmaxf(acc[ct][i] + bcol, 0.f));
  }
  bfrag a2[4];
  #pragma unroll
  for (int ks = 0; ks < 4; ++ks)
    a2[ks] = *(const bfrag*)(&f1l[w][lr * 136 + ks * 32 + lg * 8]);

  #pragma unroll
  for (int ct = 0; ct < 8; ++ct) acc[ct] = (f32x4){0.f, 0.f, 0.f, 0.f};
  #pragma unroll
  for (int ks = 0; ks < 4; ++ks)
    #pragma unroll
    for (int ct = 0; ct < 8; ++ct) {
      bfrag b = *(const bfrag*)(f1T + (size_t)(ct * 16 + lr) * 128 + ks * 32 + lg * 8);
      acc[ct] = MFMA16(a2[ks], b, acc[ct]);
    }
  #pragma unroll
  for (int ct = 0; ct < 8; ++ct) {
    int col = ct * 16 + lr;
    float bcol = b1[col];
    #pragma unroll
    for (int i = 0; i < 4; ++i)
      acc[ct][i] += bcol + bf2f(atn[(size_t)(r0 + lg * 4 + i) * 128 + col]);
  }
  float s1[4] = {0, 0, 0, 0}, s2[4] = {0, 0, 0, 0};
  #pragma unroll
  for (int ct = 0; ct < 8; ++ct)
    #pragma unroll
    for (int i = 0; i < 4; ++i) {
      s1[i] += acc[ct][i];
      s2[i] += acc[ct][i] * acc[ct][i];
    }
  #pragma unroll
  for (int i = 0; i < 4; ++i) {
    s1[i] += __shfl_xor(s1[i], 1); s2[i] += __shfl_xor(s2[i], 1);
    s1[i] += __shfl_xor(s1[i], 2); s2[i] += __shfl_xor(s2[i], 2);
    s1[i] += __shfl_xor(s1[i], 4); s2[i] += __shfl_xor(s2[i], 4);
    s1[i] += __shfl_xor(s1[i], 8); s2[i] += __shfl_xor(s2[i], 8);
  }
  float p[4] = {0, 0, 0, 0};
  #pragma unroll
  for (int i = 0; i < 4; ++i) {
    float mean = s1[i] * (1.f / 128.f);
    float var = s2[i] * (1.f / 128.f) - mean * mean;
    float inv = rsqrtf(var + 1e-5f);
    #pragma unroll
    for (int ct = 0; ct < 8; ++ct) {
      int col = ct * 16 + lr;
      p[i] += ((acc[ct][i] - mean) * inv * g[col] + bb[col]) * w4[col];
    }
  }
  #pragma unroll
  for (int i = 0; i < 4; ++i) {
    p[i] += __shfl_xor(p[i], 1);
    p[i] += __shfl_xor(p[i], 2);
    p[i] += __shfl_xor(p[i], 4);
    p[i] += __shfl_xor(p[i], 8);
  }
  if (lr == 0) {
    float bias4 = b4[0];
    #pragma unroll
    for (int i = 0; i < 4; ++i) pred[r0 + lg * 4 + i] = p[i] + bias4;
  }
}

// ---------------------------------------------------------------------------
extern "C" void kernel_launch(void* const* d_in, const int* in_sizes, int n_in,
                              void* d_out, int out_size, void* d_ws, size_t ws_size,
                              hipStream_t stream) {
  const int* hist_seq = (const int*)d_in[0];
  const int* hist_ans = (const int*)d_in[1];
  const int* new_seq = (const int*)d_in[2];
  const int* edge_index = (const int*)d_in[3];
  const float* node_x = (const float*)d_in[4];
  const float* gcn_w0 = (const float*)d_in[5];
  const float* gcn_b0 = (const float*)d_in[6];
  const float* gcn_w1 = (const float*)d_in[7];
  const float* gcn_b1 = (const float*)d_in[8];
  const float* gcn_w2 = (const float*)d_in[9];
  const float* gcn_b2 = (const float*)d_in[10];
  const float* ln0_g = (const float*)d_in[11];
  const float* ln0_b = (const float*)d_in[12];
  const float* ln1_g = (const float*)d_in[13];
  const float* ln1_b = (const float*)d_in[14];
  const float* ln2_g = (const float*)d_in[15];
  const float* ln2_b = (const float*)d_in[16];
  const float* ln3_g = (const float*)d_in[17];
  const float* ln3_b = (const float*)d_in[18];
  const float* corr_emb = (const float*)d_in[19];
  const float* lin0_w = (const float*)d_in[20];
  const float* lin0_b = (const float*)d_in[21];
  const float* lin1_w = (const float*)d_in[22];
  const float* lin2_w = (const float*)d_in[23];
  const float* lin3_w = (const float*)d_in[24];
  const float* lin4_w = (const float*)d_in[25];
  const float* lin4_b = (const float*)d_in[26];
  const float* pos_emb = (const float*)d_in[27];
  const float* mha_wq = (const float*)d_in[28];
  const float* mha_bq = (const float*)d_in[29];
  const float* mha_wk = (const float*)d_in[30];
  const float* mha_bk = (const float*)d_in[31];
  const float* mha_wv = (const float*)d_in[32];
  const float* mha_bv = (const float*)d_in[33];
  const float* mha_wo = (const float*)d_in[34];
  const float* mha_bo = (const float*)d_in[35];
  const float* ffn0_w = (const float*)d_in[36];
  const float* ffn0_b = (const float*)d_in[37];
  const float* ffn1_w = (const float*)d_in[38];
  const float* ffn1_b = (const float*)d_in[39];
  (void)in_sizes; (void)n_in; (void)out_size;

  char* ws = (char*)d_ws;
  size_t off = 0;
  auto alloc = [&](size_t bytes) -> void* {
    void* p = ws + off;
    off += (bytes + 255) & ~(size_t)255;
    return p;
  };
  int* cnt = (int*)alloc((size_t)N_NODES * 4);
  int* row_ptr = (int*)alloc((size_t)(N_NODES + 1) * 4);
  int* fill = (int*)alloc((size_t)N_NODES * 4);
  int* locpref = (int*)alloc((size_t)N_NODES * 4);
  int* btot = (int*)alloc(64 * 4);
  int* boff = (int*)alloc(64 * 4);
  float* dis = (float*)alloc((size_t)N_NODES * 4);
  int* csr_src = (int*)alloc((size_t)N_EDGES * 4);
  const size_t WB = 128 * 128 * 2;
  u16* g0T = (u16*)alloc(WB);
  u16* g1T = (u16*)alloc(WB);
  u16* g2T = (u16*)alloc(WB);
  u16* l0T = (u16*)alloc(WB);
  u16* l3T = (u16*)alloc(WB);
  u16* woT = (u16*)alloc(WB);
  u16* f0T = (u16*)alloc(WB);
  u16* f1T = (u16*)alloc(WB);
  u16* wqT = (u16*)alloc(WB);
  u16* wkT = (u16*)alloc(WB);
  u16* wvT = (u16*)alloc(WB);
  float* c01 = (float*)alloc(2 * 128 * 4);
  float* pc = (float*)alloc((size_t)2 * S_ * 128 * 4);
  u16* xa = (u16*)alloc((size_t)N_NODES * 128 * 2);
  // full-batch buffers; xb/xw overlay bufQ0's region (dead before it's written)
  const size_t CB = (size_t)BS_ * 128 * 2;   // 26.2 MB
  size_t RB = off;
  u16* bufQ0 = (u16*)(ws + RB);               // q (resid), row-major
  u16* bufQ  = (u16*)(ws + RB + CB);          // qh -> ao in place, head-major
  u16* bufK  = (u16*)(ws + RB + 2 * CB);      // kh head-major -> atn row-major
  u16* bufV  = (u16*)(ws + RB + 3 * CB);      // vh head-major
  u16* xb = bufQ0;                            // N_NODES*128*2 = 12.8 MB
  u16* xw = bufQ0 + (size_t)N_NODES * 128;    // next 12.8 MB (still within bufQ0+bufQ... fits in 26.2)
  size_t need = RB + 4 * CB;
  if (ws_size < need) return;     // diagnostic guard

  // ---- graph prep ----
  int nb = (N_NODES + 1023) / 1024;   // 49
  zero_i32_kernel<<<(N_NODES + 255) / 256, 256, 0, stream>>>(cnt, N_NODES);
  hist_kernel<<<(N_EDGES + 255) / 256, 256, 0, stream>>>(edge_index + N_EDGES, cnt, N_EDGES);
  scanA_kernel<<<nb, 1024, 0, stream>>>(cnt, locpref, btot, dis, N_NODES);
  scanB_kernel<<<1, 64, 0, stream>>>(btot, boff, nb);
  scanC_kernel<<<(N_NODES + 255) / 256, 256, 0, stream>>>(locpref, boff, row_ptr, fill, N_NODES);
  scatter_kernel<<<(N_EDGES + 255) / 256, 256, 0, stream>>>(edge_index, edge_index + N_EDGES,
                                                            fill, csr_src, N_EDGES);
  // ---- weight prep + pc table + node_x cast ----
  wprep_kernel<<<705, 256, 0, stream>>>(gcn_w0, gcn_w1, gcn_w2, lin0_w, lin3_w, mha_wo,
                                        ffn0_w, ffn1_w, lin1_w, lin2_w, mha_wq, mha_wk,
                                        mha_wv, corr_emb, g0T, g1T, g2T, l0T, l3T, woT,
                                        f0T, f1T, wqT, wkT, wvT, c01);
  pc_kernel<<<(2 * S_ * 128 + 255) / 256, 256, 0, stream>>>(lin0_b, pos_emb, c01, pc);
  f2bf8_kernel<<<(N_NODES * 16 + 255) / 256, 256, 0, stream>>>(node_x, xb, N_NODES * 16);

  int gN = (N_NODES + 63) / 64;
  int aN = (N_NODES + 3) / 4;

  // ---- GCN ----
  gemm_bf16_kernel<<<gN, 256, 0, stream>>>(xb, g0T, xw, N_NODES);
  agg_kernel<<<aN, 256, 0, stream>>>(xw, dis, row_ptr, csr_src, gcn_b0, ln0_g, ln0_b, xa, N_NODES, 1);
  gemm_bf16_kernel<<<gN, 256, 0, stream>>>(xa, g1T, xw, N_NODES);
  agg_kernel<<<aN, 256, 0, stream>>>(xw, dis, row_ptr, csr_src, gcn_b1, ln1_g, ln1_b, xa, N_NODES, 1);
  gemm_bf16_kernel<<<gN, 256, 0, stream>>>(xa, g2T, xw, N_NODES);
  agg_kernel<<<aN, 256, 0, stream>>>(xw, dis, row_ptr, csr_src, gcn_b2, nullptr, nullptr, xa, N_NODES, 0);

  // ---- transformer, full batch, 4 dispatches ----
  int gT = BS_ / 64;   // 1600
  qkv_kernel<<<2 * gT, 256, 0, stream>>>(xa, hist_seq, hist_ans, new_seq,
                                         l0T, pc, wkT, mha_bk, wvT, mha_bv,
                                         l3T, wqT, mha_bq,
                                         bufK, bufV, bufQ0, bufQ, gT);
  attn_mfma_kernel<<<B_ * 8, 256, 0, stream>>>(bufQ, bufK, bufV);
  wo_ln_kernel<<<gT, 256, 0, stream>>>(bufQ, bufQ0, woT, mha_bo, ln2_g, ln2_b, bufK);
  ffn_kernel<<<gT, 256, 0, stream>>>(bufK, f0T, ffn0_b, f1T, ffn1_b, ln3_g, ln3_b,
                                     lin4_w, lin4_b, (float*)d_out);
}

// Round 9
// 579.511 us; speedup vs baseline: 2.4881x; 1.0585x over previous
//
#include <hip/hip_runtime.h>
#include <math.h>

#define N_NODES 50000
#define N_EDGES 800000
#define B_ 512
#define S_ 200
#define D_ 128
#define BS_ (B_*S_)            // 102400 rows, full batch

typedef unsigned short u16;
typedef unsigned int u32;
using bfrag = __attribute__((ext_vector_type(8))) short;
using f32x4 = __attribute__((ext_vector_type(4))) float;

__device__ __forceinline__ u16 f2bf(float f) {        // RNE f32 -> bf16 bits
  u32 u = __float_as_uint(f);
  u32 r = (u + 0x7fffu + ((u >> 16) & 1u)) >> 16;
  return (u16)r;
}
__device__ __forceinline__ float bf2f(u16 v) { return __uint_as_float(((u32)v) << 16); }
__device__ __forceinline__ float bflo(u32 v) { return __uint_as_float(v << 16); }
__device__ __forceinline__ float bfhi(u32 v) { return __uint_as_float(v & 0xffff0000u); }
__device__ __forceinline__ u32 pack2(float a, float b) {
  return (u32)f2bf(a) | ((u32)f2bf(b) << 16);
}
#define MFMA16(a, b, c) __builtin_amdgcn_mfma_f32_16x16x32_bf16((a), (b), (c), 0, 0, 0)

// ---------------------------------------------------------------- utilities
__global__ void zero_i32_kernel(int* __restrict__ p, int n) {
  int i = blockIdx.x * 256 + threadIdx.x;
  if (i < n) p[i] = 0;
}

__global__ void f2bf8_kernel(const float* __restrict__ in, u16* __restrict__ out, int n8) {
  int i = blockIdx.x * 256 + threadIdx.x;
  if (i >= n8) return;
  float4 a = ((const float4*)in)[i * 2];
  float4 b = ((const float4*)in)[i * 2 + 1];
  uint4 o;
  o.x = pack2(a.x, a.y); o.y = pack2(a.z, a.w);
  o.z = pack2(b.x, b.y); o.w = pack2(b.z, b.w);
  ((uint4*)out)[i] = o;
}

// ---------------- fused weight prep: 8 transposes + 3 products + c01
__global__ __launch_bounds__(256) void wprep_kernel(
    const float* __restrict__ gcn_w0, const float* __restrict__ gcn_w1,
    const float* __restrict__ gcn_w2, const float* __restrict__ lin0_w,
    const float* __restrict__ lin3_w, const float* __restrict__ mha_wo,
    const float* __restrict__ ffn0_w, const float* __restrict__ ffn1_w,
    const float* __restrict__ lin1_w, const float* __restrict__ lin2_w,
    const float* __restrict__ mha_wq, const float* __restrict__ mha_wk,
    const float* __restrict__ mha_wv, const float* __restrict__ corr_emb,
    u16* __restrict__ g0T, u16* __restrict__ g1T, u16* __restrict__ g2T,
    u16* __restrict__ l0T, u16* __restrict__ l3T, u16* __restrict__ woT,
    u16* __restrict__ f0T, u16* __restrict__ f1T,
    u16* __restrict__ wqT, u16* __restrict__ wkT, u16* __restrict__ wvT,
    float* __restrict__ c01) {
  int bb = blockIdx.x;
  if (bb < 512) {                        // plain transpose W[k][c] -> D[c][k]
    const float* W; u16* D;
    switch (bb >> 6) {
      case 0: W = gcn_w0; D = g0T; break;
      case 1: W = gcn_w1; D = g1T; break;
      case 2: W = gcn_w2; D = g2T; break;
      case 3: W = lin0_w; D = l0T; break;
      case 4: W = lin3_w; D = l3T; break;
      case 5: W = mha_wo; D = woT; break;
      case 6: W = ffn0_w; D = f0T; break;
      default: W = ffn1_w; D = f1T; break;
    }
    int i = (bb & 63) * 256 + threadIdx.x;
    int k = i >> 7, c = i & 127;
    D[c * 128 + k] = f2bf(W[k * 128 + c]);
  } else if (bb < 704) {                 // (X@Y)^T -> D
    const float* X; const float* Y; u16* D;
    switch ((bb - 512) >> 6) {
      case 0: X = lin3_w; Y = mha_wq; D = wqT; break;
      case 1: X = lin2_w; Y = mha_wk; D = wkT; break;
      default: X = lin1_w; Y = mha_wv; D = wvT; break;
    }
    int i = ((bb - 512) & 63) * 256 + threadIdx.x;
    int k = i >> 7, c = i & 127;
    float acc = 0.f;
    for (int t = 0; t < 128; ++t) acc += X[k * 128 + t] * Y[t * 128 + c];
    D[c * 128 + k] = f2bf(acc);
  } else {                               // c01 = corr_emb @ lin0_w[128:]
    int idx = threadIdx.x;               // 0..255 = 2*128
    int i = idx >> 7, j = idx & 127;
    float acc = 0.f;
    for (int t = 0; t < 128; ++t)
      acc += corr_emb[i * 128 + t] * lin0_w[128 * 128 + t * 128 + j];
    c01[idx] = acc;
  }
}

// pc[a][s][c] = lin0_b[c] + pos_emb[s][c] + c01[a][c]
__global__ void pc_kernel(const float* __restrict__ lin0_b, const float* __restrict__ pos_emb,
                          const float* __restrict__ c01, float* __restrict__ pc) {
  int i = blockIdx.x * 256 + threadIdx.x;   // 51200
  int c = i & 127, s = (i >> 7) % S_, a = i / (128 * S_);
  pc[i] = lin0_b[c] + pos_emb[s * 128 + c] + c01[a * 128 + c];
}

// ---------------------------------------------------------------- graph prep
__global__ void hist_kernel(const int* __restrict__ dst, int* __restrict__ cnt, int E) {
  int e = blockIdx.x * 256 + threadIdx.x;
  if (e < E) atomicAdd(&cnt[dst[e]], 1);
}

__global__ __launch_bounds__(1024) void scanA_kernel(
    const int* __restrict__ cnt, int* __restrict__ locpref,
    int* __restrict__ btot, float* __restrict__ dis, int N) {
  __shared__ int wsum[16];
  int t = threadIdx.x, lane = t & 63, wid = t >> 6;
  int i = blockIdx.x * 1024 + t;
  int v = (i < N) ? cnt[i] : 0;
  if (i < N) dis[i] = rsqrtf(1.f + (float)v);
  int x = v;
  #pragma unroll
  for (int off = 1; off < 64; off <<= 1) {
    int y = __shfl_up(x, off);
    if (lane >= off) x += y;
  }
  if (lane == 63) wsum[wid] = x;
  __syncthreads();
  if (wid == 0 && lane < 16) {
    int s = wsum[lane];
    #pragma unroll
    for (int off = 1; off < 16; off <<= 1) {
      int y = __shfl_up(s, off);
      if (lane >= off) s += y;
    }
    wsum[lane] = s;
  }
  __syncthreads();
  int woff = (wid > 0) ? wsum[wid - 1] : 0;
  if (i < N) locpref[i] = woff + x - v;
  if (t == 1023) btot[blockIdx.x] = woff + x;
}

__global__ void scanB_kernel(const int* __restrict__ btot, int* __restrict__ boff, int nb) {
  int lane = threadIdx.x;
  int v = (lane < nb) ? btot[lane] : 0;
  int x = v;
  #pragma unroll
  for (int off = 1; off < 64; off <<= 1) {
    int y = __shfl_up(x, off);
    if (lane >= off) x += y;
  }
  if (lane < nb) boff[lane] = x - v;
}

__global__ void scanC_kernel(const int* __restrict__ locpref, const int* __restrict__ boff,
                             int* __restrict__ row_ptr, int* __restrict__ fill, int N) {
  int i = blockIdx.x * 256 + threadIdx.x;
  if (i < N) {
    int r = locpref[i] + boff[i >> 10];
    row_ptr[i] = r; fill[i] = r;
  }
  if (i == 0) row_ptr[N] = N_EDGES;
}

__global__ void scatter_kernel(const int* __restrict__ src, const int* __restrict__ dst,
                               int* __restrict__ fill, int* __restrict__ csr_src, int E) {
  int e = blockIdx.x * 256 + threadIdx.x;
  if (e >= E) return;
  int d = dst[e];
  int pos = atomicAdd(&fill[d], 1);
  csr_src[pos] = src[e];
}

// ------------------------------------------------------------ MFMA bf16 GEMM
// (GCN layers) C row-major; LDS-bounce coalesced uint4 stores.
__global__ __launch_bounds__(256) void gemm_bf16_kernel(
    const u16* __restrict__ A, const u16* __restrict__ wT,
    u16* __restrict__ C, int M) {
  __shared__ u16 ldsb[4][16 * 136];
  int t = threadIdx.x;
  int w = t >> 6, l = t & 63, lr = l & 15, lg = l >> 4;
  int r0 = blockIdx.x * 64 + w * 16;

  int row = r0 + lr;
  const u16* Arow = A + (size_t)(row < M ? row : 0) * 128;

  bfrag a[4];
  #pragma unroll
  for (int ks = 0; ks < 4; ++ks) a[ks] = *(const bfrag*)(Arow + ks * 32 + lg * 8);

  f32x4 acc[8];
  #pragma unroll
  for (int ct = 0; ct < 8; ++ct) acc[ct] = (f32x4){0.f, 0.f, 0.f, 0.f};
  #pragma unroll
  for (int ks = 0; ks < 4; ++ks)
    #pragma unroll
    for (int ct = 0; ct < 8; ++ct) {
      bfrag b = *(const bfrag*)(wT + (size_t)(ct * 16 + lr) * 128 + ks * 32 + lg * 8);
      acc[ct] = MFMA16(a[ks], b, acc[ct]);
    }
  #pragma unroll
  for (int ct = 0; ct < 8; ++ct)
    #pragma unroll
    for (int i = 0; i < 4; ++i)
      ldsb[w][(lg * 4 + i) * 136 + ct * 16 + lr] = f2bf(acc[ct][i]);
  #pragma unroll
  for (int j = 0; j < 4; ++j) {
    int c = j * 64 + l;
    int rw = c >> 4, ch = c & 15;
    int r = r0 + rw;
    if (r < M)
      *(uint4*)(C + (size_t)r * 128 + ch * 8) = *(const uint4*)&ldsb[w][rw * 136 + ch * 8];
  }
}

// ------------------------------------------------------------- GCN aggregate
__global__ __launch_bounds__(256) void agg_kernel(
    const u16* __restrict__ xw, const float* __restrict__ dis,
    const int* __restrict__ row_ptr, const int* __restrict__ csr_src,
    const float* __restrict__ bias, const float* __restrict__ lng,
    const float* __restrict__ lnb, u16* __restrict__ out, int N, int doLN) {
  int t = threadIdx.x;
  int n = blockIdx.x * 4 + (t >> 6);
  if (n >= N) return;
  int l = t & 63, cg = l & 15, eg = l >> 4;
  float dn = dis[n];
  float acc[8] = {0.f, 0.f, 0.f, 0.f, 0.f, 0.f, 0.f, 0.f};
  if (eg == 0) {
    uint4 r = *(const uint4*)(xw + (size_t)n * 128 + cg * 8);
    float w = dn * dn;
    acc[0] += w * bflo(r.x); acc[1] += w * bfhi(r.x);
    acc[2] += w * bflo(r.y); acc[3] += w * bfhi(r.y);
    acc[4] += w * bflo(r.z); acc[5] += w * bfhi(r.z);
    acc[6] += w * bflo(r.w); acc[7] += w * bfhi(r.w);
  }
  int e1 = row_ptr[n + 1];
  int e = row_ptr[n] + eg;
  int sn = (e < e1) ? csr_src[e] : -1;
  while (sn >= 0) {
    int s = sn;
    e += 4;
    sn = (e < e1) ? csr_src[e] : -1;
    float w = dis[s] * dn;
    uint4 r = *(const uint4*)(xw + (size_t)s * 128 + cg * 8);
    acc[0] += w * bflo(r.x); acc[1] += w * bfhi(r.x);
    acc[2] += w * bflo(r.y); acc[3] += w * bfhi(r.y);
    acc[4] += w * bflo(r.z); acc[5] += w * bfhi(r.z);
    acc[6] += w * bflo(r.w); acc[7] += w * bfhi(r.w);
  }
  #pragma unroll
  for (int j = 0; j < 8; ++j) {
    acc[j] += __shfl_xor(acc[j], 16);
    acc[j] += __shfl_xor(acc[j], 32);
  }
  int c0 = cg * 8;
  #pragma unroll
  for (int j = 0; j < 8; ++j) acc[j] = fmaxf(acc[j] + bias[c0 + j], 0.f);
  if (doLN) {
    float s1 = 0.f, s2 = 0.f;
    #pragma unroll
    for (int j = 0; j < 8; ++j) { s1 += acc[j]; s2 += acc[j] * acc[j]; }
    #pragma unroll
    for (int off = 1; off < 16; off <<= 1) {
      s1 += __shfl_xor(s1, off);
      s2 += __shfl_xor(s2, off);
    }
    float mean = s1 * (1.f / 128.f);
    float var = s2 * (1.f / 128.f) - mean * mean;
    float inv = rsqrtf(var + 1e-5f);
    #pragma unroll
    for (int j = 0; j < 8; ++j)
      acc[j] = (acc[j] - mean) * inv * lng[c0 + j] + lnb[c0 + j];
  }
  if (eg == 0) {
    uint4 o;
    o.x = pack2(acc[0], acc[1]); o.y = pack2(acc[2], acc[3]);
    o.z = pack2(acc[4], acc[5]); o.w = pack2(acc[6], acc[7]);
    *(uint4*)(out + (size_t)n * 128 + cg * 8) = o;
  }
}

// ----------------------- merged QKV: role A (inter->kh,vh) / role B (qh)
// head-major outputs [h][BS_][16]; coalesced via LDS bounce.
__global__ __launch_bounds__(256) void qkv_kernel(
    const u16* __restrict__ xa, const int* __restrict__ hist,
    const int* __restrict__ ans, const int* __restrict__ nseq,
    const u16* __restrict__ l0T, const float* __restrict__ pc,
    const u16* __restrict__ wkT, const float* __restrict__ bk,
    const u16* __restrict__ wvT, const float* __restrict__ bv,
    const u16* __restrict__ wqT, const float* __restrict__ bq,
    u16* __restrict__ khout, u16* __restrict__ vhout,
    u16* __restrict__ qhout, int nblk) {
  __shared__ u16 ldsb[4][16 * 136];
  int bb = blockIdx.x;
  int t = threadIdx.x, w = t >> 6, l = t & 63, lr = l & 15, lg = l >> 4;
  f32x4 acc[8];

  if (bb < nblk) {
    // ---- role A: gather(hist) -> inter(LDS) -> kh, vh ----
    int r0 = bb * 64 + w * 16;
    int arow = hist[r0 + lr];
    const u16* Arow = xa + (size_t)arow * 128;
    bfrag a[4];
    #pragma unroll
    for (int ks = 0; ks < 4; ++ks) a[ks] = *(const bfrag*)(Arow + ks * 32 + lg * 8);

    #pragma unroll
    for (int ct = 0; ct < 8; ++ct) acc[ct] = (f32x4){0.f, 0.f, 0.f, 0.f};
    #pragma unroll
    for (int ks = 0; ks < 4; ++ks)
      #pragma unroll
      for (int ct = 0; ct < 8; ++ct) {
        bfrag b = *(const bfrag*)(l0T + (size_t)(ct * 16 + lr) * 128 + ks * 32 + lg * 8);
        acc[ct] = MFMA16(a[ks], b, acc[ct]);
      }
    int pcoff[4];
    #pragma unroll
    for (int i = 0; i < 4; ++i) {
      int r = r0 + lg * 4 + i;
      pcoff[i] = (ans[r] * S_ + (r % S_)) * 128;
    }
    #pragma unroll
    for (int ct = 0; ct < 8; ++ct) {
      int col = ct * 16 + lr;
      #pragma unroll
      for (int i = 0; i < 4; ++i)
        ldsb[w][(lg * 4 + i) * 136 + col] = f2bf(acc[ct][i] + pc[pcoff[i] + col]);
    }
    bfrag a2[4];
    #pragma unroll
    for (int ks = 0; ks < 4; ++ks)
      a2[ks] = *(const bfrag*)(&ldsb[w][lr * 136 + ks * 32 + lg * 8]);

    // kh
    #pragma unroll
    for (int ct = 0; ct < 8; ++ct) acc[ct] = (f32x4){0.f, 0.f, 0.f, 0.f};
    #pragma unroll
    for (int ks = 0; ks < 4; ++ks)
      #pragma unroll
      for (int ct = 0; ct < 8; ++ct) {
        bfrag b = *(const bfrag*)(wkT + (size_t)(ct * 16 + lr) * 128 + ks * 32 + lg * 8);
        acc[ct] = MFMA16(a2[ks], b, acc[ct]);
      }
    #pragma unroll
    for (int ct = 0; ct < 8; ++ct)
      #pragma unroll
      for (int i = 0; i < 4; ++i)
        ldsb[w][(lg * 4 + i) * 136 + ct * 16 + lr] = f2bf(acc[ct][i] + bk[ct * 16 + lr]);
    #pragma unroll
    for (int j = 0; j < 4; ++j) {
      int c = j * 64 + l;
      int head = c >> 5, rw = (c >> 1) & 15, half = c & 1;
      *(uint4*)(khout + ((size_t)head * BS_ + r0 + rw) * 16 + half * 8) =
          *(const uint4*)&ldsb[w][rw * 136 + head * 16 + half * 8];
    }

    // vh
    #pragma unroll
    for (int ct = 0; ct < 8; ++ct) acc[ct] = (f32x4){0.f, 0.f, 0.f, 0.f};
    #pragma unroll
    for (int ks = 0; ks < 4; ++ks)
      #pragma unroll
      for (int ct = 0; ct < 8; ++ct) {
        bfrag b = *(const bfrag*)(wvT + (size_t)(ct * 16 + lr) * 128 + ks * 32 + lg * 8);
        acc[ct] = MFMA16(a2[ks], b, acc[ct]);
      }
    #pragma unroll
    for (int ct = 0; ct < 8; ++ct)
      #pragma unroll
      for (int i = 0; i < 4; ++i)
        ldsb[w][(lg * 4 + i) * 136 + ct * 16 + lr] = f2bf(acc[ct][i] + bv[ct * 16 + lr]);
    #pragma unroll
    for (int j = 0; j < 4; ++j) {
      int c = j * 64 + l;
      int head = c >> 5, rw = (c >> 1) & 15, half = c & 1;
      *(uint4*)(vhout + ((size_t)head * BS_ + r0 + rw) * 16 + half * 8) =
          *(const uint4*)&ldsb[w][rw * 136 + head * 16 + half * 8];
    }
  } else {
    // ---- role B: gather(new) -> qh (head-major) ----
    int r0 = (bb - nblk) * 64 + w * 16;
    int arow = nseq[r0 + lr];
    const u16* Arow = xa + (size_t)arow * 128;
    bfrag a[4];
    #pragma unroll
    for (int ks = 0; ks < 4; ++ks) a[ks] = *(const bfrag*)(Arow + ks * 32 + lg * 8);

    #pragma unroll
    for (int ct = 0; ct < 8; ++ct) acc[ct] = (f32x4){0.f, 0.f, 0.f, 0.f};
    #pragma unroll
    for (int ks = 0; ks < 4; ++ks)
      #pragma unroll
      for (int ct = 0; ct < 8; ++ct) {
        bfrag b = *(const bfrag*)(wqT + (size_t)(ct * 16 + lr) * 128 + ks * 32 + lg * 8);
        acc[ct] = MFMA16(a[ks], b, acc[ct]);
      }
    #pragma unroll
    for (int ct = 0; ct < 8; ++ct)
      #pragma unroll
      for (int i = 0; i < 4; ++i)
        ldsb[w][(lg * 4 + i) * 136 + ct * 16 + lr] = f2bf(acc[ct][i] + bq[ct * 16 + lr]);
    #pragma unroll
    for (int j = 0; j < 4; ++j) {
      int c = j * 64 + l;
      int head = c >> 5, rw = (c >> 1) & 15, half = c & 1;
      *(uint4*)(qhout + ((size_t)head * BS_ + r0 + rw) * 16 + half * 8) =
          *(const uint4*)&ldsb[w][rw * 136 + head * 16 + half * 8];
    }
  }
}

// ----------------------------------------------------------- MFMA attention
__global__ __launch_bounds__(256) void attn_mfma_kernel(
    u16* qh_ao, const u16* __restrict__ kh, const u16* __restrict__ vh) {
  __shared__ u16 Kl[208 * 24];
  __shared__ u16 Vt[16 * 232];
  __shared__ u16 Pl[4 * 16 * 232];
  int b = blockIdx.x >> 3, h = blockIdx.x & 7;
  int t = threadIdx.x;
  size_t base = ((size_t)h * BS_ + (size_t)b * S_) * 16;

  for (int i = t; i < 208 * 2; i += 256) {
    int key = i >> 1, d = (i & 1) * 8;
    uint4 v = make_uint4(0, 0, 0, 0);
    if (key < S_) v = *(const uint4*)(kh + base + (size_t)key * 16 + d);
    *(uint4*)(Kl + key * 24 + d) = v;
  }
  for (int i = t; i < 16 * 232; i += 256) {
    int d = i / 232, key = i - d * 232;
    Vt[d * 232 + key] = (key < S_) ? vh[base + (size_t)key * 16 + d] : (u16)0;
  }
  for (int i = t; i < 4 * 16 * 232 / 2; i += 256) ((u32*)Pl)[i] = 0;
  __syncthreads();

  int w = t >> 6, l = t & 63, lr = l & 15, lg = l >> 4;
  u16* Pw = Pl + w * 16 * 232;
  const f32x4 zero4 = {0.f, 0.f, 0.f, 0.f};

  for (int qi = w; qi < 13; qi += 4) {
    bfrag aq = (bfrag){0, 0, 0, 0, 0, 0, 0, 0};
    int qrow = qi * 16 + lr;
    if (lg < 2 && qrow < S_)
      aq = *(const bfrag*)(qh_ao + base + (size_t)qrow * 16 + lg * 8);
    float rsum[4] = {0.f, 0.f, 0.f, 0.f};
    for (int kj = 0; kj <= qi; ++kj) {
      bfrag bk = (bfrag){0, 0, 0, 0, 0, 0, 0, 0};
      if (lg < 2) bk = *(const bfrag*)(Kl + (kj * 16 + lr) * 24 + lg * 8);
      f32x4 sc = MFMA16(aq, bk, zero4);
      #pragma unroll
      for (int i = 0; i < 4; ++i) {
        int q = qi * 16 + lg * 4 + i, key = kj * 16 + lr;
        float p = 0.f;
        if (key <= q && q < S_) p = __expf(sc[i] * 0.25f);
        rsum[i] += p;
        Pw[(lg * 4 + i) * 232 + key] = f2bf(p);
      }
    }
    #pragma unroll
    for (int i = 0; i < 4; ++i) {
      rsum[i] += __shfl_xor(rsum[i], 1);
      rsum[i] += __shfl_xor(rsum[i], 2);
      rsum[i] += __shfl_xor(rsum[i], 4);
      rsum[i] += __shfl_xor(rsum[i], 8);
    }
    f32x4 o = zero4;
    #pragma unroll
    for (int kt = 0; kt < 7; ++kt) {
      bfrag ap = *(const bfrag*)(Pw + lr * 232 + kt * 32 + lg * 8);
      bfrag bv = *(const bfrag*)(Vt + lr * 232 + kt * 32 + lg * 8);
      o = MFMA16(ap, bv, o);
    }
    #pragma unroll
    for (int i = 0; i < 4; ++i) {
      int q = qi * 16 + lg * 4 + i;
      if (q < S_) qh_ao[base + (size_t)q * 16 + lr] = f2bf(o[i] / rsum[i]);
    }
  }
}

// ---- fused output: ao@wo + bo + gather(new)@l3T -> LN2 -> FFN -> LN3 -> pred
__global__ __launch_bounds__(256) void out_kernel(
    const u16* __restrict__ ao, const u16* __restrict__ xa,
    const int* __restrict__ nseq,
    const u16* __restrict__ woT, const float* __restrict__ bo,
    const u16* __restrict__ l3T,
    const float* __restrict__ g2, const float* __restrict__ b2,
    const u16* __restrict__ f0T, const float* __restrict__ b0f,
    const u16* __restrict__ f1T, const float* __restrict__ b1f,
    const float* __restrict__ g3, const float* __restrict__ b3,
    const float* __restrict__ w4, const float* __restrict__ b4,
    float* __restrict__ pred) {
  __shared__ u16 ldsA[4][16 * 136];
  __shared__ u16 ldsB[4][16 * 136];
  int t = threadIdx.x, w = t >> 6, l = t & 63, lr = l & 15, lg = l >> 4;
  int r0 = blockIdx.x * 64 + w * 16;

  // A-frags from ao (head-major)
  bfrag a[4];
  #pragma unroll
  for (int ks = 0; ks < 4; ++ks) {
    int head = ks * 2 + (lg >> 1);
    int d0 = (lg & 1) * 8;
    a[ks] = *(const bfrag*)(ao + ((size_t)head * BS_ + r0 + lr) * 16 + d0);
  }
  f32x4 acc[8];
  #pragma unroll
  for (int ct = 0; ct < 8; ++ct) acc[ct] = (f32x4){0.f, 0.f, 0.f, 0.f};
  #pragma unroll
  for (int ks = 0; ks < 4; ++ks)
    #pragma unroll
    for (int ct = 0; ct < 8; ++ct) {
      bfrag b = *(const bfrag*)(woT + (size_t)(ct * 16 + lr) * 128 + ks * 32 + lg * 8);
      acc[ct] = MFMA16(a[ks], b, acc[ct]);
    }
  // + residual q = gather(new)@l3T (accumulate into same acc)
  {
    int arow = nseq[r0 + lr];
    const u16* Arow = xa + (size_t)arow * 128;
    #pragma unroll
    for (int ks = 0; ks < 4; ++ks) a[ks] = *(const bfrag*)(Arow + ks * 32 + lg * 8);
    #pragma unroll
    for (int ks = 0; ks < 4; ++ks)
      #pragma unroll
      for (int ct = 0; ct < 8; ++ct) {
        bfrag b = *(const bfrag*)(l3T + (size_t)(ct * 16 + lr) * 128 + ks * 32 + lg * 8);
        acc[ct] = MFMA16(a[ks], b, acc[ct]);
      }
  }
  #pragma unroll
  for (int ct = 0; ct < 8; ++ct) {
    float bcol = bo[ct * 16 + lr];
    #pragma unroll
    for (int i = 0; i < 4; ++i) acc[ct][i] += bcol;
  }
  // LN2 -> acc holds atn (f32); bounce bf16 to ldsA
  {
    float s1[4] = {0, 0, 0, 0}, s2[4] = {0, 0, 0, 0};
    #pragma unroll
    for (int ct = 0; ct < 8; ++ct)
      #pragma unroll
      for (int i = 0; i < 4; ++i) {
        s1[i] += acc[ct][i];
        s2[i] += acc[ct][i] * acc[ct][i];
      }
    #pragma unroll
    for (int i = 0; i < 4; ++i) {
      s1[i] += __shfl_xor(s1[i], 1); s2[i] += __shfl_xor(s2[i], 1);
      s1[i] += __shfl_xor(s1[i], 2); s2[i] += __shfl_xor(s2[i], 2);
      s1[i] += __shfl_xor(s1[i], 4); s2[i] += __shfl_xor(s2[i], 4);
      s1[i] += __shfl_xor(s1[i], 8); s2[i] += __shfl_xor(s2[i], 8);
    }
    float mean[4], inv[4];
    #pragma unroll
    for (int i = 0; i < 4; ++i) {
      mean[i] = s1[i] * (1.f / 128.f);
      float var = s2[i] * (1.f / 128.f) - mean[i] * mean[i];
      inv[i] = rsqrtf(var + 1e-5f);
    }
    #pragma unroll
    for (int ct = 0; ct < 8; ++ct) {
      int col = ct * 16 + lr;
      float gc = g2[col], bc = b2[col];
      #pragma unroll
      for (int i = 0; i < 4; ++i) {
        acc[ct][i] = (acc[ct][i] - mean[i]) * inv[i] * gc + bc;
        ldsA[w][(lg * 4 + i) * 136 + col] = f2bf(acc[ct][i]);
      }
    }
  }
  // f0 GEMM from ldsA
  bfrag a2[4];
  #pragma unroll
  for (int ks = 0; ks < 4; ++ks)
    a2[ks] = *(const bfrag*)(&ldsA[w][lr * 136 + ks * 32 + lg * 8]);
  f32x4 acc2[8];
  #pragma unroll
  for (int ct = 0; ct < 8; ++ct) acc2[ct] = (f32x4){0.f, 0.f, 0.f, 0.f};
  #pragma unroll
  for (int ks = 0; ks < 4; ++ks)
    #pragma unroll
    for (int ct = 0; ct < 8; ++ct) {
      bfrag b = *(const bfrag*)(f0T + (size_t)(ct * 16 + lr) * 128 + ks * 32 + lg * 8);
      acc2[ct] = MFMA16(a2[ks], b, acc2[ct]);
    }
  #pragma unroll
  for (int ct = 0; ct < 8; ++ct) {
    int col = ct * 16 + lr;
    float bcol = b0f[col];
    #pragma unroll
    for (int i = 0; i < 4; ++i)
      ldsB[w][(lg * 4 + i) * 136 + col] = f2bf(fmaxf(acc2[ct][i] + bcol, 0.f));
  }
  // f1 GEMM from ldsB; + b1 + atn resid (f32 in acc)
  #pragma unroll
  for (int ks = 0; ks < 4; ++ks)
    a2[ks] = *(const bfrag*)(&ldsB[w][lr * 136 + ks * 32 + lg * 8]);
  #pragma unroll
  for (int ct = 0; ct < 8; ++ct) acc2[ct] = (f32x4){0.f, 0.f, 0.f, 0.f};
  #pragma unroll
  for (int ks = 0; ks < 4; ++ks)
    #pragma unroll
    for (int ct = 0; ct < 8; ++ct) {
      bfrag b = *(const bfrag*)(f1T + (size_t)(ct * 16 + lr) * 128 + ks * 32 + lg * 8);
      acc2[ct] = MFMA16(a2[ks], b, acc2[ct]);
    }
  #pragma unroll
  for (int ct = 0; ct < 8; ++ct) {
    int col = ct * 16 + lr;
    float bcol = b1f[col];
    #pragma unroll
    for (int i = 0; i < 4; ++i) acc2[ct][i] += bcol + acc[ct][i];
  }
  // LN3 -> dot w4 -> pred
  {
    float s1[4] = {0, 0, 0, 0}, s2[4] = {0, 0, 0, 0};
    #pragma unroll
    for (int ct = 0; ct < 8; ++ct)
      #pragma unroll
      for (int i = 0; i < 4; ++i) {
        s1[i] += acc2[ct][i];
        s2[i] += acc2[ct][i] * acc2[ct][i];
      }
    #pragma unroll
    for (int i = 0; i < 4; ++i) {
      s1[i] += __shfl_xor(s1[i], 1); s2[i] += __shfl_xor(s2[i], 1);
      s1[i] += __shfl_xor(s1[i], 2); s2[i] += __shfl_xor(s2[i], 2);
      s1[i] += __shfl_xor(s1[i], 4); s2[i] += __shfl_xor(s2[i], 4);
      s1[i] += __shfl_xor(s1[i], 8); s2[i] += __shfl_xor(s2[i], 8);
    }
    float p[4] = {0, 0, 0, 0};
    #pragma unroll
    for (int i = 0; i < 4; ++i) {
      float mean = s1[i] * (1.f / 128.f);
      float var = s2[i] * (1.f / 128.f) - mean * mean;
      float inv = rsqrtf(var + 1e-5f);
      #pragma unroll
      for (int ct = 0; ct < 8; ++ct) {
        int col = ct * 16 + lr;
        p[i] += ((acc2[ct][i] - mean) * inv * g3[col] + b3[col]) * w4[col];
      }
    }
    #pragma unroll
    for (int i = 0; i < 4; ++i) {
      p[i] += __shfl_xor(p[i], 1);
      p[i] += __shfl_xor(p[i], 2);
      p[i] += __shfl_xor(p[i], 4);
      p[i] += __shfl_xor(p[i], 8);
    }
    if (lr == 0) {
      float bias4 = b4[0];
      #pragma unroll
      for (int i = 0; i < 4; ++i) pred[r0 + lg * 4 + i] = p[i] + bias4;
    }
  }
}

// ---------------------------------------------------------------------------
extern "C" void kernel_launch(void* const* d_in, const int* in_sizes, int n_in,
                              void* d_out, int out_size, void* d_ws, size_t ws_size,
                              hipStream_t stream) {
  const int* hist_seq = (const int*)d_in[0];
  const int* hist_ans = (const int*)d_in[1];
  const int* new_seq = (const int*)d_in[2];
  const int* edge_index = (const int*)d_in[3];
  const float* node_x = (const float*)d_in[4];
  const float* gcn_w0 = (const float*)d_in[5];
  const float* gcn_b0 = (const float*)d_in[6];
  const float* gcn_w1 = (const float*)d_in[7];
  const float* gcn_b1 = (const float*)d_in[8];
  const float* gcn_w2 = (const float*)d_in[9];
  const float* gcn_b2 = (const float*)d_in[10];
  const float* ln0_g = (const float*)d_in[11];
  const float* ln0_b = (const float*)d_in[12];
  const float* ln1_g = (const float*)d_in[13];
  const float* ln1_b = (const float*)d_in[14];
  const float* ln2_g = (const float*)d_in[15];
  const float* ln2_b = (const float*)d_in[16];
  const float* ln3_g = (const float*)d_in[17];
  const float* ln3_b = (const float*)d_in[18];
  const float* corr_emb = (const float*)d_in[19];
  const float* lin0_w = (const float*)d_in[20];
  const float* lin0_b = (const float*)d_in[21];
  const float* lin1_w = (const float*)d_in[22];
  const float* lin2_w = (const float*)d_in[23];
  const float* lin3_w = (const float*)d_in[24];
  const float* lin4_w = (const float*)d_in[25];
  const float* lin4_b = (const float*)d_in[26];
  const float* pos_emb = (const float*)d_in[27];
  const float* mha_wq = (const float*)d_in[28];
  const float* mha_bq = (const float*)d_in[29];
  const float* mha_wk = (const float*)d_in[30];
  const float* mha_bk = (const float*)d_in[31];
  const float* mha_wv = (const float*)d_in[32];
  const float* mha_bv = (const float*)d_in[33];
  const float* mha_wo = (const float*)d_in[34];
  const float* mha_bo = (const float*)d_in[35];
  const float* ffn0_w = (const float*)d_in[36];
  const float* ffn0_b = (const float*)d_in[37];
  const float* ffn1_w = (const float*)d_in[38];
  const float* ffn1_b = (const float*)d_in[39];
  (void)in_sizes; (void)n_in; (void)out_size;

  char* ws = (char*)d_ws;
  size_t off = 0;
  auto alloc = [&](size_t bytes) -> void* {
    void* p = ws + off;
    off += (bytes + 255) & ~(size_t)255;
    return p;
  };
  int* cnt = (int*)alloc((size_t)N_NODES * 4);
  int* row_ptr = (int*)alloc((size_t)(N_NODES + 1) * 4);
  int* fill = (int*)alloc((size_t)N_NODES * 4);
  int* locpref = (int*)alloc((size_t)N_NODES * 4);
  int* btot = (int*)alloc(64 * 4);
  int* boff = (int*)alloc(64 * 4);
  float* dis = (float*)alloc((size_t)N_NODES * 4);
  int* csr_src = (int*)alloc((size_t)N_EDGES * 4);
  const size_t WB = 128 * 128 * 2;
  u16* g0T = (u16*)alloc(WB);
  u16* g1T = (u16*)alloc(WB);
  u16* g2T = (u16*)alloc(WB);
  u16* l0T = (u16*)alloc(WB);
  u16* l3T = (u16*)alloc(WB);
  u16* woT = (u16*)alloc(WB);
  u16* f0T = (u16*)alloc(WB);
  u16* f1T = (u16*)alloc(WB);
  u16* wqT = (u16*)alloc(WB);
  u16* wkT = (u16*)alloc(WB);
  u16* wvT = (u16*)alloc(WB);
  float* c01 = (float*)alloc(2 * 128 * 4);
  float* pc = (float*)alloc((size_t)2 * S_ * 128 * 4);
  u16* xa = (u16*)alloc((size_t)N_NODES * 128 * 2);
  const size_t CB = (size_t)BS_ * 128 * 2;   // 26.2 MB
  size_t RB = off;
  u16* bufQ = (u16*)(ws + RB);                // qh -> ao in place, head-major
  u16* bufK = (u16*)(ws + RB + CB);           // kh head-major
  u16* bufV = (u16*)(ws + RB + 2 * CB);       // vh head-major
  u16* xb = bufQ;                             // overlay: dead before qkv writes
  u16* xw = bufQ + (size_t)N_NODES * 128;
  size_t need = RB + 3 * CB;
  if (ws_size < need) return;     // diagnostic guard

  // ---- graph prep ----
  int nb = (N_NODES + 1023) / 1024;   // 49
  zero_i32_kernel<<<(N_NODES + 255) / 256, 256, 0, stream>>>(cnt, N_NODES);
  hist_kernel<<<(N_EDGES + 255) / 256, 256, 0, stream>>>(edge_index + N_EDGES, cnt, N_EDGES);
  scanA_kernel<<<nb, 1024, 0, stream>>>(cnt, locpref, btot, dis, N_NODES);
  scanB_kernel<<<1, 64, 0, stream>>>(btot, boff, nb);
  scanC_kernel<<<(N_NODES + 255) / 256, 256, 0, stream>>>(locpref, boff, row_ptr, fill, N_NODES);
  scatter_kernel<<<(N_EDGES + 255) / 256, 256, 0, stream>>>(edge_index, edge_index + N_EDGES,
                                                            fill, csr_src, N_EDGES);
  // ---- weight prep + pc table + node_x cast ----
  wprep_kernel<<<705, 256, 0, stream>>>(gcn_w0, gcn_w1, gcn_w2, lin0_w, lin3_w, mha_wo,
                                        ffn0_w, ffn1_w, lin1_w, lin2_w, mha_wq, mha_wk,
                                        mha_wv, corr_emb, g0T, g1T, g2T, l0T, l3T, woT,
                                        f0T, f1T, wqT, wkT, wvT, c01);
  pc_kernel<<<(2 * S_ * 128 + 255) / 256, 256, 0, stream>>>(lin0_b, pos_emb, c01, pc);
  f2bf8_kernel<<<(N_NODES * 16 + 255) / 256, 256, 0, stream>>>(node_x, xb, N_NODES * 16);

  int gN = (N_NODES + 63) / 64;
  int aN = (N_NODES + 3) / 4;

  // ---- GCN ----
  gemm_bf16_kernel<<<gN, 256, 0, stream>>>(xb, g0T, xw, N_NODES);
  agg_kernel<<<aN, 256, 0, stream>>>(xw, dis, row_ptr, csr_src, gcn_b0, ln0_g, ln0_b, xa, N_NODES, 1);
  gemm_bf16_kernel<<<gN, 256, 0, stream>>>(xa, g1T, xw, N_NODES);
  agg_kernel<<<aN, 256, 0, stream>>>(xw, dis, row_ptr, csr_src, gcn_b1, ln1_g, ln1_b, xa, N_NODES, 1);
  gemm_bf16_kernel<<<gN, 256, 0, stream>>>(xa, g2T, xw, N_NODES);
  agg_kernel<<<aN, 256, 0, stream>>>(xw, dis, row_ptr, csr_src, gcn_b2, nullptr, nullptr, xa, N_NODES, 0);

  // ---- transformer, full batch, 3 dispatches ----
  int gT = BS_ / 64;   // 1600
  qkv_kernel<<<2 * gT, 256, 0, stream>>>(xa, hist_seq, hist_ans, new_seq,
                                         l0T, pc, wkT, mha_bk, wvT, mha_bv,
                                         wqT, mha_bq, bufK, bufV, bufQ, gT);
  attn_mfma_kernel<<<B_ * 8, 256, 0, stream>>>(bufQ, bufK, bufV);
  out_kernel<<<gT, 256, 0, stream>>>(bufQ, xa, new_seq, woT, mha_bo, l3T,
                                     ln2_g, ln2_b, f0T, ffn0_b, f1T, ffn1_b,
                                     ln3_g, ln3_b, lin4_w, lin4_b, (float*)d_out);
}

// Round 10
// 450.164 us; speedup vs baseline: 3.2030x; 1.2873x over previous
//
#include <hip/hip_runtime.h>
#include <math.h>

#define N_NODES 50000
#define N_EDGES 800000
#define B_ 512
#define S_ 200
#define D_ 128
#define BS_ (B_*S_)            // 102400 rows, full batch

typedef unsigned short u16;
typedef unsigned int u32;
using bfrag = __attribute__((ext_vector_type(8))) short;
using f32x4 = __attribute__((ext_vector_type(4))) float;

__device__ __forceinline__ u16 f2bf(float f) {        // RNE f32 -> bf16 bits
  u32 u = __float_as_uint(f);
  u32 r = (u + 0x7fffu + ((u >> 16) & 1u)) >> 16;
  return (u16)r;
}
__device__ __forceinline__ float bf2f(u16 v) { return __uint_as_float(((u32)v) << 16); }
__device__ __forceinline__ float bflo(u32 v) { return __uint_as_float(v << 16); }
__device__ __forceinline__ float bfhi(u32 v) { return __uint_as_float(v & 0xffff0000u); }
__device__ __forceinline__ u32 pack2(float a, float b) {
  return (u32)f2bf(a) | ((u32)f2bf(b) << 16);
}
#define MFMA16(a, b, c) __builtin_amdgcn_mfma_f32_16x16x32_bf16((a), (b), (c), 0, 0, 0)

// stage a 128x128 bf16 weight (row-major [c][k]) into padded LDS sW[128][136]
#define STAGE_W(Wsrc) \
  for (int i_ = threadIdx.x; i_ < 2048; i_ += 256) { \
    int c_ = i_ >> 4, kg_ = i_ & 15; \
    *(uint4*)(sW + c_ * 136 + kg_ * 8) = *(const uint4*)((Wsrc) + c_ * 128 + kg_ * 8); \
  }

// ---------------------------------------------------------------- utilities
__global__ void zero_i32_kernel(int* __restrict__ p, int n) {
  int i = blockIdx.x * 256 + threadIdx.x;
  if (i < n) p[i] = 0;
}

__global__ void f2bf8_kernel(const float* __restrict__ in, u16* __restrict__ out, int n8) {
  int i = blockIdx.x * 256 + threadIdx.x;
  if (i >= n8) return;
  float4 a = ((const float4*)in)[i * 2];
  float4 b = ((const float4*)in)[i * 2 + 1];
  uint4 o;
  o.x = pack2(a.x, a.y); o.y = pack2(a.z, a.w);
  o.z = pack2(b.x, b.y); o.w = pack2(b.z, b.w);
  ((uint4*)out)[i] = o;
}

// ---------------- fused weight prep: 8 transposes + 3 products + c01
__global__ __launch_bounds__(256) void wprep_kernel(
    const float* __restrict__ gcn_w0, const float* __restrict__ gcn_w1,
    const float* __restrict__ gcn_w2, const float* __restrict__ lin0_w,
    const float* __restrict__ lin3_w, const float* __restrict__ mha_wo,
    const float* __restrict__ ffn0_w, const float* __restrict__ ffn1_w,
    const float* __restrict__ lin1_w, const float* __restrict__ lin2_w,
    const float* __restrict__ mha_wq, const float* __restrict__ mha_wk,
    const float* __restrict__ mha_wv, const float* __restrict__ corr_emb,
    u16* __restrict__ g0T, u16* __restrict__ g1T, u16* __restrict__ g2T,
    u16* __restrict__ l0T, u16* __restrict__ l3T, u16* __restrict__ woT,
    u16* __restrict__ f0T, u16* __restrict__ f1T,
    u16* __restrict__ wqT, u16* __restrict__ wkT, u16* __restrict__ wvT,
    float* __restrict__ c01) {
  int bb = blockIdx.x;
  if (bb < 512) {                        // plain transpose W[k][c] -> D[c][k]
    const float* W; u16* D;
    switch (bb >> 6) {
      case 0: W = gcn_w0; D = g0T; break;
      case 1: W = gcn_w1; D = g1T; break;
      case 2: W = gcn_w2; D = g2T; break;
      case 3: W = lin0_w; D = l0T; break;
      case 4: W = lin3_w; D = l3T; break;
      case 5: W = mha_wo; D = woT; break;
      case 6: W = ffn0_w; D = f0T; break;
      default: W = ffn1_w; D = f1T; break;
    }
    int i = (bb & 63) * 256 + threadIdx.x;
    int k = i >> 7, c = i & 127;
    D[c * 128 + k] = f2bf(W[k * 128 + c]);
  } else if (bb < 704) {                 // (X@Y)^T -> D
    const float* X; const float* Y; u16* D;
    switch ((bb - 512) >> 6) {
      case 0: X = lin3_w; Y = mha_wq; D = wqT; break;
      case 1: X = lin2_w; Y = mha_wk; D = wkT; break;
      default: X = lin1_w; Y = mha_wv; D = wvT; break;
    }
    int i = ((bb - 512) & 63) * 256 + threadIdx.x;
    int k = i >> 7, c = i & 127;
    float acc = 0.f;
    for (int t = 0; t < 128; ++t) acc += X[k * 128 + t] * Y[t * 128 + c];
    D[c * 128 + k] = f2bf(acc);
  } else {                               // c01 = corr_emb @ lin0_w[128:]
    int idx = threadIdx.x;               // 0..255 = 2*128
    int i = idx >> 7, j = idx & 127;
    float acc = 0.f;
    for (int t = 0; t < 128; ++t)
      acc += corr_emb[i * 128 + t] * lin0_w[128 * 128 + t * 128 + j];
    c01[idx] = acc;
  }
}

// pc[a][s][c] = lin0_b[c] + pos_emb[s][c] + c01[a][c]
__global__ void pc_kernel(const float* __restrict__ lin0_b, const float* __restrict__ pos_emb,
                          const float* __restrict__ c01, float* __restrict__ pc) {
  int i = blockIdx.x * 256 + threadIdx.x;   // 51200
  int c = i & 127, s = (i >> 7) % S_, a = i / (128 * S_);
  pc[i] = lin0_b[c] + pos_emb[s * 128 + c] + c01[a * 128 + c];
}

// ---------------------------------------------------------------- graph prep
__global__ void hist_kernel(const int* __restrict__ dst, int* __restrict__ cnt, int E) {
  int e = blockIdx.x * 256 + threadIdx.x;
  if (e < E) atomicAdd(&cnt[dst[e]], 1);
}

__global__ __launch_bounds__(1024) void scanA_kernel(
    const int* __restrict__ cnt, int* __restrict__ locpref,
    int* __restrict__ btot, float* __restrict__ dis, int N) {
  __shared__ int wsum[16];
  int t = threadIdx.x, lane = t & 63, wid = t >> 6;
  int i = blockIdx.x * 1024 + t;
  int v = (i < N) ? cnt[i] : 0;
  if (i < N) dis[i] = rsqrtf(1.f + (float)v);
  int x = v;
  #pragma unroll
  for (int off = 1; off < 64; off <<= 1) {
    int y = __shfl_up(x, off);
    if (lane >= off) x += y;
  }
  if (lane == 63) wsum[wid] = x;
  __syncthreads();
  if (wid == 0 && lane < 16) {
    int s = wsum[lane];
    #pragma unroll
    for (int off = 1; off < 16; off <<= 1) {
      int y = __shfl_up(s, off);
      if (lane >= off) s += y;
    }
    wsum[lane] = s;
  }
  __syncthreads();
  int woff = (wid > 0) ? wsum[wid - 1] : 0;
  if (i < N) locpref[i] = woff + x - v;
  if (t == 1023) btot[blockIdx.x] = woff + x;
}

__global__ void scanB_kernel(const int* __restrict__ btot, int* __restrict__ boff, int nb) {
  int lane = threadIdx.x;
  int v = (lane < nb) ? btot[lane] : 0;
  int x = v;
  #pragma unroll
  for (int off = 1; off < 64; off <<= 1) {
    int y = __shfl_up(x, off);
    if (lane >= off) x += y;
  }
  if (lane < nb) boff[lane] = x - v;
}

__global__ void scanC_kernel(const int* __restrict__ locpref, const int* __restrict__ boff,
                             int* __restrict__ row_ptr, int* __restrict__ fill, int N) {
  int i = blockIdx.x * 256 + threadIdx.x;
  if (i < N) {
    int r = locpref[i] + boff[i >> 10];
    row_ptr[i] = r; fill[i] = r;
  }
  if (i == 0) row_ptr[N] = N_EDGES;
}

__global__ void scatter_kernel(const int* __restrict__ src, const int* __restrict__ dst,
                               int* __restrict__ fill, int* __restrict__ csr_src, int E) {
  int e = blockIdx.x * 256 + threadIdx.x;
  if (e >= E) return;
  int d = dst[e];
  int pos = atomicAdd(&fill[d], 1);
  csr_src[pos] = src[e];
}

// ------------------------------------------------------------ MFMA bf16 GEMM
// (GCN layers) C row-major; LDS-bounce coalesced uint4 stores.
__global__ __launch_bounds__(256) void gemm_bf16_kernel(
    const u16* __restrict__ A, const u16* __restrict__ wT,
    u16* __restrict__ C, int M) {
  __shared__ u16 ldsb[4][16 * 136];
  int t = threadIdx.x;
  int w = t >> 6, l = t & 63, lr = l & 15, lg = l >> 4;
  int r0 = blockIdx.x * 64 + w * 16;

  int row = r0 + lr;
  const u16* Arow = A + (size_t)(row < M ? row : 0) * 128;

  bfrag a[4];
  #pragma unroll
  for (int ks = 0; ks < 4; ++ks) a[ks] = *(const bfrag*)(Arow + ks * 32 + lg * 8);

  f32x4 acc[8];
  #pragma unroll
  for (int ct = 0; ct < 8; ++ct) acc[ct] = (f32x4){0.f, 0.f, 0.f, 0.f};
  #pragma unroll
  for (int ks = 0; ks < 4; ++ks)
    #pragma unroll
    for (int ct = 0; ct < 8; ++ct) {
      bfrag b = *(const bfrag*)(wT + (size_t)(ct * 16 + lr) * 128 + ks * 32 + lg * 8);
      acc[ct] = MFMA16(a[ks], b, acc[ct]);
    }
  #pragma unroll
  for (int ct = 0; ct < 8; ++ct)
    #pragma unroll
    for (int i = 0; i < 4; ++i)
      ldsb[w][(lg * 4 + i) * 136 + ct * 16 + lr] = f2bf(acc[ct][i]);
  #pragma unroll
  for (int j = 0; j < 4; ++j) {
    int c = j * 64 + l;
    int rw = c >> 4, ch = c & 15;
    int r = r0 + rw;
    if (r < M)
      *(uint4*)(C + (size_t)r * 128 + ch * 8) = *(const uint4*)&ldsb[w][rw * 136 + ch * 8];
  }
}

// ------------------------------------------------------------- GCN aggregate
__global__ __launch_bounds__(256) void agg_kernel(
    const u16* __restrict__ xw, const float* __restrict__ dis,
    const int* __restrict__ row_ptr, const int* __restrict__ csr_src,
    const float* __restrict__ bias, const float* __restrict__ lng,
    const float* __restrict__ lnb, u16* __restrict__ out, int N, int doLN) {
  int t = threadIdx.x;
  int n = blockIdx.x * 4 + (t >> 6);
  if (n >= N) return;
  int l = t & 63, cg = l & 15, eg = l >> 4;
  float dn = dis[n];
  float acc[8] = {0.f, 0.f, 0.f, 0.f, 0.f, 0.f, 0.f, 0.f};
  if (eg == 0) {
    uint4 r = *(const uint4*)(xw + (size_t)n * 128 + cg * 8);
    float w = dn * dn;
    acc[0] += w * bflo(r.x); acc[1] += w * bfhi(r.x);
    acc[2] += w * bflo(r.y); acc[3] += w * bfhi(r.y);
    acc[4] += w * bflo(r.z); acc[5] += w * bfhi(r.z);
    acc[6] += w * bflo(r.w); acc[7] += w * bfhi(r.w);
  }
  int e1 = row_ptr[n + 1];
  int e = row_ptr[n] + eg;
  int sn = (e < e1) ? csr_src[e] : -1;
  while (sn >= 0) {
    int s = sn;
    e += 4;
    sn = (e < e1) ? csr_src[e] : -1;
    float w = dis[s] * dn;
    uint4 r = *(const uint4*)(xw + (size_t)s * 128 + cg * 8);
    acc[0] += w * bflo(r.x); acc[1] += w * bfhi(r.x);
    acc[2] += w * bflo(r.y); acc[3] += w * bfhi(r.y);
    acc[4] += w * bflo(r.z); acc[5] += w * bfhi(r.z);
    acc[6] += w * bflo(r.w); acc[7] += w * bfhi(r.w);
  }
  #pragma unroll
  for (int j = 0; j < 8; ++j) {
    acc[j] += __shfl_xor(acc[j], 16);
    acc[j] += __shfl_xor(acc[j], 32);
  }
  int c0 = cg * 8;
  #pragma unroll
  for (int j = 0; j < 8; ++j) acc[j] = fmaxf(acc[j] + bias[c0 + j], 0.f);
  if (doLN) {
    float s1 = 0.f, s2 = 0.f;
    #pragma unroll
    for (int j = 0; j < 8; ++j) { s1 += acc[j]; s2 += acc[j] * acc[j]; }
    #pragma unroll
    for (int off = 1; off < 16; off <<= 1) {
      s1 += __shfl_xor(s1, off);
      s2 += __shfl_xor(s2, off);
    }
    float mean = s1 * (1.f / 128.f);
    float var = s2 * (1.f / 128.f) - mean * mean;
    float inv = rsqrtf(var + 1e-5f);
    #pragma unroll
    for (int j = 0; j < 8; ++j)
      acc[j] = (acc[j] - mean) * inv * lng[c0 + j] + lnb[c0 + j];
  }
  if (eg == 0) {
    uint4 o;
    o.x = pack2(acc[0], acc[1]); o.y = pack2(acc[2], acc[3]);
    o.z = pack2(acc[4], acc[5]); o.w = pack2(acc[6], acc[7]);
    *(uint4*)(out + (size_t)n * 128 + cg * 8) = o;
  }
}

// ----------------------- merged QKV with block-level weight staging in LDS
// role A (inter->kh,vh) / role B (qh); head-major outputs [h][BS_][16].
__global__ __launch_bounds__(256) void qkv_kernel(
    const u16* __restrict__ xa, const int* __restrict__ hist,
    const int* __restrict__ ans, const int* __restrict__ nseq,
    const u16* __restrict__ l0T, const float* __restrict__ pc,
    const u16* __restrict__ wkT, const float* __restrict__ bk,
    const u16* __restrict__ wvT, const float* __restrict__ bv,
    const u16* __restrict__ wqT, const float* __restrict__ bq,
    u16* __restrict__ khout, u16* __restrict__ vhout,
    u16* __restrict__ qhout, int nblk) {
  __shared__ u16 sW[128 * 136];        // staged weight, padded stride
  __shared__ u16 ldsb[4][16 * 136];    // per-wave bounce
  int bb = blockIdx.x;
  int t = threadIdx.x, w = t >> 6, l = t & 63, lr = l & 15, lg = l >> 4;
  f32x4 acc[8];

  if (bb < nblk) {
    // ---- role A ----
    int r0 = bb * 64 + w * 16;
    int arow = hist[r0 + lr];
    const u16* Arow = xa + (size_t)arow * 128;
    bfrag a[4];
    #pragma unroll
    for (int ks = 0; ks < 4; ++ks) a[ks] = *(const bfrag*)(Arow + ks * 32 + lg * 8);

    STAGE_W(l0T);
    __syncthreads();
    #pragma unroll
    for (int ct = 0; ct < 8; ++ct) acc[ct] = (f32x4){0.f, 0.f, 0.f, 0.f};
    #pragma unroll
    for (int ks = 0; ks < 4; ++ks)
      #pragma unroll
      for (int ct = 0; ct < 8; ++ct) {
        bfrag b = *(const bfrag*)(sW + (ct * 16 + lr) * 136 + ks * 32 + lg * 8);
        acc[ct] = MFMA16(a[ks], b, acc[ct]);
      }
    int pcoff[4];
    #pragma unroll
    for (int i = 0; i < 4; ++i) {
      int r = r0 + lg * 4 + i;
      pcoff[i] = (ans[r] * S_ + (r % S_)) * 128;
    }
    #pragma unroll
    for (int ct = 0; ct < 8; ++ct) {
      int col = ct * 16 + lr;
      #pragma unroll
      for (int i = 0; i < 4; ++i)
        ldsb[w][(lg * 4 + i) * 136 + col] = f2bf(acc[ct][i] + pc[pcoff[i] + col]);
    }
    bfrag a2[4];
    #pragma unroll
    for (int ks = 0; ks < 4; ++ks)
      a2[ks] = *(const bfrag*)(&ldsb[w][lr * 136 + ks * 32 + lg * 8]);
    __syncthreads();           // all waves done reading sW(l0T)

    STAGE_W(wkT);
    __syncthreads();
    #pragma unroll
    for (int ct = 0; ct < 8; ++ct) acc[ct] = (f32x4){0.f, 0.f, 0.f, 0.f};
    #pragma unroll
    for (int ks = 0; ks < 4; ++ks)
      #pragma unroll
      for (int ct = 0; ct < 8; ++ct) {
        bfrag b = *(const bfrag*)(sW + (ct * 16 + lr) * 136 + ks * 32 + lg * 8);
        acc[ct] = MFMA16(a2[ks], b, acc[ct]);
      }
    #pragma unroll
    for (int ct = 0; ct < 8; ++ct)
      #pragma unroll
      for (int i = 0; i < 4; ++i)
        ldsb[w][(lg * 4 + i) * 136 + ct * 16 + lr] = f2bf(acc[ct][i] + bk[ct * 16 + lr]);
    #pragma unroll
    for (int j = 0; j < 4; ++j) {
      int c = j * 64 + l;
      int head = c >> 5, rw = (c >> 1) & 15, half = c & 1;
      *(uint4*)(khout + ((size_t)head * BS_ + r0 + rw) * 16 + half * 8) =
          *(const uint4*)&ldsb[w][rw * 136 + head * 16 + half * 8];
    }
    __syncthreads();           // done reading sW(wkT)

    STAGE_W(wvT);
    __syncthreads();
    #pragma unroll
    for (int ct = 0; ct < 8; ++ct) acc[ct] = (f32x4){0.f, 0.f, 0.f, 0.f};
    #pragma unroll
    for (int ks = 0; ks < 4; ++ks)
      #pragma unroll
      for (int ct = 0; ct < 8; ++ct) {
        bfrag b = *(const bfrag*)(sW + (ct * 16 + lr) * 136 + ks * 32 + lg * 8);
        acc[ct] = MFMA16(a2[ks], b, acc[ct]);
      }
    #pragma unroll
    for (int ct = 0; ct < 8; ++ct)
      #pragma unroll
      for (int i = 0; i < 4; ++i)
        ldsb[w][(lg * 4 + i) * 136 + ct * 16 + lr] = f2bf(acc[ct][i] + bv[ct * 16 + lr]);
    #pragma unroll
    for (int j = 0; j < 4; ++j) {
      int c = j * 64 + l;
      int head = c >> 5, rw = (c >> 1) & 15, half = c & 1;
      *(uint4*)(vhout + ((size_t)head * BS_ + r0 + rw) * 16 + half * 8) =
          *(const uint4*)&ldsb[w][rw * 136 + head * 16 + half * 8];
    }
  } else {
    // ---- role B ----
    int r0 = (bb - nblk) * 64 + w * 16;
    int arow = nseq[r0 + lr];
    const u16* Arow = xa + (size_t)arow * 128;
    bfrag a[4];
    #pragma unroll
    for (int ks = 0; ks < 4; ++ks) a[ks] = *(const bfrag*)(Arow + ks * 32 + lg * 8);

    STAGE_W(wqT);
    __syncthreads();
    #pragma unroll
    for (int ct = 0; ct < 8; ++ct) acc[ct] = (f32x4){0.f, 0.f, 0.f, 0.f};
    #pragma unroll
    for (int ks = 0; ks < 4; ++ks)
      #pragma unroll
      for (int ct = 0; ct < 8; ++ct) {
        bfrag b = *(const bfrag*)(sW + (ct * 16 + lr) * 136 + ks * 32 + lg * 8);
        acc[ct] = MFMA16(a[ks], b, acc[ct]);
      }
    #pragma unroll
    for (int ct = 0; ct < 8; ++ct)
      #pragma unroll
      for (int i = 0; i < 4; ++i)
        ldsb[w][(lg * 4 + i) * 136 + ct * 16 + lr] = f2bf(acc[ct][i] + bq[ct * 16 + lr]);
    #pragma unroll
    for (int j = 0; j < 4; ++j) {
      int c = j * 64 + l;
      int head = c >> 5, rw = (c >> 1) & 15, half = c & 1;
      *(uint4*)(qhout + ((size_t)head * BS_ + r0 + rw) * 16 + half * 8) =
          *(const uint4*)&ldsb[w][rw * 136 + head * 16 + half * 8];
    }
  }
}

// ----------------------------------------------------------- MFMA attention
__global__ __launch_bounds__(256) void attn_mfma_kernel(
    u16* qh_ao, const u16* __restrict__ kh, const u16* __restrict__ vh) {
  __shared__ u16 Kl[208 * 24];
  __shared__ u16 Vt[16 * 232];
  __shared__ u16 Pl[4 * 16 * 232];
  int b = blockIdx.x >> 3, h = blockIdx.x & 7;
  int t = threadIdx.x;
  size_t base = ((size_t)h * BS_ + (size_t)b * S_) * 16;

  for (int i = t; i < 208 * 2; i += 256) {
    int key = i >> 1, d = (i & 1) * 8;
    uint4 v = make_uint4(0, 0, 0, 0);
    if (key < S_) v = *(const uint4*)(kh + base + (size_t)key * 16 + d);
    *(uint4*)(Kl + key * 24 + d) = v;
  }
  for (int i = t; i < 16 * 232; i += 256) {
    int d = i / 232, key = i - d * 232;
    Vt[d * 232 + key] = (key < S_) ? vh[base + (size_t)key * 16 + d] : (u16)0;
  }
  for (int i = t; i < 4 * 16 * 232 / 2; i += 256) ((u32*)Pl)[i] = 0;
  __syncthreads();

  int w = t >> 6, l = t & 63, lr = l & 15, lg = l >> 4;
  u16* Pw = Pl + w * 16 * 232;
  const f32x4 zero4 = {0.f, 0.f, 0.f, 0.f};

  for (int qi = w; qi < 13; qi += 4) {
    bfrag aq = (bfrag){0, 0, 0, 0, 0, 0, 0, 0};
    int qrow = qi * 16 + lr;
    if (lg < 2 && qrow < S_)
      aq = *(const bfrag*)(qh_ao + base + (size_t)qrow * 16 + lg * 8);
    float rsum[4] = {0.f, 0.f, 0.f, 0.f};
    for (int kj = 0; kj <= qi; ++kj) {
      bfrag bk = (bfrag){0, 0, 0, 0, 0, 0, 0, 0};
      if (lg < 2) bk = *(const bfrag*)(Kl + (kj * 16 + lr) * 24 + lg * 8);
      f32x4 sc = MFMA16(aq, bk, zero4);
      #pragma unroll
      for (int i = 0; i < 4; ++i) {
        int q = qi * 16 + lg * 4 + i, key = kj * 16 + lr;
        float p = 0.f;
        if (key <= q && q < S_) p = __expf(sc[i] * 0.25f);
        rsum[i] += p;
        Pw[(lg * 4 + i) * 232 + key] = f2bf(p);
      }
    }
    #pragma unroll
    for (int i = 0; i < 4; ++i) {
      rsum[i] += __shfl_xor(rsum[i], 1);
      rsum[i] += __shfl_xor(rsum[i], 2);
      rsum[i] += __shfl_xor(rsum[i], 4);
      rsum[i] += __shfl_xor(rsum[i], 8);
    }
    f32x4 o = zero4;
    #pragma unroll
    for (int kt = 0; kt < 7; ++kt) {
      bfrag ap = *(const bfrag*)(Pw + lr * 232 + kt * 32 + lg * 8);
      bfrag bv = *(const bfrag*)(Vt + lr * 232 + kt * 32 + lg * 8);
      o = MFMA16(ap, bv, o);
    }
    #pragma unroll
    for (int i = 0; i < 4; ++i) {
      int q = qi * 16 + lg * 4 + i;
      if (q < S_) qh_ao[base + (size_t)q * 16 + lr] = f2bf(o[i] / rsum[i]);
    }
  }
}

// ---- fused output with staged weights:
// ao@wo + gather(new)@l3T + bo -> LN2 -> FFN -> LN3 -> pred
__global__ __launch_bounds__(256) void out_kernel(
    const u16* __restrict__ ao, const u16* __restrict__ xa,
    const int* __restrict__ nseq,
    const u16* __restrict__ woT, const float* __restrict__ bo,
    const u16* __restrict__ l3T,
    const float* __restrict__ g2, const float* __restrict__ b2,
    const u16* __restrict__ f0T, const float* __restrict__ b0f,
    const u16* __restrict__ f1T, const float* __restrict__ b1f,
    const float* __restrict__ g3, const float* __restrict__ b3,
    const float* __restrict__ w4, const float* __restrict__ b4,
    float* __restrict__ pred) {
  __shared__ u16 sW[128 * 136];
  __shared__ u16 ldsb[4][16 * 136];
  int t = threadIdx.x, w = t >> 6, l = t & 63, lr = l & 15, lg = l >> 4;
  int r0 = blockIdx.x * 64 + w * 16;

  // A-frags: ao (head-major) and xa gather (issued early, used in phase 2)
  bfrag a_ao[4], a_xa[4];
  #pragma unroll
  for (int ks = 0; ks < 4; ++ks) {
    int head = ks * 2 + (lg >> 1);
    int d0 = (lg & 1) * 8;
    a_ao[ks] = *(const bfrag*)(ao + ((size_t)head * BS_ + r0 + lr) * 16 + d0);
  }
  {
    int arow = nseq[r0 + lr];
    const u16* Arow = xa + (size_t)arow * 128;
    #pragma unroll
    for (int ks = 0; ks < 4; ++ks) a_xa[ks] = *(const bfrag*)(Arow + ks * 32 + lg * 8);
  }

  f32x4 acc[8];
  #pragma unroll
  for (int ct = 0; ct < 8; ++ct) acc[ct] = (f32x4){0.f, 0.f, 0.f, 0.f};

  STAGE_W(woT);
  __syncthreads();
  #pragma unroll
  for (int ks = 0; ks < 4; ++ks)
    #pragma unroll
    for (int ct = 0; ct < 8; ++ct) {
      bfrag b = *(const bfrag*)(sW + (ct * 16 + lr) * 136 + ks * 32 + lg * 8);
      acc[ct] = MFMA16(a_ao[ks], b, acc[ct]);
    }
  __syncthreads();             // done reading sW(woT)

  STAGE_W(l3T);
  __syncthreads();
  #pragma unroll
  for (int ks = 0; ks < 4; ++ks)
    #pragma unroll
    for (int ct = 0; ct < 8; ++ct) {
      bfrag b = *(const bfrag*)(sW + (ct * 16 + lr) * 136 + ks * 32 + lg * 8);
      acc[ct] = MFMA16(a_xa[ks], b, acc[ct]);
    }
  __syncthreads();             // done reading sW(l3T)

  #pragma unroll
  for (int ct = 0; ct < 8; ++ct) {
    float bcol = bo[ct * 16 + lr];
    #pragma unroll
    for (int i = 0; i < 4; ++i) acc[ct][i] += bcol;
  }
  // LN2 -> acc holds atn (f32); bounce to ldsb; read a2 frags
  bfrag a2[4];
  {
    float s1[4] = {0, 0, 0, 0}, s2[4] = {0, 0, 0, 0};
    #pragma unroll
    for (int ct = 0; ct < 8; ++ct)
      #pragma unroll
      for (int i = 0; i < 4; ++i) {
        s1[i] += acc[ct][i];
        s2[i] += acc[ct][i] * acc[ct][i];
      }
    #pragma unroll
    for (int i = 0; i < 4; ++i) {
      s1[i] += __shfl_xor(s1[i], 1); s2[i] += __shfl_xor(s2[i], 1);
      s1[i] += __shfl_xor(s1[i], 2); s2[i] += __shfl_xor(s2[i], 2);
      s1[i] += __shfl_xor(s1[i], 4); s2[i] += __shfl_xor(s2[i], 4);
      s1[i] += __shfl_xor(s1[i], 8); s2[i] += __shfl_xor(s2[i], 8);
    }
    float mean[4], inv[4];
    #pragma unroll
    for (int i = 0; i < 4; ++i) {
      mean[i] = s1[i] * (1.f / 128.f);
      float var = s2[i] * (1.f / 128.f) - mean[i] * mean[i];
      inv[i] = rsqrtf(var + 1e-5f);
    }
    #pragma unroll
    for (int ct = 0; ct < 8; ++ct) {
      int col = ct * 16 + lr;
      float gc = g2[col], bc = b2[col];
      #pragma unroll
      for (int i = 0; i < 4; ++i) {
        acc[ct][i] = (acc[ct][i] - mean[i]) * inv[i] * gc + bc;
        ldsb[w][(lg * 4 + i) * 136 + col] = f2bf(acc[ct][i]);
      }
    }
    #pragma unroll
    for (int ks = 0; ks < 4; ++ks)
      a2[ks] = *(const bfrag*)(&ldsb[w][lr * 136 + ks * 32 + lg * 8]);
  }

  STAGE_W(f0T);
  __syncthreads();
  f32x4 acc2[8];
  #pragma unroll
  for (int ct = 0; ct < 8; ++ct) acc2[ct] = (f32x4){0.f, 0.f, 0.f, 0.f};
  #pragma unroll
  for (int ks = 0; ks < 4; ++ks)
    #pragma unroll
    for (int ct = 0; ct < 8; ++ct) {
      bfrag b = *(const bfrag*)(sW + (ct * 16 + lr) * 136 + ks * 32 + lg * 8);
      acc2[ct] = MFMA16(a2[ks], b, acc2[ct]);
    }
  #pragma unroll
  for (int ct = 0; ct < 8; ++ct) {
    int col = ct * 16 + lr;
    float bcol = b0f[col];
    #pragma unroll
    for (int i = 0; i < 4; ++i)
      ldsb[w][(lg * 4 + i) * 136 + col] = f2bf(fmaxf(acc2[ct][i] + bcol, 0.f));
  }
  #pragma unroll
  for (int ks = 0; ks < 4; ++ks)
    a2[ks] = *(const bfrag*)(&ldsb[w][lr * 136 + ks * 32 + lg * 8]);
  __syncthreads();             // done reading sW(f0T)

  STAGE_W(f1T);
  __syncthreads();
  #pragma unroll
  for (int ct = 0; ct < 8; ++ct) acc2[ct] = (f32x4){0.f, 0.f, 0.f, 0.f};
  #pragma unroll
  for (int ks = 0; ks < 4; ++ks)
    #pragma unroll
    for (int ct = 0; ct < 8; ++ct) {
      bfrag b = *(const bfrag*)(sW + (ct * 16 + lr) * 136 + ks * 32 + lg * 8);
      acc2[ct] = MFMA16(a2[ks], b, acc2[ct]);
    }
  #pragma unroll
  for (int ct = 0; ct < 8; ++ct) {
    int col = ct * 16 + lr;
    float bcol = b1f[col];
    #pragma unroll
    for (int i = 0; i < 4; ++i) acc2[ct][i] += bcol + acc[ct][i];
  }
  // LN3 -> dot w4 -> pred
  {
    float s1[4] = {0, 0, 0, 0}, s2[4] = {0, 0, 0, 0};
    #pragma unroll
    for (int ct = 0; ct < 8; ++ct)
      #pragma unroll
      for (int i = 0; i < 4; ++i) {
        s1[i] += acc2[ct][i];
        s2[i] += acc2[ct][i] * acc2[ct][i];
      }
    #pragma unroll
    for (int i = 0; i < 4; ++i) {
      s1[i] += __shfl_xor(s1[i], 1); s2[i] += __shfl_xor(s2[i], 1);
      s1[i] += __shfl_xor(s1[i], 2); s2[i] += __shfl_xor(s2[i], 2);
      s1[i] += __shfl_xor(s1[i], 4); s2[i] += __shfl_xor(s2[i], 4);
      s1[i] += __shfl_xor(s1[i], 8); s2[i] += __shfl_xor(s2[i], 8);
    }
    float p[4] = {0, 0, 0, 0};
    #pragma unroll
    for (int i = 0; i < 4; ++i) {
      float mean = s1[i] * (1.f / 128.f);
      float var = s2[i] * (1.f / 128.f) - mean * mean;
      float inv = rsqrtf(var + 1e-5f);
      #pragma unroll
      for (int ct = 0; ct < 8; ++ct) {
        int col = ct * 16 + lr;
        p[i] += ((acc2[ct][i] - mean) * inv * g3[col] + b3[col]) * w4[col];
      }
    }
    #pragma unroll
    for (int i = 0; i < 4; ++i) {
      p[i] += __shfl_xor(p[i], 1);
      p[i] += __shfl_xor(p[i], 2);
      p[i] += __shfl_xor(p[i], 4);
      p[i] += __shfl_xor(p[i], 8);
    }
    if (lr == 0) {
      float bias4 = b4[0];
      #pragma unroll
      for (int i = 0; i < 4; ++i) pred[r0 + lg * 4 + i] = p[i] + bias4;
    }
  }
}

// ---------------------------------------------------------------------------
extern "C" void kernel_launch(void* const* d_in, const int* in_sizes, int n_in,
                              void* d_out, int out_size, void* d_ws, size_t ws_size,
                              hipStream_t stream) {
  const int* hist_seq = (const int*)d_in[0];
  const int* hist_ans = (const int*)d_in[1];
  const int* new_seq = (const int*)d_in[2];
  const int* edge_index = (const int*)d_in[3];
  const float* node_x = (const float*)d_in[4];
  const float* gcn_w0 = (const float*)d_in[5];
  const float* gcn_b0 = (const float*)d_in[6];
  const float* gcn_w1 = (const float*)d_in[7];
  const float* gcn_b1 = (const float*)d_in[8];
  const float* gcn_w2 = (const float*)d_in[9];
  const float* gcn_b2 = (const float*)d_in[10];
  const float* ln0_g = (const float*)d_in[11];
  const float* ln0_b = (const float*)d_in[12];
  const float* ln1_g = (const float*)d_in[13];
  const float* ln1_b = (const float*)d_in[14];
  const float* ln2_g = (const float*)d_in[15];
  const float* ln2_b = (const float*)d_in[16];
  const float* ln3_g = (const float*)d_in[17];
  const float* ln3_b = (const float*)d_in[18];
  const float* corr_emb = (const float*)d_in[19];
  const float* lin0_w = (const float*)d_in[20];
  const float* lin0_b = (const float*)d_in[21];
  const float* lin1_w = (const float*)d_in[22];
  const float* lin2_w = (const float*)d_in[23];
  const float* lin3_w = (const float*)d_in[24];
  const float* lin4_w = (const float*)d_in[25];
  const float* lin4_b = (const float*)d_in[26];
  const float* pos_emb = (const float*)d_in[27];
  const float* mha_wq = (const float*)d_in[28];
  const float* mha_bq = (const float*)d_in[29];
  const float* mha_wk = (const float*)d_in[30];
  const float* mha_bk = (const float*)d_in[31];
  const float* mha_wv = (const float*)d_in[32];
  const float* mha_bv = (const float*)d_in[33];
  const float* mha_wo = (const float*)d_in[34];
  const float* mha_bo = (const float*)d_in[35];
  const float* ffn0_w = (const float*)d_in[36];
  const float* ffn0_b = (const float*)d_in[37];
  const float* ffn1_w = (const float*)d_in[38];
  const float* ffn1_b = (const float*)d_in[39];
  (void)in_sizes; (void)n_in; (void)out_size;

  char* ws = (char*)d_ws;
  size_t off = 0;
  auto alloc = [&](size_t bytes) -> void* {
    void* p = ws + off;
    off += (bytes + 255) & ~(size_t)255;
    return p;
  };
  int* cnt = (int*)alloc((size_t)N_NODES * 4);
  int* row_ptr = (int*)alloc((size_t)(N_NODES + 1) * 4);
  int* fill = (int*)alloc((size_t)N_NODES * 4);
  int* locpref = (int*)alloc((size_t)N_NODES * 4);
  int* btot = (int*)alloc(64 * 4);
  int* boff = (int*)alloc(64 * 4);
  float* dis = (float*)alloc((size_t)N_NODES * 4);
  int* csr_src = (int*)alloc((size_t)N_EDGES * 4);
  const size_t WB = 128 * 128 * 2;
  u16* g0T = (u16*)alloc(WB);
  u16* g1T = (u16*)alloc(WB);
  u16* g2T = (u16*)alloc(WB);
  u16* l0T = (u16*)alloc(WB);
  u16* l3T = (u16*)alloc(WB);
  u16* woT = (u16*)alloc(WB);
  u16* f0T = (u16*)alloc(WB);
  u16* f1T = (u16*)alloc(WB);
  u16* wqT = (u16*)alloc(WB);
  u16* wkT = (u16*)alloc(WB);
  u16* wvT = (u16*)alloc(WB);
  float* c01 = (float*)alloc(2 * 128 * 4);
  float* pc = (float*)alloc((size_t)2 * S_ * 128 * 4);
  u16* xa = (u16*)alloc((size_t)N_NODES * 128 * 2);
  const size_t CB = (size_t)BS_ * 128 * 2;   // 26.2 MB
  size_t RB = off;
  u16* bufQ = (u16*)(ws + RB);                // qh -> ao in place, head-major
  u16* bufK = (u16*)(ws + RB + CB);           // kh head-major
  u16* bufV = (u16*)(ws + RB + 2 * CB);       // vh head-major
  u16* xb = bufQ;                             // overlay: dead before qkv writes
  u16* xw = bufQ + (size_t)N_NODES * 128;
  size_t need = RB + 3 * CB;
  if (ws_size < need) return;     // diagnostic guard

  // ---- graph prep ----
  int nb = (N_NODES + 1023) / 1024;   // 49
  zero_i32_kernel<<<(N_NODES + 255) / 256, 256, 0, stream>>>(cnt, N_NODES);
  hist_kernel<<<(N_EDGES + 255) / 256, 256, 0, stream>>>(edge_index + N_EDGES, cnt, N_EDGES);
  scanA_kernel<<<nb, 1024, 0, stream>>>(cnt, locpref, btot, dis, N_NODES);
  scanB_kernel<<<1, 64, 0, stream>>>(btot, boff, nb);
  scanC_kernel<<<(N_NODES + 255) / 256, 256, 0, stream>>>(locpref, boff, row_ptr, fill, N_NODES);
  scatter_kernel<<<(N_EDGES + 255) / 256, 256, 0, stream>>>(edge_index, edge_index + N_EDGES,
                                                            fill, csr_src, N_EDGES);
  // ---- weight prep + pc table + node_x cast ----
  wprep_kernel<<<705, 256, 0, stream>>>(gcn_w0, gcn_w1, gcn_w2, lin0_w, lin3_w, mha_wo,
                                        ffn0_w, ffn1_w, lin1_w, lin2_w, mha_wq, mha_wk,
                                        mha_wv, corr_emb, g0T, g1T, g2T, l0T, l3T, woT,
                                        f0T, f1T, wqT, wkT, wvT, c01);
  pc_kernel<<<(2 * S_ * 128 + 255) / 256, 256, 0, stream>>>(lin0_b, pos_emb, c01, pc);
  f2bf8_kernel<<<(N_NODES * 16 + 255) / 256, 256, 0, stream>>>(node_x, xb, N_NODES * 16);

  int gN = (N_NODES + 63) / 64;
  int aN = (N_NODES + 3) / 4;

  // ---- GCN ----
  gemm_bf16_kernel<<<gN, 256, 0, stream>>>(xb, g0T, xw, N_NODES);
  agg_kernel<<<aN, 256, 0, stream>>>(xw, dis, row_ptr, csr_src, gcn_b0, ln0_g, ln0_b, xa, N_NODES, 1);
  gemm_bf16_kernel<<<gN, 256, 0, stream>>>(xa, g1T, xw, N_NODES);
  agg_kernel<<<aN, 256, 0, stream>>>(xw, dis, row_ptr, csr_src, gcn_b1, ln1_g, ln1_b, xa, N_NODES, 1);
  gemm_bf16_kernel<<<gN, 256, 0, stream>>>(xa, g2T, xw, N_NODES);
  agg_kernel<<<aN, 256, 0, stream>>>(xw, dis, row_ptr, csr_src, gcn_b2, nullptr, nullptr, xa, N_NODES, 0);

  // ---- transformer, full batch, 3 dispatches ----
  int gT = BS_ / 64;   // 1600
  qkv_kernel<<<2 * gT, 256, 0, stream>>>(xa, hist_seq, hist_ans, new_seq,
                                         l0T, pc, wkT, mha_bk, wvT, mha_bv,
                                         wqT, mha_bq, bufK, bufV, bufQ, gT);
  attn_mfma_kernel<<<B_ * 8, 256, 0, stream>>>(bufQ, bufK, bufV);
  out_kernel<<<gT, 256, 0, stream>>>(bufQ, xa, new_seq, woT, mha_bo, l3T,
                                     ln2_g, ln2_b, f0T, ffn0_b, f1T, ffn1_b,
                                     ln3_g, ln3_b, lin4_w, lin4_b, (float*)d_out);
}

// Round 11
// 447.148 us; speedup vs baseline: 3.2246x; 1.0067x over previous
//
#include <hip/hip_runtime.h>
#include <math.h>

#define N_NODES 50000
#define N_EDGES 800000
#define B_ 512
#define S_ 200
#define D_ 128
#define BS_ (B_*S_)            // 102400 rows, full batch
#define PSTR 228               // P-buffer row stride (u16) — bank-spread writes

typedef unsigned short u16;
typedef unsigned int u32;
using bfrag = __attribute__((ext_vector_type(8))) short;
using f32x4 = __attribute__((ext_vector_type(4))) float;

__device__ __forceinline__ u16 f2bf(float f) {        // round-half-up f32->bf16 (2 ops)
  return (u16)((__float_as_uint(f) + 0x8000u) >> 16);
}
__device__ __forceinline__ float bf2f(u16 v) { return __uint_as_float(((u32)v) << 16); }
__device__ __forceinline__ float bflo(u32 v) { return __uint_as_float(v << 16); }
__device__ __forceinline__ float bfhi(u32 v) { return __uint_as_float(v & 0xffff0000u); }
__device__ __forceinline__ u32 pack2(float a, float b) {
  return (u32)f2bf(a) | ((u32)f2bf(b) << 16);
}
#define MFMA16(a, b, c) __builtin_amdgcn_mfma_f32_16x16x32_bf16((a), (b), (c), 0, 0, 0)

// stage a 128x128 bf16 weight (row-major [c][k]) into padded LDS sW[128][136]
#define STAGE_W(Wsrc) \
  for (int i_ = threadIdx.x; i_ < 2048; i_ += 256) { \
    int c_ = i_ >> 4, kg_ = i_ & 15; \
    *(uint4*)(sW + c_ * 136 + kg_ * 8) = *(const uint4*)((Wsrc) + c_ * 128 + kg_ * 8); \
  }

// ---------------------------------------------------------------- utilities
__global__ void zero_i32_kernel(int* __restrict__ p, int n) {
  int i = blockIdx.x * 256 + threadIdx.x;
  if (i < n) p[i] = 0;
}

__global__ void f2bf8_kernel(const float* __restrict__ in, u16* __restrict__ out, int n8) {
  int i = blockIdx.x * 256 + threadIdx.x;
  if (i >= n8) return;
  float4 a = ((const float4*)in)[i * 2];
  float4 b = ((const float4*)in)[i * 2 + 1];
  uint4 o;
  o.x = pack2(a.x, a.y); o.y = pack2(a.z, a.w);
  o.z = pack2(b.x, b.y); o.w = pack2(b.z, b.w);
  ((uint4*)out)[i] = o;
}

// ---------------- fused weight prep: 8 transposes + 3 products + c01
__global__ __launch_bounds__(256) void wprep_kernel(
    const float* __restrict__ gcn_w0, const float* __restrict__ gcn_w1,
    const float* __restrict__ gcn_w2, const float* __restrict__ lin0_w,
    const float* __restrict__ lin3_w, const float* __restrict__ mha_wo,
    const float* __restrict__ ffn0_w, const float* __restrict__ ffn1_w,
    const float* __restrict__ lin1_w, const float* __restrict__ lin2_w,
    const float* __restrict__ mha_wq, const float* __restrict__ mha_wk,
    const float* __restrict__ mha_wv, const float* __restrict__ corr_emb,
    u16* __restrict__ g0T, u16* __restrict__ g1T, u16* __restrict__ g2T,
    u16* __restrict__ l0T, u16* __restrict__ l3T, u16* __restrict__ woT,
    u16* __restrict__ f0T, u16* __restrict__ f1T,
    u16* __restrict__ wqT, u16* __restrict__ wkT, u16* __restrict__ wvT,
    float* __restrict__ c01) {
  int bb = blockIdx.x;
  if (bb < 512) {                        // plain transpose W[k][c] -> D[c][k]
    const float* W; u16* D;
    switch (bb >> 6) {
      case 0: W = gcn_w0; D = g0T; break;
      case 1: W = gcn_w1; D = g1T; break;
      case 2: W = gcn_w2; D = g2T; break;
      case 3: W = lin0_w; D = l0T; break;
      case 4: W = lin3_w; D = l3T; break;
      case 5: W = mha_wo; D = woT; break;
      case 6: W = ffn0_w; D = f0T; break;
      default: W = ffn1_w; D = f1T; break;
    }
    int i = (bb & 63) * 256 + threadIdx.x;
    int k = i >> 7, c = i & 127;
    D[c * 128 + k] = f2bf(W[k * 128 + c]);
  } else if (bb < 704) {                 // (X@Y)^T -> D
    const float* X; const float* Y; u16* D;
    switch ((bb - 512) >> 6) {
      case 0: X = lin3_w; Y = mha_wq; D = wqT; break;
      case 1: X = lin2_w; Y = mha_wk; D = wkT; break;
      default: X = lin1_w; Y = mha_wv; D = wvT; break;
    }
    int i = ((bb - 512) & 63) * 256 + threadIdx.x;
    int k = i >> 7, c = i & 127;
    float acc = 0.f;
    for (int t = 0; t < 128; ++t) acc += X[k * 128 + t] * Y[t * 128 + c];
    D[c * 128 + k] = f2bf(acc);
  } else {                               // c01 = corr_emb @ lin0_w[128:]
    int idx = threadIdx.x;               // 0..255 = 2*128
    int i = idx >> 7, j = idx & 127;
    float acc = 0.f;
    for (int t = 0; t < 128; ++t)
      acc += corr_emb[i * 128 + t] * lin0_w[128 * 128 + t * 128 + j];
    c01[idx] = acc;
  }
}

// pc[a][s][c] = lin0_b[c] + pos_emb[s][c] + c01[a][c]
__global__ void pc_kernel(const float* __restrict__ lin0_b, const float* __restrict__ pos_emb,
                          const float* __restrict__ c01, float* __restrict__ pc) {
  int i = blockIdx.x * 256 + threadIdx.x;   // 51200
  int c = i & 127, s = (i >> 7) % S_, a = i / (128 * S_);
  pc[i] = lin0_b[c] + pos_emb[s * 128 + c] + c01[a * 128 + c];
}

// ---------------------------------------------------------------- graph prep
__global__ void hist_kernel(const int* __restrict__ dst, int* __restrict__ cnt, int E) {
  int e = blockIdx.x * 256 + threadIdx.x;
  if (e < E) atomicAdd(&cnt[dst[e]], 1);
}

__global__ __launch_bounds__(1024) void scanA_kernel(
    const int* __restrict__ cnt, int* __restrict__ locpref,
    int* __restrict__ btot, float* __restrict__ dis, int N) {
  __shared__ int wsum[16];
  int t = threadIdx.x, lane = t & 63, wid = t >> 6;
  int i = blockIdx.x * 1024 + t;
  int v = (i < N) ? cnt[i] : 0;
  if (i < N) dis[i] = rsqrtf(1.f + (float)v);
  int x = v;
  #pragma unroll
  for (int off = 1; off < 64; off <<= 1) {
    int y = __shfl_up(x, off);
    if (lane >= off) x += y;
  }
  if (lane == 63) wsum[wid] = x;
  __syncthreads();
  if (wid == 0 && lane < 16) {
    int s = wsum[lane];
    #pragma unroll
    for (int off = 1; off < 16; off <<= 1) {
      int y = __shfl_up(s, off);
      if (lane >= off) s += y;
    }
    wsum[lane] = s;
  }
  __syncthreads();
  int woff = (wid > 0) ? wsum[wid - 1] : 0;
  if (i < N) locpref[i] = woff + x - v;
  if (t == 1023) btot[blockIdx.x] = woff + x;
}

__global__ void scanB_kernel(const int* __restrict__ btot, int* __restrict__ boff, int nb) {
  int lane = threadIdx.x;
  int v = (lane < nb) ? btot[lane] : 0;
  int x = v;
  #pragma unroll
  for (int off = 1; off < 64; off <<= 1) {
    int y = __shfl_up(x, off);
    if (lane >= off) x += y;
  }
  if (lane < nb) boff[lane] = x - v;
}

__global__ void scanC_kernel(const int* __restrict__ locpref, const int* __restrict__ boff,
                             int* __restrict__ row_ptr, int* __restrict__ fill, int N) {
  int i = blockIdx.x * 256 + threadIdx.x;
  if (i < N) {
    int r = locpref[i] + boff[i >> 10];
    row_ptr[i] = r; fill[i] = r;
  }
  if (i == 0) row_ptr[N] = N_EDGES;
}

__global__ void scatter_kernel(const int* __restrict__ src, const int* __restrict__ dst,
                               int* __restrict__ fill, int* __restrict__ csr_src, int E) {
  int e = blockIdx.x * 256 + threadIdx.x;
  if (e >= E) return;
  int d = dst[e];
  int pos = atomicAdd(&fill[d], 1);
  csr_src[pos] = src[e];
}

// ------------------------------------------------------------ MFMA bf16 GEMM
// (GCN layers) C row-major; LDS-bounce coalesced uint4 stores.
__global__ __launch_bounds__(256) void gemm_bf16_kernel(
    const u16* __restrict__ A, const u16* __restrict__ wT,
    u16* __restrict__ C, int M) {
  __shared__ u16 ldsb[4][16 * 136];
  int t = threadIdx.x;
  int w = t >> 6, l = t & 63, lr = l & 15, lg = l >> 4;
  int r0 = blockIdx.x * 64 + w * 16;

  int row = r0 + lr;
  const u16* Arow = A + (size_t)(row < M ? row : 0) * 128;

  bfrag a[4];
  #pragma unroll
  for (int ks = 0; ks < 4; ++ks) a[ks] = *(const bfrag*)(Arow + ks * 32 + lg * 8);

  f32x4 acc[8];
  #pragma unroll
  for (int ct = 0; ct < 8; ++ct) acc[ct] = (f32x4){0.f, 0.f, 0.f, 0.f};
  #pragma unroll
  for (int ks = 0; ks < 4; ++ks)
    #pragma unroll
    for (int ct = 0; ct < 8; ++ct) {
      bfrag b = *(const bfrag*)(wT + (size_t)(ct * 16 + lr) * 128 + ks * 32 + lg * 8);
      acc[ct] = MFMA16(a[ks], b, acc[ct]);
    }
  #pragma unroll
  for (int ct = 0; ct < 8; ++ct)
    #pragma unroll
    for (int i = 0; i < 4; ++i)
      ldsb[w][(lg * 4 + i) * 136 + ct * 16 + lr] = f2bf(acc[ct][i]);
  #pragma unroll
  for (int j = 0; j < 4; ++j) {
    int c = j * 64 + l;
    int rw = c >> 4, ch = c & 15;
    int r = r0 + rw;
    if (r < M)
      *(uint4*)(C + (size_t)r * 128 + ch * 8) = *(const uint4*)&ldsb[w][rw * 136 + ch * 8];
  }
}

// ------------------------------------------------------------- GCN aggregate
__global__ __launch_bounds__(256) void agg_kernel(
    const u16* __restrict__ xw, const float* __restrict__ dis,
    const int* __restrict__ row_ptr, const int* __restrict__ csr_src,
    const float* __restrict__ bias, const float* __restrict__ lng,
    const float* __restrict__ lnb, u16* __restrict__ out, int N, int doLN) {
  int t = threadIdx.x;
  int n = blockIdx.x * 4 + (t >> 6);
  if (n >= N) return;
  int l = t & 63, cg = l & 15, eg = l >> 4;
  float dn = dis[n];
  float acc[8] = {0.f, 0.f, 0.f, 0.f, 0.f, 0.f, 0.f, 0.f};
  if (eg == 0) {
    uint4 r = *(const uint4*)(xw + (size_t)n * 128 + cg * 8);
    float w = dn * dn;
    acc[0] += w * bflo(r.x); acc[1] += w * bfhi(r.x);
    acc[2] += w * bflo(r.y); acc[3] += w * bfhi(r.y);
    acc[4] += w * bflo(r.z); acc[5] += w * bfhi(r.z);
    acc[6] += w * bflo(r.w); acc[7] += w * bfhi(r.w);
  }
  int e1 = row_ptr[n + 1];
  int e = row_ptr[n] + eg;
  int sn = (e < e1) ? csr_src[e] : -1;
  while (sn >= 0) {
    int s = sn;
    e += 4;
    sn = (e < e1) ? csr_src[e] : -1;
    float w = dis[s] * dn;
    uint4 r = *(const uint4*)(xw + (size_t)s * 128 + cg * 8);
    acc[0] += w * bflo(r.x); acc[1] += w * bfhi(r.x);
    acc[2] += w * bflo(r.y); acc[3] += w * bfhi(r.y);
    acc[4] += w * bflo(r.z); acc[5] += w * bfhi(r.z);
    acc[6] += w * bflo(r.w); acc[7] += w * bfhi(r.w);
  }
  #pragma unroll
  for (int j = 0; j < 8; ++j) {
    acc[j] += __shfl_xor(acc[j], 16);
    acc[j] += __shfl_xor(acc[j], 32);
  }
  int c0 = cg * 8;
  #pragma unroll
  for (int j = 0; j < 8; ++j) acc[j] = fmaxf(acc[j] + bias[c0 + j], 0.f);
  if (doLN) {
    float s1 = 0.f, s2 = 0.f;
    #pragma unroll
    for (int j = 0; j < 8; ++j) { s1 += acc[j]; s2 += acc[j] * acc[j]; }
    #pragma unroll
    for (int off = 1; off < 16; off <<= 1) {
      s1 += __shfl_xor(s1, off);
      s2 += __shfl_xor(s2, off);
    }
    float mean = s1 * (1.f / 128.f);
    float var = s2 * (1.f / 128.f) - mean * mean;
    float inv = rsqrtf(var + 1e-5f);
    #pragma unroll
    for (int j = 0; j < 8; ++j)
      acc[j] = (acc[j] - mean) * inv * lng[c0 + j] + lnb[c0 + j];
  }
  if (eg == 0) {
    uint4 o;
    o.x = pack2(acc[0], acc[1]); o.y = pack2(acc[2], acc[3]);
    o.z = pack2(acc[4], acc[5]); o.w = pack2(acc[6], acc[7]);
    *(uint4*)(out + (size_t)n * 128 + cg * 8) = o;
  }
}

// ----------------------- merged QKV with block-level weight staging in LDS
// role A (inter->kh,vh) / role B (qh, pre-scaled by 0.25 for attention).
__global__ __launch_bounds__(256) void qkv_kernel(
    const u16* __restrict__ xa, const int* __restrict__ hist,
    const int* __restrict__ ans, const int* __restrict__ nseq,
    const u16* __restrict__ l0T, const float* __restrict__ pc,
    const u16* __restrict__ wkT, const float* __restrict__ bk,
    const u16* __restrict__ wvT, const float* __restrict__ bv,
    const u16* __restrict__ wqT, const float* __restrict__ bq,
    u16* __restrict__ khout, u16* __restrict__ vhout,
    u16* __restrict__ qhout, int nblk) {
  __shared__ u16 sW[128 * 136];        // staged weight, padded stride
  __shared__ u16 ldsb[4][16 * 136];    // per-wave bounce
  int bb = blockIdx.x;
  int t = threadIdx.x, w = t >> 6, l = t & 63, lr = l & 15, lg = l >> 4;
  f32x4 acc[8];

  if (bb < nblk) {
    // ---- role A ----
    int r0 = bb * 64 + w * 16;
    int arow = hist[r0 + lr];
    const u16* Arow = xa + (size_t)arow * 128;
    bfrag a[4];
    #pragma unroll
    for (int ks = 0; ks < 4; ++ks) a[ks] = *(const bfrag*)(Arow + ks * 32 + lg * 8);

    STAGE_W(l0T);
    __syncthreads();
    #pragma unroll
    for (int ct = 0; ct < 8; ++ct) acc[ct] = (f32x4){0.f, 0.f, 0.f, 0.f};
    #pragma unroll
    for (int ks = 0; ks < 4; ++ks)
      #pragma unroll
      for (int ct = 0; ct < 8; ++ct) {
        bfrag b = *(const bfrag*)(sW + (ct * 16 + lr) * 136 + ks * 32 + lg * 8);
        acc[ct] = MFMA16(a[ks], b, acc[ct]);
      }
    int pcoff[4];
    #pragma unroll
    for (int i = 0; i < 4; ++i) {
      int r = r0 + lg * 4 + i;
      pcoff[i] = (ans[r] * S_ + (r % S_)) * 128;
    }
    #pragma unroll
    for (int ct = 0; ct < 8; ++ct) {
      int col = ct * 16 + lr;
      #pragma unroll
      for (int i = 0; i < 4; ++i)
        ldsb[w][(lg * 4 + i) * 136 + col] = f2bf(acc[ct][i] + pc[pcoff[i] + col]);
    }
    bfrag a2[4];
    #pragma unroll
    for (int ks = 0; ks < 4; ++ks)
      a2[ks] = *(const bfrag*)(&ldsb[w][lr * 136 + ks * 32 + lg * 8]);
    __syncthreads();           // all waves done reading sW(l0T)

    STAGE_W(wkT);
    __syncthreads();
    #pragma unroll
    for (int ct = 0; ct < 8; ++ct) acc[ct] = (f32x4){0.f, 0.f, 0.f, 0.f};
    #pragma unroll
    for (int ks = 0; ks < 4; ++ks)
      #pragma unroll
      for (int ct = 0; ct < 8; ++ct) {
        bfrag b = *(const bfrag*)(sW + (ct * 16 + lr) * 136 + ks * 32 + lg * 8);
        acc[ct] = MFMA16(a2[ks], b, acc[ct]);
      }
    #pragma unroll
    for (int ct = 0; ct < 8; ++ct)
      #pragma unroll
      for (int i = 0; i < 4; ++i)
        ldsb[w][(lg * 4 + i) * 136 + ct * 16 + lr] = f2bf(acc[ct][i] + bk[ct * 16 + lr]);
    #pragma unroll
    for (int j = 0; j < 4; ++j) {
      int c = j * 64 + l;
      int head = c >> 5, rw = (c >> 1) & 15, half = c & 1;
      *(uint4*)(khout + ((size_t)head * BS_ + r0 + rw) * 16 + half * 8) =
          *(const uint4*)&ldsb[w][rw * 136 + head * 16 + half * 8];
    }
    __syncthreads();           // done reading sW(wkT)

    STAGE_W(wvT);
    __syncthreads();
    #pragma unroll
    for (int ct = 0; ct < 8; ++ct) acc[ct] = (f32x4){0.f, 0.f, 0.f, 0.f};
    #pragma unroll
    for (int ks = 0; ks < 4; ++ks)
      #pragma unroll
      for (int ct = 0; ct < 8; ++ct) {
        bfrag b = *(const bfrag*)(sW + (ct * 16 + lr) * 136 + ks * 32 + lg * 8);
        acc[ct] = MFMA16(a2[ks], b, acc[ct]);
      }
    #pragma unroll
    for (int ct = 0; ct < 8; ++ct)
      #pragma unroll
      for (int i = 0; i < 4; ++i)
        ldsb[w][(lg * 4 + i) * 136 + ct * 16 + lr] = f2bf(acc[ct][i] + bv[ct * 16 + lr]);
    #pragma unroll
    for (int j = 0; j < 4; ++j) {
      int c = j * 64 + l;
      int head = c >> 5, rw = (c >> 1) & 15, half = c & 1;
      *(uint4*)(vhout + ((size_t)head * BS_ + r0 + rw) * 16 + half * 8) =
          *(const uint4*)&ldsb[w][rw * 136 + head * 16 + half * 8];
    }
  } else {
    // ---- role B: qh scaled by 0.25 (attention score scale folded in) ----
    int r0 = (bb - nblk) * 64 + w * 16;
    int arow = nseq[r0 + lr];
    const u16* Arow = xa + (size_t)arow * 128;
    bfrag a[4];
    #pragma unroll
    for (int ks = 0; ks < 4; ++ks) a[ks] = *(const bfrag*)(Arow + ks * 32 + lg * 8);

    STAGE_W(wqT);
    __syncthreads();
    #pragma unroll
    for (int ct = 0; ct < 8; ++ct) acc[ct] = (f32x4){0.f, 0.f, 0.f, 0.f};
    #pragma unroll
    for (int ks = 0; ks < 4; ++ks)
      #pragma unroll
      for (int ct = 0; ct < 8; ++ct) {
        bfrag b = *(const bfrag*)(sW + (ct * 16 + lr) * 136 + ks * 32 + lg * 8);
        acc[ct] = MFMA16(a[ks], b, acc[ct]);
      }
    #pragma unroll
    for (int ct = 0; ct < 8; ++ct)
      #pragma unroll
      for (int i = 0; i < 4; ++i)
        ldsb[w][(lg * 4 + i) * 136 + ct * 16 + lr] =
            f2bf((acc[ct][i] + bq[ct * 16 + lr]) * 0.25f);
    #pragma unroll
    for (int j = 0; j < 4; ++j) {
      int c = j * 64 + l;
      int head = c >> 5, rw = (c >> 1) & 15, half = c & 1;
      *(uint4*)(qhout + ((size_t)head * BS_ + r0 + rw) * 16 + half * 8) =
          *(const uint4*)&ldsb[w][rw * 136 + head * 16 + half * 8];
    }
  }
}

// ----------------------------------------------------------- MFMA attention
// qh pre-scaled by 0.25. Balanced qi partition, mask-free off-diagonal,
// PV bounded by valid key range. In-place ao over qh.
__global__ __launch_bounds__(256) void attn_mfma_kernel(
    u16* qh_ao, const u16* __restrict__ kh, const u16* __restrict__ vh) {
  __shared__ u16 Kl[208 * 24];
  __shared__ u16 Vt[16 * 232];
  __shared__ u16 Pl[4 * 16 * PSTR];
  int b = blockIdx.x >> 3, h = blockIdx.x & 7;
  int t = threadIdx.x;
  size_t base = ((size_t)h * BS_ + (size_t)b * S_) * 16;

  for (int i = t; i < 208 * 2; i += 256) {
    int key = i >> 1, d = (i & 1) * 8;
    uint4 v = make_uint4(0, 0, 0, 0);
    if (key < S_) v = *(const uint4*)(kh + base + (size_t)key * 16 + d);
    *(uint4*)(Kl + key * 24 + d) = v;
  }
  for (int i = t; i < 16 * 232; i += 256) {
    int d = i / 232, key = i - d * 232;
    Vt[d * 232 + key] = (key < S_) ? vh[base + (size_t)key * 16 + d] : (u16)0;
  }
  for (int i = t; i < 4 * 16 * PSTR / 2; i += 256) ((u32*)Pl)[i] = 0;
  __syncthreads();

  int w = t >> 6, l = t & 63, lr = l & 15, lg = l >> 4;
  u16* Pw = Pl + w * 16 * PSTR;
  const f32x4 zero4 = {0.f, 0.f, 0.f, 0.f};
  // balanced qi partition (increasing per wave): w0{1,7,12} w1{0,8,11} w2{2,9,10} w3{3,4,5,6}
  u32 qpack = (w == 0) ? 0xFC71u : (w == 1) ? 0xFB80u : (w == 2) ? 0xFA92u : 0x6543u;
  int qlocal = lg * 4;   // local q row base for this lane group

  for (int s = 0; s < 4; ++s) {
    int qi = (qpack >> (4 * s)) & 15;
    if (qi == 15) break;
    bfrag aq = (bfrag){0, 0, 0, 0, 0, 0, 0, 0};
    int qrow = qi * 16 + lr;
    if (lg < 2 && qrow < S_)
      aq = *(const bfrag*)(qh_ao + base + (size_t)qrow * 16 + lg * 8);
    float rsum[4] = {0.f, 0.f, 0.f, 0.f};
    // off-diagonal tiles: no masking needed
    for (int kj = 0; kj < qi; ++kj) {
      bfrag bk = (bfrag){0, 0, 0, 0, 0, 0, 0, 0};
      if (lg < 2) bk = *(const bfrag*)(Kl + (kj * 16 + lr) * 24 + lg * 8);
      f32x4 sc = MFMA16(aq, bk, zero4);
      #pragma unroll
      for (int i = 0; i < 4; ++i) {
        float p = __expf(sc[i]);
        rsum[i] += p;
        Pw[(qlocal + i) * PSTR + kj * 16 + lr] = f2bf(p);
      }
    }
    // diagonal tile kj == qi: causal mask lr <= local q; masked slots stay zero
    {
      bfrag bk = (bfrag){0, 0, 0, 0, 0, 0, 0, 0};
      if (lg < 2) bk = *(const bfrag*)(Kl + (qi * 16 + lr) * 24 + lg * 8);
      f32x4 sc = MFMA16(aq, bk, zero4);
      #pragma unroll
      for (int i = 0; i < 4; ++i) {
        if (lr <= qlocal + i) {
          float p = __expf(sc[i]);
          rsum[i] += p;
          Pw[(qlocal + i) * PSTR + qi * 16 + lr] = f2bf(p);
        }
      }
    }
    #pragma unroll
    for (int i = 0; i < 4; ++i) {
      rsum[i] += __shfl_xor(rsum[i], 1);
      rsum[i] += __shfl_xor(rsum[i], 2);
      rsum[i] += __shfl_xor(rsum[i], 4);
      rsum[i] += __shfl_xor(rsum[i], 8);
    }
    f32x4 o = zero4;
    int ktmax = (qi + 2) >> 1;   // covers keys 0 .. (qi+1)*16-1 (rest zero)
    for (int kt = 0; kt < ktmax; ++kt) {
      bfrag ap = *(const bfrag*)(Pw + lr * PSTR + kt * 32 + lg * 8);
      bfrag bv = *(const bfrag*)(Vt + lr * 232 + kt * 32 + lg * 8);
      o = MFMA16(ap, bv, o);
    }
    #pragma unroll
    for (int i = 0; i < 4; ++i) {
      int q = qi * 16 + qlocal + i;
      if (q < S_) qh_ao[base + (size_t)q * 16 + lr] = f2bf(o[i] / rsum[i]);
    }
  }
}

// ---- fused output with staged weights:
// ao@wo + gather(new)@l3T + bo -> LN2 -> FFN -> LN3 -> pred
__global__ __launch_bounds__(256) void out_kernel(
    const u16* __restrict__ ao, const u16* __restrict__ xa,
    const int* __restrict__ nseq,
    const u16* __restrict__ woT, const float* __restrict__ bo,
    const u16* __restrict__ l3T,
    const float* __restrict__ g2, const float* __restrict__ b2,
    const u16* __restrict__ f0T, const float* __restrict__ b0f,
    const u16* __restrict__ f1T, const float* __restrict__ b1f,
    const float* __restrict__ g3, const float* __restrict__ b3,
    const float* __restrict__ w4, const float* __restrict__ b4,
    float* __restrict__ pred) {
  __shared__ u16 sW[128 * 136];
  __shared__ u16 ldsb[4][16 * 136];
  int t = threadIdx.x, w = t >> 6, l = t & 63, lr = l & 15, lg = l >> 4;
  int r0 = blockIdx.x * 64 + w * 16;

  bfrag a_ao[4], a_xa[4];
  #pragma unroll
  for (int ks = 0; ks < 4; ++ks) {
    int head = ks * 2 + (lg >> 1);
    int d0 = (lg & 1) * 8;
    a_ao[ks] = *(const bfrag*)(ao + ((size_t)head * BS_ + r0 + lr) * 16 + d0);
  }
  {
    int arow = nseq[r0 + lr];
    const u16* Arow = xa + (size_t)arow * 128;
    #pragma unroll
    for (int ks = 0; ks < 4; ++ks) a_xa[ks] = *(const bfrag*)(Arow + ks * 32 + lg * 8);
  }

  f32x4 acc[8];
  #pragma unroll
  for (int ct = 0; ct < 8; ++ct) acc[ct] = (f32x4){0.f, 0.f, 0.f, 0.f};

  STAGE_W(woT);
  __syncthreads();
  #pragma unroll
  for (int ks = 0; ks < 4; ++ks)
    #pragma unroll
    for (int ct = 0; ct < 8; ++ct) {
      bfrag b = *(const bfrag*)(sW + (ct * 16 + lr) * 136 + ks * 32 + lg * 8);
      acc[ct] = MFMA16(a_ao[ks], b, acc[ct]);
    }
  __syncthreads();

  STAGE_W(l3T);
  __syncthreads();
  #pragma unroll
  for (int ks = 0; ks < 4; ++ks)
    #pragma unroll
    for (int ct = 0; ct < 8; ++ct) {
      bfrag b = *(const bfrag*)(sW + (ct * 16 + lr) * 136 + ks * 32 + lg * 8);
      acc[ct] = MFMA16(a_xa[ks], b, acc[ct]);
    }
  __syncthreads();

  #pragma unroll
  for (int ct = 0; ct < 8; ++ct) {
    float bcol = bo[ct * 16 + lr];
    #pragma unroll
    for (int i = 0; i < 4; ++i) acc[ct][i] += bcol;
  }
  // LN2 -> acc holds atn (f32); bounce to ldsb; read a2 frags
  bfrag a2[4];
  {
    float s1[4] = {0, 0, 0, 0}, s2[4] = {0, 0, 0, 0};
    #pragma unroll
    for (int ct = 0; ct < 8; ++ct)
      #pragma unroll
      for (int i = 0; i < 4; ++i) {
        s1[i] += acc[ct][i];
        s2[i] += acc[ct][i] * acc[ct][i];
      }
    #pragma unroll
    for (int i = 0; i < 4; ++i) {
      s1[i] += __shfl_xor(s1[i], 1); s2[i] += __shfl_xor(s2[i], 1);
      s1[i] += __shfl_xor(s1[i], 2); s2[i] += __shfl_xor(s2[i], 2);
      s1[i] += __shfl_xor(s1[i], 4); s2[i] += __shfl_xor(s2[i], 4);
      s1[i] += __shfl_xor(s1[i], 8); s2[i] += __shfl_xor(s2[i], 8);
    }
    float mean[4], inv[4];
    #pragma unroll
    for (int i = 0; i < 4; ++i) {
      mean[i] = s1[i] * (1.f / 128.f);
      float var = s2[i] * (1.f / 128.f) - mean[i] * mean[i];
      inv[i] = rsqrtf(var + 1e-5f);
    }
    #pragma unroll
    for (int ct = 0; ct < 8; ++ct) {
      int col = ct * 16 + lr;
      float gc = g2[col], bc = b2[col];
      #pragma unroll
      for (int i = 0; i < 4; ++i) {
        acc[ct][i] = (acc[ct][i] - mean[i]) * inv[i] * gc + bc;
        ldsb[w][(lg * 4 + i) * 136 + col] = f2bf(acc[ct][i]);
      }
    }
    #pragma unroll
    for (int ks = 0; ks < 4; ++ks)
      a2[ks] = *(const bfrag*)(&ldsb[w][lr * 136 + ks * 32 + lg * 8]);
  }

  STAGE_W(f0T);
  __syncthreads();
  f32x4 acc2[8];
  #pragma unroll
  for (int ct = 0; ct < 8; ++ct) acc2[ct] = (f32x4){0.f, 0.f, 0.f, 0.f};
  #pragma unroll
  for (int ks = 0; ks < 4; ++ks)
    #pragma unroll
    for (int ct = 0; ct < 8; ++ct) {
      bfrag b = *(const bfrag*)(sW + (ct * 16 + lr) * 136 + ks * 32 + lg * 8);
      acc2[ct] = MFMA16(a2[ks], b, acc2[ct]);
    }
  #pragma unroll
  for (int ct = 0; ct < 8; ++ct) {
    int col = ct * 16 + lr;
    float bcol = b0f[col];
    #pragma unroll
    for (int i = 0; i < 4; ++i)
      ldsb[w][(lg * 4 + i) * 136 + col] = f2bf(fmaxf(acc2[ct][i] + bcol, 0.f));
  }
  #pragma unroll
  for (int ks = 0; ks < 4; ++ks)
    a2[ks] = *(const bfrag*)(&ldsb[w][lr * 136 + ks * 32 + lg * 8]);
  __syncthreads();

  STAGE_W(f1T);
  __syncthreads();
  #pragma unroll
  for (int ct = 0; ct < 8; ++ct) acc2[ct] = (f32x4){0.f, 0.f, 0.f, 0.f};
  #pragma unroll
  for (int ks = 0; ks < 4; ++ks)
    #pragma unroll
    for (int ct = 0; ct < 8; ++ct) {
      bfrag b = *(const bfrag*)(sW + (ct * 16 + lr) * 136 + ks * 32 + lg * 8);
      acc2[ct] = MFMA16(a2[ks], b, acc2[ct]);
    }
  #pragma unroll
  for (int ct = 0; ct < 8; ++ct) {
    int col = ct * 16 + lr;
    float bcol = b1f[col];
    #pragma unroll
    for (int i = 0; i < 4; ++i) acc2[ct][i] += bcol + acc[ct][i];
  }
  // LN3 -> dot w4 -> pred
  {
    float s1[4] = {0, 0, 0, 0}, s2[4] = {0, 0, 0, 0};
    #pragma unroll
    for (int ct = 0; ct < 8; ++ct)
      #pragma unroll
      for (int i = 0; i < 4; ++i) {
        s1[i] += acc2[ct][i];
        s2[i] += acc2[ct][i] * acc2[ct][i];
      }
    #pragma unroll
    for (int i = 0; i < 4; ++i) {
      s1[i] += __shfl_xor(s1[i], 1); s2[i] += __shfl_xor(s2[i], 1);
      s1[i] += __shfl_xor(s1[i], 2); s2[i] += __shfl_xor(s2[i], 2);
      s1[i] += __shfl_xor(s1[i], 4); s2[i] += __shfl_xor(s2[i], 4);
      s1[i] += __shfl_xor(s1[i], 8); s2[i] += __shfl_xor(s2[i], 8);
    }
    float p[4] = {0, 0, 0, 0};
    #pragma unroll
    for (int i = 0; i < 4; ++i) {
      float mean = s1[i] * (1.f / 128.f);
      float var = s2[i] * (1.f / 128.f) - mean * mean;
      float inv = rsqrtf(var + 1e-5f);
      #pragma unroll
      for (int ct = 0; ct < 8; ++ct) {
        int col = ct * 16 + lr;
        p[i] += ((acc2[ct][i] - mean) * inv * g3[col] + b3[col]) * w4[col];
      }
    }
    #pragma unroll
    for (int i = 0; i < 4; ++i) {
      p[i] += __shfl_xor(p[i], 1);
      p[i] += __shfl_xor(p[i], 2);
      p[i] += __shfl_xor(p[i], 4);
      p[i] += __shfl_xor(p[i], 8);
    }
    if (lr == 0) {
      float bias4 = b4[0];
      #pragma unroll
      for (int i = 0; i < 4; ++i) pred[r0 + lg * 4 + i] = p[i] + bias4;
    }
  }
}

// ---------------------------------------------------------------------------
extern "C" void kernel_launch(void* const* d_in, const int* in_sizes, int n_in,
                              void* d_out, int out_size, void* d_ws, size_t ws_size,
                              hipStream_t stream) {
  const int* hist_seq = (const int*)d_in[0];
  const int* hist_ans = (const int*)d_in[1];
  const int* new_seq = (const int*)d_in[2];
  const int* edge_index = (const int*)d_in[3];
  const float* node_x = (const float*)d_in[4];
  const float* gcn_w0 = (const float*)d_in[5];
  const float* gcn_b0 = (const float*)d_in[6];
  const float* gcn_w1 = (const float*)d_in[7];
  const float* gcn_b1 = (const float*)d_in[8];
  const float* gcn_w2 = (const float*)d_in[9];
  const float* gcn_b2 = (const float*)d_in[10];
  const float* ln0_g = (const float*)d_in[11];
  const float* ln0_b = (const float*)d_in[12];
  const float* ln1_g = (const float*)d_in[13];
  const float* ln1_b = (const float*)d_in[14];
  const float* ln2_g = (const float*)d_in[15];
  const float* ln2_b = (const float*)d_in[16];
  const float* ln3_g = (const float*)d_in[17];
  const float* ln3_b = (const float*)d_in[18];
  const float* corr_emb = (const float*)d_in[19];
  const float* lin0_w = (const float*)d_in[20];
  const float* lin0_b = (const float*)d_in[21];
  const float* lin1_w = (const float*)d_in[22];
  const float* lin2_w = (const float*)d_in[23];
  const float* lin3_w = (const float*)d_in[24];
  const float* lin4_w = (const float*)d_in[25];
  const float* lin4_b = (const float*)d_in[26];
  const float* pos_emb = (const float*)d_in[27];
  const float* mha_wq = (const float*)d_in[28];
  const float* mha_bq = (const float*)d_in[29];
  const float* mha_wk = (const float*)d_in[30];
  const float* mha_bk = (const float*)d_in[31];
  const float* mha_wv = (const float*)d_in[32];
  const float* mha_bv = (const float*)d_in[33];
  const float* mha_wo = (const float*)d_in[34];
  const float* mha_bo = (const float*)d_in[35];
  const float* ffn0_w = (const float*)d_in[36];
  const float* ffn0_b = (const float*)d_in[37];
  const float* ffn1_w = (const float*)d_in[38];
  const float* ffn1_b = (const float*)d_in[39];
  (void)in_sizes; (void)n_in; (void)out_size;

  char* ws = (char*)d_ws;
  size_t off = 0;
  auto alloc = [&](size_t bytes) -> void* {
    void* p = ws + off;
    off += (bytes + 255) & ~(size_t)255;
    return p;
  };
  int* cnt = (int*)alloc((size_t)N_NODES * 4);
  int* row_ptr = (int*)alloc((size_t)(N_NODES + 1) * 4);
  int* fill = (int*)alloc((size_t)N_NODES * 4);
  int* locpref = (int*)alloc((size_t)N_NODES * 4);
  int* btot = (int*)alloc(64 * 4);
  int* boff = (int*)alloc(64 * 4);
  float* dis = (float*)alloc((size_t)N_NODES * 4);
  int* csr_src = (int*)alloc((size_t)N_EDGES * 4);
  const size_t WB = 128 * 128 * 2;
  u16* g0T = (u16*)alloc(WB);
  u16* g1T = (u16*)alloc(WB);
  u16* g2T = (u16*)alloc(WB);
  u16* l0T = (u16*)alloc(WB);
  u16* l3T = (u16*)alloc(WB);
  u16* woT = (u16*)alloc(WB);
  u16* f0T = (u16*)alloc(WB);
  u16* f1T = (u16*)alloc(WB);
  u16* wqT = (u16*)alloc(WB);
  u16* wkT = (u16*)alloc(WB);
  u16* wvT = (u16*)alloc(WB);
  float* c01 = (float*)alloc(2 * 128 * 4);
  float* pc = (float*)alloc((size_t)2 * S_ * 128 * 4);
  u16* xa = (u16*)alloc((size_t)N_NODES * 128 * 2);
  const size_t CB = (size_t)BS_ * 128 * 2;   // 26.2 MB
  size_t RB = off;
  u16* bufQ = (u16*)(ws + RB);                // qh -> ao in place, head-major
  u16* bufK = (u16*)(ws + RB + CB);           // kh head-major
  u16* bufV = (u16*)(ws + RB + 2 * CB);       // vh head-major
  u16* xb = bufQ;                             // overlay: dead before qkv writes
  u16* xw = bufQ + (size_t)N_NODES * 128;
  size_t need = RB + 3 * CB;
  if (ws_size < need) return;     // diagnostic guard

  // ---- graph prep ----
  int nb = (N_NODES + 1023) / 1024;   // 49
  zero_i32_kernel<<<(N_NODES + 255) / 256, 256, 0, stream>>>(cnt, N_NODES);
  hist_kernel<<<(N_EDGES + 255) / 256, 256, 0, stream>>>(edge_index + N_EDGES, cnt, N_EDGES);
  scanA_kernel<<<nb, 1024, 0, stream>>>(cnt, locpref, btot, dis, N_NODES);
  scanB_kernel<<<1, 64, 0, stream>>>(btot, boff, nb);
  scanC_kernel<<<(N_NODES + 255) / 256, 256, 0, stream>>>(locpref, boff, row_ptr, fill, N_NODES);
  scatter_kernel<<<(N_EDGES + 255) / 256, 256, 0, stream>>>(edge_index, edge_index + N_EDGES,
                                                            fill, csr_src, N_EDGES);
  // ---- weight prep + pc table + node_x cast ----
  wprep_kernel<<<705, 256, 0, stream>>>(gcn_w0, gcn_w1, gcn_w2, lin0_w, lin3_w, mha_wo,
                                        ffn0_w, ffn1_w, lin1_w, lin2_w, mha_wq, mha_wk,
                                        mha_wv, corr_emb, g0T, g1T, g2T, l0T, l3T, woT,
                                        f0T, f1T, wqT, wkT, wvT, c01);
  pc_kernel<<<(2 * S_ * 128 + 255) / 256, 256, 0, stream>>>(lin0_b, pos_emb, c01, pc);
  f2bf8_kernel<<<(N_NODES * 16 + 255) / 256, 256, 0, stream>>>(node_x, xb, N_NODES * 16);

  int gN = (N_NODES + 63) / 64;
  int aN = (N_NODES + 3) / 4;

  // ---- GCN ----
  gemm_bf16_kernel<<<gN, 256, 0, stream>>>(xb, g0T, xw, N_NODES);
  agg_kernel<<<aN, 256, 0, stream>>>(xw, dis, row_ptr, csr_src, gcn_b0, ln0_g, ln0_b, xa, N_NODES, 1);
  gemm_bf16_kernel<<<gN, 256, 0, stream>>>(xa, g1T, xw, N_NODES);
  agg_kernel<<<aN, 256, 0, stream>>>(xw, dis, row_ptr, csr_src, gcn_b1, ln1_g, ln1_b, xa, N_NODES, 1);
  gemm_bf16_kernel<<<gN, 256, 0, stream>>>(xa, g2T, xw, N_NODES);
  agg_kernel<<<aN, 256, 0, stream>>>(xw, dis, row_ptr, csr_src, gcn_b2, nullptr, nullptr, xa, N_NODES, 0);

  // ---- transformer, full batch, 3 dispatches ----
  int gT = BS_ / 64;   // 1600
  qkv_kernel<<<2 * gT, 256, 0, stream>>>(xa, hist_seq, hist_ans, new_seq,
                                         l0T, pc, wkT, mha_bk, wvT, mha_bv,
                                         wqT, mha_bq, bufK, bufV, bufQ, gT);
  attn_mfma_kernel<<<B_ * 8, 256, 0, stream>>>(bufQ, bufK, bufV);
  out_kernel<<<gT, 256, 0, stream>>>(bufQ, xa, new_seq, woT, mha_bo, l3T,
                                     ln2_g, ln2_b, f0T, ffn0_b, f1T, ffn1_b,
                                     ln3_g, ln3_b, lin4_w, lin4_b, (float*)d_out);
}

// Round 12
// 417.283 us; speedup vs baseline: 3.4554x; 1.0716x over previous
//
#include <hip/hip_runtime.h>
#include <math.h>

#define N_NODES 50000
#define N_EDGES 800000
#define B_ 512
#define S_ 200
#define D_ 128
#define BS_ (B_*S_)            // 102400 rows, full batch

typedef unsigned short u16;
typedef unsigned int u32;
using bfrag = __attribute__((ext_vector_type(8))) short;
using f32x4 = __attribute__((ext_vector_type(4))) float;
using i32x4 = __attribute__((ext_vector_type(4))) int;

__device__ __forceinline__ u16 f2bf(float f) {        // round-half-up f32->bf16 (2 ops)
  return (u16)((__float_as_uint(f) + 0x8000u) >> 16);
}
__device__ __forceinline__ float bf2f(u16 v) { return __uint_as_float(((u32)v) << 16); }
__device__ __forceinline__ float bflo(u32 v) { return __uint_as_float(v << 16); }
__device__ __forceinline__ float bfhi(u32 v) { return __uint_as_float(v & 0xffff0000u); }
__device__ __forceinline__ u32 pack2(float a, float b) {
  return (u32)f2bf(a) | ((u32)f2bf(b) << 16);
}
#define MFMA16(a, b, c) __builtin_amdgcn_mfma_f32_16x16x32_bf16((a), (b), (c), 0, 0, 0)

// stage a 128x128 bf16 weight (row-major [c][k]) into padded LDS sW[128][136]
#define STAGE_W(Wsrc) \
  for (int i_ = threadIdx.x; i_ < 2048; i_ += 256) { \
    int c_ = i_ >> 4, kg_ = i_ & 15; \
    *(uint4*)(sW + c_ * 136 + kg_ * 8) = *(const uint4*)((Wsrc) + c_ * 128 + kg_ * 8); \
  }

// ---------------------------------------------------------------- utilities
__global__ void zero_i32_kernel(int* __restrict__ p, int n) {
  int i = blockIdx.x * 256 + threadIdx.x;
  if (i < n) p[i] = 0;
}

__global__ void f2bf8_kernel(const float* __restrict__ in, u16* __restrict__ out, int n8) {
  int i = blockIdx.x * 256 + threadIdx.x;
  if (i >= n8) return;
  float4 a = ((const float4*)in)[i * 2];
  float4 b = ((const float4*)in)[i * 2 + 1];
  uint4 o;
  o.x = pack2(a.x, a.y); o.y = pack2(a.z, a.w);
  o.z = pack2(b.x, b.y); o.w = pack2(b.z, b.w);
  ((uint4*)out)[i] = o;
}

// ---------------- fused weight prep: 8 transposes + 3 products + c01
__global__ __launch_bounds__(256) void wprep_kernel(
    const float* __restrict__ gcn_w0, const float* __restrict__ gcn_w1,
    const float* __restrict__ gcn_w2, const float* __restrict__ lin0_w,
    const float* __restrict__ lin3_w, const float* __restrict__ mha_wo,
    const float* __restrict__ ffn0_w, const float* __restrict__ ffn1_w,
    const float* __restrict__ lin1_w, const float* __restrict__ lin2_w,
    const float* __restrict__ mha_wq, const float* __restrict__ mha_wk,
    const float* __restrict__ mha_wv, const float* __restrict__ corr_emb,
    u16* __restrict__ g0T, u16* __restrict__ g1T, u16* __restrict__ g2T,
    u16* __restrict__ l0T, u16* __restrict__ l3T, u16* __restrict__ woT,
    u16* __restrict__ f0T, u16* __restrict__ f1T,
    u16* __restrict__ wqT, u16* __restrict__ wkT, u16* __restrict__ wvT,
    float* __restrict__ c01) {
  int bb = blockIdx.x;
  if (bb < 512) {                        // plain transpose W[k][c] -> D[c][k]
    const float* W; u16* D;
    switch (bb >> 6) {
      case 0: W = gcn_w0; D = g0T; break;
      case 1: W = gcn_w1; D = g1T; break;
      case 2: W = gcn_w2; D = g2T; break;
      case 3: W = lin0_w; D = l0T; break;
      case 4: W = lin3_w; D = l3T; break;
      case 5: W = mha_wo; D = woT; break;
      case 6: W = ffn0_w; D = f0T; break;
      default: W = ffn1_w; D = f1T; break;
    }
    int i = (bb & 63) * 256 + threadIdx.x;
    int k = i >> 7, c = i & 127;
    D[c * 128 + k] = f2bf(W[k * 128 + c]);
  } else if (bb < 704) {                 // (X@Y)^T -> D
    const float* X; const float* Y; u16* D;
    switch ((bb - 512) >> 6) {
      case 0: X = lin3_w; Y = mha_wq; D = wqT; break;
      case 1: X = lin2_w; Y = mha_wk; D = wkT; break;
      default: X = lin1_w; Y = mha_wv; D = wvT; break;
    }
    int i = ((bb - 512) & 63) * 256 + threadIdx.x;
    int k = i >> 7, c = i & 127;
    float acc = 0.f;
    for (int t = 0; t < 128; ++t) acc += X[k * 128 + t] * Y[t * 128 + c];
    D[c * 128 + k] = f2bf(acc);
  } else {                               // c01 = corr_emb @ lin0_w[128:]
    int idx = threadIdx.x;               // 0..255 = 2*128
    int i = idx >> 7, j = idx & 127;
    float acc = 0.f;
    for (int t = 0; t < 128; ++t)
      acc += corr_emb[i * 128 + t] * lin0_w[128 * 128 + t * 128 + j];
    c01[idx] = acc;
  }
}

// pc[a][s][c] = lin0_b[c] + pos_emb[s][c] + c01[a][c]
__global__ void pc_kernel(const float* __restrict__ lin0_b, const float* __restrict__ pos_emb,
                          const float* __restrict__ c01, float* __restrict__ pc) {
  int i = blockIdx.x * 256 + threadIdx.x;   // 51200
  int c = i & 127, s = (i >> 7) % S_, a = i / (128 * S_);
  pc[i] = lin0_b[c] + pos_emb[s * 128 + c] + c01[a * 128 + c];
}

// ---------------------------------------------------------------- graph prep
__global__ void hist_kernel(const int* __restrict__ dst, int* __restrict__ cnt, int E) {
  int e = blockIdx.x * 256 + threadIdx.x;
  if (e < E) atomicAdd(&cnt[dst[e]], 1);
}

__global__ __launch_bounds__(1024) void scanA_kernel(
    const int* __restrict__ cnt, int* __restrict__ locpref,
    int* __restrict__ btot, float* __restrict__ dis, int N) {
  __shared__ int wsum[16];
  int t = threadIdx.x, lane = t & 63, wid = t >> 6;
  int i = blockIdx.x * 1024 + t;
  int v = (i < N) ? cnt[i] : 0;
  if (i < N) dis[i] = rsqrtf(1.f + (float)v);
  int x = v;
  #pragma unroll
  for (int off = 1; off < 64; off <<= 1) {
    int y = __shfl_up(x, off);
    if (lane >= off) x += y;
  }
  if (lane == 63) wsum[wid] = x;
  __syncthreads();
  if (wid == 0 && lane < 16) {
    int s = wsum[lane];
    #pragma unroll
    for (int off = 1; off < 16; off <<= 1) {
      int y = __shfl_up(s, off);
      if (lane >= off) s += y;
    }
    wsum[lane] = s;
  }
  __syncthreads();
  int woff = (wid > 0) ? wsum[wid - 1] : 0;
  if (i < N) locpref[i] = woff + x - v;
  if (t == 1023) btot[blockIdx.x] = woff + x;
}

__global__ void scanB_kernel(const int* __restrict__ btot, int* __restrict__ boff, int nb) {
  int lane = threadIdx.x;
  int v = (lane < nb) ? btot[lane] : 0;
  int x = v;
  #pragma unroll
  for (int off = 1; off < 64; off <<= 1) {
    int y = __shfl_up(x, off);
    if (lane >= off) x += y;
  }
  if (lane < nb) boff[lane] = x - v;
}

__global__ void scanC_kernel(const int* __restrict__ locpref, const int* __restrict__ boff,
                             int* __restrict__ row_ptr, int* __restrict__ fill, int N) {
  int i = blockIdx.x * 256 + threadIdx.x;
  if (i < N) {
    int r = locpref[i] + boff[i >> 10];
    row_ptr[i] = r; fill[i] = r;
  }
  if (i == 0) row_ptr[N] = N_EDGES;
}

__global__ void scatter_kernel(const int* __restrict__ src, const int* __restrict__ dst,
                               int* __restrict__ fill, int* __restrict__ csr_src, int E) {
  int e = blockIdx.x * 256 + threadIdx.x;
  if (e >= E) return;
  int d = dst[e];
  int pos = atomicAdd(&fill[d], 1);
  csr_src[pos] = src[e];
}

// ------------------------------------------------------------ MFMA bf16 GEMM
// (GCN layers) C row-major; LDS-bounce coalesced uint4 stores.
__global__ __launch_bounds__(256) void gemm_bf16_kernel(
    const u16* __restrict__ A, const u16* __restrict__ wT,
    u16* __restrict__ C, int M) {
  __shared__ u16 ldsb[4][16 * 136];
  int t = threadIdx.x;
  int w = t >> 6, l = t & 63, lr = l & 15, lg = l >> 4;
  int r0 = blockIdx.x * 64 + w * 16;

  int row = r0 + lr;
  const u16* Arow = A + (size_t)(row < M ? row : 0) * 128;

  bfrag a[4];
  #pragma unroll
  for (int ks = 0; ks < 4; ++ks) a[ks] = *(const bfrag*)(Arow + ks * 32 + lg * 8);

  f32x4 acc[8];
  #pragma unroll
  for (int ct = 0; ct < 8; ++ct) acc[ct] = (f32x4){0.f, 0.f, 0.f, 0.f};
  #pragma unroll
  for (int ks = 0; ks < 4; ++ks)
    #pragma unroll
    for (int ct = 0; ct < 8; ++ct) {
      bfrag b = *(const bfrag*)(wT + (size_t)(ct * 16 + lr) * 128 + ks * 32 + lg * 8);
      acc[ct] = MFMA16(a[ks], b, acc[ct]);
    }
  #pragma unroll
  for (int ct = 0; ct < 8; ++ct)
    #pragma unroll
    for (int i = 0; i < 4; ++i)
      ldsb[w][(lg * 4 + i) * 136 + ct * 16 + lr] = f2bf(acc[ct][i]);
  #pragma unroll
  for (int j = 0; j < 4; ++j) {
    int c = j * 64 + l;
    int rw = c >> 4, ch = c & 15;
    int r = r0 + rw;
    if (r < M)
      *(uint4*)(C + (size_t)r * 128 + ch * 8) = *(const uint4*)&ldsb[w][rw * 136 + ch * 8];
  }
}

// ------------------------------------------------------------- GCN aggregate
__global__ __launch_bounds__(256) void agg_kernel(
    const u16* __restrict__ xw, const float* __restrict__ dis,
    const int* __restrict__ row_ptr, const int* __restrict__ csr_src,
    const float* __restrict__ bias, const float* __restrict__ lng,
    const float* __restrict__ lnb, u16* __restrict__ out, int N, int doLN) {
  int t = threadIdx.x;
  int n = blockIdx.x * 4 + (t >> 6);
  if (n >= N) return;
  int l = t & 63, cg = l & 15, eg = l >> 4;
  float dn = dis[n];
  float acc[8] = {0.f, 0.f, 0.f, 0.f, 0.f, 0.f, 0.f, 0.f};
  if (eg == 0) {
    uint4 r = *(const uint4*)(xw + (size_t)n * 128 + cg * 8);
    float w = dn * dn;
    acc[0] += w * bflo(r.x); acc[1] += w * bfhi(r.x);
    acc[2] += w * bflo(r.y); acc[3] += w * bfhi(r.y);
    acc[4] += w * bflo(r.z); acc[5] += w * bfhi(r.z);
    acc[6] += w * bflo(r.w); acc[7] += w * bfhi(r.w);
  }
  int e1 = row_ptr[n + 1];
  int e = row_ptr[n] + eg;
  int sn = (e < e1) ? csr_src[e] : -1;
  while (sn >= 0) {
    int s = sn;
    e += 4;
    sn = (e < e1) ? csr_src[e] : -1;
    float w = dis[s] * dn;
    uint4 r = *(const uint4*)(xw + (size_t)s * 128 + cg * 8);
    acc[0] += w * bflo(r.x); acc[1] += w * bfhi(r.x);
    acc[2] += w * bflo(r.y); acc[3] += w * bfhi(r.y);
    acc[4] += w * bflo(r.z); acc[5] += w * bfhi(r.z);
    acc[6] += w * bflo(r.w); acc[7] += w * bfhi(r.w);
  }
  #pragma unroll
  for (int j = 0; j < 8; ++j) {
    acc[j] += __shfl_xor(acc[j], 16);
    acc[j] += __shfl_xor(acc[j], 32);
  }
  int c0 = cg * 8;
  #pragma unroll
  for (int j = 0; j < 8; ++j) acc[j] = fmaxf(acc[j] + bias[c0 + j], 0.f);
  if (doLN) {
    float s1 = 0.f, s2 = 0.f;
    #pragma unroll
    for (int j = 0; j < 8; ++j) { s1 += acc[j]; s2 += acc[j] * acc[j]; }
    #pragma unroll
    for (int off = 1; off < 16; off <<= 1) {
      s1 += __shfl_xor(s1, off);
      s2 += __shfl_xor(s2, off);
    }
    float mean = s1 * (1.f / 128.f);
    float var = s2 * (1.f / 128.f) - mean * mean;
    float inv = rsqrtf(var + 1e-5f);
    #pragma unroll
    for (int j = 0; j < 8; ++j)
      acc[j] = (acc[j] - mean) * inv * lng[c0 + j] + lnb[c0 + j];
  }
  if (eg == 0) {
    uint4 o;
    o.x = pack2(acc[0], acc[1]); o.y = pack2(acc[2], acc[3]);
    o.z = pack2(acc[4], acc[5]); o.w = pack2(acc[6], acc[7]);
    *(uint4*)(out + (size_t)n * 128 + cg * 8) = o;
  }
}

// ----------------------- merged QKV with block-level weight staging in LDS
// role A (inter->kh,vh) / role B (qh, pre-scaled by 0.25 for attention).
__global__ __launch_bounds__(256) void qkv_kernel(
    const u16* __restrict__ xa, const int* __restrict__ hist,
    const int* __restrict__ ans, const int* __restrict__ nseq,
    const u16* __restrict__ l0T, const float* __restrict__ pc,
    const u16* __restrict__ wkT, const float* __restrict__ bk,
    const u16* __restrict__ wvT, const float* __restrict__ bv,
    const u16* __restrict__ wqT, const float* __restrict__ bq,
    u16* __restrict__ khout, u16* __restrict__ vhout,
    u16* __restrict__ qhout, int nblk) {
  __shared__ u16 sW[128 * 136];        // staged weight, padded stride
  __shared__ u16 ldsb[4][16 * 136];    // per-wave bounce
  int bb = blockIdx.x;
  int t = threadIdx.x, w = t >> 6, l = t & 63, lr = l & 15, lg = l >> 4;
  f32x4 acc[8];

  if (bb < nblk) {
    // ---- role A ----
    int r0 = bb * 64 + w * 16;
    int arow = hist[r0 + lr];
    const u16* Arow = xa + (size_t)arow * 128;
    bfrag a[4];
    #pragma unroll
    for (int ks = 0; ks < 4; ++ks) a[ks] = *(const bfrag*)(Arow + ks * 32 + lg * 8);

    STAGE_W(l0T);
    __syncthreads();
    #pragma unroll
    for (int ct = 0; ct < 8; ++ct) acc[ct] = (f32x4){0.f, 0.f, 0.f, 0.f};
    #pragma unroll
    for (int ks = 0; ks < 4; ++ks)
      #pragma unroll
      for (int ct = 0; ct < 8; ++ct) {
        bfrag b = *(const bfrag*)(sW + (ct * 16 + lr) * 136 + ks * 32 + lg * 8);
        acc[ct] = MFMA16(a[ks], b, acc[ct]);
      }
    int pcoff[4];
    #pragma unroll
    for (int i = 0; i < 4; ++i) {
      int r = r0 + lg * 4 + i;
      pcoff[i] = (ans[r] * S_ + (r % S_)) * 128;
    }
    #pragma unroll
    for (int ct = 0; ct < 8; ++ct) {
      int col = ct * 16 + lr;
      #pragma unroll
      for (int i = 0; i < 4; ++i)
        ldsb[w][(lg * 4 + i) * 136 + col] = f2bf(acc[ct][i] + pc[pcoff[i] + col]);
    }
    bfrag a2[4];
    #pragma unroll
    for (int ks = 0; ks < 4; ++ks)
      a2[ks] = *(const bfrag*)(&ldsb[w][lr * 136 + ks * 32 + lg * 8]);
    __syncthreads();           // all waves done reading sW(l0T)

    STAGE_W(wkT);
    __syncthreads();
    #pragma unroll
    for (int ct = 0; ct < 8; ++ct) acc[ct] = (f32x4){0.f, 0.f, 0.f, 0.f};
    #pragma unroll
    for (int ks = 0; ks < 4; ++ks)
      #pragma unroll
      for (int ct = 0; ct < 8; ++ct) {
        bfrag b = *(const bfrag*)(sW + (ct * 16 + lr) * 136 + ks * 32 + lg * 8);
        acc[ct] = MFMA16(a2[ks], b, acc[ct]);
      }
    #pragma unroll
    for (int ct = 0; ct < 8; ++ct)
      #pragma unroll
      for (int i = 0; i < 4; ++i)
        ldsb[w][(lg * 4 + i) * 136 + ct * 16 + lr] = f2bf(acc[ct][i] + bk[ct * 16 + lr]);
    #pragma unroll
    for (int j = 0; j < 4; ++j) {
      int c = j * 64 + l;
      int head = c >> 5, rw = (c >> 1) & 15, half = c & 1;
      *(uint4*)(khout + ((size_t)head * BS_ + r0 + rw) * 16 + half * 8) =
          *(const uint4*)&ldsb[w][rw * 136 + head * 16 + half * 8];
    }
    __syncthreads();           // done reading sW(wkT)

    STAGE_W(wvT);
    __syncthreads();
    #pragma unroll
    for (int ct = 0; ct < 8; ++ct) acc[ct] = (f32x4){0.f, 0.f, 0.f, 0.f};
    #pragma unroll
    for (int ks = 0; ks < 4; ++ks)
      #pragma unroll
      for (int ct = 0; ct < 8; ++ct) {
        bfrag b = *(const bfrag*)(sW + (ct * 16 + lr) * 136 + ks * 32 + lg * 8);
        acc[ct] = MFMA16(a2[ks], b, acc[ct]);
      }
    #pragma unroll
    for (int ct = 0; ct < 8; ++ct)
      #pragma unroll
      for (int i = 0; i < 4; ++i)
        ldsb[w][(lg * 4 + i) * 136 + ct * 16 + lr] = f2bf(acc[ct][i] + bv[ct * 16 + lr]);
    #pragma unroll
    for (int j = 0; j < 4; ++j) {
      int c = j * 64 + l;
      int head = c >> 5, rw = (c >> 1) & 15, half = c & 1;
      *(uint4*)(vhout + ((size_t)head * BS_ + r0 + rw) * 16 + half * 8) =
          *(const uint4*)&ldsb[w][rw * 136 + head * 16 + half * 8];
    }
  } else {
    // ---- role B: qh scaled by 0.25 (attention score scale folded in) ----
    int r0 = (bb - nblk) * 64 + w * 16;
    int arow = nseq[r0 + lr];
    const u16* Arow = xa + (size_t)arow * 128;
    bfrag a[4];
    #pragma unroll
    for (int ks = 0; ks < 4; ++ks) a[ks] = *(const bfrag*)(Arow + ks * 32 + lg * 8);

    STAGE_W(wqT);
    __syncthreads();
    #pragma unroll
    for (int ct = 0; ct < 8; ++ct) acc[ct] = (f32x4){0.f, 0.f, 0.f, 0.f};
    #pragma unroll
    for (int ks = 0; ks < 4; ++ks)
      #pragma unroll
      for (int ct = 0; ct < 8; ++ct) {
        bfrag b = *(const bfrag*)(sW + (ct * 16 + lr) * 136 + ks * 32 + lg * 8);
        acc[ct] = MFMA16(a[ks], b, acc[ct]);
      }
    #pragma unroll
    for (int ct = 0; ct < 8; ++ct)
      #pragma unroll
      for (int i = 0; i < 4; ++i)
        ldsb[w][(lg * 4 + i) * 136 + ct * 16 + lr] =
            f2bf((acc[ct][i] + bq[ct * 16 + lr]) * 0.25f);
    #pragma unroll
    for (int j = 0; j < 4; ++j) {
      int c = j * 64 + l;
      int head = c >> 5, rw = (c >> 1) & 15, half = c & 1;
      *(uint4*)(qhout + ((size_t)head * BS_ + r0 + rw) * 16 + half * 8) =
          *(const uint4*)&ldsb[w][rw * 136 + head * 16 + half * 8];
    }
  }
}

// ----------------------------------------------------------- MFMA attention
// Register-P flash attention via swapped operands:
//   S^T = MFMA(K, Q)  -> lane owns q-col (lr), keys in rows (lg*4+i)
//   P^T redistributed cross-lane (8 shfl) -> B-operand
//   O^T = MFMA(V^T, P^T, acc) -> lane holds O[q=lr][d=lg*4+i]
// LDS = Kl + Vt only (17.4 KB) -> high occupancy. In-place ao over qh.
__global__ __launch_bounds__(256) void attn_mfma_kernel(
    u16* qh_ao, const u16* __restrict__ kh, const u16* __restrict__ vh) {
  __shared__ u16 Kl[208 * 24];   // [key][d0..15] pad 24
  __shared__ u16 Vt[16 * 232];   // [d][key], keys>=200 zero
  int b = blockIdx.x >> 3, h = blockIdx.x & 7;
  int t = threadIdx.x;
  size_t base = ((size_t)h * BS_ + (size_t)b * S_) * 16;

  for (int i = t; i < 208 * 2; i += 256) {
    int key = i >> 1, d = (i & 1) * 8;
    uint4 v = make_uint4(0, 0, 0, 0);
    if (key < S_) v = *(const uint4*)(kh + base + (size_t)key * 16 + d);
    *(uint4*)(Kl + key * 24 + d) = v;
  }
  for (int i = t; i < 16 * 232; i += 256) {
    int d = i / 232, key = i - d * 232;
    Vt[d * 232 + key] = (key < S_) ? vh[base + (size_t)key * 16 + d] : (u16)0;
  }
  __syncthreads();

  int w = t >> 6, l = t & 63, lr = l & 15, lg = l >> 4;
  const f32x4 zero4 = {0.f, 0.f, 0.f, 0.f};
  const bfrag zerob = (bfrag){0, 0, 0, 0, 0, 0, 0, 0};
  // balanced qi partition: w0{1,7,12} w1{0,8,11} w2{2,9,10} w3{3,4,5,6}
  u32 qpack = (w == 0) ? 0xFC71u : (w == 1) ? 0xFB80u : (w == 2) ? 0xFA92u : 0x6543u;
  int srcA = lr + ((lg & 1) << 5);   // shuffle source lanes
  int srcB = srcA + 16;
  bool hiTile = (lg >= 2);

  for (int s = 0; s < 4; ++s) {
    int qi = (qpack >> (4 * s)) & 15;
    if (qi == 15) break;
    int qrow = qi * 16 + lr;
    bfrag qf = zerob;
    if (lg < 2 && qrow < S_)
      qf = *(const bfrag*)(qh_ao + base + (size_t)qrow * 16 + lg * 8);
    float rsum = 0.f;
    f32x4 o = zero4;
    int ktmax = (qi + 2) >> 1;
    for (int kt = 0; kt < ktmax; ++kt) {
      int kj0 = kt * 2, kj1 = kt * 2 + 1;
      u32 P0t0, P1t0, P0t1 = 0, P1t1 = 0;
      {  // tile kj0 (always <= qi)
        bfrag kf = zerob;
        if (lg < 2) kf = *(const bfrag*)(Kl + (kj0 * 16 + lr) * 24 + lg * 8);
        f32x4 sc = MFMA16(kf, qf, zero4);
        float p0, p1, p2, p3;
        if (kj0 == qi) {      // diagonal: keep key_local <= q_local
          p0 = (lg * 4 + 0 <= lr) ? __expf(sc[0]) : 0.f;
          p1 = (lg * 4 + 1 <= lr) ? __expf(sc[1]) : 0.f;
          p2 = (lg * 4 + 2 <= lr) ? __expf(sc[2]) : 0.f;
          p3 = (lg * 4 + 3 <= lr) ? __expf(sc[3]) : 0.f;
        } else {
          p0 = __expf(sc[0]); p1 = __expf(sc[1]);
          p2 = __expf(sc[2]); p3 = __expf(sc[3]);
        }
        rsum += (p0 + p1) + (p2 + p3);
        P0t0 = pack2(p0, p1); P1t0 = pack2(p2, p3);
      }
      if (kj1 <= qi) {
        bfrag kf = zerob;
        if (lg < 2) kf = *(const bfrag*)(Kl + (kj1 * 16 + lr) * 24 + lg * 8);
        f32x4 sc = MFMA16(kf, qf, zero4);
        float p0, p1, p2, p3;
        if (kj1 == qi) {
          p0 = (lg * 4 + 0 <= lr) ? __expf(sc[0]) : 0.f;
          p1 = (lg * 4 + 1 <= lr) ? __expf(sc[1]) : 0.f;
          p2 = (lg * 4 + 2 <= lr) ? __expf(sc[2]) : 0.f;
          p3 = (lg * 4 + 3 <= lr) ? __expf(sc[3]) : 0.f;
        } else {
          p0 = __expf(sc[0]); p1 = __expf(sc[1]);
          p2 = __expf(sc[2]); p3 = __expf(sc[3]);
        }
        rsum += (p0 + p1) + (p2 + p3);
        P0t1 = pack2(p0, p1); P1t1 = pack2(p2, p3);
      }
      // redistribute P^T: dest (lg,lr) needs keys kt*32+lg*8..+7 for q=lr
      u32 x0 = __shfl(P0t0, srcA), x1 = __shfl(P1t0, srcA);
      u32 x2 = __shfl(P0t0, srcB), x3 = __shfl(P1t0, srcB);
      u32 y0 = __shfl(P0t1, srcA), y1 = __shfl(P1t1, srcA);
      u32 y2 = __shfl(P0t1, srcB), y3 = __shfl(P1t1, srcB);
      i32x4 pi;
      pi[0] = (int)(hiTile ? y0 : x0);
      pi[1] = (int)(hiTile ? y1 : x1);
      pi[2] = (int)(hiTile ? y2 : x2);
      pi[3] = (int)(hiTile ? y3 : x3);
      bfrag pb = __builtin_bit_cast(bfrag, pi);
      bfrag vf = *(const bfrag*)(Vt + lr * 232 + kt * 32 + lg * 8);
      o = MFMA16(vf, pb, o);
    }
    rsum += __shfl_xor(rsum, 16);
    rsum += __shfl_xor(rsum, 32);
    if (qrow < S_) {
      float inv = 1.f / rsum;
      uint2 ov;
      ov.x = pack2(o[0] * inv, o[1] * inv);
      ov.y = pack2(o[2] * inv, o[3] * inv);
      *(uint2*)(qh_ao + base + (size_t)qrow * 16 + lg * 4) = ov;
    }
  }
}

// ---- fused output with staged weights:
// ao@wo + gather(new)@l3T + bo -> LN2 -> FFN -> LN3 -> pred
__global__ __launch_bounds__(256) void out_kernel(
    const u16* __restrict__ ao, const u16* __restrict__ xa,
    const int* __restrict__ nseq,
    const u16* __restrict__ woT, const float* __restrict__ bo,
    const u16* __restrict__ l3T,
    const float* __restrict__ g2, const float* __restrict__ b2,
    const u16* __restrict__ f0T, const float* __restrict__ b0f,
    const u16* __restrict__ f1T, const float* __restrict__ b1f,
    const float* __restrict__ g3, const float* __restrict__ b3,
    const float* __restrict__ w4, const float* __restrict__ b4,
    float* __restrict__ pred) {
  __shared__ u16 sW[128 * 136];
  __shared__ u16 ldsb[4][16 * 136];
  int t = threadIdx.x, w = t >> 6, l = t & 63, lr = l & 15, lg = l >> 4;
  int r0 = blockIdx.x * 64 + w * 16;

  bfrag a_ao[4], a_xa[4];
  #pragma unroll
  for (int ks = 0; ks < 4; ++ks) {
    int head = ks * 2 + (lg >> 1);
    int d0 = (lg & 1) * 8;
    a_ao[ks] = *(const bfrag*)(ao + ((size_t)head * BS_ + r0 + lr) * 16 + d0);
  }
  {
    int arow = nseq[r0 + lr];
    const u16* Arow = xa + (size_t)arow * 128;
    #pragma unroll
    for (int ks = 0; ks < 4; ++ks) a_xa[ks] = *(const bfrag*)(Arow + ks * 32 + lg * 8);
  }

  f32x4 acc[8];
  #pragma unroll
  for (int ct = 0; ct < 8; ++ct) acc[ct] = (f32x4){0.f, 0.f, 0.f, 0.f};

  STAGE_W(woT);
  __syncthreads();
  #pragma unroll
  for (int ks = 0; ks < 4; ++ks)
    #pragma unroll
    for (int ct = 0; ct < 8; ++ct) {
      bfrag b = *(const bfrag*)(sW + (ct * 16 + lr) * 136 + ks * 32 + lg * 8);
      acc[ct] = MFMA16(a_ao[ks], b, acc[ct]);
    }
  __syncthreads();

  STAGE_W(l3T);
  __syncthreads();
  #pragma unroll
  for (int ks = 0; ks < 4; ++ks)
    #pragma unroll
    for (int ct = 0; ct < 8; ++ct) {
      bfrag b = *(const bfrag*)(sW + (ct * 16 + lr) * 136 + ks * 32 + lg * 8);
      acc[ct] = MFMA16(a_xa[ks], b, acc[ct]);
    }
  __syncthreads();

  #pragma unroll
  for (int ct = 0; ct < 8; ++ct) {
    float bcol = bo[ct * 16 + lr];
    #pragma unroll
    for (int i = 0; i < 4; ++i) acc[ct][i] += bcol;
  }
  // LN2 -> acc holds atn (f32); bounce to ldsb; read a2 frags
  bfrag a2[4];
  {
    float s1[4] = {0, 0, 0, 0}, s2[4] = {0, 0, 0, 0};
    #pragma unroll
    for (int ct = 0; ct < 8; ++ct)
      #pragma unroll
      for (int i = 0; i < 4; ++i) {
        s1[i] += acc[ct][i];
        s2[i] += acc[ct][i] * acc[ct][i];
      }
    #pragma unroll
    for (int i = 0; i < 4; ++i) {
      s1[i] += __shfl_xor(s1[i], 1); s2[i] += __shfl_xor(s2[i], 1);
      s1[i] += __shfl_xor(s1[i], 2); s2[i] += __shfl_xor(s2[i], 2);
      s1[i] += __shfl_xor(s1[i], 4); s2[i] += __shfl_xor(s2[i], 4);
      s1[i] += __shfl_xor(s1[i], 8); s2[i] += __shfl_xor(s2[i], 8);
    }
    float mean[4], inv[4];
    #pragma unroll
    for (int i = 0; i < 4; ++i) {
      mean[i] = s1[i] * (1.f / 128.f);
      float var = s2[i] * (1.f / 128.f) - mean[i] * mean[i];
      inv[i] = rsqrtf(var + 1e-5f);
    }
    #pragma unroll
    for (int ct = 0; ct < 8; ++ct) {
      int col = ct * 16 + lr;
      float gc = g2[col], bc = b2[col];
      #pragma unroll
      for (int i = 0; i < 4; ++i) {
        acc[ct][i] = (acc[ct][i] - mean[i]) * inv[i] * gc + bc;
        ldsb[w][(lg * 4 + i) * 136 + col] = f2bf(acc[ct][i]);
      }
    }
    #pragma unroll
    for (int ks = 0; ks < 4; ++ks)
      a2[ks] = *(const bfrag*)(&ldsb[w][lr * 136 + ks * 32 + lg * 8]);
  }

  STAGE_W(f0T);
  __syncthreads();
  f32x4 acc2[8];
  #pragma unroll
  for (int ct = 0; ct < 8; ++ct) acc2[ct] = (f32x4){0.f, 0.f, 0.f, 0.f};
  #pragma unroll
  for (int ks = 0; ks < 4; ++ks)
    #pragma unroll
    for (int ct = 0; ct < 8; ++ct) {
      bfrag b = *(const bfrag*)(sW + (ct * 16 + lr) * 136 + ks * 32 + lg * 8);
      acc2[ct] = MFMA16(a2[ks], b, acc2[ct]);
    }
  #pragma unroll
  for (int ct = 0; ct < 8; ++ct) {
    int col = ct * 16 + lr;
    float bcol = b0f[col];
    #pragma unroll
    for (int i = 0; i < 4; ++i)
      ldsb[w][(lg * 4 + i) * 136 + col] = f2bf(fmaxf(acc2[ct][i] + bcol, 0.f));
  }
  #pragma unroll
  for (int ks = 0; ks < 4; ++ks)
    a2[ks] = *(const bfrag*)(&ldsb[w][lr * 136 + ks * 32 + lg * 8]);
  __syncthreads();

  STAGE_W(f1T);
  __syncthreads();
  #pragma unroll
  for (int ct = 0; ct < 8; ++ct) acc2[ct] = (f32x4){0.f, 0.f, 0.f, 0.f};
  #pragma unroll
  for (int ks = 0; ks < 4; ++ks)
    #pragma unroll
    for (int ct = 0; ct < 8; ++ct) {
      bfrag b = *(const bfrag*)(sW + (ct * 16 + lr) * 136 + ks * 32 + lg * 8);
      acc2[ct] = MFMA16(a2[ks], b, acc2[ct]);
    }
  #pragma unroll
  for (int ct = 0; ct < 8; ++ct) {
    int col = ct * 16 + lr;
    float bcol = b1f[col];
    #pragma unroll
    for (int i = 0; i < 4; ++i) acc2[ct][i] += bcol + acc[ct][i];
  }
  // LN3 -> dot w4 -> pred
  {
    float s1[4] = {0, 0, 0, 0}, s2[4] = {0, 0, 0, 0};
    #pragma unroll
    for (int ct = 0; ct < 8; ++ct)
      #pragma unroll
      for (int i = 0; i < 4; ++i) {
        s1[i] += acc2[ct][i];
        s2[i] += acc2[ct][i] * acc2[ct][i];
      }
    #pragma unroll
    for (int i = 0; i < 4; ++i) {
      s1[i] += __shfl_xor(s1[i], 1); s2[i] += __shfl_xor(s2[i], 1);
      s1[i] += __shfl_xor(s1[i], 2); s2[i] += __shfl_xor(s2[i], 2);
      s1[i] += __shfl_xor(s1[i], 4); s2[i] += __shfl_xor(s2[i], 4);
      s1[i] += __shfl_xor(s1[i], 8); s2[i] += __shfl_xor(s2[i], 8);
    }
    float p[4] = {0, 0, 0, 0};
    #pragma unroll
    for (int i = 0; i < 4; ++i) {
      float mean = s1[i] * (1.f / 128.f);
      float var = s2[i] * (1.f / 128.f) - mean * mean;
      float inv = rsqrtf(var + 1e-5f);
      #pragma unroll
      for (int ct = 0; ct < 8; ++ct) {
        int col = ct * 16 + lr;
        p[i] += ((acc2[ct][i] - mean) * inv * g3[col] + b3[col]) * w4[col];
      }
    }
    #pragma unroll
    for (int i = 0; i < 4; ++i) {
      p[i] += __shfl_xor(p[i], 1);
      p[i] += __shfl_xor(p[i], 2);
      p[i] += __shfl_xor(p[i], 4);
      p[i] += __shfl_xor(p[i], 8);
    }
    if (lr == 0) {
      float bias4 = b4[0];
      #pragma unroll
      for (int i = 0; i < 4; ++i) pred[r0 + lg * 4 + i] = p[i] + bias4;
    }
  }
}

// ---------------------------------------------------------------------------
extern "C" void kernel_launch(void* const* d_in, const int* in_sizes, int n_in,
                              void* d_out, int out_size, void* d_ws, size_t ws_size,
                              hipStream_t stream) {
  const int* hist_seq = (const int*)d_in[0];
  const int* hist_ans = (const int*)d_in[1];
  const int* new_seq = (const int*)d_in[2];
  const int* edge_index = (const int*)d_in[3];
  const float* node_x = (const float*)d_in[4];
  const float* gcn_w0 = (const float*)d_in[5];
  const float* gcn_b0 = (const float*)d_in[6];
  const float* gcn_w1 = (const float*)d_in[7];
  const float* gcn_b1 = (const float*)d_in[8];
  const float* gcn_w2 = (const float*)d_in[9];
  const float* gcn_b2 = (const float*)d_in[10];
  const float* ln0_g = (const float*)d_in[11];
  const float* ln0_b = (const float*)d_in[12];
  const float* ln1_g = (const float*)d_in[13];
  const float* ln1_b = (const float*)d_in[14];
  const float* ln2_g = (const float*)d_in[15];
  const float* ln2_b = (const float*)d_in[16];
  const float* ln3_g = (const float*)d_in[17];
  const float* ln3_b = (const float*)d_in[18];
  const float* corr_emb = (const float*)d_in[19];
  const float* lin0_w = (const float*)d_in[20];
  const float* lin0_b = (const float*)d_in[21];
  const float* lin1_w = (const float*)d_in[22];
  const float* lin2_w = (const float*)d_in[23];
  const float* lin3_w = (const float*)d_in[24];
  const float* lin4_w = (const float*)d_in[25];
  const float* lin4_b = (const float*)d_in[26];
  const float* pos_emb = (const float*)d_in[27];
  const float* mha_wq = (const float*)d_in[28];
  const float* mha_bq = (const float*)d_in[29];
  const float* mha_wk = (const float*)d_in[30];
  const float* mha_bk = (const float*)d_in[31];
  const float* mha_wv = (const float*)d_in[32];
  const float* mha_bv = (const float*)d_in[33];
  const float* mha_wo = (const float*)d_in[34];
  const float* mha_bo = (const float*)d_in[35];
  const float* ffn0_w = (const float*)d_in[36];
  const float* ffn0_b = (const float*)d_in[37];
  const float* ffn1_w = (const float*)d_in[38];
  const float* ffn1_b = (const float*)d_in[39];
  (void)in_sizes; (void)n_in; (void)out_size;

  char* ws = (char*)d_ws;
  size_t off = 0;
  auto alloc = [&](size_t bytes) -> void* {
    void* p = ws + off;
    off += (bytes + 255) & ~(size_t)255;
    return p;
  };
  int* cnt = (int*)alloc((size_t)N_NODES * 4);
  int* row_ptr = (int*)alloc((size_t)(N_NODES + 1) * 4);
  int* fill = (int*)alloc((size_t)N_NODES * 4);
  int* locpref = (int*)alloc((size_t)N_NODES * 4);
  int* btot = (int*)alloc(64 * 4);
  int* boff = (int*)alloc(64 * 4);
  float* dis = (float*)alloc((size_t)N_NODES * 4);
  int* csr_src = (int*)alloc((size_t)N_EDGES * 4);
  const size_t WB = 128 * 128 * 2;
  u16* g0T = (u16*)alloc(WB);
  u16* g1T = (u16*)alloc(WB);
  u16* g2T = (u16*)alloc(WB);
  u16* l0T = (u16*)alloc(WB);
  u16* l3T = (u16*)alloc(WB);
  u16* woT = (u16*)alloc(WB);
  u16* f0T = (u16*)alloc(WB);
  u16* f1T = (u16*)alloc(WB);
  u16* wqT = (u16*)alloc(WB);
  u16* wkT = (u16*)alloc(WB);
  u16* wvT = (u16*)alloc(WB);
  float* c01 = (float*)alloc(2 * 128 * 4);
  float* pc = (float*)alloc((size_t)2 * S_ * 128 * 4);
  u16* xa = (u16*)alloc((size_t)N_NODES * 128 * 2);
  const size_t CB = (size_t)BS_ * 128 * 2;   // 26.2 MB
  size_t RB = off;
  u16* bufQ = (u16*)(ws + RB);                // qh -> ao in place, head-major
  u16* bufK = (u16*)(ws + RB + CB);           // kh head-major
  u16* bufV = (u16*)(ws + RB + 2 * CB);       // vh head-major
  u16* xb = bufQ;                             // overlay: dead before qkv writes
  u16* xw = bufQ + (size_t)N_NODES * 128;
  size_t need = RB + 3 * CB;
  if (ws_size < need) return;     // diagnostic guard

  // ---- graph prep ----
  int nb = (N_NODES + 1023) / 1024;   // 49
  zero_i32_kernel<<<(N_NODES + 255) / 256, 256, 0, stream>>>(cnt, N_NODES);
  hist_kernel<<<(N_EDGES + 255) / 256, 256, 0, stream>>>(edge_index + N_EDGES, cnt, N_EDGES);
  scanA_kernel<<<nb, 1024, 0, stream>>>(cnt, locpref, btot, dis, N_NODES);
  scanB_kernel<<<1, 64, 0, stream>>>(btot, boff, nb);
  scanC_kernel<<<(N_NODES + 255) / 256, 256, 0, stream>>>(locpref, boff, row_ptr, fill, N_NODES);
  scatter_kernel<<<(N_EDGES + 255) / 256, 256, 0, stream>>>(edge_index, edge_index + N_EDGES,
                                                            fill, csr_src, N_EDGES);
  // ---- weight prep + pc table + node_x cast ----
  wprep_kernel<<<705, 256, 0, stream>>>(gcn_w0, gcn_w1, gcn_w2, lin0_w, lin3_w, mha_wo,
                                        ffn0_w, ffn1_w, lin1_w, lin2_w, mha_wq, mha_wk,
                                        mha_wv, corr_emb, g0T, g1T, g2T, l0T, l3T, woT,
                                        f0T, f1T, wqT, wkT, wvT, c01);
  pc_kernel<<<(2 * S_ * 128 + 255) / 256, 256, 0, stream>>>(lin0_b, pos_emb, c01, pc);
  f2bf8_kernel<<<(N_NODES * 16 + 255) / 256, 256, 0, stream>>>(node_x, xb, N_NODES * 16);

  int gN = (N_NODES + 63) / 64;
  int aN = (N_NODES + 3) / 4;

  // ---- GCN ----
  gemm_bf16_kernel<<<gN, 256, 0, stream>>>(xb, g0T, xw, N_NODES);
  agg_kernel<<<aN, 256, 0, stream>>>(xw, dis, row_ptr, csr_src, gcn_b0, ln0_g, ln0_b, xa, N_NODES, 1);
  gemm_bf16_kernel<<<gN, 256, 0, stream>>>(xa, g1T, xw, N_NODES);
  agg_kernel<<<aN, 256, 0, stream>>>(xw, dis, row_ptr, csr_src, gcn_b1, ln1_g, ln1_b, xa, N_NODES, 1);
  gemm_bf16_kernel<<<gN, 256, 0, stream>>>(xa, g2T, xw, N_NODES);
  agg_kernel<<<aN, 256, 0, stream>>>(xw, dis, row_ptr, csr_src, gcn_b2, nullptr, nullptr, xa, N_NODES, 0);

  // ---- transformer, full batch, 3 dispatches ----
  int gT = BS_ / 64;   // 1600
  qkv_kernel<<<2 * gT, 256, 0, stream>>>(xa, hist_seq, hist_ans, new_seq,
                                         l0T, pc, wkT, mha_bk, wvT, mha_bv,
                                         wqT, mha_bq, bufK, bufV, bufQ, gT);
  attn_mfma_kernel<<<B_ * 8, 256, 0, stream>>>(bufQ, bufK, bufV);
  out_kernel<<<gT, 256, 0, stream>>>(bufQ, xa, new_seq, woT, mha_bo, l3T,
                                     ln2_g, ln2_b, f0T, ffn0_b, f1T, ffn1_b,
                                     ln3_g, ln3_b, lin4_w, lin4_b, (float*)d_out);
}

// Round 13
// 382.564 us; speedup vs baseline: 3.7690x; 1.0908x over previous
//
#include <hip/hip_runtime.h>
#include <math.h>

#define N_NODES 50000
#define N_EDGES 800000
#define B_ 512
#define S_ 200
#define D_ 128
#define BS_ (B_*S_)            // 102400 rows, full batch

typedef unsigned short u16;
typedef unsigned int u32;
using bfrag = __attribute__((ext_vector_type(8))) short;
using f32x4 = __attribute__((ext_vector_type(4))) float;
using i32x4 = __attribute__((ext_vector_type(4))) int;

__device__ __forceinline__ u16 f2bf(float f) {        // round-half-up f32->bf16 (2 ops)
  return (u16)((__float_as_uint(f) + 0x8000u) >> 16);
}
__device__ __forceinline__ float bf2f(u16 v) { return __uint_as_float(((u32)v) << 16); }
__device__ __forceinline__ float bflo(u32 v) { return __uint_as_float(v << 16); }
__device__ __forceinline__ float bfhi(u32 v) { return __uint_as_float(v & 0xffff0000u); }
__device__ __forceinline__ u32 pack2(float a, float b) {
  return (u32)f2bf(a) | ((u32)f2bf(b) << 16);
}
#define MFMA16(a, b, c) __builtin_amdgcn_mfma_f32_16x16x32_bf16((a), (b), (c), 0, 0, 0)

// stage a 128x128 bf16 weight (row-major [c][k]) into padded LDS sW[128][136]
#define STAGE_W(Wsrc) \
  for (int i_ = threadIdx.x; i_ < 2048; i_ += 256) { \
    int c_ = i_ >> 4, kg_ = i_ & 15; \
    *(uint4*)(sW + c_ * 136 + kg_ * 8) = *(const uint4*)((Wsrc) + c_ * 128 + kg_ * 8); \
  }

// -------------------- fused prep: zero cnt + 8 transposes + 3 products + pc + f2bf8
__global__ __launch_bounds__(256) void prep_kernel(
    int* __restrict__ cnt,
    const float* __restrict__ gcn_w0, const float* __restrict__ gcn_w1,
    const float* __restrict__ gcn_w2, const float* __restrict__ lin0_w,
    const float* __restrict__ lin3_w, const float* __restrict__ mha_wo,
    const float* __restrict__ ffn0_w, const float* __restrict__ ffn1_w,
    const float* __restrict__ lin1_w, const float* __restrict__ lin2_w,
    const float* __restrict__ mha_wq, const float* __restrict__ mha_wk,
    const float* __restrict__ mha_wv, const float* __restrict__ corr_emb,
    const float* __restrict__ lin0_b, const float* __restrict__ pos_emb,
    const float* __restrict__ node_x,
    u16* __restrict__ g0T, u16* __restrict__ g1T, u16* __restrict__ g2T,
    u16* __restrict__ l0T, u16* __restrict__ l3T, u16* __restrict__ woT,
    u16* __restrict__ f0T, u16* __restrict__ f1T,
    u16* __restrict__ wqT, u16* __restrict__ wkT, u16* __restrict__ wvT,
    float* __restrict__ pc, u16* __restrict__ xb) {
  int bb = blockIdx.x;
  int t = threadIdx.x;
  if (bb < 196) {                         // zero cnt
    int i = bb * 256 + t;
    if (i < N_NODES) cnt[i] = 0;
  } else if (bb < 708) {                  // plain transpose W[k][c] -> D[c][k]
    int idx = bb - 196;
    const float* W; u16* D;
    switch (idx >> 6) {
      case 0: W = gcn_w0; D = g0T; break;
      case 1: W = gcn_w1; D = g1T; break;
      case 2: W = gcn_w2; D = g2T; break;
      case 3: W = lin0_w; D = l0T; break;
      case 4: W = lin3_w; D = l3T; break;
      case 5: W = mha_wo; D = woT; break;
      case 6: W = ffn0_w; D = f0T; break;
      default: W = ffn1_w; D = f1T; break;
    }
    int i = (idx & 63) * 256 + t;
    int k = i >> 7, c = i & 127;
    D[c * 128 + k] = f2bf(W[k * 128 + c]);
  } else if (bb < 900) {                  // (X@Y)^T -> D
    int idx = bb - 708;
    const float* X; const float* Y; u16* D;
    switch (idx >> 6) {
      case 0: X = lin3_w; Y = mha_wq; D = wqT; break;
      case 1: X = lin2_w; Y = mha_wk; D = wkT; break;
      default: X = lin1_w; Y = mha_wv; D = wvT; break;
    }
    int i = (idx & 63) * 256 + t;
    int k = i >> 7, c = i & 127;
    float acc = 0.f;
    for (int q = 0; q < 128; ++q) acc += X[k * 128 + q] * Y[q * 128 + c];
    D[c * 128 + k] = f2bf(acc);
  } else if (bb < 1100) {                 // pc[a][s][c] = lin0_b + pos_emb + corr@lin0_w[128:]
    int i = (bb - 900) * 256 + t;         // 51200
    int c = i & 127, s = (i >> 7) % S_, a = i / (128 * S_);
    float acc = lin0_b[c] + pos_emb[s * 128 + c];
    for (int q = 0; q < 128; ++q)
      acc += corr_emb[a * 128 + q] * lin0_w[(128 + q) * 128 + c];
    pc[i] = acc;
  } else {                                // f2bf8: node_x -> xb
    int i = (bb - 1100) * 256 + t;        // 800000
    if (i < N_NODES * 16) {
      float4 a4 = ((const float4*)node_x)[i * 2];
      float4 b4 = ((const float4*)node_x)[i * 2 + 1];
      uint4 o;
      o.x = pack2(a4.x, a4.y); o.y = pack2(a4.z, a4.w);
      o.z = pack2(b4.x, b4.y); o.w = pack2(b4.z, b4.w);
      ((uint4*)xb)[i] = o;
    }
  }
}

// ---------------------------------------------------------------- graph prep
__global__ void hist_kernel(const int* __restrict__ dst, int* __restrict__ cnt, int E) {
  int e = blockIdx.x * 256 + threadIdx.x;
  if (e < E) atomicAdd(&cnt[dst[e]], 1);
}

__global__ __launch_bounds__(1024) void scanA_kernel(
    const int* __restrict__ cnt, int* __restrict__ locpref,
    int* __restrict__ btot, float* __restrict__ dis, int N) {
  __shared__ int wsum[16];
  int t = threadIdx.x, lane = t & 63, wid = t >> 6;
  int i = blockIdx.x * 1024 + t;
  int v = (i < N) ? cnt[i] : 0;
  if (i < N) dis[i] = rsqrtf(1.f + (float)v);
  int x = v;
  #pragma unroll
  for (int off = 1; off < 64; off <<= 1) {
    int y = __shfl_up(x, off);
    if (lane >= off) x += y;
  }
  if (lane == 63) wsum[wid] = x;
  __syncthreads();
  if (wid == 0 && lane < 16) {
    int s = wsum[lane];
    #pragma unroll
    for (int off = 1; off < 16; off <<= 1) {
      int y = __shfl_up(s, off);
      if (lane >= off) s += y;
    }
    wsum[lane] = s;
  }
  __syncthreads();
  int woff = (wid > 0) ? wsum[wid - 1] : 0;
  if (i < N) locpref[i] = woff + x - v;
  if (t == 1023) btot[blockIdx.x] = woff + x;
}

__global__ void scanB_kernel(const int* __restrict__ btot, int* __restrict__ boff, int nb) {
  int lane = threadIdx.x;
  int v = (lane < nb) ? btot[lane] : 0;
  int x = v;
  #pragma unroll
  for (int off = 1; off < 64; off <<= 1) {
    int y = __shfl_up(x, off);
    if (lane >= off) x += y;
  }
  if (lane < nb) boff[lane] = x - v;
}

__global__ void scanC_kernel(const int* __restrict__ locpref, const int* __restrict__ boff,
                             int* __restrict__ row_ptr, int* __restrict__ fill, int N) {
  int i = blockIdx.x * 256 + threadIdx.x;
  if (i < N) {
    int r = locpref[i] + boff[i >> 10];
    row_ptr[i] = r; fill[i] = r;
  }
  if (i == 0) row_ptr[N] = N_EDGES;
}

__global__ void scatter_kernel(const int* __restrict__ src, const int* __restrict__ dst,
                               int* __restrict__ fill, int* __restrict__ csr_src, int E) {
  int e = blockIdx.x * 256 + threadIdx.x;
  if (e >= E) return;
  int d = dst[e];
  int pos = atomicAdd(&fill[d], 1);
  csr_src[pos] = src[e];
}

// ------------------------------------------------------------ MFMA bf16 GEMM
// (GCN layers) block-staged weight; LDS-bounce coalesced uint4 stores.
__global__ __launch_bounds__(256) void gemm_bf16_kernel(
    const u16* __restrict__ A, const u16* __restrict__ wT,
    u16* __restrict__ C, int M) {
  __shared__ u16 sW[128 * 136];
  __shared__ u16 ldsb[4][16 * 136];
  int t = threadIdx.x;
  int w = t >> 6, l = t & 63, lr = l & 15, lg = l >> 4;
  int r0 = blockIdx.x * 64 + w * 16;

  int row = r0 + lr;
  const u16* Arow = A + (size_t)(row < M ? row : 0) * 128;

  bfrag a[4];
  #pragma unroll
  for (int ks = 0; ks < 4; ++ks) a[ks] = *(const bfrag*)(Arow + ks * 32 + lg * 8);

  STAGE_W(wT);
  __syncthreads();

  f32x4 acc[8];
  #pragma unroll
  for (int ct = 0; ct < 8; ++ct) acc[ct] = (f32x4){0.f, 0.f, 0.f, 0.f};
  #pragma unroll
  for (int ks = 0; ks < 4; ++ks)
    #pragma unroll
    for (int ct = 0; ct < 8; ++ct) {
      bfrag b = *(const bfrag*)(sW + (ct * 16 + lr) * 136 + ks * 32 + lg * 8);
      acc[ct] = MFMA16(a[ks], b, acc[ct]);
    }
  #pragma unroll
  for (int ct = 0; ct < 8; ++ct)
    #pragma unroll
    for (int i = 0; i < 4; ++i)
      ldsb[w][(lg * 4 + i) * 136 + ct * 16 + lr] = f2bf(acc[ct][i]);
  #pragma unroll
  for (int j = 0; j < 4; ++j) {
    int c = j * 64 + l;
    int rw = c >> 4, ch = c & 15;
    int r = r0 + rw;
    if (r < M)
      *(uint4*)(C + (size_t)r * 128 + ch * 8) = *(const uint4*)&ldsb[w][rw * 136 + ch * 8];
  }
}

// ------------------------------------------------------------- GCN aggregate
// wave per node; 16 colgrp x 4 edgegrp, 2 edges per edgegrp in flight (8 total)
__global__ __launch_bounds__(256) void agg_kernel(
    const u16* __restrict__ xw, const float* __restrict__ dis,
    const int* __restrict__ row_ptr, const int* __restrict__ csr_src,
    const float* __restrict__ bias, const float* __restrict__ lng,
    const float* __restrict__ lnb, u16* __restrict__ out, int N, int doLN) {
  int t = threadIdx.x;
  int n = blockIdx.x * 4 + (t >> 6);
  if (n >= N) return;
  int l = t & 63, cg = l & 15, eg = l >> 4;
  float dn = dis[n];
  float acc[8] = {0.f, 0.f, 0.f, 0.f, 0.f, 0.f, 0.f, 0.f};
  if (eg == 0) {
    uint4 r = *(const uint4*)(xw + (size_t)n * 128 + cg * 8);
    float w = dn * dn;
    acc[0] += w * bflo(r.x); acc[1] += w * bfhi(r.x);
    acc[2] += w * bflo(r.y); acc[3] += w * bfhi(r.y);
    acc[4] += w * bflo(r.z); acc[5] += w * bfhi(r.z);
    acc[6] += w * bflo(r.w); acc[7] += w * bfhi(r.w);
  }
  int e1 = row_ptr[n + 1];
  int e = row_ptr[n] + eg;
  int sn0 = (e < e1) ? csr_src[e] : -1;
  int sn1 = (e + 4 < e1) ? csr_src[e + 4] : -1;
  while (sn0 >= 0) {
    int s0 = sn0;
    int s1 = (sn1 >= 0) ? sn1 : sn0;            // safe address
    float w0 = dis[s0] * dn;
    float w1 = (sn1 >= 0) ? dis[s1] * dn : 0.f; // masked weight
    e += 8;
    sn0 = (e < e1) ? csr_src[e] : -1;
    sn1 = (e + 4 < e1) ? csr_src[e + 4] : -1;
    uint4 r0 = *(const uint4*)(xw + (size_t)s0 * 128 + cg * 8);
    uint4 r1 = *(const uint4*)(xw + (size_t)s1 * 128 + cg * 8);
    acc[0] += w0 * bflo(r0.x); acc[1] += w0 * bfhi(r0.x);
    acc[2] += w0 * bflo(r0.y); acc[3] += w0 * bfhi(r0.y);
    acc[4] += w0 * bflo(r0.z); acc[5] += w0 * bfhi(r0.z);
    acc[6] += w0 * bflo(r0.w); acc[7] += w0 * bfhi(r0.w);
    acc[0] += w1 * bflo(r1.x); acc[1] += w1 * bfhi(r1.x);
    acc[2] += w1 * bflo(r1.y); acc[3] += w1 * bfhi(r1.y);
    acc[4] += w1 * bflo(r1.z); acc[5] += w1 * bfhi(r1.z);
    acc[6] += w1 * bflo(r1.w); acc[7] += w1 * bfhi(r1.w);
  }
  #pragma unroll
  for (int j = 0; j < 8; ++j) {
    acc[j] += __shfl_xor(acc[j], 16);
    acc[j] += __shfl_xor(acc[j], 32);
  }
  int c0 = cg * 8;
  #pragma unroll
  for (int j = 0; j < 8; ++j) acc[j] = fmaxf(acc[j] + bias[c0 + j], 0.f);
  if (doLN) {
    float s1 = 0.f, s2 = 0.f;
    #pragma unroll
    for (int j = 0; j < 8; ++j) { s1 += acc[j]; s2 += acc[j] * acc[j]; }
    #pragma unroll
    for (int off = 1; off < 16; off <<= 1) {
      s1 += __shfl_xor(s1, off);
      s2 += __shfl_xor(s2, off);
    }
    float mean = s1 * (1.f / 128.f);
    float var = s2 * (1.f / 128.f) - mean * mean;
    float inv = rsqrtf(var + 1e-5f);
    #pragma unroll
    for (int j = 0; j < 8; ++j)
      acc[j] = (acc[j] - mean) * inv * lng[c0 + j] + lnb[c0 + j];
  }
  if (eg == 0) {
    uint4 o;
    o.x = pack2(acc[0], acc[1]); o.y = pack2(acc[2], acc[3]);
    o.z = pack2(acc[4], acc[5]); o.w = pack2(acc[6], acc[7]);
    *(uint4*)(out + (size_t)n * 128 + cg * 8) = o;
  }
}

// ----------------------- merged QKV with block-level weight staging in LDS
// role A (inter->kh,vh) / role B (qh, pre-scaled by 0.25 for attention).
__global__ __launch_bounds__(256) void qkv_kernel(
    const u16* __restrict__ xa, const int* __restrict__ hist,
    const int* __restrict__ ans, const int* __restrict__ nseq,
    const u16* __restrict__ l0T, const float* __restrict__ pc,
    const u16* __restrict__ wkT, const float* __restrict__ bk,
    const u16* __restrict__ wvT, const float* __restrict__ bv,
    const u16* __restrict__ wqT, const float* __restrict__ bq,
    u16* __restrict__ khout, u16* __restrict__ vhout,
    u16* __restrict__ qhout, int nblk) {
  __shared__ u16 sW[128 * 136];        // staged weight, padded stride
  __shared__ u16 ldsb[4][16 * 136];    // per-wave bounce
  int bb = blockIdx.x;
  int t = threadIdx.x, w = t >> 6, l = t & 63, lr = l & 15, lg = l >> 4;
  f32x4 acc[8];

  if (bb < nblk) {
    // ---- role A ----
    int r0 = bb * 64 + w * 16;
    int arow = hist[r0 + lr];
    const u16* Arow = xa + (size_t)arow * 128;
    bfrag a[4];
    #pragma unroll
    for (int ks = 0; ks < 4; ++ks) a[ks] = *(const bfrag*)(Arow + ks * 32 + lg * 8);

    STAGE_W(l0T);
    __syncthreads();
    #pragma unroll
    for (int ct = 0; ct < 8; ++ct) acc[ct] = (f32x4){0.f, 0.f, 0.f, 0.f};
    #pragma unroll
    for (int ks = 0; ks < 4; ++ks)
      #pragma unroll
      for (int ct = 0; ct < 8; ++ct) {
        bfrag b = *(const bfrag*)(sW + (ct * 16 + lr) * 136 + ks * 32 + lg * 8);
        acc[ct] = MFMA16(a[ks], b, acc[ct]);
      }
    int pcoff[4];
    #pragma unroll
    for (int i = 0; i < 4; ++i) {
      int r = r0 + lg * 4 + i;
      pcoff[i] = (ans[r] * S_ + (r % S_)) * 128;
    }
    #pragma unroll
    for (int ct = 0; ct < 8; ++ct) {
      int col = ct * 16 + lr;
      #pragma unroll
      for (int i = 0; i < 4; ++i)
        ldsb[w][(lg * 4 + i) * 136 + col] = f2bf(acc[ct][i] + pc[pcoff[i] + col]);
    }
    bfrag a2[4];
    #pragma unroll
    for (int ks = 0; ks < 4; ++ks)
      a2[ks] = *(const bfrag*)(&ldsb[w][lr * 136 + ks * 32 + lg * 8]);
    __syncthreads();           // all waves done reading sW(l0T)

    STAGE_W(wkT);
    __syncthreads();
    #pragma unroll
    for (int ct = 0; ct < 8; ++ct) acc[ct] = (f32x4){0.f, 0.f, 0.f, 0.f};
    #pragma unroll
    for (int ks = 0; ks < 4; ++ks)
      #pragma unroll
      for (int ct = 0; ct < 8; ++ct) {
        bfrag b = *(const bfrag*)(sW + (ct * 16 + lr) * 136 + ks * 32 + lg * 8);
        acc[ct] = MFMA16(a2[ks], b, acc[ct]);
      }
    #pragma unroll
    for (int ct = 0; ct < 8; ++ct)
      #pragma unroll
      for (int i = 0; i < 4; ++i)
        ldsb[w][(lg * 4 + i) * 136 + ct * 16 + lr] = f2bf(acc[ct][i] + bk[ct * 16 + lr]);
    #pragma unroll
    for (int j = 0; j < 4; ++j) {
      int c = j * 64 + l;
      int head = c >> 5, rw = (c >> 1) & 15, half = c & 1;
      *(uint4*)(khout + ((size_t)head * BS_ + r0 + rw) * 16 + half * 8) =
          *(const uint4*)&ldsb[w][rw * 136 + head * 16 + half * 8];
    }
    __syncthreads();           // done reading sW(wkT)

    STAGE_W(wvT);
    __syncthreads();
    #pragma unroll
    for (int ct = 0; ct < 8; ++ct) acc[ct] = (f32x4){0.f, 0.f, 0.f, 0.f};
    #pragma unroll
    for (int ks = 0; ks < 4; ++ks)
      #pragma unroll
      for (int ct = 0; ct < 8; ++ct) {
        bfrag b = *(const bfrag*)(sW + (ct * 16 + lr) * 136 + ks * 32 + lg * 8);
        acc[ct] = MFMA16(a2[ks], b, acc[ct]);
      }
    #pragma unroll
    for (int ct = 0; ct < 8; ++ct)
      #pragma unroll
      for (int i = 0; i < 4; ++i)
        ldsb[w][(lg * 4 + i) * 136 + ct * 16 + lr] = f2bf(acc[ct][i] + bv[ct * 16 + lr]);
    #pragma unroll
    for (int j = 0; j < 4; ++j) {
      int c = j * 64 + l;
      int head = c >> 5, rw = (c >> 1) & 15, half = c & 1;
      *(uint4*)(vhout + ((size_t)head * BS_ + r0 + rw) * 16 + half * 8) =
          *(const uint4*)&ldsb[w][rw * 136 + head * 16 + half * 8];
    }
  } else {
    // ---- role B: qh scaled by 0.25 (attention score scale folded in) ----
    int r0 = (bb - nblk) * 64 + w * 16;
    int arow = nseq[r0 + lr];
    const u16* Arow = xa + (size_t)arow * 128;
    bfrag a[4];
    #pragma unroll
    for (int ks = 0; ks < 4; ++ks) a[ks] = *(const bfrag*)(Arow + ks * 32 + lg * 8);

    STAGE_W(wqT);
    __syncthreads();
    #pragma unroll
    for (int ct = 0; ct < 8; ++ct) acc[ct] = (f32x4){0.f, 0.f, 0.f, 0.f};
    #pragma unroll
    for (int ks = 0; ks < 4; ++ks)
      #pragma unroll
      for (int ct = 0; ct < 8; ++ct) {
        bfrag b = *(const bfrag*)(sW + (ct * 16 + lr) * 136 + ks * 32 + lg * 8);
        acc[ct] = MFMA16(a[ks], b, acc[ct]);
      }
    #pragma unroll
    for (int ct = 0; ct < 8; ++ct)
      #pragma unroll
      for (int i = 0; i < 4; ++i)
        ldsb[w][(lg * 4 + i) * 136 + ct * 16 + lr] =
            f2bf((acc[ct][i] + bq[ct * 16 + lr]) * 0.25f);
    #pragma unroll
    for (int j = 0; j < 4; ++j) {
      int c = j * 64 + l;
      int head = c >> 5, rw = (c >> 1) & 15, half = c & 1;
      *(uint4*)(qhout + ((size_t)head * BS_ + r0 + rw) * 16 + half * 8) =
          *(const uint4*)&ldsb[w][rw * 136 + head * 16 + half * 8];
    }
  }
}

// ----------------------------------------------------------- MFMA attention
// Register-P flash attention via swapped operands (round-12 structure).
__global__ __launch_bounds__(256) void attn_mfma_kernel(
    u16* qh_ao, const u16* __restrict__ kh, const u16* __restrict__ vh) {
  __shared__ u16 Kl[208 * 24];   // [key][d0..15] pad 24
  __shared__ u16 Vt[16 * 232];   // [d][key], keys>=200 zero
  int b = blockIdx.x >> 3, h = blockIdx.x & 7;
  int t = threadIdx.x;
  size_t base = ((size_t)h * BS_ + (size_t)b * S_) * 16;

  for (int i = t; i < 208 * 2; i += 256) {
    int key = i >> 1, d = (i & 1) * 8;
    uint4 v = make_uint4(0, 0, 0, 0);
    if (key < S_) v = *(const uint4*)(kh + base + (size_t)key * 16 + d);
    *(uint4*)(Kl + key * 24 + d) = v;
  }
  for (int i = t; i < 16 * 232; i += 256) {
    int d = i / 232, key = i - d * 232;
    Vt[d * 232 + key] = (key < S_) ? vh[base + (size_t)key * 16 + d] : (u16)0;
  }
  __syncthreads();

  int w = t >> 6, l = t & 63, lr = l & 15, lg = l >> 4;
  const f32x4 zero4 = {0.f, 0.f, 0.f, 0.f};
  const bfrag zerob = (bfrag){0, 0, 0, 0, 0, 0, 0, 0};
  u32 qpack = (w == 0) ? 0xFC71u : (w == 1) ? 0xFB80u : (w == 2) ? 0xFA92u : 0x6543u;
  int srcA = lr + ((lg & 1) << 5);
  int srcB = srcA + 16;
  bool hiTile = (lg >= 2);

  for (int s = 0; s < 4; ++s) {
    int qi = (qpack >> (4 * s)) & 15;
    if (qi == 15) break;
    int qrow = qi * 16 + lr;
    bfrag qf = zerob;
    if (lg < 2 && qrow < S_)
      qf = *(const bfrag*)(qh_ao + base + (size_t)qrow * 16 + lg * 8);
    float rsum = 0.f;
    f32x4 o = zero4;
    int ktmax = (qi + 2) >> 1;
    for (int kt = 0; kt < ktmax; ++kt) {
      int kj0 = kt * 2, kj1 = kt * 2 + 1;
      u32 P0t0, P1t0, P0t1 = 0, P1t1 = 0;
      {
        bfrag kf = zerob;
        if (lg < 2) kf = *(const bfrag*)(Kl + (kj0 * 16 + lr) * 24 + lg * 8);
        f32x4 sc = MFMA16(kf, qf, zero4);
        float p0, p1, p2, p3;
        if (kj0 == qi) {
          p0 = (lg * 4 + 0 <= lr) ? __expf(sc[0]) : 0.f;
          p1 = (lg * 4 + 1 <= lr) ? __expf(sc[1]) : 0.f;
          p2 = (lg * 4 + 2 <= lr) ? __expf(sc[2]) : 0.f;
          p3 = (lg * 4 + 3 <= lr) ? __expf(sc[3]) : 0.f;
        } else {
          p0 = __expf(sc[0]); p1 = __expf(sc[1]);
          p2 = __expf(sc[2]); p3 = __expf(sc[3]);
        }
        rsum += (p0 + p1) + (p2 + p3);
        P0t0 = pack2(p0, p1); P1t0 = pack2(p2, p3);
      }
      if (kj1 <= qi) {
        bfrag kf = zerob;
        if (lg < 2) kf = *(const bfrag*)(Kl + (kj1 * 16 + lr) * 24 + lg * 8);
        f32x4 sc = MFMA16(kf, qf, zero4);
        float p0, p1, p2, p3;
        if (kj1 == qi) {
          p0 = (lg * 4 + 0 <= lr) ? __expf(sc[0]) : 0.f;
          p1 = (lg * 4 + 1 <= lr) ? __expf(sc[1]) : 0.f;
          p2 = (lg * 4 + 2 <= lr) ? __expf(sc[2]) : 0.f;
          p3 = (lg * 4 + 3 <= lr) ? __expf(sc[3]) : 0.f;
        } else {
          p0 = __expf(sc[0]); p1 = __expf(sc[1]);
          p2 = __expf(sc[2]); p3 = __expf(sc[3]);
        }
        rsum += (p0 + p1) + (p2 + p3);
        P0t1 = pack2(p0, p1); P1t1 = pack2(p2, p3);
      }
      u32 x0 = __shfl(P0t0, srcA), x1 = __shfl(P1t0, srcA);
      u32 x2 = __shfl(P0t0, srcB), x3 = __shfl(P1t0, srcB);
      u32 y0 = __shfl(P0t1, srcA), y1 = __shfl(P1t1, srcA);
      u32 y2 = __shfl(P0t1, srcB), y3 = __shfl(P1t1, srcB);
      i32x4 pi;
      pi[0] = (int)(hiTile ? y0 : x0);
      pi[1] = (int)(hiTile ? y1 : x1);
      pi[2] = (int)(hiTile ? y2 : x2);
      pi[3] = (int)(hiTile ? y3 : x3);
      bfrag pb = __builtin_bit_cast(bfrag, pi);
      bfrag vf = *(const bfrag*)(Vt + lr * 232 + kt * 32 + lg * 8);
      o = MFMA16(vf, pb, o);
    }
    rsum += __shfl_xor(rsum, 16);
    rsum += __shfl_xor(rsum, 32);
    if (qrow < S_) {
      float inv = 1.f / rsum;
      uint2 ov;
      ov.x = pack2(o[0] * inv, o[1] * inv);
      ov.y = pack2(o[2] * inv, o[3] * inv);
      *(uint2*)(qh_ao + base + (size_t)qrow * 16 + lg * 4) = ov;
    }
  }
}

// ---- fused output with staged weights:
// ao@wo + gather(new)@l3T + bo -> LN2 -> FFN -> LN3 -> pred
__global__ __launch_bounds__(256) void out_kernel(
    const u16* __restrict__ ao, const u16* __restrict__ xa,
    const int* __restrict__ nseq,
    const u16* __restrict__ woT, const float* __restrict__ bo,
    const u16* __restrict__ l3T,
    const float* __restrict__ g2, const float* __restrict__ b2,
    const u16* __restrict__ f0T, const float* __restrict__ b0f,
    const u16* __restrict__ f1T, const float* __restrict__ b1f,
    const float* __restrict__ g3, const float* __restrict__ b3,
    const float* __restrict__ w4, const float* __restrict__ b4,
    float* __restrict__ pred) {
  __shared__ u16 sW[128 * 136];
  __shared__ u16 ldsb[4][16 * 136];
  int t = threadIdx.x, w = t >> 6, l = t & 63, lr = l & 15, lg = l >> 4;
  int r0 = blockIdx.x * 64 + w * 16;

  bfrag a_ao[4], a_xa[4];
  #pragma unroll
  for (int ks = 0; ks < 4; ++ks) {
    int head = ks * 2 + (lg >> 1);
    int d0 = (lg & 1) * 8;
    a_ao[ks] = *(const bfrag*)(ao + ((size_t)head * BS_ + r0 + lr) * 16 + d0);
  }
  {
    int arow = nseq[r0 + lr];
    const u16* Arow = xa + (size_t)arow * 128;
    #pragma unroll
    for (int ks = 0; ks < 4; ++ks) a_xa[ks] = *(const bfrag*)(Arow + ks * 32 + lg * 8);
  }

  f32x4 acc[8];
  #pragma unroll
  for (int ct = 0; ct < 8; ++ct) acc[ct] = (f32x4){0.f, 0.f, 0.f, 0.f};

  STAGE_W(woT);
  __syncthreads();
  #pragma unroll
  for (int ks = 0; ks < 4; ++ks)
    #pragma unroll
    for (int ct = 0; ct < 8; ++ct) {
      bfrag b = *(const bfrag*)(sW + (ct * 16 + lr) * 136 + ks * 32 + lg * 8);
      acc[ct] = MFMA16(a_ao[ks], b, acc[ct]);
    }
  __syncthreads();

  STAGE_W(l3T);
  __syncthreads();
  #pragma unroll
  for (int ks = 0; ks < 4; ++ks)
    #pragma unroll
    for (int ct = 0; ct < 8; ++ct) {
      bfrag b = *(const bfrag*)(sW + (ct * 16 + lr) * 136 + ks * 32 + lg * 8);
      acc[ct] = MFMA16(a_xa[ks], b, acc[ct]);
    }
  __syncthreads();

  #pragma unroll
  for (int ct = 0; ct < 8; ++ct) {
    float bcol = bo[ct * 16 + lr];
    #pragma unroll
    for (int i = 0; i < 4; ++i) acc[ct][i] += bcol;
  }
  // LN2 -> acc holds atn (f32); bounce to ldsb; read a2 frags
  bfrag a2[4];
  {
    float s1[4] = {0, 0, 0, 0}, s2[4] = {0, 0, 0, 0};
    #pragma unroll
    for (int ct = 0; ct < 8; ++ct)
      #pragma unroll
      for (int i = 0; i < 4; ++i) {
        s1[i] += acc[ct][i];
        s2[i] += acc[ct][i] * acc[ct][i];
      }
    #pragma unroll
    for (int i = 0; i < 4; ++i) {
      s1[i] += __shfl_xor(s1[i], 1); s2[i] += __shfl_xor(s2[i], 1);
      s1[i] += __shfl_xor(s1[i], 2); s2[i] += __shfl_xor(s2[i], 2);
      s1[i] += __shfl_xor(s1[i], 4); s2[i] += __shfl_xor(s2[i], 4);
      s1[i] += __shfl_xor(s1[i], 8); s2[i] += __shfl_xor(s2[i], 8);
    }
    float mean[4], inv[4];
    #pragma unroll
    for (int i = 0; i < 4; ++i) {
      mean[i] = s1[i] * (1.f / 128.f);
      float var = s2[i] * (1.f / 128.f) - mean[i] * mean[i];
      inv[i] = rsqrtf(var + 1e-5f);
    }
    #pragma unroll
    for (int ct = 0; ct < 8; ++ct) {
      int col = ct * 16 + lr;
      float gc = g2[col], bc = b2[col];
      #pragma unroll
      for (int i = 0; i < 4; ++i) {
        acc[ct][i] = (acc[ct][i] - mean[i]) * inv[i] * gc + bc;
        ldsb[w][(lg * 4 + i) * 136 + col] = f2bf(acc[ct][i]);
      }
    }
    #pragma unroll
    for (int ks = 0; ks < 4; ++ks)
      a2[ks] = *(const bfrag*)(&ldsb[w][lr * 136 + ks * 32 + lg * 8]);
  }

  STAGE_W(f0T);
  __syncthreads();
  f32x4 acc2[8];
  #pragma unroll
  for (int ct = 0; ct < 8; ++ct) acc2[ct] = (f32x4){0.f, 0.f, 0.f, 0.f};
  #pragma unroll
  for (int ks = 0; ks < 4; ++ks)
    #pragma unroll
    for (int ct = 0; ct < 8; ++ct) {
      bfrag b = *(const bfrag*)(sW + (ct * 16 + lr) * 136 + ks * 32 + lg * 8);
      acc2[ct] = MFMA16(a2[ks], b, acc2[ct]);
    }
  #pragma unroll
  for (int ct = 0; ct < 8; ++ct) {
    int col = ct * 16 + lr;
    float bcol = b0f[col];
    #pragma unroll
    for (int i = 0; i < 4; ++i)
      ldsb[w][(lg * 4 + i) * 136 + col] = f2bf(fmaxf(acc2[ct][i] + bcol, 0.f));
  }
  #pragma unroll
  for (int ks = 0; ks < 4; ++ks)
    a2[ks] = *(const bfrag*)(&ldsb[w][lr * 136 + ks * 32 + lg * 8]);
  __syncthreads();

  STAGE_W(f1T);
  __syncthreads();
  #pragma unroll
  for (int ct = 0; ct < 8; ++ct) acc2[ct] = (f32x4){0.f, 0.f, 0.f, 0.f};
  #pragma unroll
  for (int ks = 0; ks < 4; ++ks)
    #pragma unroll
    for (int ct = 0; ct < 8; ++ct) {
      bfrag b = *(const bfrag*)(sW + (ct * 16 + lr) * 136 + ks * 32 + lg * 8);
      acc2[ct] = MFMA16(a2[ks], b, acc2[ct]);
    }
  #pragma unroll
  for (int ct = 0; ct < 8; ++ct) {
    int col = ct * 16 + lr;
    float bcol = b1f[col];
    #pragma unroll
    for (int i = 0; i < 4; ++i) acc2[ct][i] += bcol + acc[ct][i];
  }
  // LN3 -> dot w4 -> pred
  {
    float s1[4] = {0, 0, 0, 0}, s2[4] = {0, 0, 0, 0};
    #pragma unroll
    for (int ct = 0; ct < 8; ++ct)
      #pragma unroll
      for (int i = 0; i < 4; ++i) {
        s1[i] += acc2[ct][i];
        s2[i] += acc2[ct][i] * acc2[ct][i];
      }
    #pragma unroll
    for (int i = 0; i < 4; ++i) {
      s1[i] += __shfl_xor(s1[i], 1); s2[i] += __shfl_xor(s2[i], 1);
      s1[i] += __shfl_xor(s1[i], 2); s2[i] += __shfl_xor(s2[i], 2);
      s1[i] += __shfl_xor(s1[i], 4); s2[i] += __shfl_xor(s2[i], 4);
      s1[i] += __shfl_xor(s1[i], 8); s2[i] += __shfl_xor(s2[i], 8);
    }
    float p[4] = {0, 0, 0, 0};
    #pragma unroll
    for (int i = 0; i < 4; ++i) {
      float mean = s1[i] * (1.f / 128.f);
      float var = s2[i] * (1.f / 128.f) - mean * mean;
      float inv = rsqrtf(var + 1e-5f);
      #pragma unroll
      for (int ct = 0; ct < 8; ++ct) {
        int col = ct * 16 + lr;
        p[i] += ((acc2[ct][i] - mean) * inv * g3[col] + b3[col]) * w4[col];
      }
    }
    #pragma unroll
    for (int i = 0; i < 4; ++i) {
      p[i] += __shfl_xor(p[i], 1);
      p[i] += __shfl_xor(p[i], 2);
      p[i] += __shfl_xor(p[i], 4);
      p[i] += __shfl_xor(p[i], 8);
    }
    if (lr == 0) {
      float bias4 = b4[0];
      #pragma unroll
      for (int i = 0; i < 4; ++i) pred[r0 + lg * 4 + i] = p[i] + bias4;
    }
  }
}

// ---------------------------------------------------------------------------
extern "C" void kernel_launch(void* const* d_in, const int* in_sizes, int n_in,
                              void* d_out, int out_size, void* d_ws, size_t ws_size,
                              hipStream_t stream) {
  const int* hist_seq = (const int*)d_in[0];
  const int* hist_ans = (const int*)d_in[1];
  const int* new_seq = (const int*)d_in[2];
  const int* edge_index = (const int*)d_in[3];
  const float* node_x = (const float*)d_in[4];
  const float* gcn_w0 = (const float*)d_in[5];
  const float* gcn_b0 = (const float*)d_in[6];
  const float* gcn_w1 = (const float*)d_in[7];
  const float* gcn_b1 = (const float*)d_in[8];
  const float* gcn_w2 = (const float*)d_in[9];
  const float* gcn_b2 = (const float*)d_in[10];
  const float* ln0_g = (const float*)d_in[11];
  const float* ln0_b = (const float*)d_in[12];
  const float* ln1_g = (const float*)d_in[13];
  const float* ln1_b = (const float*)d_in[14];
  const float* ln2_g = (const float*)d_in[15];
  const float* ln2_b = (const float*)d_in[16];
  const float* ln3_g = (const float*)d_in[17];
  const float* ln3_b = (const float*)d_in[18];
  const float* corr_emb = (const float*)d_in[19];
  const float* lin0_w = (const float*)d_in[20];
  const float* lin0_b = (const float*)d_in[21];
  const float* lin1_w = (const float*)d_in[22];
  const float* lin2_w = (const float*)d_in[23];
  const float* lin3_w = (const float*)d_in[24];
  const float* lin4_w = (const float*)d_in[25];
  const float* lin4_b = (const float*)d_in[26];
  const float* pos_emb = (const float*)d_in[27];
  const float* mha_wq = (const float*)d_in[28];
  const float* mha_bq = (const float*)d_in[29];
  const float* mha_wk = (const float*)d_in[30];
  const float* mha_bk = (const float*)d_in[31];
  const float* mha_wv = (const float*)d_in[32];
  const float* mha_bv = (const float*)d_in[33];
  const float* mha_wo = (const float*)d_in[34];
  const float* mha_bo = (const float*)d_in[35];
  const float* ffn0_w = (const float*)d_in[36];
  const float* ffn0_b = (const float*)d_in[37];
  const float* ffn1_w = (const float*)d_in[38];
  const float* ffn1_b = (const float*)d_in[39];
  (void)in_sizes; (void)n_in; (void)out_size;

  char* ws = (char*)d_ws;
  size_t off = 0;
  auto alloc = [&](size_t bytes) -> void* {
    void* p = ws + off;
    off += (bytes + 255) & ~(size_t)255;
    return p;
  };
  int* cnt = (int*)alloc((size_t)N_NODES * 4);
  int* row_ptr = (int*)alloc((size_t)(N_NODES + 1) * 4);
  int* fill = (int*)alloc((size_t)N_NODES * 4);
  int* locpref = (int*)alloc((size_t)N_NODES * 4);
  int* btot = (int*)alloc(64 * 4);
  int* boff = (int*)alloc(64 * 4);
  float* dis = (float*)alloc((size_t)N_NODES * 4);
  int* csr_src = (int*)alloc((size_t)N_EDGES * 4);
  const size_t WB = 128 * 128 * 2;
  u16* g0T = (u16*)alloc(WB);
  u16* g1T = (u16*)alloc(WB);
  u16* g2T = (u16*)alloc(WB);
  u16* l0T = (u16*)alloc(WB);
  u16* l3T = (u16*)alloc(WB);
  u16* woT = (u16*)alloc(WB);
  u16* f0T = (u16*)alloc(WB);
  u16* f1T = (u16*)alloc(WB);
  u16* wqT = (u16*)alloc(WB);
  u16* wkT = (u16*)alloc(WB);
  u16* wvT = (u16*)alloc(WB);
  float* pc = (float*)alloc((size_t)2 * S_ * 128 * 4);
  u16* xa = (u16*)alloc((size_t)N_NODES * 128 * 2);
  const size_t CB = (size_t)BS_ * 128 * 2;   // 26.2 MB
  size_t RB = off;
  u16* bufQ = (u16*)(ws + RB);                // qh -> ao in place, head-major
  u16* bufK = (u16*)(ws + RB + CB);           // kh head-major
  u16* bufV = (u16*)(ws + RB + 2 * CB);       // vh head-major
  u16* xb = bufQ;                             // overlay: dead before qkv writes
  u16* xw = bufQ + (size_t)N_NODES * 128;
  size_t need = RB + 3 * CB;
  if (ws_size < need) return;     // diagnostic guard

  // ---- fused prep (zero cnt, weight transposes/products, pc, node_x cast) ----
  prep_kernel<<<4225, 256, 0, stream>>>(cnt, gcn_w0, gcn_w1, gcn_w2, lin0_w, lin3_w,
                                        mha_wo, ffn0_w, ffn1_w, lin1_w, lin2_w,
                                        mha_wq, mha_wk, mha_wv, corr_emb, lin0_b,
                                        pos_emb, node_x, g0T, g1T, g2T, l0T, l3T,
                                        woT, f0T, f1T, wqT, wkT, wvT, pc, xb);
  // ---- graph prep ----
  int nb = (N_NODES + 1023) / 1024;   // 49
  hist_kernel<<<(N_EDGES + 255) / 256, 256, 0, stream>>>(edge_index + N_EDGES, cnt, N_EDGES);
  scanA_kernel<<<nb, 1024, 0, stream>>>(cnt, locpref, btot, dis, N_NODES);
  scanB_kernel<<<1, 64, 0, stream>>>(btot, boff, nb);
  scanC_kernel<<<(N_NODES + 255) / 256, 256, 0, stream>>>(locpref, boff, row_ptr, fill, N_NODES);
  scatter_kernel<<<(N_EDGES + 255) / 256, 256, 0, stream>>>(edge_index, edge_index + N_EDGES,
                                                            fill, csr_src, N_EDGES);

  int gN = (N_NODES + 63) / 64;
  int aN = (N_NODES + 3) / 4;

  // ---- GCN ----
  gemm_bf16_kernel<<<gN, 256, 0, stream>>>(xb, g0T, xw, N_NODES);
  agg_kernel<<<aN, 256, 0, stream>>>(xw, dis, row_ptr, csr_src, gcn_b0, ln0_g, ln0_b, xa, N_NODES, 1);
  gemm_bf16_kernel<<<gN, 256, 0, stream>>>(xa, g1T, xw, N_NODES);
  agg_kernel<<<aN, 256, 0, stream>>>(xw, dis, row_ptr, csr_src, gcn_b1, ln1_g, ln1_b, xa, N_NODES, 1);
  gemm_bf16_kernel<<<gN, 256, 0, stream>>>(xa, g2T, xw, N_NODES);
  agg_kernel<<<aN, 256, 0, stream>>>(xw, dis, row_ptr, csr_src, gcn_b2, nullptr, nullptr, xa, N_NODES, 0);

  // ---- transformer, full batch, 3 dispatches ----
  int gT = BS_ / 64;   // 1600
  qkv_kernel<<<2 * gT, 256, 0, stream>>>(xa, hist_seq, hist_ans, new_seq,
                                         l0T, pc, wkT, mha_bk, wvT, mha_bv,
                                         wqT, mha_bq, bufK, bufV, bufQ, gT);
  attn_mfma_kernel<<<B_ * 8, 256, 0, stream>>>(bufQ, bufK, bufV);
  out_kernel<<<gT, 256, 0, stream>>>(bufQ, xa, new_seq, woT, mha_bo, l3T,
                                     ln2_g, ln2_b, f0T, ffn0_b, f1T, ffn1_b,
                                     ln3_g, ln3_b, lin4_w, lin4_b, (float*)d_out);
}